// Round 1
// baseline (13440.808 us; speedup 1.0000x reference)
//
#include <hip/hip_runtime.h>

constexpr int B_ = 32;
constexpr int N_ = 1024;
constexpr int C_ = 64;
constexpr int T_ = 24;
constexpr int F_ = 64;
constexpr int CT_ = C_ * T_;     // 1536
constexpr int KCH_ = 3;

__device__ __forceinline__ float sigmoidf_(float x) {
    return 1.0f / (1.0f + __expf(-x));
}

__device__ __forceinline__ void ld8_(float* d, const float* s) {
    float4 a = *reinterpret_cast<const float4*>(s);
    float4 b = *reinterpret_cast<const float4*>(s + 4);
    d[0]=a.x; d[1]=a.y; d[2]=a.z; d[3]=a.w;
    d[4]=b.x; d[5]=b.y; d[6]=b.z; d[7]=b.w;
}

// ---------------- temporal attention prep ----------------
// rhs_t[b,n,t] = sum_c U3[c] * x[b,n,c,t]
__global__ void k_rhs_t(const float* __restrict__ x, const float* __restrict__ U3,
                        float* __restrict__ rhs_t) {
    int idx = blockIdx.x * 256 + threadIdx.x;           // over B*N*T
    if (idx >= B_ * N_ * T_) return;
    int t = idx % T_;
    int n = (idx / T_) % N_;
    int b = idx / (N_ * T_);
    const float* xp = x + ((size_t)(b * N_ + n)) * CT_ + t;
    float acc = 0.f;
#pragma unroll
    for (int c = 0; c < C_; ++c) acc += U3[c] * xp[c * T_];
    rhs_t[idx] = acc;
}

// partial[b,chunk,flat] = sum_{n in chunk} U1[n] * x[b,n,flat]   (flat = c*T+t)
__global__ void k_lhs_partial(const float* __restrict__ x, const float* __restrict__ U1,
                              float* __restrict__ partial) {
    int b = blockIdx.y, chunk = blockIdx.x;
    int tid = threadIdx.x;
    float acc[6] = {0, 0, 0, 0, 0, 0};
    int n0 = chunk * 64;
    for (int nn = 0; nn < 64; ++nn) {
        int n = n0 + nn;
        float u = U1[n];
        const float* xp = x + ((size_t)(b * N_ + n)) * CT_;
#pragma unroll
        for (int e = 0; e < 6; ++e) acc[e] += u * xp[tid + e * 256];
    }
    float* pp = partial + ((size_t)(b * 16 + chunk)) * CT_;
#pragma unroll
    for (int e = 0; e < 6; ++e) pp[tid + e * 256] = acc[e];
}

// lhs_t0[b,flat] = sum_chunk partial
__global__ void k_lhs_reduce(const float* __restrict__ partial, float* __restrict__ lhs_t0) {
    int idx = blockIdx.x * 256 + threadIdx.x;           // B*CT
    if (idx >= B_ * CT_) return;
    int b = idx / CT_, flat = idx % CT_;
    float acc = 0.f;
#pragma unroll
    for (int ch = 0; ch < 16; ++ch) acc += partial[((size_t)(b * 16 + ch)) * CT_ + flat];
    lhs_t0[idx] = acc;
}

// lhs_t[b,t,n2] = sum_c lhs_t0[b, c*T+t] * U2[c,n2]
__global__ void k_lhs_t(const float* __restrict__ lhs_t0, const float* __restrict__ U2,
                        float* __restrict__ lhs_t) {
    int idx = blockIdx.x * 256 + threadIdx.x;           // B*T*N
    if (idx >= B_ * T_ * N_) return;
    int n2 = idx % N_;
    int t = (idx / N_) % T_;
    int b = idx / (T_ * N_);
    const float* l0 = lhs_t0 + (size_t)b * CT_;
    float acc = 0.f;
#pragma unroll
    for (int c = 0; c < C_; ++c) acc += l0[c * T_ + t] * U2[c * N_ + n2];
    lhs_t[idx] = acc;
}

// per-batch: prod_t -> sigmoid(+b_e) -> @V_e^T -> softmax over i  => E[b,i,j]
__global__ void k_temporal_E(const float* __restrict__ lhs_t, const float* __restrict__ rhs_t,
                             const float* __restrict__ b_e, const float* __restrict__ V_e,
                             float* __restrict__ E) {
    int b = blockIdx.x;
    int tid = threadIdx.x;                               // 576 threads
    int i = tid / T_, u = tid % T_;
    __shared__ float sig[T_][T_];
    __shared__ float e0s[T_][T_];
    __shared__ float mcol[T_], scol[T_];
    const float* lt = lhs_t + (size_t)b * T_ * N_ + (size_t)i * N_;
    const float* rt = rhs_t + (size_t)b * N_ * T_ + u;
    float acc = 0.f;
    for (int n = 0; n < N_; ++n) acc += lt[n] * rt[(size_t)n * T_];
    sig[i][u] = sigmoidf_(acc + b_e[i * T_ + u]);
    __syncthreads();
    int j = u;
    float e0 = 0.f;
#pragma unroll
    for (int kk = 0; kk < T_; ++kk) e0 += sig[i][kk] * V_e[j * T_ + kk];
    e0s[i][j] = e0;
    __syncthreads();
    if (tid < T_) {
        float mx = -1e30f;
        for (int ii = 0; ii < T_; ++ii) mx = fmaxf(mx, e0s[ii][tid]);
        float s = 0.f;
        for (int ii = 0; ii < T_; ++ii) s += __expf(e0s[ii][tid] - mx);
        mcol[tid] = mx; scol[tid] = s;
    }
    __syncthreads();
    E[(size_t)b * T_ * T_ + i * T_ + j] = __expf(e0s[i][j] - mcol[j]) / scol[j];
}

// x_TAt[b,n,c,u] = sum_t x[b,n,c,t] * E[b,t,u]
__global__ void k_xTAt(const float* __restrict__ x, const float* __restrict__ E,
                       float* __restrict__ xw) {
    int b = blockIdx.y;
    int nc = blockIdx.x * 256 + threadIdx.x;            // 0..N*C-1
    __shared__ float Es[T_ * T_];
    for (int e = threadIdx.x; e < T_ * T_; e += 256) Es[e] = E[(size_t)b * T_ * T_ + e];
    __syncthreads();
    const float* xp = x + (size_t)b * N_ * CT_ + (size_t)nc * T_;
    float xv[T_];
#pragma unroll
    for (int t = 0; t < T_; ++t) xv[t] = xp[t];
    float* op = xw + (size_t)b * N_ * CT_ + (size_t)nc * T_;
#pragma unroll
    for (int u = 0; u < T_; ++u) {
        float acc = 0.f;
#pragma unroll
        for (int t = 0; t < T_; ++t) acc += xv[t] * Es[t * T_ + u];
        op[u] = acc;
    }
}

// ---------------- spatial attention prep ----------------
// lhs_s[b,n,t2] = sum_c (sum_t xw[b,n,c,t]*W1[t]) * W2[c,t2];  rhs_s[b,t,m] = sum_c W3[c]*xw[b,m,c,t]
__global__ __launch_bounds__(256) void k_spatial_prep(const float* __restrict__ xw,
        const float* __restrict__ W1g, const float* __restrict__ W2,
        const float* __restrict__ W3g, float* __restrict__ lhs_s, float* __restrict__ rhs_s) {
    __shared__ float W2s[C_ * T_];
    __shared__ float W1s[T_];
    __shared__ float W3s[C_];
    int tid = threadIdx.x;
    for (int e = tid; e < C_ * T_; e += 256) W2s[e] = W2[e];
    if (tid < T_) W1s[tid] = W1g[tid];
    if (tid < C_) W3s[tid] = W3g[tid];
    __syncthreads();
    int idx = blockIdx.x * 256 + tid;                    // over B*N
    int b = idx / N_, m = idx % N_;
    const float* xp = xw + (size_t)idx * CT_;
    float lacc[T_], racc[T_];
#pragma unroll
    for (int t = 0; t < T_; ++t) { lacc[t] = 0.f; racc[t] = 0.f; }
    for (int c = 0; c < C_; ++c) {
        float l0 = 0.f;
        float w3 = W3s[c];
        const float* xc = xp + c * T_;
#pragma unroll
        for (int t = 0; t < T_; ++t) {
            float v = xc[t];
            l0 += v * W1s[t];
            racc[t] += w3 * v;
        }
#pragma unroll
        for (int t2 = 0; t2 < T_; ++t2) lacc[t2] += l0 * W2s[c * T_ + t2];
    }
    float* lp = lhs_s + (size_t)idx * T_;
#pragma unroll
    for (int t = 0; t < T_; ++t) lp[t] = lacc[t];
#pragma unroll
    for (int t = 0; t < T_; ++t) rhs_s[((size_t)b * T_ + t) * N_ + m] = racc[t];
}

// ---------------- S0 GEMM: S0[b,i,j] = sum_k sigmoid(dot24(lhs_s[i],rhs_s[:,k]) + b_s[i,k]) * V_s[j,k]
__global__ __launch_bounds__(256) void k_S0(const float* __restrict__ lhs_s,
        const float* __restrict__ rhs_s, const float* __restrict__ b_s,
        const float* __restrict__ V_s, float* __restrict__ S) {
    constexpr int TIS = 128, TJS = 128, KC = 32;
    int b = blockIdx.z;
    int i0 = blockIdx.y * TIS, j0 = blockIdx.x * TJS;
    int tid = threadIdx.x;
    int ty = tid / 16, tx = tid % 16;
    __shared__ float lhsL[TIS * T_];
    __shared__ float rhsc[T_][KC];
    __shared__ float Asub[KC][TIS + 4];
    __shared__ float Vsub[KC][TJS + 4];
    for (int e = tid; e < TIS * T_; e += 256)
        lhsL[e] = lhs_s[((size_t)b * N_ + i0) * T_ + e];
    float acc[8][8] = {};
    for (int k0 = 0; k0 < N_; k0 += KC) {
        __syncthreads();
        for (int e = tid; e < T_ * KC; e += 256) {
            int t = e / KC, kk = e % KC;
            rhsc[t][kk] = rhs_s[((size_t)b * T_ + t) * N_ + k0 + kk];
        }
#pragma unroll
        for (int e = 0; e < 16; ++e) {
            int idx = e * 256 + tid;
            int kk = idx % KC, jj = idx / KC;
            Vsub[kk][jj] = V_s[(size_t)(j0 + jj) * N_ + k0 + kk];
        }
        __syncthreads();
#pragma unroll
        for (int e = 0; e < 16; ++e) {
            int idx = e * 256 + tid;
            int kk = idx % KC, ii = idx / KC;
            float p = 0.f;
#pragma unroll
            for (int t = 0; t < T_; ++t) p += lhsL[ii * T_ + t] * rhsc[t][kk];
            p += b_s[(size_t)(i0 + ii) * N_ + k0 + kk];
            Asub[kk][ii] = sigmoidf_(p);
        }
        __syncthreads();
        for (int kk = 0; kk < KC; ++kk) {
            float a[8], v[8];
            ld8_(a, &Asub[kk][ty * 8]);
            ld8_(v, &Vsub[kk][tx * 8]);
#pragma unroll
            for (int r = 0; r < 8; ++r)
#pragma unroll
                for (int s = 0; s < 8; ++s) acc[r][s] = fmaf(a[r], v[s], acc[r][s]);
        }
    }
    for (int r = 0; r < 8; ++r) {
        int i = i0 + ty * 8 + r;
        float* op = S + ((size_t)b * N_ + i) * N_ + j0 + tx * 8;
#pragma unroll
        for (int s = 0; s < 8; ++s) op[s] = acc[r][s];
    }
}

// softmax over axis 1 (rows i) of S[b,i,j], per column j
__global__ void k_softmax_S(float* __restrict__ S) {
    int b = blockIdx.y;
    int jj = threadIdx.x % 64;
    int ig = threadIdx.x / 64;
    int j = blockIdx.x * 64 + jj;
    __shared__ float redm[4][64], reds[4][64];
    float mx = -1e30f;
    for (int i = ig; i < N_; i += 4) mx = fmaxf(mx, S[((size_t)b * N_ + i) * N_ + j]);
    redm[ig][jj] = mx;
    __syncthreads();
    mx = fmaxf(fmaxf(redm[0][jj], redm[1][jj]), fmaxf(redm[2][jj], redm[3][jj]));
    float sm = 0.f;
    for (int i = ig; i < N_; i += 4) sm += __expf(S[((size_t)b * N_ + i) * N_ + j] - mx);
    reds[ig][jj] = sm;
    __syncthreads();
    float tot = reds[0][jj] + reds[1][jj] + reds[2][jj] + reds[3][jj];
    float inv = 1.f / tot;
    for (int i = ig; i < N_; i += 4) {
        size_t o = ((size_t)b * N_ + i) * N_ + j;
        S[o] = __expf(S[o] - mx) * inv;
    }
}

// ---------------- Cheb conv GEMM: rhs[b,i,ct] = sum_m (cheb_k[m,i]*S[b,m,i]) * x[b,m,ct]
__global__ __launch_bounds__(256) void k_cheb_gemm(const float* __restrict__ cheb_k,
        const float* __restrict__ S, const float* __restrict__ x, float* __restrict__ rhs) {
    constexpr int TI = 128, TC = 128, MC = 32;
    int b = blockIdx.z;
    int i0 = blockIdx.y * TI, ct0 = blockIdx.x * TC;
    int tid = threadIdx.x;
    int ty = tid / 16, tx = tid % 16;
    __shared__ float At[MC][TI + 4];
    __shared__ float Bt[MC][TC + 4];
    float acc[8][8] = {};
    for (int m0 = 0; m0 < N_; m0 += MC) {
        __syncthreads();
#pragma unroll
        for (int e = 0; e < 16; ++e) {
            int idx = e * 256 + tid;
            int ii = idx % TI, mm = idx / TI;
            At[mm][ii] = cheb_k[(size_t)(m0 + mm) * N_ + i0 + ii] *
                         S[((size_t)b * N_ + m0 + mm) * N_ + i0 + ii];
        }
#pragma unroll
        for (int e = 0; e < 16; ++e) {
            int idx = e * 256 + tid;
            int cc = idx % TC, mm = idx / TC;
            Bt[mm][cc] = x[((size_t)b * N_ + m0 + mm) * CT_ + ct0 + cc];
        }
        __syncthreads();
        for (int mm = 0; mm < MC; ++mm) {
            float a[8], v[8];
            ld8_(a, &At[mm][ty * 8]);
            ld8_(v, &Bt[mm][tx * 8]);
#pragma unroll
            for (int r = 0; r < 8; ++r)
#pragma unroll
                for (int s = 0; s < 8; ++s) acc[r][s] = fmaf(a[r], v[s], acc[r][s]);
        }
    }
    for (int r = 0; r < 8; ++r) {
        int i = i0 + ty * 8 + r;
        float* op = rhs + ((size_t)b * N_ + i) * CT_ + ct0 + tx * 8;
#pragma unroll
        for (int s = 0; s < 8; ++s) op[s] = acc[r][s];
    }
}

// out[b,i,f,t] (+)= sum_c rhs[b,i,c,t] * Theta_k[c,f]
__global__ void k_theta(const float* __restrict__ rhs, const float* __restrict__ Theta_k,
                        float* __restrict__ out, int accumulate) {
    int b = blockIdx.y, i = blockIdx.x;
    int tid = threadIdx.x;
    __shared__ float rl[CT_];
    __shared__ float Th[C_ * F_];
    for (int e = tid; e < CT_; e += 256) rl[e] = rhs[((size_t)b * N_ + i) * CT_ + e];
    for (int e = tid; e < C_ * F_; e += 256) Th[e] = Theta_k[e];
    __syncthreads();
#pragma unroll
    for (int e = 0; e < 6; ++e) {
        int o = e * 256 + tid;
        int f = o / T_, t = o % T_;
        float acc = 0.f;
#pragma unroll
        for (int c = 0; c < C_; ++c) acc += rl[c * T_ + t] * Th[c * F_ + f];
        float* op = out + ((size_t)b * N_ + i) * CT_ + o;
        *op = accumulate ? (*op + acc) : acc;
    }
}

// ---------------- fused: relu(gcn) -> time conv + residual conv -> relu -> LayerNorm(ft)
__global__ __launch_bounds__(256) void k_final(const float* __restrict__ x,
        const float* __restrict__ sgin, const float* __restrict__ tc_w,
        const float* __restrict__ tc_b, const float* __restrict__ rc_w,
        const float* __restrict__ rc_b, const float* __restrict__ ln_g,
        const float* __restrict__ ln_b, float* __restrict__ out) {
    int b = blockIdx.y;
    int n0 = blockIdx.x * 4;
    int tid = threadIdx.x;
    __shared__ float shm[2 * 4 * CT_];                  // 12288 floats
    __shared__ float mus[4][T_], rstds[4][T_];
    float* sg = shm;                                     // [4][C][T] relu'd gcn
    float* xr = shm + 4 * CT_;                           // [4][C][T] raw x
    size_t base = ((size_t)b * N_ + n0) * CT_;
    for (int e = tid; e < 4 * CT_; e += 256) {
        sg[e] = fmaxf(sgin[base + e], 0.f);
        xr[e] = x[base + e];
    }
    __syncthreads();
    int ft = tid % 64, nl = tid / 64;
    float acc[T_];
    float tb = tc_b[ft] + rc_b[ft];
#pragma unroll
    for (int t = 0; t < T_; ++t) acc[t] = tb;
    const float* sgn = sg + nl * CT_;
    const float* xrn = xr + nl * CT_;
    for (int c = 0; c < C_; ++c) {
        float w0 = tc_w[(ft * C_ + c) * 3 + 0];
        float w1 = tc_w[(ft * C_ + c) * 3 + 1];
        float w2 = tc_w[(ft * C_ + c) * 3 + 2];
        float rw = rc_w[ft * C_ + c];
        const float* sc = sgn + c * T_;
        const float* xc = xrn + c * T_;
#pragma unroll
        for (int t = 0; t < T_; ++t) {
            float v = sc[t] * w1 + xc[t] * rw;
            if (t > 0) v += sc[t - 1] * w0;
            if (t < T_ - 1) v += sc[t + 1] * w2;
            acc[t] += v;
        }
    }
#pragma unroll
    for (int t = 0; t < T_; ++t) acc[t] = fmaxf(acc[t], 0.f);
    __syncthreads();
    float* o2 = shm;                                     // reuse: [4][64][25]
#pragma unroll
    for (int t = 0; t < T_; ++t) o2[(nl * 64 + ft) * 25 + t] = acc[t];
    __syncthreads();
    if (tid < 4 * T_) {
        int nn = tid / T_, t = tid % T_;
        float s = 0.f, s2 = 0.f;
        for (int f = 0; f < 64; ++f) {
            float v = o2[(nn * 64 + f) * 25 + t];
            s += v; s2 += v * v;
        }
        float mu = s * (1.f / 64.f);
        float var = s2 * (1.f / 64.f) - mu * mu;
        mus[nn][t] = mu;
        rstds[nn][t] = rsqrtf(var + 1e-5f);
    }
    __syncthreads();
    float g = ln_g[ft], bb = ln_b[ft];
    float* op = out + ((size_t)b * N_ + n0 + nl) * CT_ + ft * T_;
#pragma unroll
    for (int t = 0; t < T_; ++t)
        op[t] = (o2[(nl * 64 + ft) * 25 + t] - mus[nl][t]) * rstds[nl][t] * g + bb;
}

extern "C" void kernel_launch(void* const* d_in, const int* in_sizes, int n_in,
                              void* d_out, int out_size, void* d_ws, size_t ws_size,
                              hipStream_t stream) {
    const float* x    = (const float*)d_in[0];
    const float* cheb = (const float*)d_in[1];
    const float* U1   = (const float*)d_in[2];
    const float* U2   = (const float*)d_in[3];
    const float* U3   = (const float*)d_in[4];
    const float* b_e  = (const float*)d_in[5];
    const float* V_e  = (const float*)d_in[6];
    const float* W1   = (const float*)d_in[7];
    const float* W2   = (const float*)d_in[8];
    const float* W3   = (const float*)d_in[9];
    const float* b_s  = (const float*)d_in[10];
    const float* V_s  = (const float*)d_in[11];
    const float* Theta= (const float*)d_in[12];
    const float* tc_w = (const float*)d_in[13];
    const float* tc_b = (const float*)d_in[14];
    const float* rc_w = (const float*)d_in[15];
    const float* rc_b = (const float*)d_in[16];
    const float* ln_g = (const float*)d_in[17];
    const float* ln_b = (const float*)d_in[18];
    float* out = (float*)d_out;
    float* ws = (float*)d_ws;

    size_t off = 0;
    float* lhs_t   = ws + off; off += (size_t)B_ * T_ * N_;
    float* rhs_t   = ws + off; off += (size_t)B_ * N_ * T_;
    float* Ebuf    = ws + off; off += (size_t)B_ * T_ * T_;
    float* partial = ws + off; off += (size_t)B_ * 16 * CT_;
    float* lhs_t0  = ws + off; off += (size_t)B_ * CT_;
    float* lhs_s   = ws + off; off += (size_t)B_ * N_ * T_;
    float* rhs_s   = ws + off; off += (size_t)B_ * T_ * N_;
    float* Sbuf    = ws + off; off += (size_t)B_ * N_ * N_;
    float* xw      = ws + off; off += (size_t)B_ * N_ * CT_;   // x_TAt, then cheb rhs

    dim3 b256(256);
    k_rhs_t<<<dim3((B_ * N_ * T_) / 256), b256, 0, stream>>>(x, U3, rhs_t);
    k_lhs_partial<<<dim3(16, B_), b256, 0, stream>>>(x, U1, partial);
    k_lhs_reduce<<<dim3((B_ * CT_) / 256), b256, 0, stream>>>(partial, lhs_t0);
    k_lhs_t<<<dim3((B_ * T_ * N_) / 256), b256, 0, stream>>>(lhs_t0, U2, lhs_t);
    k_temporal_E<<<dim3(B_), dim3(576), 0, stream>>>(lhs_t, rhs_t, b_e, V_e, Ebuf);
    k_xTAt<<<dim3(N_ * C_ / 256, B_), b256, 0, stream>>>(x, Ebuf, xw);
    k_spatial_prep<<<dim3(B_ * N_ / 256), b256, 0, stream>>>(xw, W1, W2, W3, lhs_s, rhs_s);
    k_S0<<<dim3(N_ / 128, N_ / 128, B_), b256, 0, stream>>>(lhs_s, rhs_s, b_s, V_s, Sbuf);
    k_softmax_S<<<dim3(N_ / 64, B_), b256, 0, stream>>>(Sbuf);
    for (int k = 0; k < KCH_; ++k) {
        k_cheb_gemm<<<dim3(CT_ / 128, N_ / 128, B_), b256, 0, stream>>>(
            cheb + (size_t)k * N_ * N_, Sbuf, x, xw);
        k_theta<<<dim3(N_, B_), b256, 0, stream>>>(xw, Theta + (size_t)k * C_ * F_, out, k);
    }
    k_final<<<dim3(N_ / 4, B_), b256, 0, stream>>>(x, out, tc_w, tc_b, rc_w, rc_b,
                                                  ln_g, ln_b, out);
}

// Round 2
// 4179.798 us; speedup vs baseline: 3.2157x; 3.2157x over previous
//
#include <hip/hip_runtime.h>

typedef __attribute__((ext_vector_type(8))) short short8;   // 8 bf16 (4 VGPRs)
typedef __attribute__((ext_vector_type(4))) float f32x4;

constexpr int B_ = 32;
constexpr int N_ = 1024;
constexpr int C_ = 64;
constexpr int T_ = 24;
constexpr int F_ = 64;
constexpr int CT_ = C_ * T_;     // 1536
constexpr int KS_ = 3072;        // stacked K = 3*1024

__device__ __forceinline__ float sigmoidf_(float x) {
    return 1.0f / (1.0f + __expf(-x));
}
__device__ __forceinline__ unsigned short f2b(float f) {   // RNE f32->bf16
    union { float f; unsigned u; } v; v.f = f;
    unsigned r = v.u + 0x7FFFu + ((v.u >> 16) & 1u);
    return (unsigned short)(r >> 16);
}
__device__ __forceinline__ float b2f(unsigned short h) {
    union { unsigned u; float f; } v; v.u = ((unsigned)h) << 16; return v.f;
}

// ---------------- temporal attention prep (unchanged, cheap) ----------------
__global__ void k_rhs_t(const float* __restrict__ x, const float* __restrict__ U3,
                        float* __restrict__ rhs_t) {
    int idx = blockIdx.x * 256 + threadIdx.x;
    if (idx >= B_ * N_ * T_) return;
    int t = idx % T_;
    int n = (idx / T_) % N_;
    int b = idx / (N_ * T_);
    const float* xp = x + ((size_t)(b * N_ + n)) * CT_ + t;
    float acc = 0.f;
#pragma unroll
    for (int c = 0; c < C_; ++c) acc += U3[c] * xp[c * T_];
    rhs_t[idx] = acc;
}

__global__ void k_lhs_partial(const float* __restrict__ x, const float* __restrict__ U1,
                              float* __restrict__ partial) {
    int b = blockIdx.y, chunk = blockIdx.x;
    int tid = threadIdx.x;
    float acc[6] = {0, 0, 0, 0, 0, 0};
    int n0 = chunk * 64;
    for (int nn = 0; nn < 64; ++nn) {
        int n = n0 + nn;
        float u = U1[n];
        const float* xp = x + ((size_t)(b * N_ + n)) * CT_;
#pragma unroll
        for (int e = 0; e < 6; ++e) acc[e] += u * xp[tid + e * 256];
    }
    float* pp = partial + ((size_t)(b * 16 + chunk)) * CT_;
#pragma unroll
    for (int e = 0; e < 6; ++e) pp[tid + e * 256] = acc[e];
}

__global__ void k_lhs_reduce(const float* __restrict__ partial, float* __restrict__ lhs_t0) {
    int idx = blockIdx.x * 256 + threadIdx.x;
    if (idx >= B_ * CT_) return;
    int b = idx / CT_, flat = idx % CT_;
    float acc = 0.f;
#pragma unroll
    for (int ch = 0; ch < 16; ++ch) acc += partial[((size_t)(b * 16 + ch)) * CT_ + flat];
    lhs_t0[idx] = acc;
}

__global__ void k_lhs_t(const float* __restrict__ lhs_t0, const float* __restrict__ U2,
                        float* __restrict__ lhs_t) {
    int idx = blockIdx.x * 256 + threadIdx.x;
    if (idx >= B_ * T_ * N_) return;
    int n2 = idx % N_;
    int t = (idx / N_) % T_;
    int b = idx / (T_ * N_);
    const float* l0 = lhs_t0 + (size_t)b * CT_;
    float acc = 0.f;
#pragma unroll
    for (int c = 0; c < C_; ++c) acc += l0[c * T_ + t] * U2[c * N_ + n2];
    lhs_t[idx] = acc;
}

__global__ void k_temporal_E(const float* __restrict__ lhs_t, const float* __restrict__ rhs_t,
                             const float* __restrict__ b_e, const float* __restrict__ V_e,
                             float* __restrict__ E) {
    int b = blockIdx.x;
    int tid = threadIdx.x;                               // 576 threads
    int i = tid / T_, u = tid % T_;
    __shared__ float sig[T_][T_];
    __shared__ float e0s[T_][T_];
    __shared__ float mcol[T_], scol[T_];
    const float* lt = lhs_t + (size_t)b * T_ * N_ + (size_t)i * N_;
    const float* rt = rhs_t + (size_t)b * N_ * T_ + u;
    float acc = 0.f;
    for (int n = 0; n < N_; ++n) acc += lt[n] * rt[(size_t)n * T_];
    sig[i][u] = sigmoidf_(acc + b_e[i * T_ + u]);
    __syncthreads();
    int j = u;
    float e0 = 0.f;
#pragma unroll
    for (int kk = 0; kk < T_; ++kk) e0 += sig[i][kk] * V_e[j * T_ + kk];
    e0s[i][j] = e0;
    __syncthreads();
    if (tid < T_) {
        float mx = -1e30f;
        for (int ii = 0; ii < T_; ++ii) mx = fmaxf(mx, e0s[ii][tid]);
        float s = 0.f;
        for (int ii = 0; ii < T_; ++ii) s += __expf(e0s[ii][tid] - mx);
        mcol[tid] = mx; scol[tid] = s;
    }
    __syncthreads();
    E[(size_t)b * T_ * T_ + i * T_ + j] = __expf(e0s[i][j] - mcol[j]) / scol[j];
}

__global__ void k_xTAt(const float* __restrict__ x, const float* __restrict__ E,
                       float* __restrict__ xw) {
    int b = blockIdx.y;
    int nc = blockIdx.x * 256 + threadIdx.x;
    __shared__ float Es[T_ * T_];
    for (int e = threadIdx.x; e < T_ * T_; e += 256) Es[e] = E[(size_t)b * T_ * T_ + e];
    __syncthreads();
    const float* xp = x + (size_t)b * N_ * CT_ + (size_t)nc * T_;
    float xv[T_];
#pragma unroll
    for (int t = 0; t < T_; ++t) xv[t] = xp[t];
    float* op = xw + (size_t)b * N_ * CT_ + (size_t)nc * T_;
#pragma unroll
    for (int u = 0; u < T_; ++u) {
        float acc = 0.f;
#pragma unroll
        for (int t = 0; t < T_; ++t) acc += xv[t] * Es[t * T_ + u];
        op[u] = acc;
    }
}

// ---------------- spatial attention prep (unchanged) ----------------
__global__ __launch_bounds__(256) void k_spatial_prep(const float* __restrict__ xw,
        const float* __restrict__ W1g, const float* __restrict__ W2,
        const float* __restrict__ W3g, float* __restrict__ lhs_s, float* __restrict__ rhs_s) {
    __shared__ float W2s[C_ * T_];
    __shared__ float W1s[T_];
    __shared__ float W3s[C_];
    int tid = threadIdx.x;
    for (int e = tid; e < C_ * T_; e += 256) W2s[e] = W2[e];
    if (tid < T_) W1s[tid] = W1g[tid];
    if (tid < C_) W3s[tid] = W3g[tid];
    __syncthreads();
    int idx = blockIdx.x * 256 + tid;
    int b = idx / N_, m = idx % N_;
    const float* xp = xw + (size_t)idx * CT_;
    float lacc[T_], racc[T_];
#pragma unroll
    for (int t = 0; t < T_; ++t) { lacc[t] = 0.f; racc[t] = 0.f; }
    for (int c = 0; c < C_; ++c) {
        float l0 = 0.f;
        float w3 = W3s[c];
        const float* xc = xp + c * T_;
#pragma unroll
        for (int t = 0; t < T_; ++t) {
            float v = xc[t];
            l0 += v * W1s[t];
            racc[t] += w3 * v;
        }
#pragma unroll
        for (int t2 = 0; t2 < T_; ++t2) lacc[t2] += l0 * W2s[c * T_ + t2];
    }
    float* lp = lhs_s + (size_t)idx * T_;
#pragma unroll
    for (int t = 0; t < T_; ++t) lp[t] = lacc[t];
#pragma unroll
    for (int t = 0; t < T_; ++t) rhs_s[((size_t)b * T_ + t) * N_ + m] = racc[t];
}

// ---------------- converters / builders ----------------
__global__ void k_cvt_vs(const float* __restrict__ v, unsigned short* __restrict__ o) {
    int i = blockIdx.x * 256 + threadIdx.x;
    o[i] = f2b(v[i]);
}

// xT[b][ct][m] (bf16) = x[b][m][ct]
__global__ __launch_bounds__(256) void k_transpose_x(const float* __restrict__ x,
                                                     unsigned short* __restrict__ xT) {
    __shared__ float tile[64][65];
    int b = blockIdx.z, m0 = blockIdx.y * 64, ct0 = blockIdx.x * 64;
    int tid = threadIdx.x;
#pragma unroll
    for (int e = 0; e < 16; ++e) {
        int idx = e * 256 + tid; int mm = idx >> 6, cc = idx & 63;
        tile[mm][cc] = x[((size_t)(b * N_ + m0 + mm)) * CT_ + ct0 + cc];
    }
    __syncthreads();
#pragma unroll
    for (int e = 0; e < 16; ++e) {
        int idx = e * 256 + tid; int rr = idx >> 6, mm = idx & 63;
        xT[((size_t)b * CT_ + ct0 + rr) * N_ + m0 + mm] = f2b(tile[mm][rr]);
    }
}

// sigA[b][i][k] (bf16) = sigmoid(dot24(lhs_s[b,i,:], rhs_s[b,:,k]) + b_s[i,k])
__global__ __launch_bounds__(256) void k_sig(const float* __restrict__ lhs_s,
        const float* __restrict__ rhs_s, const float* __restrict__ b_s,
        unsigned short* __restrict__ sigA) {
    int b = blockIdx.z, i0 = blockIdx.y * 64, k0 = blockIdx.x * 256;
    int tid = threadIdx.x;
    __shared__ float lh[64 * T_];
    __shared__ float rh[T_][256];
    for (int e = tid; e < 64 * T_; e += 256) lh[e] = lhs_s[((size_t)b * N_ + i0) * T_ + e];
#pragma unroll
    for (int t = 0; t < T_; ++t) rh[t][tid] = rhs_s[((size_t)b * T_ + t) * N_ + k0 + tid];
    __syncthreads();
    int kg = k0 + tid;
    for (int ii = 0; ii < 64; ++ii) {
        float acc = b_s[(size_t)(i0 + ii) * N_ + kg];
#pragma unroll
        for (int t = 0; t < T_; ++t) acc += lh[ii * T_ + t] * rh[t][tid];
        sigA[((size_t)b * N_ + i0 + ii) * N_ + kg] = f2b(sigmoidf_(acc));
    }
}

// yT[b][f*24+t][k*1024+m] (bf16) = sum_c Theta[k,c,f] * x[b,m,c,t]   (reads xT)
__global__ __launch_bounds__(256) void k_yT(const unsigned short* __restrict__ xT,
        const float* __restrict__ Theta, unsigned short* __restrict__ yT) {
    int b = blockIdx.z, t = blockIdx.y, m0 = blockIdx.x * 256;
    int tid = threadIdx.x;
    float xr[64];
#pragma unroll
    for (int c = 0; c < 64; ++c)
        xr[c] = b2f(xT[((size_t)b * CT_ + c * T_ + t) * N_ + m0 + tid]);
    for (int k = 0; k < 3; ++k) {
        float acc[64];
#pragma unroll
        for (int f = 0; f < 64; ++f) acc[f] = 0.f;
#pragma unroll 4
        for (int c = 0; c < 64; ++c) {
            float xc = xr[c];
            const float* th = Theta + ((size_t)k * 64 + c) * 64;   // uniform -> s_load
#pragma unroll
            for (int f = 0; f < 64; ++f) acc[f] = fmaf(th[f], xc, acc[f]);
        }
#pragma unroll
        for (int f = 0; f < 64; ++f)
            yT[((size_t)b * CT_ + f * T_ + t) * KS_ + k * N_ + m0 + tid] = f2b(acc[f]);
    }
}

// chebSt[b][i][k*1024+m] (bf16) = cheb[k][m][i] * S[b][m][i]
__global__ __launch_bounds__(256) void k_chebSt(const float* __restrict__ cheb,
        const float* __restrict__ S, unsigned short* __restrict__ cs) {
    int b = blockIdx.z, i0 = blockIdx.y * 64, m0 = blockIdx.x * 64;
    int tid = threadIdx.x;
    __shared__ float st[64][65];
    __shared__ float cb[64][65];
#pragma unroll
    for (int e = 0; e < 16; ++e) {
        int idx = e * 256 + tid; int mm = idx >> 6, ii = idx & 63;
        st[mm][ii] = S[((size_t)b * N_ + m0 + mm) * N_ + i0 + ii];
    }
    for (int k = 0; k < 3; ++k) {
        __syncthreads();
#pragma unroll
        for (int e = 0; e < 16; ++e) {
            int idx = e * 256 + tid; int mm = idx >> 6, ii = idx & 63;
            cb[mm][ii] = cheb[((size_t)k * N_ + m0 + mm) * N_ + i0 + ii];
        }
        __syncthreads();
#pragma unroll
        for (int e = 0; e < 16; ++e) {
            int idx = e * 256 + tid; int mm = idx & 63, ii = idx >> 6;
            cs[((size_t)b * N_ + i0 + ii) * KS_ + k * N_ + m0 + mm] =
                f2b(st[mm][ii] * cb[mm][ii]);
        }
    }
}

// ---------------- MFMA GEMM: C[b] = A[b] * Bt[b]^T  (A: MxK rows, Bt: NxK rows)
__global__ __launch_bounds__(256, 2) void k_gemm_bt(
        const unsigned short* __restrict__ A, long lda, long sA,
        const unsigned short* __restrict__ Bt, long ldb, long sB,
        float* __restrict__ Cc, long ldc, long sC, int K) {
    int b = blockIdx.z;
    int i0 = blockIdx.y * 128, j0 = blockIdx.x * 128;
    const unsigned short* Ab = A + (size_t)b * sA + (size_t)i0 * lda;
    const unsigned short* Bb = Bt + (size_t)b * sB + (size_t)j0 * ldb;
    __shared__ __align__(16) unsigned short As[128 * 72];   // 64 data + 8 pad per row
    __shared__ __align__(16) unsigned short Bs[128 * 72];
    int tid = threadIdx.x;
    int lane = tid & 63, w = tid >> 6;
    int wy = w >> 1, wx = w & 1;                            // 2x2 waves of 64x64
    f32x4 acc[4][4];
#pragma unroll
    for (int mi = 0; mi < 4; ++mi)
#pragma unroll
        for (int ni = 0; ni < 4; ++ni) acc[mi][ni] = (f32x4){0.f, 0.f, 0.f, 0.f};
    uint4 ra[4], rb[4];
#pragma unroll
    for (int e = 0; e < 4; ++e) {                           // prologue loads (k0=0)
        int chunk = e * 256 + tid;
        int row = chunk >> 3, c8 = chunk & 7;
        ra[e] = *(const uint4*)(Ab + (size_t)row * lda + c8 * 8);
        rb[e] = *(const uint4*)(Bb + (size_t)row * ldb + c8 * 8);
    }
    for (int k0 = 0; k0 < K; k0 += 64) {
        __syncthreads();
#pragma unroll
        for (int e = 0; e < 4; ++e) {
            int chunk = e * 256 + tid;
            int row = chunk >> 3, c8 = chunk & 7;
            *(uint4*)&As[row * 72 + c8 * 8] = ra[e];
            *(uint4*)&Bs[row * 72 + c8 * 8] = rb[e];
        }
        __syncthreads();
        if (k0 + 64 < K) {
            int kn = k0 + 64;
#pragma unroll
            for (int e = 0; e < 4; ++e) {
                int chunk = e * 256 + tid;
                int row = chunk >> 3, c8 = chunk & 7;
                ra[e] = *(const uint4*)(Ab + (size_t)row * lda + kn + c8 * 8);
                rb[e] = *(const uint4*)(Bb + (size_t)row * ldb + kn + c8 * 8);
            }
        }
#pragma unroll
        for (int kk = 0; kk < 2; ++kk) {
            short8 af[4], bfr[4];
#pragma unroll
            for (int mi = 0; mi < 4; ++mi) {
                int row = wy * 64 + mi * 16 + (lane & 15);
                af[mi] = *(const short8*)&As[row * 72 + kk * 32 + (lane >> 4) * 8];
            }
#pragma unroll
            for (int ni = 0; ni < 4; ++ni) {
                int row = wx * 64 + ni * 16 + (lane & 15);
                bfr[ni] = *(const short8*)&Bs[row * 72 + kk * 32 + (lane >> 4) * 8];
            }
#pragma unroll
            for (int mi = 0; mi < 4; ++mi)
#pragma unroll
                for (int ni = 0; ni < 4; ++ni)
                    acc[mi][ni] = __builtin_amdgcn_mfma_f32_16x16x32_bf16(
                        af[mi], bfr[ni], acc[mi][ni], 0, 0, 0);
        }
    }
    float* Cb = Cc + (size_t)b * sC;
#pragma unroll
    for (int mi = 0; mi < 4; ++mi) {
#pragma unroll
        for (int r = 0; r < 4; ++r) {
            int i = i0 + wy * 64 + mi * 16 + (lane >> 4) * 4 + r;
            float* cp = Cb + (size_t)i * ldc + j0 + wx * 64 + (lane & 15);
#pragma unroll
            for (int ni = 0; ni < 4; ++ni) cp[ni * 16] = acc[mi][ni][r];
        }
    }
}

// softmax over axis m (rows) of S[b,m,i], per column i — in place
__global__ void k_softmax_S(float* __restrict__ S) {
    int b = blockIdx.y;
    int jj = threadIdx.x % 64;
    int ig = threadIdx.x / 64;
    int j = blockIdx.x * 64 + jj;
    __shared__ float redm[4][64], reds[4][64];
    float mx = -1e30f;
    for (int i = ig; i < N_; i += 4) mx = fmaxf(mx, S[((size_t)b * N_ + i) * N_ + j]);
    redm[ig][jj] = mx;
    __syncthreads();
    mx = fmaxf(fmaxf(redm[0][jj], redm[1][jj]), fmaxf(redm[2][jj], redm[3][jj]));
    float sm = 0.f;
    for (int i = ig; i < N_; i += 4) sm += __expf(S[((size_t)b * N_ + i) * N_ + j] - mx);
    reds[ig][jj] = sm;
    __syncthreads();
    float tot = reds[0][jj] + reds[1][jj] + reds[2][jj] + reds[3][jj];
    float inv = 1.f / tot;
    for (int i = ig; i < N_; i += 4) {
        size_t o = ((size_t)b * N_ + i) * N_ + j;
        S[o] = __expf(S[o] - mx) * inv;
    }
}

// ---------------- fused: relu(gcn) -> time conv + residual conv -> relu -> LN ----------------
__global__ __launch_bounds__(256) void k_final(const float* __restrict__ x,
        const float* __restrict__ sgin, const float* __restrict__ tc_w,
        const float* __restrict__ tc_b, const float* __restrict__ rc_w,
        const float* __restrict__ rc_b, const float* __restrict__ ln_g,
        const float* __restrict__ ln_b, float* __restrict__ out) {
    int b = blockIdx.y;
    int n0 = blockIdx.x * 4;
    int tid = threadIdx.x;
    __shared__ float shm[2 * 4 * CT_];
    __shared__ float mus[4][T_], rstds[4][T_];
    float* sg = shm;
    float* xr = shm + 4 * CT_;
    size_t base = ((size_t)b * N_ + n0) * CT_;
    for (int e = tid; e < 4 * CT_; e += 256) {
        sg[e] = fmaxf(sgin[base + e], 0.f);
        xr[e] = x[base + e];
    }
    __syncthreads();
    int ft = tid % 64, nl = tid / 64;
    float acc[T_];
    float tb = tc_b[ft] + rc_b[ft];
#pragma unroll
    for (int t = 0; t < T_; ++t) acc[t] = tb;
    const float* sgn = sg + nl * CT_;
    const float* xrn = xr + nl * CT_;
    for (int c = 0; c < C_; ++c) {
        float w0 = tc_w[(ft * C_ + c) * 3 + 0];
        float w1 = tc_w[(ft * C_ + c) * 3 + 1];
        float w2 = tc_w[(ft * C_ + c) * 3 + 2];
        float rw = rc_w[ft * C_ + c];
        const float* sc = sgn + c * T_;
        const float* xc = xrn + c * T_;
#pragma unroll
        for (int t = 0; t < T_; ++t) {
            float v = sc[t] * w1 + xc[t] * rw;
            if (t > 0) v += sc[t - 1] * w0;
            if (t < T_ - 1) v += sc[t + 1] * w2;
            acc[t] += v;
        }
    }
#pragma unroll
    for (int t = 0; t < T_; ++t) acc[t] = fmaxf(acc[t], 0.f);
    __syncthreads();
    float* o2 = shm;
#pragma unroll
    for (int t = 0; t < T_; ++t) o2[(nl * 64 + ft) * 25 + t] = acc[t];
    __syncthreads();
    if (tid < 4 * T_) {
        int nn = tid / T_, t = tid % T_;
        float s = 0.f, s2 = 0.f;
        for (int f = 0; f < 64; ++f) {
            float v = o2[(nn * 64 + f) * 25 + t];
            s += v; s2 += v * v;
        }
        float mu = s * (1.f / 64.f);
        float var = s2 * (1.f / 64.f) - mu * mu;
        mus[nn][t] = mu;
        rstds[nn][t] = rsqrtf(var + 1e-5f);
    }
    __syncthreads();
    float g = ln_g[ft], bb = ln_b[ft];
    float* op = out + ((size_t)b * N_ + n0 + nl) * CT_ + ft * T_;
#pragma unroll
    for (int t = 0; t < T_; ++t)
        op[t] = (o2[(nl * 64 + ft) * 25 + t] - mus[nl][t]) * rstds[nl][t] * g + bb;
}

extern "C" void kernel_launch(void* const* d_in, const int* in_sizes, int n_in,
                              void* d_out, int out_size, void* d_ws, size_t ws_size,
                              hipStream_t stream) {
    const float* x    = (const float*)d_in[0];
    const float* cheb = (const float*)d_in[1];
    const float* U1   = (const float*)d_in[2];
    const float* U2   = (const float*)d_in[3];
    const float* U3   = (const float*)d_in[4];
    const float* b_e  = (const float*)d_in[5];
    const float* V_e  = (const float*)d_in[6];
    const float* W1   = (const float*)d_in[7];
    const float* W2   = (const float*)d_in[8];
    const float* W3   = (const float*)d_in[9];
    const float* b_s  = (const float*)d_in[10];
    const float* V_s  = (const float*)d_in[11];
    const float* Theta= (const float*)d_in[12];
    const float* tc_w = (const float*)d_in[13];
    const float* tc_b = (const float*)d_in[14];
    const float* rc_w = (const float*)d_in[15];
    const float* rc_b = (const float*)d_in[16];
    const float* ln_g = (const float*)d_in[17];
    const float* ln_b = (const float*)d_in[18];
    float* out = (float*)d_out;

    char* base = (char*)d_ws;
    size_t o = 0;
    auto alloc = [&](size_t bytes) { size_t r = o; o += (bytes + 255) & ~(size_t)255; return r; };
    float* lhs_t   = (float*)(base + alloc((size_t)B_ * T_ * N_ * 4));
    float* rhs_t   = (float*)(base + alloc((size_t)B_ * N_ * T_ * 4));
    float* Ebuf    = (float*)(base + alloc((size_t)B_ * T_ * T_ * 4));
    float* partial = (float*)(base + alloc((size_t)B_ * 16 * CT_ * 4));
    float* lhs_t0  = (float*)(base + alloc((size_t)B_ * CT_ * 4));
    float* lhs_s   = (float*)(base + alloc((size_t)B_ * N_ * T_ * 4));
    float* rhs_s   = (float*)(base + alloc((size_t)B_ * T_ * N_ * 4));
    unsigned short* V_sb = (unsigned short*)(base + alloc((size_t)N_ * N_ * 2));
    // RegA: xw (192MiB f32) -> xT (96MiB bf16) -> chebSt (192MiB bf16)   [disjoint lifetimes]
    size_t regA = alloc((size_t)B_ * N_ * KS_ * 2);
    // RegB: sigA (64MiB bf16) -> yT (276MiB bf16)                        [disjoint lifetimes]
    size_t regB = alloc((size_t)B_ * CT_ * KS_ * 2);
    float*          xw     = (float*)(base + regA);
    unsigned short* xT     = (unsigned short*)(base + regA);
    unsigned short* chebSt = (unsigned short*)(base + regA);
    unsigned short* sigA   = (unsigned short*)(base + regB);
    unsigned short* yT     = (unsigned short*)(base + regB);
    float* Sb  = out;        // S scores live in d_out until the stacked GEMM overwrites
    float* gcn = out;

    dim3 b256(256);
    k_cvt_vs<<<dim3(N_ * N_ / 256), b256, 0, stream>>>(V_s, V_sb);
    k_rhs_t<<<dim3((B_ * N_ * T_) / 256), b256, 0, stream>>>(x, U3, rhs_t);
    k_lhs_partial<<<dim3(16, B_), b256, 0, stream>>>(x, U1, partial);
    k_lhs_reduce<<<dim3((B_ * CT_) / 256), b256, 0, stream>>>(partial, lhs_t0);
    k_lhs_t<<<dim3((B_ * T_ * N_) / 256), b256, 0, stream>>>(lhs_t0, U2, lhs_t);
    k_temporal_E<<<dim3(B_), dim3(576), 0, stream>>>(lhs_t, rhs_t, b_e, V_e, Ebuf);
    k_xTAt<<<dim3(N_ * C_ / 256, B_), b256, 0, stream>>>(x, Ebuf, xw);
    k_spatial_prep<<<dim3(B_ * N_ / 256), b256, 0, stream>>>(xw, W1, W2, W3, lhs_s, rhs_s);
    k_transpose_x<<<dim3(CT_ / 64, N_ / 64, B_), b256, 0, stream>>>(x, xT);   // xw dead
    k_sig<<<dim3(N_ / 256, N_ / 64, B_), b256, 0, stream>>>(lhs_s, rhs_s, b_s, sigA);
    k_gemm_bt<<<dim3(N_ / 128, N_ / 128, B_), b256, 0, stream>>>(
        sigA, N_, (long)N_ * N_, V_sb, N_, 0, Sb, N_, (long)N_ * N_, N_);
    k_softmax_S<<<dim3(N_ / 64, B_), b256, 0, stream>>>(Sb);
    k_yT<<<dim3(N_ / 256, T_, B_), b256, 0, stream>>>(xT, Theta, yT);          // sigA dead
    k_chebSt<<<dim3(N_ / 64, N_ / 64, B_), b256, 0, stream>>>(cheb, Sb, chebSt); // xT dead
    k_gemm_bt<<<dim3(CT_ / 128, N_ / 128, B_), b256, 0, stream>>>(
        chebSt, KS_, (long)N_ * KS_, yT, KS_, (long)CT_ * KS_,
        gcn, CT_, (long)N_ * CT_, KS_);                                       // Sb dead
    k_final<<<dim3(N_ / 4, B_), b256, 0, stream>>>(x, gcn, tc_w, tc_b, rc_w, rc_b,
                                                   ln_g, ln_b, out);
}

// Round 3
// 2163.592 us; speedup vs baseline: 6.2123x; 1.9319x over previous
//
#include <hip/hip_runtime.h>

typedef __attribute__((ext_vector_type(8))) short short8;   // 8 bf16 (4 VGPRs)
typedef __attribute__((ext_vector_type(4))) float f32x4;

constexpr int B_ = 32;
constexpr int N_ = 1024;
constexpr int C_ = 64;
constexpr int T_ = 24;
constexpr int F_ = 64;
constexpr int CT_ = C_ * T_;     // 1536
constexpr int KS_ = 3072;        // stacked K = 3*1024

__device__ __forceinline__ float sigmoidf_(float x) {
    return 1.0f / (1.0f + __expf(-x));
}
__device__ __forceinline__ unsigned short f2b(float f) {   // RNE f32->bf16
    union { float f; unsigned u; } v; v.f = f;
    unsigned r = v.u + 0x7FFFu + ((v.u >> 16) & 1u);
    return (unsigned short)(r >> 16);
}
__device__ __forceinline__ float b2f(unsigned short h) {
    union { unsigned u; float f; } v; v.u = ((unsigned)h) << 16; return v.f;
}
__device__ __forceinline__ void gload_lds16(const unsigned short* g, unsigned short* l) {
    __builtin_amdgcn_global_load_lds(
        (const __attribute__((address_space(1))) unsigned int*)g,
        (__attribute__((address_space(3))) unsigned int*)l, 16, 0, 0);
}

// ---------------- temporal attention prep ----------------
__global__ void k_rhs_t(const float* __restrict__ x, const float* __restrict__ U3,
                        float* __restrict__ rhs_t) {
    int idx = blockIdx.x * 256 + threadIdx.x;
    if (idx >= B_ * N_ * T_) return;
    int t = idx % T_;
    int n = (idx / T_) % N_;
    int b = idx / (N_ * T_);
    const float* xp = x + ((size_t)(b * N_ + n)) * CT_ + t;
    float acc = 0.f;
#pragma unroll
    for (int c = 0; c < C_; ++c) acc += U3[c] * xp[c * T_];
    rhs_t[idx] = acc;
}

__global__ void k_lhs_partial(const float* __restrict__ x, const float* __restrict__ U1,
                              float* __restrict__ partial) {
    int b = blockIdx.y, chunk = blockIdx.x;
    int tid = threadIdx.x;
    float acc[6] = {0, 0, 0, 0, 0, 0};
    int n0 = chunk * 64;
    for (int nn = 0; nn < 64; ++nn) {
        int n = n0 + nn;
        float u = U1[n];
        const float* xp = x + ((size_t)(b * N_ + n)) * CT_;
#pragma unroll
        for (int e = 0; e < 6; ++e) acc[e] += u * xp[tid + e * 256];
    }
    float* pp = partial + ((size_t)(b * 16 + chunk)) * CT_;
#pragma unroll
    for (int e = 0; e < 6; ++e) pp[tid + e * 256] = acc[e];
}

__global__ void k_lhs_reduce(const float* __restrict__ partial, float* __restrict__ lhs_t0) {
    int idx = blockIdx.x * 256 + threadIdx.x;
    if (idx >= B_ * CT_) return;
    int b = idx / CT_, flat = idx % CT_;
    float acc = 0.f;
#pragma unroll
    for (int ch = 0; ch < 16; ++ch) acc += partial[((size_t)(b * 16 + ch)) * CT_ + flat];
    lhs_t0[idx] = acc;
}

__global__ void k_lhs_t(const float* __restrict__ lhs_t0, const float* __restrict__ U2,
                        float* __restrict__ lhs_t) {
    int idx = blockIdx.x * 256 + threadIdx.x;
    if (idx >= B_ * T_ * N_) return;
    int n2 = idx % N_;
    int t = (idx / N_) % T_;
    int b = idx / (T_ * N_);
    const float* l0 = lhs_t0 + (size_t)b * CT_;
    float acc = 0.f;
#pragma unroll
    for (int c = 0; c < C_; ++c) acc += l0[c * T_ + t] * U2[c * N_ + n2];
    lhs_t[idx] = acc;
}

__global__ void k_temporal_E(const float* __restrict__ lhs_t, const float* __restrict__ rhs_t,
                             const float* __restrict__ b_e, const float* __restrict__ V_e,
                             float* __restrict__ E) {
    int b = blockIdx.x;
    int tid = threadIdx.x;                               // 576 threads
    int i = tid / T_, u = tid % T_;
    __shared__ float sig[T_][T_];
    __shared__ float e0s[T_][T_];
    __shared__ float mcol[T_], scol[T_];
    const float* lt = lhs_t + (size_t)b * T_ * N_ + (size_t)i * N_;
    const float* rt = rhs_t + (size_t)b * N_ * T_ + u;
    float acc = 0.f;
    for (int n = 0; n < N_; ++n) acc += lt[n] * rt[(size_t)n * T_];
    sig[i][u] = sigmoidf_(acc + b_e[i * T_ + u]);
    __syncthreads();
    int j = u;
    float e0 = 0.f;
#pragma unroll
    for (int kk = 0; kk < T_; ++kk) e0 += sig[i][kk] * V_e[j * T_ + kk];
    e0s[i][j] = e0;
    __syncthreads();
    if (tid < T_) {
        float mx = -1e30f;
        for (int ii = 0; ii < T_; ++ii) mx = fmaxf(mx, e0s[ii][tid]);
        float s = 0.f;
        for (int ii = 0; ii < T_; ++ii) s += __expf(e0s[ii][tid] - mx);
        mcol[tid] = mx; scol[tid] = s;
    }
    __syncthreads();
    E[(size_t)b * T_ * T_ + i * T_ + j] = __expf(e0s[i][j] - mcol[j]) / scol[j];
}

__global__ void k_xTAt(const float* __restrict__ x, const float* __restrict__ E,
                       float* __restrict__ xw) {
    int b = blockIdx.y;
    int nc = blockIdx.x * 256 + threadIdx.x;
    __shared__ float Es[T_ * T_];
    for (int e = threadIdx.x; e < T_ * T_; e += 256) Es[e] = E[(size_t)b * T_ * T_ + e];
    __syncthreads();
    const float* xp = x + (size_t)b * N_ * CT_ + (size_t)nc * T_;
    float xv[T_];
#pragma unroll
    for (int t = 0; t < T_; ++t) xv[t] = xp[t];
    float* op = xw + (size_t)b * N_ * CT_ + (size_t)nc * T_;
#pragma unroll
    for (int u = 0; u < T_; ++u) {
        float acc = 0.f;
#pragma unroll
        for (int t = 0; t < T_; ++t) acc += xv[t] * Es[t * T_ + u];
        op[u] = acc;
    }
}

// ---------------- spatial attention prep ----------------
__global__ __launch_bounds__(256) void k_spatial_prep(const float* __restrict__ xw,
        const float* __restrict__ W1g, const float* __restrict__ W2,
        const float* __restrict__ W3g, float* __restrict__ lhs_s, float* __restrict__ rhs_s) {
    __shared__ float W2s[C_ * T_];
    __shared__ float W1s[T_];
    __shared__ float W3s[C_];
    int tid = threadIdx.x;
    for (int e = tid; e < C_ * T_; e += 256) W2s[e] = W2[e];
    if (tid < T_) W1s[tid] = W1g[tid];
    if (tid < C_) W3s[tid] = W3g[tid];
    __syncthreads();
    int idx = blockIdx.x * 256 + tid;
    int b = idx / N_, m = idx % N_;
    const float* xp = xw + (size_t)idx * CT_;
    float lacc[T_], racc[T_];
#pragma unroll
    for (int t = 0; t < T_; ++t) { lacc[t] = 0.f; racc[t] = 0.f; }
    for (int c = 0; c < C_; ++c) {
        float l0 = 0.f;
        float w3 = W3s[c];
        const float* xc = xp + c * T_;
#pragma unroll
        for (int t = 0; t < T_; ++t) {
            float v = xc[t];
            l0 += v * W1s[t];
            racc[t] += w3 * v;
        }
#pragma unroll
        for (int t2 = 0; t2 < T_; ++t2) lacc[t2] += l0 * W2s[c * T_ + t2];
    }
    float* lp = lhs_s + (size_t)idx * T_;
#pragma unroll
    for (int t = 0; t < T_; ++t) lp[t] = lacc[t];
#pragma unroll
    for (int t = 0; t < T_; ++t) rhs_s[((size_t)b * T_ + t) * N_ + m] = racc[t];
}

// ---------------- converters / builders ----------------
__global__ void k_cvt_vs(const float* __restrict__ v, unsigned short* __restrict__ o) {
    int i = blockIdx.x * 256 + threadIdx.x;
    o[i] = f2b(v[i]);
}

// xT[b][ct][m] (bf16) = x[b][m][ct]
__global__ __launch_bounds__(256) void k_transpose_x(const float* __restrict__ x,
                                                     unsigned short* __restrict__ xT) {
    __shared__ float tile[64][65];
    int b = blockIdx.z, m0 = blockIdx.y * 64, ct0 = blockIdx.x * 64;
    int tid = threadIdx.x;
#pragma unroll
    for (int e = 0; e < 16; ++e) {
        int idx = e * 256 + tid; int mm = idx >> 6, cc = idx & 63;
        tile[mm][cc] = x[((size_t)(b * N_ + m0 + mm)) * CT_ + ct0 + cc];
    }
    __syncthreads();
#pragma unroll
    for (int e = 0; e < 16; ++e) {
        int idx = e * 256 + tid; int rr = idx >> 6, mm = idx & 63;
        xT[((size_t)b * CT_ + ct0 + rr) * N_ + m0 + mm] = f2b(tile[mm][rr]);
    }
}

// sigA[b][i][k] (bf16) = sigmoid(dot24(lhs_s[b,i,:], rhs_s[b,:,k]) + b_s[i,k])
__global__ __launch_bounds__(256) void k_sig(const float* __restrict__ lhs_s,
        const float* __restrict__ rhs_s, const float* __restrict__ b_s,
        unsigned short* __restrict__ sigA) {
    int b = blockIdx.z, i0 = blockIdx.y * 64, k0 = blockIdx.x * 256;
    int tid = threadIdx.x;
    __shared__ float lh[64 * T_];
    __shared__ float rh[T_][256];
    for (int e = tid; e < 64 * T_; e += 256) lh[e] = lhs_s[((size_t)b * N_ + i0) * T_ + e];
#pragma unroll
    for (int t = 0; t < T_; ++t) rh[t][tid] = rhs_s[((size_t)b * T_ + t) * N_ + k0 + tid];
    __syncthreads();
    int kg = k0 + tid;
    for (int ii = 0; ii < 64; ++ii) {
        float acc = b_s[(size_t)(i0 + ii) * N_ + kg];
#pragma unroll
        for (int t = 0; t < T_; ++t) acc += lh[ii * T_ + t] * rh[t][tid];
        sigA[((size_t)b * N_ + i0 + ii) * N_ + kg] = f2b(sigmoidf_(acc));
    }
}

// yT[b][f*24+t][k*1024+m] (bf16) = sum_c Theta[k,c,f] * x[b,m,c,t]   (reads xT)
__global__ __launch_bounds__(256) void k_yT(const unsigned short* __restrict__ xT,
        const float* __restrict__ Theta, unsigned short* __restrict__ yT) {
    int b = blockIdx.z, t = blockIdx.y, m0 = blockIdx.x * 256;
    int tid = threadIdx.x;
    float xr[64];
#pragma unroll
    for (int c = 0; c < 64; ++c)
        xr[c] = b2f(xT[((size_t)b * CT_ + c * T_ + t) * N_ + m0 + tid]);
    for (int k = 0; k < 3; ++k) {
        float acc[64];
#pragma unroll
        for (int f = 0; f < 64; ++f) acc[f] = 0.f;
#pragma unroll 4
        for (int c = 0; c < 64; ++c) {
            float xc = xr[c];
            const float* th = Theta + ((size_t)k * 64 + c) * 64;   // uniform -> s_load
#pragma unroll
            for (int f = 0; f < 64; ++f) acc[f] = fmaf(th[f], xc, acc[f]);
        }
#pragma unroll
        for (int f = 0; f < 64; ++f)
            yT[((size_t)b * CT_ + f * T_ + t) * KS_ + k * N_ + m0 + tid] = f2b(acc[f]);
    }
}

// chebSt[b][i][k*1024+m] (bf16) = cheb[k][m][i] * S[b][m][i]
__global__ __launch_bounds__(256) void k_chebSt(const float* __restrict__ cheb,
        const float* __restrict__ S, unsigned short* __restrict__ cs) {
    int b = blockIdx.z, i0 = blockIdx.y * 64, m0 = blockIdx.x * 64;
    int tid = threadIdx.x;
    __shared__ float st[64][65];
    __shared__ float cb[64][65];
#pragma unroll
    for (int e = 0; e < 16; ++e) {
        int idx = e * 256 + tid; int mm = idx >> 6, ii = idx & 63;
        st[mm][ii] = S[((size_t)b * N_ + m0 + mm) * N_ + i0 + ii];
    }
    for (int k = 0; k < 3; ++k) {
        __syncthreads();
#pragma unroll
        for (int e = 0; e < 16; ++e) {
            int idx = e * 256 + tid; int mm = idx >> 6, ii = idx & 63;
            cb[mm][ii] = cheb[((size_t)k * N_ + m0 + mm) * N_ + i0 + ii];
        }
        __syncthreads();
#pragma unroll
        for (int e = 0; e < 16; ++e) {
            int idx = e * 256 + tid; int mm = idx & 63, ii = idx >> 6;
            cs[((size_t)b * N_ + i0 + ii) * KS_ + k * N_ + m0 + mm] =
                f2b(st[mm][ii] * cb[mm][ii]);
        }
    }
}

// ---------------- 256x256-tile MFMA GEMM: C[b] = A[b] * Bt[b]^T ----------------
// A: M x K bf16 rows (lda), Bt: Ncols x K bf16 rows (ldb), C: M x Ncols f32 (ldc).
// Grid: flat 1D = B * nby * nbx blocks of 512 threads; XCD-swizzled (nwg % 8 == 0).
// LDS: single-buffered 64KB; T2 XOR-swizzle (slot ^ row&7) with pre-swizzled
// global source (linear LDS dest for global_load_lds) + swizzled ds_read.
__global__ __launch_bounds__(512, 2) void k_gemm256(
        const unsigned short* __restrict__ A, long lda, long sA,
        const unsigned short* __restrict__ Bt, long ldb, long sB,
        float* __restrict__ Cc, long ldc, long sC, int K, int nbx, int nby) {
    __shared__ __align__(16) unsigned short As[256 * 64];   // 32KB, 128B rows
    __shared__ __align__(16) unsigned short Bs[256 * 64];   // 32KB
    int tid = threadIdx.x;
    int lane = tid & 63, w = tid >> 6;
    int wy = w >> 2, wx = w & 3;                            // 2 x 4 waves -> 128x64 per wave

    // XCD-aware bijective swizzle (nwg multiple of 8), j-fastest tile order
    int nwg = gridDim.x;
    int cpx = nwg >> 3;
    int logical = (blockIdx.x & 7) * cpx + (blockIdx.x >> 3);
    int tpb = nbx * nby;
    int b = logical / tpb;
    int tile = logical % tpb;
    int i0 = (tile / nbx) * 256;
    int j0 = (tile % nbx) * 256;

    const unsigned short* Ab = A + (size_t)b * sA + (size_t)i0 * lda;
    const unsigned short* Bb = Bt + (size_t)b * sB + (size_t)j0 * ldb;

    f32x4 acc[8][4];
#pragma unroll
    for (int mi = 0; mi < 8; ++mi)
#pragma unroll
        for (int ni = 0; ni < 4; ++ni) acc[mi][ni] = (f32x4){0.f, 0.f, 0.f, 0.f};

    for (int k0 = 0; k0 < K; k0 += 64) {
        if (k0) __syncthreads();                            // prev compute done
#pragma unroll
        for (int e = 0; e < 4; ++e) {                       // stage A (4 x 8KB)
            int chunk = e * 512 + tid;                      // 0..2047
            int row = chunk >> 3, slot = chunk & 7;
            int gslot = slot ^ (row & 7);                   // inverse swizzle on source
            gload_lds16(Ab + (size_t)row * lda + k0 + gslot * 8, &As[chunk * 8]);
        }
#pragma unroll
        for (int e = 0; e < 4; ++e) {                       // stage B
            int chunk = e * 512 + tid;
            int row = chunk >> 3, slot = chunk & 7;
            int gslot = slot ^ (row & 7);
            gload_lds16(Bb + (size_t)row * ldb + k0 + gslot * 8, &Bs[chunk * 8]);
        }
        __syncthreads();                                    // drains vmcnt too
#pragma unroll
        for (int kk = 0; kk < 2; ++kk) {
            short8 af[8], bf[4];
#pragma unroll
            for (int mi = 0; mi < 8; ++mi) {
                int r = wy * 128 + mi * 16 + (lane & 15);
                int slot = (kk * 4 + (lane >> 4)) ^ (r & 7);
                af[mi] = *(const short8*)&As[r * 64 + slot * 8];
            }
#pragma unroll
            for (int ni = 0; ni < 4; ++ni) {
                int r = wx * 64 + ni * 16 + (lane & 15);
                int slot = (kk * 4 + (lane >> 4)) ^ (r & 7);
                bf[ni] = *(const short8*)&Bs[r * 64 + slot * 8];
            }
#pragma unroll
            for (int mi = 0; mi < 8; ++mi)
#pragma unroll
                for (int ni = 0; ni < 4; ++ni)
                    acc[mi][ni] = __builtin_amdgcn_mfma_f32_16x16x32_bf16(
                        af[mi], bf[ni], acc[mi][ni], 0, 0, 0);
        }
    }
    float* Cb = Cc + (size_t)b * sC;
#pragma unroll
    for (int mi = 0; mi < 8; ++mi) {
#pragma unroll
        for (int r = 0; r < 4; ++r) {
            int i = i0 + wy * 128 + mi * 16 + (lane >> 4) * 4 + r;
            float* cp = Cb + (size_t)i * ldc + j0 + wx * 64 + (lane & 15);
#pragma unroll
            for (int ni = 0; ni < 4; ++ni) cp[ni * 16] = acc[mi][ni][r];
        }
    }
}

// softmax over axis m (rows) of S[b,m,i], per column i — in place
__global__ void k_softmax_S(float* __restrict__ S) {
    int b = blockIdx.y;
    int jj = threadIdx.x % 64;
    int ig = threadIdx.x / 64;
    int j = blockIdx.x * 64 + jj;
    __shared__ float redm[4][64], reds[4][64];
    float mx = -1e30f;
    for (int i = ig; i < N_; i += 4) mx = fmaxf(mx, S[((size_t)b * N_ + i) * N_ + j]);
    redm[ig][jj] = mx;
    __syncthreads();
    mx = fmaxf(fmaxf(redm[0][jj], redm[1][jj]), fmaxf(redm[2][jj], redm[3][jj]));
    float sm = 0.f;
    for (int i = ig; i < N_; i += 4) sm += __expf(S[((size_t)b * N_ + i) * N_ + j] - mx);
    reds[ig][jj] = sm;
    __syncthreads();
    float tot = reds[0][jj] + reds[1][jj] + reds[2][jj] + reds[3][jj];
    float inv = 1.f / tot;
    for (int i = ig; i < N_; i += 4) {
        size_t o = ((size_t)b * N_ + i) * N_ + j;
        S[o] = __expf(S[o] - mx) * inv;
    }
}

// ---------------- fused: relu(gcn) -> time conv + residual conv -> relu -> LN ----------------
__global__ __launch_bounds__(256) void k_final(const float* __restrict__ x,
        const float* __restrict__ sgin, const float* __restrict__ tc_w,
        const float* __restrict__ tc_b, const float* __restrict__ rc_w,
        const float* __restrict__ rc_b, const float* __restrict__ ln_g,
        const float* __restrict__ ln_b, float* __restrict__ out) {
    int b = blockIdx.y;
    int n0 = blockIdx.x * 4;
    int tid = threadIdx.x;
    __shared__ float shm[2 * 4 * CT_];
    __shared__ float mus[4][T_], rstds[4][T_];
    float* sg = shm;
    float* xr = shm + 4 * CT_;
    size_t base = ((size_t)b * N_ + n0) * CT_;
    for (int e = tid; e < 4 * CT_; e += 256) {
        sg[e] = fmaxf(sgin[base + e], 0.f);
        xr[e] = x[base + e];
    }
    __syncthreads();
    int ft = tid % 64, nl = tid / 64;
    float acc[T_];
    float tb = tc_b[ft] + rc_b[ft];
#pragma unroll
    for (int t = 0; t < T_; ++t) acc[t] = tb;
    const float* sgn = sg + nl * CT_;
    const float* xrn = xr + nl * CT_;
    for (int c = 0; c < C_; ++c) {
        float w0 = tc_w[(ft * C_ + c) * 3 + 0];
        float w1 = tc_w[(ft * C_ + c) * 3 + 1];
        float w2 = tc_w[(ft * C_ + c) * 3 + 2];
        float rw = rc_w[ft * C_ + c];
        const float* sc = sgn + c * T_;
        const float* xc = xrn + c * T_;
#pragma unroll
        for (int t = 0; t < T_; ++t) {
            float v = sc[t] * w1 + xc[t] * rw;
            if (t > 0) v += sc[t - 1] * w0;
            if (t < T_ - 1) v += sc[t + 1] * w2;
            acc[t] += v;
        }
    }
#pragma unroll
    for (int t = 0; t < T_; ++t) acc[t] = fmaxf(acc[t], 0.f);
    __syncthreads();
    float* o2 = shm;
#pragma unroll
    for (int t = 0; t < T_; ++t) o2[(nl * 64 + ft) * 25 + t] = acc[t];
    __syncthreads();
    if (tid < 4 * T_) {
        int nn = tid / T_, t = tid % T_;
        float s = 0.f, s2 = 0.f;
        for (int f = 0; f < 64; ++f) {
            float v = o2[(nn * 64 + f) * 25 + t];
            s += v; s2 += v * v;
        }
        float mu = s * (1.f / 64.f);
        float var = s2 * (1.f / 64.f) - mu * mu;
        mus[nn][t] = mu;
        rstds[nn][t] = rsqrtf(var + 1e-5f);
    }
    __syncthreads();
    float g = ln_g[ft], bb = ln_b[ft];
    float* op = out + ((size_t)b * N_ + n0 + nl) * CT_ + ft * T_;
#pragma unroll
    for (int t = 0; t < T_; ++t)
        op[t] = (o2[(nl * 64 + ft) * 25 + t] - mus[nl][t]) * rstds[nl][t] * g + bb;
}

extern "C" void kernel_launch(void* const* d_in, const int* in_sizes, int n_in,
                              void* d_out, int out_size, void* d_ws, size_t ws_size,
                              hipStream_t stream) {
    const float* x    = (const float*)d_in[0];
    const float* cheb = (const float*)d_in[1];
    const float* U1   = (const float*)d_in[2];
    const float* U2   = (const float*)d_in[3];
    const float* U3   = (const float*)d_in[4];
    const float* b_e  = (const float*)d_in[5];
    const float* V_e  = (const float*)d_in[6];
    const float* W1   = (const float*)d_in[7];
    const float* W2   = (const float*)d_in[8];
    const float* W3   = (const float*)d_in[9];
    const float* b_s  = (const float*)d_in[10];
    const float* V_s  = (const float*)d_in[11];
    const float* Theta= (const float*)d_in[12];
    const float* tc_w = (const float*)d_in[13];
    const float* tc_b = (const float*)d_in[14];
    const float* rc_w = (const float*)d_in[15];
    const float* rc_b = (const float*)d_in[16];
    const float* ln_g = (const float*)d_in[17];
    const float* ln_b = (const float*)d_in[18];
    float* out = (float*)d_out;

    char* base = (char*)d_ws;
    size_t o = 0;
    auto alloc = [&](size_t bytes) { size_t r = o; o += (bytes + 255) & ~(size_t)255; return r; };
    float* lhs_t   = (float*)(base + alloc((size_t)B_ * T_ * N_ * 4));
    float* rhs_t   = (float*)(base + alloc((size_t)B_ * N_ * T_ * 4));
    float* Ebuf    = (float*)(base + alloc((size_t)B_ * T_ * T_ * 4));
    float* partial = (float*)(base + alloc((size_t)B_ * 16 * CT_ * 4));
    float* lhs_t0  = (float*)(base + alloc((size_t)B_ * CT_ * 4));
    float* lhs_s   = (float*)(base + alloc((size_t)B_ * N_ * T_ * 4));
    float* rhs_s   = (float*)(base + alloc((size_t)B_ * T_ * N_ * 4));
    unsigned short* V_sb = (unsigned short*)(base + alloc((size_t)N_ * N_ * 2));
    // RegA: xw (f32) -> xT (bf16) -> chebSt (bf16)   [disjoint lifetimes]
    size_t regA = alloc((size_t)B_ * N_ * KS_ * 2);
    // RegB: sigA (bf16) -> yT (bf16)                 [disjoint lifetimes]
    size_t regB = alloc((size_t)B_ * CT_ * KS_ * 2);
    float*          xw     = (float*)(base + regA);
    unsigned short* xT     = (unsigned short*)(base + regA);
    unsigned short* chebSt = (unsigned short*)(base + regA);
    unsigned short* sigA   = (unsigned short*)(base + regB);
    unsigned short* yT     = (unsigned short*)(base + regB);
    float* Sb  = out;        // S scores live in d_out until the stacked GEMM overwrites
    float* gcn = out;

    dim3 b256(256);
    k_cvt_vs<<<dim3(N_ * N_ / 256), b256, 0, stream>>>(V_s, V_sb);
    k_rhs_t<<<dim3((B_ * N_ * T_) / 256), b256, 0, stream>>>(x, U3, rhs_t);
    k_lhs_partial<<<dim3(16, B_), b256, 0, stream>>>(x, U1, partial);
    k_lhs_reduce<<<dim3((B_ * CT_) / 256), b256, 0, stream>>>(partial, lhs_t0);
    k_lhs_t<<<dim3((B_ * T_ * N_) / 256), b256, 0, stream>>>(lhs_t0, U2, lhs_t);
    k_temporal_E<<<dim3(B_), dim3(576), 0, stream>>>(lhs_t, rhs_t, b_e, V_e, Ebuf);
    k_xTAt<<<dim3(N_ * C_ / 256, B_), b256, 0, stream>>>(x, Ebuf, xw);
    k_spatial_prep<<<dim3(B_ * N_ / 256), b256, 0, stream>>>(xw, W1, W2, W3, lhs_s, rhs_s);
    k_transpose_x<<<dim3(CT_ / 64, N_ / 64, B_), b256, 0, stream>>>(x, xT);   // xw dead
    k_sig<<<dim3(N_ / 256, N_ / 64, B_), b256, 0, stream>>>(lhs_s, rhs_s, b_s, sigA);
    // S0 GEMM: M=1024, Ncols=1024, K=1024; nbx=nby=4; nwg=512 (%8==0)
    k_gemm256<<<dim3(B_ * 4 * 4), dim3(512), 0, stream>>>(
        sigA, N_, (long)N_ * N_, V_sb, N_, 0, Sb, N_, (long)N_ * N_, N_, 4, 4);
    k_softmax_S<<<dim3(N_ / 64, B_), b256, 0, stream>>>(Sb);
    k_yT<<<dim3(N_ / 256, T_, B_), b256, 0, stream>>>(xT, Theta, yT);          // sigA dead
    k_chebSt<<<dim3(N_ / 64, N_ / 64, B_), b256, 0, stream>>>(cheb, Sb, chebSt); // xT dead
    // stacked GEMM: M=1024, Ncols=1536, K=3072; nbx=6, nby=4; nwg=768 (%8==0)
    k_gemm256<<<dim3(B_ * 4 * 6), dim3(512), 0, stream>>>(
        chebSt, KS_, (long)N_ * KS_, yT, KS_, (long)CT_ * KS_,
        gcn, CT_, (long)N_ * CT_, KS_, 6, 4);                                 // Sb dead
    k_final<<<dim3(N_ / 4, B_), b256, 0, stream>>>(x, gcn, tc_w, tc_b, rc_w, rc_b,
                                                   ln_g, ln_b, out);
}

// Round 4
// 1981.673 us; speedup vs baseline: 6.7826x; 1.0918x over previous
//
#include <hip/hip_runtime.h>

typedef __attribute__((ext_vector_type(8))) short short8;   // 8 bf16 (4 VGPRs)
typedef __attribute__((ext_vector_type(4))) float f32x4;

constexpr int B_ = 32;
constexpr int N_ = 1024;
constexpr int C_ = 64;
constexpr int T_ = 24;
constexpr int F_ = 64;
constexpr int CT_ = C_ * T_;     // 1536
constexpr int KS_ = 3072;        // stacked K = 3*1024

__device__ __forceinline__ float sigmoidf_(float x) {
    return 1.0f / (1.0f + __expf(-x));
}
__device__ __forceinline__ unsigned short f2b(float f) {   // RNE f32->bf16
    union { float f; unsigned u; } v; v.f = f;
    unsigned r = v.u + 0x7FFFu + ((v.u >> 16) & 1u);
    return (unsigned short)(r >> 16);
}
__device__ __forceinline__ float b2f(unsigned short h) {
    union { unsigned u; float f; } v; v.u = ((unsigned)h) << 16; return v.f;
}
__device__ __forceinline__ void gload_lds16(const unsigned short* g, unsigned short* l) {
    __builtin_amdgcn_global_load_lds(
        (const __attribute__((address_space(1))) unsigned int*)g,
        (__attribute__((address_space(3))) unsigned int*)l, 16, 0, 0);
}

// ---------------- temporal attention prep ----------------
__global__ void k_rhs_t(const float* __restrict__ x, const float* __restrict__ U3,
                        float* __restrict__ rhs_t) {
    int idx = blockIdx.x * 256 + threadIdx.x;
    if (idx >= B_ * N_ * T_) return;
    int t = idx % T_;
    int n = (idx / T_) % N_;
    int b = idx / (N_ * T_);
    const float* xp = x + ((size_t)(b * N_ + n)) * CT_ + t;
    float acc = 0.f;
#pragma unroll
    for (int c = 0; c < C_; ++c) acc += U3[c] * xp[c * T_];
    rhs_t[idx] = acc;
}

__global__ void k_lhs_partial(const float* __restrict__ x, const float* __restrict__ U1,
                              float* __restrict__ partial) {
    int b = blockIdx.y, chunk = blockIdx.x;
    int tid = threadIdx.x;
    float acc[6] = {0, 0, 0, 0, 0, 0};
    int n0 = chunk * 64;
    for (int nn = 0; nn < 64; ++nn) {
        int n = n0 + nn;
        float u = U1[n];
        const float* xp = x + ((size_t)(b * N_ + n)) * CT_;
#pragma unroll
        for (int e = 0; e < 6; ++e) acc[e] += u * xp[tid + e * 256];
    }
    float* pp = partial + ((size_t)(b * 16 + chunk)) * CT_;
#pragma unroll
    for (int e = 0; e < 6; ++e) pp[tid + e * 256] = acc[e];
}

__global__ void k_lhs_reduce(const float* __restrict__ partial, float* __restrict__ lhs_t0) {
    int idx = blockIdx.x * 256 + threadIdx.x;
    if (idx >= B_ * CT_) return;
    int b = idx / CT_, flat = idx % CT_;
    float acc = 0.f;
#pragma unroll
    for (int ch = 0; ch < 16; ++ch) acc += partial[((size_t)(b * 16 + ch)) * CT_ + flat];
    lhs_t0[idx] = acc;
}

__global__ void k_lhs_t(const float* __restrict__ lhs_t0, const float* __restrict__ U2,
                        float* __restrict__ lhs_t) {
    int idx = blockIdx.x * 256 + threadIdx.x;
    if (idx >= B_ * T_ * N_) return;
    int n2 = idx % N_;
    int t = (idx / N_) % T_;
    int b = idx / (T_ * N_);
    const float* l0 = lhs_t0 + (size_t)b * CT_;
    float acc = 0.f;
#pragma unroll
    for (int c = 0; c < C_; ++c) acc += l0[c * T_ + t] * U2[c * N_ + n2];
    lhs_t[idx] = acc;
}

__global__ void k_temporal_E(const float* __restrict__ lhs_t, const float* __restrict__ rhs_t,
                             const float* __restrict__ b_e, const float* __restrict__ V_e,
                             float* __restrict__ E) {
    int b = blockIdx.x;
    int tid = threadIdx.x;                               // 576 threads
    int i = tid / T_, u = tid % T_;
    __shared__ float sig[T_][T_];
    __shared__ float e0s[T_][T_];
    __shared__ float mcol[T_], scol[T_];
    const float* lt = lhs_t + (size_t)b * T_ * N_ + (size_t)i * N_;
    const float* rt = rhs_t + (size_t)b * N_ * T_ + u;
    float acc = 0.f;
    for (int n = 0; n < N_; ++n) acc += lt[n] * rt[(size_t)n * T_];
    sig[i][u] = sigmoidf_(acc + b_e[i * T_ + u]);
    __syncthreads();
    int j = u;
    float e0 = 0.f;
#pragma unroll
    for (int kk = 0; kk < T_; ++kk) e0 += sig[i][kk] * V_e[j * T_ + kk];
    e0s[i][j] = e0;
    __syncthreads();
    if (tid < T_) {
        float mx = -1e30f;
        for (int ii = 0; ii < T_; ++ii) mx = fmaxf(mx, e0s[ii][tid]);
        float s = 0.f;
        for (int ii = 0; ii < T_; ++ii) s += __expf(e0s[ii][tid] - mx);
        mcol[tid] = mx; scol[tid] = s;
    }
    __syncthreads();
    E[(size_t)b * T_ * T_ + i * T_ + j] = __expf(e0s[i][j] - mcol[j]) / scol[j];
}

__global__ void k_xTAt(const float* __restrict__ x, const float* __restrict__ E,
                       float* __restrict__ xw) {
    int b = blockIdx.y;
    int nc = blockIdx.x * 256 + threadIdx.x;
    __shared__ float Es[T_ * T_];
    for (int e = threadIdx.x; e < T_ * T_; e += 256) Es[e] = E[(size_t)b * T_ * T_ + e];
    __syncthreads();
    const float* xp = x + (size_t)b * N_ * CT_ + (size_t)nc * T_;
    float xv[T_];
#pragma unroll
    for (int t = 0; t < T_; ++t) xv[t] = xp[t];
    float* op = xw + (size_t)b * N_ * CT_ + (size_t)nc * T_;
#pragma unroll
    for (int u = 0; u < T_; ++u) {
        float acc = 0.f;
#pragma unroll
        for (int t = 0; t < T_; ++t) acc += xv[t] * Es[t * T_ + u];
        op[u] = acc;
    }
}

// ---------------- spatial attention prep ----------------
__global__ __launch_bounds__(256) void k_spatial_prep(const float* __restrict__ xw,
        const float* __restrict__ W1g, const float* __restrict__ W2,
        const float* __restrict__ W3g, float* __restrict__ lhs_s, float* __restrict__ rhs_s) {
    __shared__ float W2s[C_ * T_];
    __shared__ float W1s[T_];
    __shared__ float W3s[C_];
    int tid = threadIdx.x;
    for (int e = tid; e < C_ * T_; e += 256) W2s[e] = W2[e];
    if (tid < T_) W1s[tid] = W1g[tid];
    if (tid < C_) W3s[tid] = W3g[tid];
    __syncthreads();
    int idx = blockIdx.x * 256 + tid;
    int b = idx / N_, m = idx % N_;
    const float* xp = xw + (size_t)idx * CT_;
    float lacc[T_], racc[T_];
#pragma unroll
    for (int t = 0; t < T_; ++t) { lacc[t] = 0.f; racc[t] = 0.f; }
    for (int c = 0; c < C_; ++c) {
        float l0 = 0.f;
        float w3 = W3s[c];
        const float* xc = xp + c * T_;
#pragma unroll
        for (int t = 0; t < T_; ++t) {
            float v = xc[t];
            l0 += v * W1s[t];
            racc[t] += w3 * v;
        }
#pragma unroll
        for (int t2 = 0; t2 < T_; ++t2) lacc[t2] += l0 * W2s[c * T_ + t2];
    }
    float* lp = lhs_s + (size_t)idx * T_;
#pragma unroll
    for (int t = 0; t < T_; ++t) lp[t] = lacc[t];
#pragma unroll
    for (int t = 0; t < T_; ++t) rhs_s[((size_t)b * T_ + t) * N_ + m] = racc[t];
}

// ---------------- converters / builders ----------------
__global__ void k_cvt_vs(const float* __restrict__ v, unsigned short* __restrict__ o) {
    int i = blockIdx.x * 256 + threadIdx.x;
    o[i] = f2b(v[i]);
}

// wpack[ft*64+c] = (tc_w0, tc_w1, tc_w2, rc_w)
__global__ void k_wpack(const float* __restrict__ tc_w, const float* __restrict__ rc_w,
                        float4* __restrict__ wpack) {
    int i = blockIdx.x * 256 + threadIdx.x;              // over F_*C_ = 4096
    if (i >= F_ * C_) return;
    wpack[i] = make_float4(tc_w[i * 3 + 0], tc_w[i * 3 + 1], tc_w[i * 3 + 2], rc_w[i]);
}

// xT[b][ct][m] (bf16) = x[b][m][ct]
__global__ __launch_bounds__(256) void k_transpose_x(const float* __restrict__ x,
                                                     unsigned short* __restrict__ xT) {
    __shared__ float tile[64][65];
    int b = blockIdx.z, m0 = blockIdx.y * 64, ct0 = blockIdx.x * 64;
    int tid = threadIdx.x;
#pragma unroll
    for (int e = 0; e < 16; ++e) {
        int idx = e * 256 + tid; int mm = idx >> 6, cc = idx & 63;
        tile[mm][cc] = x[((size_t)(b * N_ + m0 + mm)) * CT_ + ct0 + cc];
    }
    __syncthreads();
#pragma unroll
    for (int e = 0; e < 16; ++e) {
        int idx = e * 256 + tid; int rr = idx >> 6, mm = idx & 63;
        xT[((size_t)b * CT_ + ct0 + rr) * N_ + m0 + mm] = f2b(tile[mm][rr]);
    }
}

// sigA[b][i][k] (bf16) = sigmoid(dot24(lhs_s[b,i,:], rhs_s[b,:,k]) + b_s[i,k])
__global__ __launch_bounds__(256) void k_sig(const float* __restrict__ lhs_s,
        const float* __restrict__ rhs_s, const float* __restrict__ b_s,
        unsigned short* __restrict__ sigA) {
    int b = blockIdx.z, i0 = blockIdx.y * 64, k0 = blockIdx.x * 256;
    int tid = threadIdx.x;
    __shared__ float lh[64 * T_];
    __shared__ float rh[T_][256];
    for (int e = tid; e < 64 * T_; e += 256) lh[e] = lhs_s[((size_t)b * N_ + i0) * T_ + e];
#pragma unroll
    for (int t = 0; t < T_; ++t) rh[t][tid] = rhs_s[((size_t)b * T_ + t) * N_ + k0 + tid];
    __syncthreads();
    int kg = k0 + tid;
    for (int ii = 0; ii < 64; ++ii) {
        float acc = b_s[(size_t)(i0 + ii) * N_ + kg];
#pragma unroll
        for (int t = 0; t < T_; ++t) acc += lh[ii * T_ + t] * rh[t][tid];
        sigA[((size_t)b * N_ + i0 + ii) * N_ + kg] = f2b(sigmoidf_(acc));
    }
}

// yT[b][f*24+t][k*1024+m] (bf16) = sum_c Theta[k,c,f] * x[b,m,c,t]   (reads xT)
__global__ __launch_bounds__(256) void k_yT(const unsigned short* __restrict__ xT,
        const float* __restrict__ Theta, unsigned short* __restrict__ yT) {
    int b = blockIdx.z, t = blockIdx.y, m0 = blockIdx.x * 256;
    int tid = threadIdx.x;
    float xr[64];
#pragma unroll
    for (int c = 0; c < 64; ++c)
        xr[c] = b2f(xT[((size_t)b * CT_ + c * T_ + t) * N_ + m0 + tid]);
    for (int k = 0; k < 3; ++k) {
        float acc[64];
#pragma unroll
        for (int f = 0; f < 64; ++f) acc[f] = 0.f;
#pragma unroll 4
        for (int c = 0; c < 64; ++c) {
            float xc = xr[c];
            const float* th = Theta + ((size_t)k * 64 + c) * 64;   // uniform -> s_load
#pragma unroll
            for (int f = 0; f < 64; ++f) acc[f] = fmaf(th[f], xc, acc[f]);
        }
#pragma unroll
        for (int f = 0; f < 64; ++f)
            yT[((size_t)b * CT_ + f * T_ + t) * KS_ + k * N_ + m0 + tid] = f2b(acc[f]);
    }
}

// chebSt[b][i][k*1024+m] (bf16) = cheb[k][m][i] * S[b][m][i]
__global__ __launch_bounds__(256) void k_chebSt(const float* __restrict__ cheb,
        const float* __restrict__ S, unsigned short* __restrict__ cs) {
    int b = blockIdx.z, i0 = blockIdx.y * 64, m0 = blockIdx.x * 64;
    int tid = threadIdx.x;
    __shared__ float st[64][65];
    __shared__ float cb[64][65];
#pragma unroll
    for (int e = 0; e < 16; ++e) {
        int idx = e * 256 + tid; int mm = idx >> 6, ii = idx & 63;
        st[mm][ii] = S[((size_t)b * N_ + m0 + mm) * N_ + i0 + ii];
    }
    for (int k = 0; k < 3; ++k) {
        __syncthreads();
#pragma unroll
        for (int e = 0; e < 16; ++e) {
            int idx = e * 256 + tid; int mm = idx >> 6, ii = idx & 63;
            cb[mm][ii] = cheb[((size_t)k * N_ + m0 + mm) * N_ + i0 + ii];
        }
        __syncthreads();
#pragma unroll
        for (int e = 0; e < 16; ++e) {
            int idx = e * 256 + tid; int mm = idx & 63, ii = idx >> 6;
            cs[((size_t)b * N_ + i0 + ii) * KS_ + k * N_ + m0 + mm] =
                f2b(st[mm][ii] * cb[mm][ii]);
        }
    }
}

// ---------------- 256x256-tile MFMA GEMM: C[b] = A[b] * Bt[b]^T ----------------
__global__ __launch_bounds__(512, 2) void k_gemm256(
        const unsigned short* __restrict__ A, long lda, long sA,
        const unsigned short* __restrict__ Bt, long ldb, long sB,
        float* __restrict__ Cc, long ldc, long sC, int K, int nbx, int nby) {
    __shared__ __align__(16) unsigned short As[256 * 64];   // 32KB, 128B rows
    __shared__ __align__(16) unsigned short Bs[256 * 64];   // 32KB
    int tid = threadIdx.x;
    int lane = tid & 63, w = tid >> 6;
    int wy = w >> 2, wx = w & 3;                            // 2 x 4 waves -> 128x64 per wave

    int nwg = gridDim.x;
    int cpx = nwg >> 3;
    int logical = (blockIdx.x & 7) * cpx + (blockIdx.x >> 3);
    int tpb = nbx * nby;
    int b = logical / tpb;
    int tile = logical % tpb;
    int i0 = (tile / nbx) * 256;
    int j0 = (tile % nbx) * 256;

    const unsigned short* Ab = A + (size_t)b * sA + (size_t)i0 * lda;
    const unsigned short* Bb = Bt + (size_t)b * sB + (size_t)j0 * ldb;

    f32x4 acc[8][4];
#pragma unroll
    for (int mi = 0; mi < 8; ++mi)
#pragma unroll
        for (int ni = 0; ni < 4; ++ni) acc[mi][ni] = (f32x4){0.f, 0.f, 0.f, 0.f};

    for (int k0 = 0; k0 < K; k0 += 64) {
        if (k0) __syncthreads();
#pragma unroll
        for (int e = 0; e < 4; ++e) {                       // stage A (4 x 8KB)
            int chunk = e * 512 + tid;
            int row = chunk >> 3, slot = chunk & 7;
            int gslot = slot ^ (row & 7);
            gload_lds16(Ab + (size_t)row * lda + k0 + gslot * 8, &As[chunk * 8]);
        }
#pragma unroll
        for (int e = 0; e < 4; ++e) {                       // stage B
            int chunk = e * 512 + tid;
            int row = chunk >> 3, slot = chunk & 7;
            int gslot = slot ^ (row & 7);
            gload_lds16(Bb + (size_t)row * ldb + k0 + gslot * 8, &Bs[chunk * 8]);
        }
        __syncthreads();
#pragma unroll
        for (int kk = 0; kk < 2; ++kk) {
            short8 af[8], bf[4];
#pragma unroll
            for (int mi = 0; mi < 8; ++mi) {
                int r = wy * 128 + mi * 16 + (lane & 15);
                int slot = (kk * 4 + (lane >> 4)) ^ (r & 7);
                af[mi] = *(const short8*)&As[r * 64 + slot * 8];
            }
#pragma unroll
            for (int ni = 0; ni < 4; ++ni) {
                int r = wx * 64 + ni * 16 + (lane & 15);
                int slot = (kk * 4 + (lane >> 4)) ^ (r & 7);
                bf[ni] = *(const short8*)&Bs[r * 64 + slot * 8];
            }
#pragma unroll
            for (int mi = 0; mi < 8; ++mi)
#pragma unroll
                for (int ni = 0; ni < 4; ++ni)
                    acc[mi][ni] = __builtin_amdgcn_mfma_f32_16x16x32_bf16(
                        af[mi], bf[ni], acc[mi][ni], 0, 0, 0);
        }
    }
    float* Cb = Cc + (size_t)b * sC;
#pragma unroll
    for (int mi = 0; mi < 8; ++mi) {
#pragma unroll
        for (int r = 0; r < 4; ++r) {
            int i = i0 + wy * 128 + mi * 16 + (lane >> 4) * 4 + r;
            float* cp = Cb + (size_t)i * ldc + j0 + wx * 64 + (lane & 15);
#pragma unroll
            for (int ni = 0; ni < 4; ++ni) cp[ni * 16] = acc[mi][ni][r];
        }
    }
}

// softmax over axis m (rows) of S[b,m,i], per column i — in place
__global__ void k_softmax_S(float* __restrict__ S) {
    int b = blockIdx.y;
    int jj = threadIdx.x % 64;
    int ig = threadIdx.x / 64;
    int j = blockIdx.x * 64 + jj;
    __shared__ float redm[4][64], reds[4][64];
    float mx = -1e30f;
    for (int i = ig; i < N_; i += 4) mx = fmaxf(mx, S[((size_t)b * N_ + i) * N_ + j]);
    redm[ig][jj] = mx;
    __syncthreads();
    mx = fmaxf(fmaxf(redm[0][jj], redm[1][jj]), fmaxf(redm[2][jj], redm[3][jj]));
    float sm = 0.f;
    for (int i = ig; i < N_; i += 4) sm += __expf(S[((size_t)b * N_ + i) * N_ + j] - mx);
    reds[ig][jj] = sm;
    __syncthreads();
    float tot = reds[0][jj] + reds[1][jj] + reds[2][jj] + reds[3][jj];
    float inv = 1.f / tot;
    for (int i = ig; i < N_; i += 4) {
        size_t o = ((size_t)b * N_ + i) * N_ + j;
        S[o] = __expf(S[o] - mx) * inv;
    }
}

// ---------------- fused: relu(gcn) -> time conv + residual conv -> relu -> LN ----------------
// 256 threads = 4 n-rows x (16 ft-groups x 4 t-groups); each thread: 4 ft x 6 t.
// Register-blocked: each LDS data window feeds 4 ft (3.4x less LDS traffic than 1-ft/thread).
__global__ __launch_bounds__(256) void k_final(const float* __restrict__ x,
        const float* __restrict__ sgin, const float4* __restrict__ wpack,
        const float* __restrict__ tc_b, const float* __restrict__ rc_b,
        const float* __restrict__ ln_g, const float* __restrict__ ln_b,
        float* __restrict__ out) {
    int b = blockIdx.y;
    int n0 = blockIdx.x * 4;
    int tid = threadIdx.x;
    __shared__ float shm[2 * 4 * CT_];                   // 48KB
    __shared__ float mus[4][T_], rstds[4][T_];
    float* sg = shm;                                     // [4][C][T] relu'd gcn
    float* xr = shm + 4 * CT_;                           // [4][C][T] raw x
    size_t base = ((size_t)b * N_ + n0) * CT_;
    for (int e = tid; e < 4 * CT_; e += 256) {
        sg[e] = fmaxf(sgin[base + e], 0.f);
        xr[e] = x[base + e];
    }
    __syncthreads();
    int nl = tid >> 6;
    int lane6 = tid & 63;
    int f0 = (lane6 >> 2) * 4;                           // ft group
    int t0 = (lane6 & 3) * 6;                            // t group
    float acc[4][6];
#pragma unroll
    for (int j = 0; j < 4; ++j) {
        float tb = tc_b[f0 + j] + rc_b[f0 + j];
#pragma unroll
        for (int d = 0; d < 6; ++d) acc[j][d] = tb;
    }
    const float* sgn = sg + nl * CT_;
    const float* xrn = xr + nl * CT_;
#pragma unroll 2
    for (int c = 0; c < C_; ++c) {
        const float* sc = sgn + c * T_;
        const float* xc = xrn + c * T_;
        float sv[8], xv[6];
#pragma unroll
        for (int d = 0; d < 8; ++d) {
            int t = t0 - 1 + d;
            sv[d] = ((unsigned)t < 24u) ? sc[t] : 0.f;   // zero-pad conv boundary
        }
#pragma unroll
        for (int d = 0; d < 6; ++d) xv[d] = xc[t0 + d];
#pragma unroll
        for (int j = 0; j < 4; ++j) {
            float4 w = wpack[(f0 + j) * C_ + c];
#pragma unroll
            for (int d = 0; d < 6; ++d) {
                float v = fmaf(sv[d + 1], w.y, xv[d] * w.w);
                v = fmaf(sv[d], w.x, v);
                v = fmaf(sv[d + 2], w.z, v);
                acc[j][d] += v;
            }
        }
    }
#pragma unroll
    for (int j = 0; j < 4; ++j)
#pragma unroll
        for (int d = 0; d < 6; ++d) acc[j][d] = fmaxf(acc[j][d], 0.f);
    __syncthreads();                                     // done reading sg/xr
    float* o2 = shm;                                     // reuse: [4][64][25]
#pragma unroll
    for (int j = 0; j < 4; ++j)
#pragma unroll
        for (int d = 0; d < 6; ++d)
            o2[(nl * 64 + f0 + j) * 25 + t0 + d] = acc[j][d];
    __syncthreads();
    if (tid < 4 * T_) {
        int nn = tid / T_, t = tid % T_;
        float s = 0.f, s2 = 0.f;
        for (int f = 0; f < 64; ++f) {
            float v = o2[(nn * 64 + f) * 25 + t];
            s += v; s2 += v * v;
        }
        float mu = s * (1.f / 64.f);
        float var = s2 * (1.f / 64.f) - mu * mu;
        mus[nn][t] = mu;
        rstds[nn][t] = rsqrtf(var + 1e-5f);
    }
    __syncthreads();
    float* op = out + ((size_t)b * N_ + n0 + nl) * CT_;
#pragma unroll
    for (int j = 0; j < 4; ++j) {
        float g = ln_g[f0 + j], bb = ln_b[f0 + j];
#pragma unroll
        for (int d = 0; d < 6; ++d) {
            int t = t0 + d;
            op[(f0 + j) * T_ + t] = (acc[j][d] - mus[nl][t]) * rstds[nl][t] * g + bb;
        }
    }
}

extern "C" void kernel_launch(void* const* d_in, const int* in_sizes, int n_in,
                              void* d_out, int out_size, void* d_ws, size_t ws_size,
                              hipStream_t stream) {
    const float* x    = (const float*)d_in[0];
    const float* cheb = (const float*)d_in[1];
    const float* U1   = (const float*)d_in[2];
    const float* U2   = (const float*)d_in[3];
    const float* U3   = (const float*)d_in[4];
    const float* b_e  = (const float*)d_in[5];
    const float* V_e  = (const float*)d_in[6];
    const float* W1   = (const float*)d_in[7];
    const float* W2   = (const float*)d_in[8];
    const float* W3   = (const float*)d_in[9];
    const float* b_s  = (const float*)d_in[10];
    const float* V_s  = (const float*)d_in[11];
    const float* Theta= (const float*)d_in[12];
    const float* tc_w = (const float*)d_in[13];
    const float* tc_b = (const float*)d_in[14];
    const float* rc_w = (const float*)d_in[15];
    const float* rc_b = (const float*)d_in[16];
    const float* ln_g = (const float*)d_in[17];
    const float* ln_b = (const float*)d_in[18];
    float* out = (float*)d_out;

    char* base = (char*)d_ws;
    size_t o = 0;
    auto alloc = [&](size_t bytes) { size_t r = o; o += (bytes + 255) & ~(size_t)255; return r; };
    float* lhs_t   = (float*)(base + alloc((size_t)B_ * T_ * N_ * 4));
    float* rhs_t   = (float*)(base + alloc((size_t)B_ * N_ * T_ * 4));
    float* Ebuf    = (float*)(base + alloc((size_t)B_ * T_ * T_ * 4));
    float* partial = (float*)(base + alloc((size_t)B_ * 16 * CT_ * 4));
    float* lhs_t0  = (float*)(base + alloc((size_t)B_ * CT_ * 4));
    float* lhs_s   = (float*)(base + alloc((size_t)B_ * N_ * T_ * 4));
    float* rhs_s   = (float*)(base + alloc((size_t)B_ * T_ * N_ * 4));
    unsigned short* V_sb = (unsigned short*)(base + alloc((size_t)N_ * N_ * 2));
    float4* wpack  = (float4*)(base + alloc((size_t)F_ * C_ * 16));
    // RegA: xw (f32) -> xT (bf16) -> chebSt (bf16)   [disjoint lifetimes]
    size_t regA = alloc((size_t)B_ * N_ * KS_ * 2);
    // RegB: sigA (bf16) -> yT (bf16)                 [disjoint lifetimes]
    size_t regB = alloc((size_t)B_ * CT_ * KS_ * 2);
    float*          xw     = (float*)(base + regA);
    unsigned short* xT     = (unsigned short*)(base + regA);
    unsigned short* chebSt = (unsigned short*)(base + regA);
    unsigned short* sigA   = (unsigned short*)(base + regB);
    unsigned short* yT     = (unsigned short*)(base + regB);
    float* Sb  = out;        // S scores live in d_out until the stacked GEMM overwrites
    float* gcn = out;

    dim3 b256(256);
    k_cvt_vs<<<dim3(N_ * N_ / 256), b256, 0, stream>>>(V_s, V_sb);
    k_wpack<<<dim3((F_ * C_ + 255) / 256), b256, 0, stream>>>(tc_w, rc_w, wpack);
    k_rhs_t<<<dim3((B_ * N_ * T_) / 256), b256, 0, stream>>>(x, U3, rhs_t);
    k_lhs_partial<<<dim3(16, B_), b256, 0, stream>>>(x, U1, partial);
    k_lhs_reduce<<<dim3((B_ * CT_) / 256), b256, 0, stream>>>(partial, lhs_t0);
    k_lhs_t<<<dim3((B_ * T_ * N_) / 256), b256, 0, stream>>>(lhs_t0, U2, lhs_t);
    k_temporal_E<<<dim3(B_), dim3(576), 0, stream>>>(lhs_t, rhs_t, b_e, V_e, Ebuf);
    k_xTAt<<<dim3(N_ * C_ / 256, B_), b256, 0, stream>>>(x, Ebuf, xw);
    k_spatial_prep<<<dim3(B_ * N_ / 256), b256, 0, stream>>>(xw, W1, W2, W3, lhs_s, rhs_s);
    k_transpose_x<<<dim3(CT_ / 64, N_ / 64, B_), b256, 0, stream>>>(x, xT);   // xw dead
    k_sig<<<dim3(N_ / 256, N_ / 64, B_), b256, 0, stream>>>(lhs_s, rhs_s, b_s, sigA);
    // S0 GEMM: M=1024, Ncols=1024, K=1024; nwg=512 (%8==0)
    k_gemm256<<<dim3(B_ * 4 * 4), dim3(512), 0, stream>>>(
        sigA, N_, (long)N_ * N_, V_sb, N_, 0, Sb, N_, (long)N_ * N_, N_, 4, 4);
    k_softmax_S<<<dim3(N_ / 64, B_), b256, 0, stream>>>(Sb);
    k_yT<<<dim3(N_ / 256, T_, B_), b256, 0, stream>>>(xT, Theta, yT);          // sigA dead
    k_chebSt<<<dim3(N_ / 64, N_ / 64, B_), b256, 0, stream>>>(cheb, Sb, chebSt); // xT dead
    // stacked GEMM: M=1024, Ncols=1536, K=3072; nwg=768 (%8==0)
    k_gemm256<<<dim3(B_ * 4 * 6), dim3(512), 0, stream>>>(
        chebSt, KS_, (long)N_ * KS_, yT, KS_, (long)CT_ * KS_,
        gcn, CT_, (long)N_ * CT_, KS_, 6, 4);                                 // Sb dead
    k_final<<<dim3(N_ / 4, B_), b256, 0, stream>>>(x, gcn, wpack, tc_b, rc_b,
                                                   ln_g, ln_b, out);
}

// Round 5
// 1709.615 us; speedup vs baseline: 7.8619x; 1.1591x over previous
//
#include <hip/hip_runtime.h>

typedef __attribute__((ext_vector_type(8))) short short8;   // 8 bf16 (4 VGPRs)
typedef __attribute__((ext_vector_type(4))) float f32x4;

constexpr int B_ = 32;
constexpr int N_ = 1024;
constexpr int C_ = 64;
constexpr int T_ = 24;
constexpr int F_ = 64;
constexpr int CT_ = C_ * T_;     // 1536
constexpr int KS_ = 3072;        // stacked K = 3*1024

__device__ __forceinline__ float sigmoidf_(float x) {
    return 1.0f / (1.0f + __expf(-x));
}
__device__ __forceinline__ unsigned short f2b(float f) {   // RNE f32->bf16
    union { float f; unsigned u; } v; v.f = f;
    unsigned r = v.u + 0x7FFFu + ((v.u >> 16) & 1u);
    return (unsigned short)(r >> 16);
}
__device__ __forceinline__ float b2f(unsigned short h) {
    union { unsigned u; float f; } v; v.u = ((unsigned)h) << 16; return v.f;
}
__device__ __forceinline__ void gload_lds16(const unsigned short* g, unsigned short* l) {
    __builtin_amdgcn_global_load_lds(
        (const __attribute__((address_space(1))) unsigned int*)g,
        (__attribute__((address_space(3))) unsigned int*)l, 16, 0, 0);
}

// ---------------- temporal attention prep ----------------
__global__ void k_rhs_t(const float* __restrict__ x, const float* __restrict__ U3,
                        float* __restrict__ rhs_t) {
    int idx = blockIdx.x * 256 + threadIdx.x;
    if (idx >= B_ * N_ * T_) return;
    int t = idx % T_;
    int n = (idx / T_) % N_;
    int b = idx / (N_ * T_);
    const float* xp = x + ((size_t)(b * N_ + n)) * CT_ + t;
    float acc = 0.f;
#pragma unroll
    for (int c = 0; c < C_; ++c) acc += U3[c] * xp[c * T_];
    rhs_t[idx] = acc;
}

__global__ void k_lhs_partial(const float* __restrict__ x, const float* __restrict__ U1,
                              float* __restrict__ partial) {
    int b = blockIdx.y, chunk = blockIdx.x;
    int tid = threadIdx.x;
    float acc[6] = {0, 0, 0, 0, 0, 0};
    int n0 = chunk * 64;
    for (int nn = 0; nn < 64; ++nn) {
        int n = n0 + nn;
        float u = U1[n];
        const float* xp = x + ((size_t)(b * N_ + n)) * CT_;
#pragma unroll
        for (int e = 0; e < 6; ++e) acc[e] += u * xp[tid + e * 256];
    }
    float* pp = partial + ((size_t)(b * 16 + chunk)) * CT_;
#pragma unroll
    for (int e = 0; e < 6; ++e) pp[tid + e * 256] = acc[e];
}

__global__ void k_lhs_reduce(const float* __restrict__ partial, float* __restrict__ lhs_t0) {
    int idx = blockIdx.x * 256 + threadIdx.x;
    if (idx >= B_ * CT_) return;
    int b = idx / CT_, flat = idx % CT_;
    float acc = 0.f;
#pragma unroll
    for (int ch = 0; ch < 16; ++ch) acc += partial[((size_t)(b * 16 + ch)) * CT_ + flat];
    lhs_t0[idx] = acc;
}

__global__ void k_lhs_t(const float* __restrict__ lhs_t0, const float* __restrict__ U2,
                        float* __restrict__ lhs_t) {
    int idx = blockIdx.x * 256 + threadIdx.x;
    if (idx >= B_ * T_ * N_) return;
    int n2 = idx % N_;
    int t = (idx / N_) % T_;
    int b = idx / (T_ * N_);
    const float* l0 = lhs_t0 + (size_t)b * CT_;
    float acc = 0.f;
#pragma unroll
    for (int c = 0; c < C_; ++c) acc += l0[c * T_ + t] * U2[c * N_ + n2];
    lhs_t[idx] = acc;
}

__global__ void k_temporal_E(const float* __restrict__ lhs_t, const float* __restrict__ rhs_t,
                             const float* __restrict__ b_e, const float* __restrict__ V_e,
                             float* __restrict__ E) {
    int b = blockIdx.x;
    int tid = threadIdx.x;                               // 576 threads
    int i = tid / T_, u = tid % T_;
    __shared__ float sig[T_][T_];
    __shared__ float e0s[T_][T_];
    __shared__ float mcol[T_], scol[T_];
    const float* lt = lhs_t + (size_t)b * T_ * N_ + (size_t)i * N_;
    const float* rt = rhs_t + (size_t)b * N_ * T_ + u;
    float acc = 0.f;
    for (int n = 0; n < N_; ++n) acc += lt[n] * rt[(size_t)n * T_];
    sig[i][u] = sigmoidf_(acc + b_e[i * T_ + u]);
    __syncthreads();
    int j = u;
    float e0 = 0.f;
#pragma unroll
    for (int kk = 0; kk < T_; ++kk) e0 += sig[i][kk] * V_e[j * T_ + kk];
    e0s[i][j] = e0;
    __syncthreads();
    if (tid < T_) {
        float mx = -1e30f;
        for (int ii = 0; ii < T_; ++ii) mx = fmaxf(mx, e0s[ii][tid]);
        float s = 0.f;
        for (int ii = 0; ii < T_; ++ii) s += __expf(e0s[ii][tid] - mx);
        mcol[tid] = mx; scol[tid] = s;
    }
    __syncthreads();
    E[(size_t)b * T_ * T_ + i * T_ + j] = __expf(e0s[i][j] - mcol[j]) / scol[j];
}

__global__ void k_xTAt(const float* __restrict__ x, const float* __restrict__ E,
                       float* __restrict__ xw) {
    int b = blockIdx.y;
    int nc = blockIdx.x * 256 + threadIdx.x;
    __shared__ float Es[T_ * T_];
    for (int e = threadIdx.x; e < T_ * T_; e += 256) Es[e] = E[(size_t)b * T_ * T_ + e];
    __syncthreads();
    const float* xp = x + (size_t)b * N_ * CT_ + (size_t)nc * T_;
    float xv[T_];
#pragma unroll
    for (int t = 0; t < T_; ++t) xv[t] = xp[t];
    float* op = xw + (size_t)b * N_ * CT_ + (size_t)nc * T_;
#pragma unroll
    for (int u = 0; u < T_; ++u) {
        float acc = 0.f;
#pragma unroll
        for (int t = 0; t < T_; ++t) acc += xv[t] * Es[t * T_ + u];
        op[u] = acc;
    }
}

// ---------------- spatial attention prep ----------------
__global__ __launch_bounds__(256) void k_spatial_prep(const float* __restrict__ xw,
        const float* __restrict__ W1g, const float* __restrict__ W2,
        const float* __restrict__ W3g, float* __restrict__ lhs_s, float* __restrict__ rhs_s) {
    __shared__ float W2s[C_ * T_];
    __shared__ float W1s[T_];
    __shared__ float W3s[C_];
    int tid = threadIdx.x;
    for (int e = tid; e < C_ * T_; e += 256) W2s[e] = W2[e];
    if (tid < T_) W1s[tid] = W1g[tid];
    if (tid < C_) W3s[tid] = W3g[tid];
    __syncthreads();
    int idx = blockIdx.x * 256 + tid;
    int b = idx / N_, m = idx % N_;
    const float* xp = xw + (size_t)idx * CT_;
    float lacc[T_], racc[T_];
#pragma unroll
    for (int t = 0; t < T_; ++t) { lacc[t] = 0.f; racc[t] = 0.f; }
    for (int c = 0; c < C_; ++c) {
        float l0 = 0.f;
        float w3 = W3s[c];
        const float* xc = xp + c * T_;
#pragma unroll
        for (int t = 0; t < T_; ++t) {
            float v = xc[t];
            l0 += v * W1s[t];
            racc[t] += w3 * v;
        }
#pragma unroll
        for (int t2 = 0; t2 < T_; ++t2) lacc[t2] += l0 * W2s[c * T_ + t2];
    }
    float* lp = lhs_s + (size_t)idx * T_;
#pragma unroll
    for (int t = 0; t < T_; ++t) lp[t] = lacc[t];
#pragma unroll
    for (int t = 0; t < T_; ++t) rhs_s[((size_t)b * T_ + t) * N_ + m] = racc[t];
}

// ---------------- converters / builders ----------------
__global__ void k_cvt_vs(const float* __restrict__ v, unsigned short* __restrict__ o) {
    int i = blockIdx.x * 256 + threadIdx.x;
    o[i] = f2b(v[i]);
}

// Wcat[ft][k], k = sel*64+c: sel 0..2 -> tc_w taps, sel 3 -> rc_w.  bf16 [64][256]
__global__ void k_wcat(const float* __restrict__ tc_w, const float* __restrict__ rc_w,
                       unsigned short* __restrict__ Wcat) {
    int i = blockIdx.x * 256 + threadIdx.x;              // over 64*256
    if (i >= F_ * 256) return;
    int ft = i >> 8, k = i & 255;
    int sel = k >> 6, c = k & 63;
    float v = (sel < 3) ? tc_w[(ft * C_ + c) * 3 + sel] : rc_w[ft * C_ + c];
    Wcat[i] = f2b(v);
}

// xT[b][ct][m] (bf16) = x[b][m][ct]
__global__ __launch_bounds__(256) void k_transpose_x(const float* __restrict__ x,
                                                     unsigned short* __restrict__ xT) {
    __shared__ float tile[64][65];
    int b = blockIdx.z, m0 = blockIdx.y * 64, ct0 = blockIdx.x * 64;
    int tid = threadIdx.x;
#pragma unroll
    for (int e = 0; e < 16; ++e) {
        int idx = e * 256 + tid; int mm = idx >> 6, cc = idx & 63;
        tile[mm][cc] = x[((size_t)(b * N_ + m0 + mm)) * CT_ + ct0 + cc];
    }
    __syncthreads();
#pragma unroll
    for (int e = 0; e < 16; ++e) {
        int idx = e * 256 + tid; int rr = idx >> 6, mm = idx & 63;
        xT[((size_t)b * CT_ + ct0 + rr) * N_ + m0 + mm] = f2b(tile[mm][rr]);
    }
}

// sigA[b][i][k] (bf16) = sigmoid(dot24(lhs_s[b,i,:], rhs_s[b,:,k]) + b_s[i,k])
__global__ __launch_bounds__(256) void k_sig(const float* __restrict__ lhs_s,
        const float* __restrict__ rhs_s, const float* __restrict__ b_s,
        unsigned short* __restrict__ sigA) {
    int b = blockIdx.z, i0 = blockIdx.y * 64, k0 = blockIdx.x * 256;
    int tid = threadIdx.x;
    __shared__ float lh[64 * T_];
    __shared__ float rh[T_][256];
    for (int e = tid; e < 64 * T_; e += 256) lh[e] = lhs_s[((size_t)b * N_ + i0) * T_ + e];
#pragma unroll
    for (int t = 0; t < T_; ++t) rh[t][tid] = rhs_s[((size_t)b * T_ + t) * N_ + k0 + tid];
    __syncthreads();
    int kg = k0 + tid;
    for (int ii = 0; ii < 64; ++ii) {
        float acc = b_s[(size_t)(i0 + ii) * N_ + kg];
#pragma unroll
        for (int t = 0; t < T_; ++t) acc += lh[ii * T_ + t] * rh[t][tid];
        sigA[((size_t)b * N_ + i0 + ii) * N_ + kg] = f2b(sigmoidf_(acc));
    }
}

// yT[b][f*24+t][k*1024+m] (bf16) = sum_c Theta[k,c,f] * x[b,m,c,t]   (reads xT)
__global__ __launch_bounds__(256) void k_yT(const unsigned short* __restrict__ xT,
        const float* __restrict__ Theta, unsigned short* __restrict__ yT) {
    int b = blockIdx.z, t = blockIdx.y, m0 = blockIdx.x * 256;
    int tid = threadIdx.x;
    float xr[64];
#pragma unroll
    for (int c = 0; c < 64; ++c)
        xr[c] = b2f(xT[((size_t)b * CT_ + c * T_ + t) * N_ + m0 + tid]);
    for (int k = 0; k < 3; ++k) {
        float acc[64];
#pragma unroll
        for (int f = 0; f < 64; ++f) acc[f] = 0.f;
#pragma unroll 4
        for (int c = 0; c < 64; ++c) {
            float xc = xr[c];
            const float* th = Theta + ((size_t)k * 64 + c) * 64;   // uniform -> s_load
#pragma unroll
            for (int f = 0; f < 64; ++f) acc[f] = fmaf(th[f], xc, acc[f]);
        }
#pragma unroll
        for (int f = 0; f < 64; ++f)
            yT[((size_t)b * CT_ + f * T_ + t) * KS_ + k * N_ + m0 + tid] = f2b(acc[f]);
    }
}

// chebSt[b][i][k*1024+m] (bf16) = cheb[k][m][i] * S[b][m][i]
__global__ __launch_bounds__(256) void k_chebSt(const float* __restrict__ cheb,
        const float* __restrict__ S, unsigned short* __restrict__ cs) {
    int b = blockIdx.z, i0 = blockIdx.y * 64, m0 = blockIdx.x * 64;
    int tid = threadIdx.x;
    __shared__ float st[64][65];
    __shared__ float cb[64][65];
#pragma unroll
    for (int e = 0; e < 16; ++e) {
        int idx = e * 256 + tid; int mm = idx >> 6, ii = idx & 63;
        st[mm][ii] = S[((size_t)b * N_ + m0 + mm) * N_ + i0 + ii];
    }
    for (int k = 0; k < 3; ++k) {
        __syncthreads();
#pragma unroll
        for (int e = 0; e < 16; ++e) {
            int idx = e * 256 + tid; int mm = idx >> 6, ii = idx & 63;
            cb[mm][ii] = cheb[((size_t)k * N_ + m0 + mm) * N_ + i0 + ii];
        }
        __syncthreads();
#pragma unroll
        for (int e = 0; e < 16; ++e) {
            int idx = e * 256 + tid; int mm = idx & 63, ii = idx >> 6;
            cs[((size_t)b * N_ + i0 + ii) * KS_ + k * N_ + m0 + mm] =
                f2b(st[mm][ii] * cb[mm][ii]);
        }
    }
}

// ---------------- 256x256-tile MFMA GEMM: C[b] = A[b] * Bt[b]^T ----------------
__global__ __launch_bounds__(512, 2) void k_gemm256(
        const unsigned short* __restrict__ A, long lda, long sA,
        const unsigned short* __restrict__ Bt, long ldb, long sB,
        float* __restrict__ Cc, long ldc, long sC, int K, int nbx, int nby) {
    __shared__ __align__(16) unsigned short As[256 * 64];   // 32KB, 128B rows
    __shared__ __align__(16) unsigned short Bs[256 * 64];   // 32KB
    int tid = threadIdx.x;
    int lane = tid & 63, w = tid >> 6;
    int wy = w >> 2, wx = w & 3;                            // 2 x 4 waves -> 128x64 per wave

    int nwg = gridDim.x;
    int cpx = nwg >> 3;
    int logical = (blockIdx.x & 7) * cpx + (blockIdx.x >> 3);
    int tpb = nbx * nby;
    int b = logical / tpb;
    int tile = logical % tpb;
    int i0 = (tile / nbx) * 256;
    int j0 = (tile % nbx) * 256;

    const unsigned short* Ab = A + (size_t)b * sA + (size_t)i0 * lda;
    const unsigned short* Bb = Bt + (size_t)b * sB + (size_t)j0 * ldb;

    f32x4 acc[8][4];
#pragma unroll
    for (int mi = 0; mi < 8; ++mi)
#pragma unroll
        for (int ni = 0; ni < 4; ++ni) acc[mi][ni] = (f32x4){0.f, 0.f, 0.f, 0.f};

    for (int k0 = 0; k0 < K; k0 += 64) {
        if (k0) __syncthreads();
#pragma unroll
        for (int e = 0; e < 4; ++e) {                       // stage A (4 x 8KB)
            int chunk = e * 512 + tid;
            int row = chunk >> 3, slot = chunk & 7;
            int gslot = slot ^ (row & 7);
            gload_lds16(Ab + (size_t)row * lda + k0 + gslot * 8, &As[chunk * 8]);
        }
#pragma unroll
        for (int e = 0; e < 4; ++e) {                       // stage B
            int chunk = e * 512 + tid;
            int row = chunk >> 3, slot = chunk & 7;
            int gslot = slot ^ (row & 7);
            gload_lds16(Bb + (size_t)row * ldb + k0 + gslot * 8, &Bs[chunk * 8]);
        }
        __syncthreads();
#pragma unroll
        for (int kk = 0; kk < 2; ++kk) {
            short8 af[8], bf[4];
#pragma unroll
            for (int mi = 0; mi < 8; ++mi) {
                int r = wy * 128 + mi * 16 + (lane & 15);
                int slot = (kk * 4 + (lane >> 4)) ^ (r & 7);
                af[mi] = *(const short8*)&As[r * 64 + slot * 8];
            }
#pragma unroll
            for (int ni = 0; ni < 4; ++ni) {
                int r = wx * 64 + ni * 16 + (lane & 15);
                int slot = (kk * 4 + (lane >> 4)) ^ (r & 7);
                bf[ni] = *(const short8*)&Bs[r * 64 + slot * 8];
            }
#pragma unroll
            for (int mi = 0; mi < 8; ++mi)
#pragma unroll
                for (int ni = 0; ni < 4; ++ni)
                    acc[mi][ni] = __builtin_amdgcn_mfma_f32_16x16x32_bf16(
                        af[mi], bf[ni], acc[mi][ni], 0, 0, 0);
        }
    }
    float* Cb = Cc + (size_t)b * sC;
#pragma unroll
    for (int mi = 0; mi < 8; ++mi) {
#pragma unroll
        for (int r = 0; r < 4; ++r) {
            int i = i0 + wy * 128 + mi * 16 + (lane >> 4) * 4 + r;
            float* cp = Cb + (size_t)i * ldc + j0 + wx * 64 + (lane & 15);
#pragma unroll
            for (int ni = 0; ni < 4; ++ni) cp[ni * 16] = acc[mi][ni][r];
        }
    }
}

// softmax over axis m (rows) of S[b,m,i], per column i — in place
__global__ void k_softmax_S(float* __restrict__ S) {
    int b = blockIdx.y;
    int jj = threadIdx.x % 64;
    int ig = threadIdx.x / 64;
    int j = blockIdx.x * 64 + jj;
    __shared__ float redm[4][64], reds[4][64];
    float mx = -1e30f;
    for (int i = ig; i < N_; i += 4) mx = fmaxf(mx, S[((size_t)b * N_ + i) * N_ + j]);
    redm[ig][jj] = mx;
    __syncthreads();
    mx = fmaxf(fmaxf(redm[0][jj], redm[1][jj]), fmaxf(redm[2][jj], redm[3][jj]));
    float sm = 0.f;
    for (int i = ig; i < N_; i += 4) sm += __expf(S[((size_t)b * N_ + i) * N_ + j] - mx);
    reds[ig][jj] = sm;
    __syncthreads();
    float tot = reds[0][jj] + reds[1][jj] + reds[2][jj] + reds[3][jj];
    float inv = 1.f / tot;
    for (int i = ig; i < N_; i += 4) {
        size_t o = ((size_t)b * N_ + i) * N_ + j;
        S[o] = __expf(S[o] - mx) * inv;
    }
}

// ---------------- fused epilogue via MFMA ----------------
// out[(n,t), ft] = LN( relu( sum_{sel,c} A[(n,t)][sel*64+c] * Wcat[ft][sel*64+c] + tb[ft] ) )
// A: sel<3 -> relu(gcn)[n][c][t+sel-1] (zero-padded), sel=3 -> x[n][c][t].
// Block: 4 n-rows, 256 thr = 4 waves; M=96 rows (6 tiles), each wave owns one 16-ft N-tile.
// LDS: sgb [4][26][64] bf16 (t-major, pad rows tt=0/25) + xb [4][24][64] bf16, both
// XOR-swizzled on 16B slots (write & read same involution); reused as C[96][66] f32.
__global__ __launch_bounds__(256) void k_final(const float* __restrict__ x,
        const float* __restrict__ sgin, const unsigned short* __restrict__ Wcat,
        const float* __restrict__ tc_b, const float* __restrict__ rc_b,
        const float* __restrict__ ln_g, const float* __restrict__ ln_b,
        float* __restrict__ out) {
    int b = blockIdx.y;
    int n0 = blockIdx.x * 4;
    int tid = threadIdx.x;
    int lane = tid & 63, wv = tid >> 6;

    __shared__ __align__(16) char smem[25600];
    unsigned short* sgb = (unsigned short*)smem;            // [4][26][64]
    unsigned short* xb  = (unsigned short*)(smem + 13312);  // [4][24][64]
    float* Cl = (float*)smem;                               // [96][66] (after reuse barrier)
    __shared__ float tbs[64], gs[64], bbs[64];
    __shared__ float mus[96], rss[96];

    if (tid < 64) {
        tbs[tid] = tc_b[tid] + rc_b[tid];
        gs[tid] = ln_g[tid];
        bbs[tid] = ln_b[tid];
    }
    // zero-pad rows tt=0 and tt=25 of sgb
    for (int e = tid; e < 512; e += 256) {
        int nl = e >> 7, r = (e >> 6) & 1, c = e & 63;
        int tt = r ? 25 : 0;
        sgb[(nl * 26 + tt) * 64 + (((c >> 3) ^ (tt & 7)) << 3) + (c & 7)] = 0;
    }
    // stage data: e = ((nl*64 + c)*24 + tl), coalesced over tl
    size_t base = ((size_t)b * N_ + n0) * CT_;
#pragma unroll
    for (int i = 0; i < 24; ++i) {
        int e = i * 256 + tid;
        int nl = e / CT_;
        int rem = e - nl * CT_;
        int c = rem / 24;
        int tl = rem - c * 24;
        float sv = fmaxf(sgin[base + e], 0.f);
        float xv = x[base + e];
        int tt = tl + 1;
        sgb[(nl * 26 + tt) * 64 + (((c >> 3) ^ (tt & 7)) << 3) + (c & 7)] = f2b(sv);
        xb[(nl * 24 + tl) * 64 + (((c >> 3) ^ (tl & 7)) << 3) + (c & 7)] = f2b(xv);
    }

    // B-fragments from global Wcat (32KB, L2-hot): lane col = ft, kgroup = lane>>4
    int ft = wv * 16 + (lane & 15);
    int g4 = lane >> 4;
    short8 bfr[8];
#pragma unroll
    for (int ks = 0; ks < 8; ++ks)
        bfr[ks] = *(const short8*)&Wcat[ft * 256 + ks * 32 + g4 * 8];

    // per-M-tile row decomposition
    int rnl[6], rt[6];
#pragma unroll
    for (int mi = 0; mi < 6; ++mi) {
        int row = mi * 16 + (lane & 15);
        rnl[mi] = row / 24;
        rt[mi] = row - rnl[mi] * 24;
    }

    __syncthreads();

    f32x4 acc[6];
#pragma unroll
    for (int mi = 0; mi < 6; ++mi) acc[mi] = (f32x4){0.f, 0.f, 0.f, 0.f};
#pragma unroll
    for (int mi = 0; mi < 6; ++mi) {
        int nl = rnl[mi], t = rt[mi];
#pragma unroll
        for (int ks = 0; ks < 8; ++ks) {
            const int sel = ks >> 1;                       // 0,0,1,1,2,2,3,3
            int slot = (ks & 1) * 4 + g4;                  // 16B slot index (0..7)
            short8 af;
            if (sel < 3) {
                int tt = t + sel;
                af = *(const short8*)&sgb[(nl * 26 + tt) * 64 + ((slot ^ (tt & 7)) << 3)];
            } else {
                af = *(const short8*)&xb[(nl * 24 + t) * 64 + ((slot ^ (t & 7)) << 3)];
            }
            acc[mi] = __builtin_amdgcn_mfma_f32_16x16x32_bf16(af, bfr[ks], acc[mi], 0, 0, 0);
        }
    }

    __syncthreads();                                       // sgb/xb dead -> reuse as Cl
#pragma unroll
    for (int mi = 0; mi < 6; ++mi)
#pragma unroll
        for (int r = 0; r < 4; ++r)
            Cl[(mi * 16 + (lane >> 4) * 4 + r) * 66 + wv * 16 + (lane & 15)] = acc[mi][r];
    __syncthreads();

    if (tid < 96) {
        float s = 0.f, s2 = 0.f;
#pragma unroll
        for (int f = 0; f < 64; ++f) {
            float v = fmaxf(Cl[tid * 66 + f] + tbs[f], 0.f);
            s += v; s2 += v * v;
        }
        float mu = s * (1.f / 64.f);
        float var = s2 * (1.f / 64.f) - mu * mu;
        mus[tid] = mu;
        rss[tid] = rsqrtf(var + 1e-5f);
    }
    __syncthreads();

#pragma unroll
    for (int i = 0; i < 24; ++i) {
        int e = i * 256 + tid;                              // ((nl*64 + f)*24 + t)
        int nl = e / CT_;
        int rem = e - nl * CT_;
        int f = rem / 24;
        int t = rem - f * 24;
        int row = nl * 24 + t;
        float v = fmaxf(Cl[row * 66 + f] + tbs[f], 0.f);
        out[base + e] = (v - mus[row]) * rss[row] * gs[f] + bbs[f];
    }
}

extern "C" void kernel_launch(void* const* d_in, const int* in_sizes, int n_in,
                              void* d_out, int out_size, void* d_ws, size_t ws_size,
                              hipStream_t stream) {
    const float* x    = (const float*)d_in[0];
    const float* cheb = (const float*)d_in[1];
    const float* U1   = (const float*)d_in[2];
    const float* U2   = (const float*)d_in[3];
    const float* U3   = (const float*)d_in[4];
    const float* b_e  = (const float*)d_in[5];
    const float* V_e  = (const float*)d_in[6];
    const float* W1   = (const float*)d_in[7];
    const float* W2   = (const float*)d_in[8];
    const float* W3   = (const float*)d_in[9];
    const float* b_s  = (const float*)d_in[10];
    const float* V_s  = (const float*)d_in[11];
    const float* Theta= (const float*)d_in[12];
    const float* tc_w = (const float*)d_in[13];
    const float* tc_b = (const float*)d_in[14];
    const float* rc_w = (const float*)d_in[15];
    const float* rc_b = (const float*)d_in[16];
    const float* ln_g = (const float*)d_in[17];
    const float* ln_b = (const float*)d_in[18];
    float* out = (float*)d_out;

    char* base = (char*)d_ws;
    size_t o = 0;
    auto alloc = [&](size_t bytes) { size_t r = o; o += (bytes + 255) & ~(size_t)255; return r; };
    float* lhs_t   = (float*)(base + alloc((size_t)B_ * T_ * N_ * 4));
    float* rhs_t   = (float*)(base + alloc((size_t)B_ * N_ * T_ * 4));
    float* Ebuf    = (float*)(base + alloc((size_t)B_ * T_ * T_ * 4));
    float* partial = (float*)(base + alloc((size_t)B_ * 16 * CT_ * 4));
    float* lhs_t0  = (float*)(base + alloc((size_t)B_ * CT_ * 4));
    float* lhs_s   = (float*)(base + alloc((size_t)B_ * N_ * T_ * 4));
    float* rhs_s   = (float*)(base + alloc((size_t)B_ * T_ * N_ * 4));
    unsigned short* V_sb = (unsigned short*)(base + alloc((size_t)N_ * N_ * 2));
    unsigned short* Wcat = (unsigned short*)(base + alloc((size_t)F_ * 256 * 2));
    // RegA: xw (f32) -> xT (bf16) -> chebSt (bf16)   [disjoint lifetimes]
    size_t regA = alloc((size_t)B_ * N_ * KS_ * 2);
    // RegB: sigA (bf16) -> yT (bf16)                 [disjoint lifetimes]
    size_t regB = alloc((size_t)B_ * CT_ * KS_ * 2);
    float*          xw     = (float*)(base + regA);
    unsigned short* xT     = (unsigned short*)(base + regA);
    unsigned short* chebSt = (unsigned short*)(base + regA);
    unsigned short* sigA   = (unsigned short*)(base + regB);
    unsigned short* yT     = (unsigned short*)(base + regB);
    float* Sb  = out;        // S scores live in d_out until the stacked GEMM overwrites
    float* gcn = out;

    dim3 b256(256);
    k_cvt_vs<<<dim3(N_ * N_ / 256), b256, 0, stream>>>(V_s, V_sb);
    k_wcat<<<dim3((F_ * 256 + 255) / 256), b256, 0, stream>>>(tc_w, rc_w, Wcat);
    k_rhs_t<<<dim3((B_ * N_ * T_) / 256), b256, 0, stream>>>(x, U3, rhs_t);
    k_lhs_partial<<<dim3(16, B_), b256, 0, stream>>>(x, U1, partial);
    k_lhs_reduce<<<dim3((B_ * CT_) / 256), b256, 0, stream>>>(partial, lhs_t0);
    k_lhs_t<<<dim3((B_ * T_ * N_) / 256), b256, 0, stream>>>(lhs_t0, U2, lhs_t);
    k_temporal_E<<<dim3(B_), dim3(576), 0, stream>>>(lhs_t, rhs_t, b_e, V_e, Ebuf);
    k_xTAt<<<dim3(N_ * C_ / 256, B_), b256, 0, stream>>>(x, Ebuf, xw);
    k_spatial_prep<<<dim3(B_ * N_ / 256), b256, 0, stream>>>(xw, W1, W2, W3, lhs_s, rhs_s);
    k_transpose_x<<<dim3(CT_ / 64, N_ / 64, B_), b256, 0, stream>>>(x, xT);   // xw dead
    k_sig<<<dim3(N_ / 256, N_ / 64, B_), b256, 0, stream>>>(lhs_s, rhs_s, b_s, sigA);
    // S0 GEMM: M=1024, Ncols=1024, K=1024; nwg=512 (%8==0)
    k_gemm256<<<dim3(B_ * 4 * 4), dim3(512), 0, stream>>>(
        sigA, N_, (long)N_ * N_, V_sb, N_, 0, Sb, N_, (long)N_ * N_, N_, 4, 4);
    k_softmax_S<<<dim3(N_ / 64, B_), b256, 0, stream>>>(Sb);
    k_yT<<<dim3(N_ / 256, T_, B_), b256, 0, stream>>>(xT, Theta, yT);          // sigA dead
    k_chebSt<<<dim3(N_ / 64, N_ / 64, B_), b256, 0, stream>>>(cheb, Sb, chebSt); // xT dead
    // stacked GEMM: M=1024, Ncols=1536, K=3072; nwg=768 (%8==0)
    k_gemm256<<<dim3(B_ * 4 * 6), dim3(512), 0, stream>>>(
        chebSt, KS_, (long)N_ * KS_, yT, KS_, (long)CT_ * KS_,
        gcn, CT_, (long)N_ * CT_, KS_, 6, 4);                                 // Sb dead
    k_final<<<dim3(N_ / 4, B_), b256, 0, stream>>>(x, gcn, Wcat, tc_b, rc_b,
                                                   ln_g, ln_b, out);
}

// Round 6
// 1622.225 us; speedup vs baseline: 8.2854x; 1.0539x over previous
//
#include <hip/hip_runtime.h>

typedef __attribute__((ext_vector_type(8))) short short8;   // 8 bf16 (4 VGPRs)
typedef __attribute__((ext_vector_type(4))) float f32x4;

constexpr int B_ = 32;
constexpr int N_ = 1024;
constexpr int C_ = 64;
constexpr int T_ = 24;
constexpr int F_ = 64;
constexpr int CT_ = C_ * T_;     // 1536
constexpr int KS_ = 3072;        // stacked K = 3*1024

__device__ __forceinline__ float sigmoidf_(float x) {
    return 1.0f / (1.0f + __expf(-x));
}
__device__ __forceinline__ unsigned short f2b(float f) {   // RNE f32->bf16
    union { float f; unsigned u; } v; v.f = f;
    unsigned r = v.u + 0x7FFFu + ((v.u >> 16) & 1u);
    return (unsigned short)(r >> 16);
}
__device__ __forceinline__ float b2f(unsigned short h) {
    union { unsigned u; float f; } v; v.u = ((unsigned)h) << 16; return v.f;
}
__device__ __forceinline__ void gload_lds16(const unsigned short* g, unsigned short* l) {
    __builtin_amdgcn_global_load_lds(
        (const __attribute__((address_space(1))) unsigned int*)g,
        (__attribute__((address_space(3))) unsigned int*)l, 16, 0, 0);
}

// ---------------- temporal attention prep ----------------
__global__ void k_rhs_t(const float* __restrict__ x, const float* __restrict__ U3,
                        float* __restrict__ rhs_t) {
    int idx = blockIdx.x * 256 + threadIdx.x;
    if (idx >= B_ * N_ * T_) return;
    int t = idx % T_;
    int n = (idx / T_) % N_;
    int b = idx / (N_ * T_);
    const float* xp = x + ((size_t)(b * N_ + n)) * CT_ + t;
    float acc = 0.f;
#pragma unroll
    for (int c = 0; c < C_; ++c) acc += U3[c] * xp[c * T_];
    rhs_t[idx] = acc;
}

__global__ void k_lhs_partial(const float* __restrict__ x, const float* __restrict__ U1,
                              float* __restrict__ partial) {
    int b = blockIdx.y, chunk = blockIdx.x;
    int tid = threadIdx.x;
    float acc[6] = {0, 0, 0, 0, 0, 0};
    int n0 = chunk * 64;
    for (int nn = 0; nn < 64; ++nn) {
        int n = n0 + nn;
        float u = U1[n];
        const float* xp = x + ((size_t)(b * N_ + n)) * CT_;
#pragma unroll
        for (int e = 0; e < 6; ++e) acc[e] += u * xp[tid + e * 256];
    }
    float* pp = partial + ((size_t)(b * 16 + chunk)) * CT_;
#pragma unroll
    for (int e = 0; e < 6; ++e) pp[tid + e * 256] = acc[e];
}

__global__ void k_lhs_reduce(const float* __restrict__ partial, float* __restrict__ lhs_t0) {
    int idx = blockIdx.x * 256 + threadIdx.x;
    if (idx >= B_ * CT_) return;
    int b = idx / CT_, flat = idx % CT_;
    float acc = 0.f;
#pragma unroll
    for (int ch = 0; ch < 16; ++ch) acc += partial[((size_t)(b * 16 + ch)) * CT_ + flat];
    lhs_t0[idx] = acc;
}

__global__ void k_lhs_t(const float* __restrict__ lhs_t0, const float* __restrict__ U2,
                        float* __restrict__ lhs_t) {
    int idx = blockIdx.x * 256 + threadIdx.x;
    if (idx >= B_ * T_ * N_) return;
    int n2 = idx % N_;
    int t = (idx / N_) % T_;
    int b = idx / (T_ * N_);
    const float* l0 = lhs_t0 + (size_t)b * CT_;
    float acc = 0.f;
#pragma unroll
    for (int c = 0; c < C_; ++c) acc += l0[c * T_ + t] * U2[c * N_ + n2];
    lhs_t[idx] = acc;
}

__global__ void k_temporal_E(const float* __restrict__ lhs_t, const float* __restrict__ rhs_t,
                             const float* __restrict__ b_e, const float* __restrict__ V_e,
                             float* __restrict__ E) {
    int b = blockIdx.x;
    int tid = threadIdx.x;                               // 576 threads
    int i = tid / T_, u = tid % T_;
    __shared__ float sig[T_][T_];
    __shared__ float e0s[T_][T_];
    __shared__ float mcol[T_], scol[T_];
    const float* lt = lhs_t + (size_t)b * T_ * N_ + (size_t)i * N_;
    const float* rt = rhs_t + (size_t)b * N_ * T_ + u;
    float acc = 0.f;
    for (int n = 0; n < N_; ++n) acc += lt[n] * rt[(size_t)n * T_];
    sig[i][u] = sigmoidf_(acc + b_e[i * T_ + u]);
    __syncthreads();
    int j = u;
    float e0 = 0.f;
#pragma unroll
    for (int kk = 0; kk < T_; ++kk) e0 += sig[i][kk] * V_e[j * T_ + kk];
    e0s[i][j] = e0;
    __syncthreads();
    if (tid < T_) {
        float mx = -1e30f;
        for (int ii = 0; ii < T_; ++ii) mx = fmaxf(mx, e0s[ii][tid]);
        float s = 0.f;
        for (int ii = 0; ii < T_; ++ii) s += __expf(e0s[ii][tid] - mx);
        mcol[tid] = mx; scol[tid] = s;
    }
    __syncthreads();
    E[(size_t)b * T_ * T_ + i * T_ + j] = __expf(e0s[i][j] - mcol[j]) / scol[j];
}

__global__ void k_xTAt(const float* __restrict__ x, const float* __restrict__ E,
                       float* __restrict__ xw) {
    int b = blockIdx.y;
    int nc = blockIdx.x * 256 + threadIdx.x;
    __shared__ float Es[T_ * T_];
    for (int e = threadIdx.x; e < T_ * T_; e += 256) Es[e] = E[(size_t)b * T_ * T_ + e];
    __syncthreads();
    const float* xp = x + (size_t)b * N_ * CT_ + (size_t)nc * T_;
    float xv[T_];
#pragma unroll
    for (int t = 0; t < T_; ++t) xv[t] = xp[t];
    float* op = xw + (size_t)b * N_ * CT_ + (size_t)nc * T_;
#pragma unroll
    for (int u = 0; u < T_; ++u) {
        float acc = 0.f;
#pragma unroll
        for (int t = 0; t < T_; ++t) acc += xv[t] * Es[t * T_ + u];
        op[u] = acc;
    }
}

// ---------------- spatial attention prep ----------------
__global__ __launch_bounds__(256) void k_spatial_prep(const float* __restrict__ xw,
        const float* __restrict__ W1g, const float* __restrict__ W2,
        const float* __restrict__ W3g, float* __restrict__ lhs_s, float* __restrict__ rhs_s) {
    __shared__ float W2s[C_ * T_];
    __shared__ float W1s[T_];
    __shared__ float W3s[C_];
    int tid = threadIdx.x;
    for (int e = tid; e < C_ * T_; e += 256) W2s[e] = W2[e];
    if (tid < T_) W1s[tid] = W1g[tid];
    if (tid < C_) W3s[tid] = W3g[tid];
    __syncthreads();
    int idx = blockIdx.x * 256 + tid;
    int b = idx / N_, m = idx % N_;
    const float* xp = xw + (size_t)idx * CT_;
    float lacc[T_], racc[T_];
#pragma unroll
    for (int t = 0; t < T_; ++t) { lacc[t] = 0.f; racc[t] = 0.f; }
    for (int c = 0; c < C_; ++c) {
        float l0 = 0.f;
        float w3 = W3s[c];
        const float* xc = xp + c * T_;
#pragma unroll
        for (int t = 0; t < T_; ++t) {
            float v = xc[t];
            l0 += v * W1s[t];
            racc[t] += w3 * v;
        }
#pragma unroll
        for (int t2 = 0; t2 < T_; ++t2) lacc[t2] += l0 * W2s[c * T_ + t2];
    }
    float* lp = lhs_s + (size_t)idx * T_;
#pragma unroll
    for (int t = 0; t < T_; ++t) lp[t] = lacc[t];
#pragma unroll
    for (int t = 0; t < T_; ++t) rhs_s[((size_t)b * T_ + t) * N_ + m] = racc[t];
}

// ---------------- converters / builders ----------------
__global__ void k_cvt_vs(const float* __restrict__ v, unsigned short* __restrict__ o) {
    int i = blockIdx.x * 256 + threadIdx.x;
    o[i] = f2b(v[i]);
}

// Wcat[ft][k], k = sel*64+c: sel 0..2 -> tc_w taps, sel 3 -> rc_w.  bf16 [64][256]
__global__ void k_wcat(const float* __restrict__ tc_w, const float* __restrict__ rc_w,
                       unsigned short* __restrict__ Wcat) {
    int i = blockIdx.x * 256 + threadIdx.x;              // over 64*256
    if (i >= F_ * 256) return;
    int ft = i >> 8, k = i & 255;
    int sel = k >> 6, c = k & 63;
    float v = (sel < 3) ? tc_w[(ft * C_ + c) * 3 + sel] : rc_w[ft * C_ + c];
    Wcat[i] = f2b(v);
}

// xT[b][ct][m] (bf16) = x[b][m][ct]
__global__ __launch_bounds__(256) void k_transpose_x(const float* __restrict__ x,
                                                     unsigned short* __restrict__ xT) {
    __shared__ float tile[64][65];
    int b = blockIdx.z, m0 = blockIdx.y * 64, ct0 = blockIdx.x * 64;
    int tid = threadIdx.x;
#pragma unroll
    for (int e = 0; e < 16; ++e) {
        int idx = e * 256 + tid; int mm = idx >> 6, cc = idx & 63;
        tile[mm][cc] = x[((size_t)(b * N_ + m0 + mm)) * CT_ + ct0 + cc];
    }
    __syncthreads();
#pragma unroll
    for (int e = 0; e < 16; ++e) {
        int idx = e * 256 + tid; int rr = idx >> 6, mm = idx & 63;
        xT[((size_t)b * CT_ + ct0 + rr) * N_ + m0 + mm] = f2b(tile[mm][rr]);
    }
}

// sigA[b][i][k] (bf16) = sigmoid(dot24(lhs_s[b,i,:], rhs_s[b,:,k]) + b_s[i,k])
__global__ __launch_bounds__(256) void k_sig(const float* __restrict__ lhs_s,
        const float* __restrict__ rhs_s, const float* __restrict__ b_s,
        unsigned short* __restrict__ sigA) {
    int b = blockIdx.z, i0 = blockIdx.y * 64, k0 = blockIdx.x * 256;
    int tid = threadIdx.x;
    __shared__ float lh[64 * T_];
    __shared__ float rh[T_][256];
    for (int e = tid; e < 64 * T_; e += 256) lh[e] = lhs_s[((size_t)b * N_ + i0) * T_ + e];
#pragma unroll
    for (int t = 0; t < T_; ++t) rh[t][tid] = rhs_s[((size_t)b * T_ + t) * N_ + k0 + tid];
    __syncthreads();
    int kg = k0 + tid;
    for (int ii = 0; ii < 64; ++ii) {
        float acc = b_s[(size_t)(i0 + ii) * N_ + kg];
#pragma unroll
        for (int t = 0; t < T_; ++t) acc += lh[ii * T_ + t] * rh[t][tid];
        sigA[((size_t)b * N_ + i0 + ii) * N_ + kg] = f2b(sigmoidf_(acc));
    }
}

// yT[b][f*24+t][k*1024+m] (bf16) = sum_c Theta[k,c,f] * x[b,m,c,t]   (reads xT)
__global__ __launch_bounds__(256) void k_yT(const unsigned short* __restrict__ xT,
        const float* __restrict__ Theta, unsigned short* __restrict__ yT) {
    int b = blockIdx.z, t = blockIdx.y, m0 = blockIdx.x * 256;
    int tid = threadIdx.x;
    float xr[64];
#pragma unroll
    for (int c = 0; c < 64; ++c)
        xr[c] = b2f(xT[((size_t)b * CT_ + c * T_ + t) * N_ + m0 + tid]);
    for (int k = 0; k < 3; ++k) {
        float acc[64];
#pragma unroll
        for (int f = 0; f < 64; ++f) acc[f] = 0.f;
#pragma unroll 4
        for (int c = 0; c < 64; ++c) {
            float xc = xr[c];
            const float* th = Theta + ((size_t)k * 64 + c) * 64;   // uniform -> s_load
#pragma unroll
            for (int f = 0; f < 64; ++f) acc[f] = fmaf(th[f], xc, acc[f]);
        }
#pragma unroll
        for (int f = 0; f < 64; ++f)
            yT[((size_t)b * CT_ + f * T_ + t) * KS_ + k * N_ + m0 + tid] = f2b(acc[f]);
    }
}

// chebSt[b][i][k*1024+m] (bf16) = cheb[k][m][i] * S[b][m][i]
__global__ __launch_bounds__(256) void k_chebSt(const float* __restrict__ cheb,
        const float* __restrict__ S, unsigned short* __restrict__ cs) {
    int b = blockIdx.z, i0 = blockIdx.y * 64, m0 = blockIdx.x * 64;
    int tid = threadIdx.x;
    __shared__ float st[64][65];
    __shared__ float cb[64][65];
#pragma unroll
    for (int e = 0; e < 16; ++e) {
        int idx = e * 256 + tid; int mm = idx >> 6, ii = idx & 63;
        st[mm][ii] = S[((size_t)b * N_ + m0 + mm) * N_ + i0 + ii];
    }
    for (int k = 0; k < 3; ++k) {
        __syncthreads();
#pragma unroll
        for (int e = 0; e < 16; ++e) {
            int idx = e * 256 + tid; int mm = idx >> 6, ii = idx & 63;
            cb[mm][ii] = cheb[((size_t)k * N_ + m0 + mm) * N_ + i0 + ii];
        }
        __syncthreads();
#pragma unroll
        for (int e = 0; e < 16; ++e) {
            int idx = e * 256 + tid; int mm = idx & 63, ii = idx >> 6;
            cs[((size_t)b * N_ + i0 + ii) * KS_ + k * N_ + m0 + mm] =
                f2b(st[mm][ii] * cb[mm][ii]);
        }
    }
}

// ---------------- 256x256-tile MFMA GEMM, counted-vmcnt double-buffer ----------------
// C[b] = A[b] * Bt[b]^T.  LDS: 2 x 64KB K-tile buffers (128 KiB, 1 block/CU).
// Loop: ds_read kk0 -> MFMA kk0 -> ds_read kk1 -> lgkm(0)+bar -> STAGE(kt+2 into
// just-read buffer) -> MFMA kk1 -> vmcnt(8) (counted: kt+1 retired, kt+2 in flight)
// -> bar.  Raw s_barrier (no implicit vmcnt drain); T2 swizzle + XCD swizzle as before.
__global__ __launch_bounds__(512, 2) void k_gemm256(
        const unsigned short* __restrict__ A, long lda, long sA,
        const unsigned short* __restrict__ Bt, long ldb, long sB,
        float* __restrict__ Cc, long ldc, long sC, int K, int nbx, int nby) {
    __shared__ __align__(16) unsigned short As[2][256 * 64];   // 2 x 32KB
    __shared__ __align__(16) unsigned short Bs[2][256 * 64];   // 2 x 32KB
    int tid = threadIdx.x;
    int lane = tid & 63, w = tid >> 6;
    int wy = w >> 2, wx = w & 3;                            // 2 x 4 waves -> 128x64 per wave

    int nwg = gridDim.x;
    int cpx = nwg >> 3;
    int logical = (blockIdx.x & 7) * cpx + (blockIdx.x >> 3);
    int tpb = nbx * nby;
    int b = logical / tpb;
    int tile = logical % tpb;
    int i0 = (tile / nbx) * 256;
    int j0 = (tile % nbx) * 256;

    const unsigned short* Ab = A + (size_t)b * sA + (size_t)i0 * lda;
    const unsigned short* Bb = Bt + (size_t)b * sB + (size_t)j0 * ldb;

    // stage K-tile kt (4+4 gload_lds per thread) into buffer d
    auto STAGE = [&](int kt, int d) {
        int kof = kt << 6;
#pragma unroll
        for (int e = 0; e < 4; ++e) {
            int chunk = e * 512 + tid;
            int row = chunk >> 3, slot = chunk & 7;
            int gslot = slot ^ (row & 7);                   // inverse swizzle on source
            gload_lds16(Ab + (size_t)row * lda + kof + gslot * 8, &As[d][chunk * 8]);
        }
#pragma unroll
        for (int e = 0; e < 4; ++e) {
            int chunk = e * 512 + tid;
            int row = chunk >> 3, slot = chunk & 7;
            int gslot = slot ^ (row & 7);
            gload_lds16(Bb + (size_t)row * ldb + kof + gslot * 8, &Bs[d][chunk * 8]);
        }
    };

    f32x4 acc[8][4];
#pragma unroll
    for (int mi = 0; mi < 8; ++mi)
#pragma unroll
        for (int ni = 0; ni < 4; ++ni) acc[mi][ni] = (f32x4){0.f, 0.f, 0.f, 0.f};

    int nt = K >> 6;                                        // >= 2 for all our shapes
    STAGE(0, 0);
    STAGE(1, 1);
    asm volatile("s_waitcnt vmcnt(8)" ::: "memory");        // K-tile 0 resident
    __builtin_amdgcn_s_barrier();
    __builtin_amdgcn_sched_barrier(0);

    for (int kt = 0; kt < nt; ++kt) {
        int cur = kt & 1;
        const unsigned short* Asb = As[cur];
        const unsigned short* Bsb = Bs[cur];
        short8 af0[8], bf0[4], af1[8], bf1[4];
        // kk = 0 fragments
#pragma unroll
        for (int mi = 0; mi < 8; ++mi) {
            int r = wy * 128 + mi * 16 + (lane & 15);
            int slot = (lane >> 4) ^ (r & 7);
            af0[mi] = *(const short8*)&Asb[r * 64 + slot * 8];
        }
#pragma unroll
        for (int ni = 0; ni < 4; ++ni) {
            int r = wx * 64 + ni * 16 + (lane & 15);
            int slot = (lane >> 4) ^ (r & 7);
            bf0[ni] = *(const short8*)&Bsb[r * 64 + slot * 8];
        }
        __builtin_amdgcn_s_setprio(1);
#pragma unroll
        for (int mi = 0; mi < 8; ++mi)
#pragma unroll
            for (int ni = 0; ni < 4; ++ni)
                acc[mi][ni] = __builtin_amdgcn_mfma_f32_16x16x32_bf16(
                    af0[mi], bf0[ni], acc[mi][ni], 0, 0, 0);
        __builtin_amdgcn_s_setprio(0);
        // kk = 1 fragments
#pragma unroll
        for (int mi = 0; mi < 8; ++mi) {
            int r = wy * 128 + mi * 16 + (lane & 15);
            int slot = (4 + (lane >> 4)) ^ (r & 7);
            af1[mi] = *(const short8*)&Asb[r * 64 + slot * 8];
        }
#pragma unroll
        for (int ni = 0; ni < 4; ++ni) {
            int r = wx * 64 + ni * 16 + (lane & 15);
            int slot = (4 + (lane >> 4)) ^ (r & 7);
            bf1[ni] = *(const short8*)&Bsb[r * 64 + slot * 8];
        }
        asm volatile("s_waitcnt lgkmcnt(0)" ::: "memory");  // all my LDS reads retired
        __builtin_amdgcn_sched_barrier(0);
        __builtin_amdgcn_s_barrier();                       // all waves done with buf[cur]
        __builtin_amdgcn_sched_barrier(0);
        if (kt + 2 < nt) STAGE(kt + 2, cur);                // overwrite freed buffer
        __builtin_amdgcn_sched_barrier(0);
        __builtin_amdgcn_s_setprio(1);
#pragma unroll
        for (int mi = 0; mi < 8; ++mi)
#pragma unroll
            for (int ni = 0; ni < 4; ++ni)
                acc[mi][ni] = __builtin_amdgcn_mfma_f32_16x16x32_bf16(
                    af1[mi], bf1[ni], acc[mi][ni], 0, 0, 0);
        __builtin_amdgcn_s_setprio(0);
        // counted: allow the 8 loads just issued (kt+2) to remain in flight;
        // guarantees kt+1's 8 loads (issued one iteration ago) have retired.
        asm volatile("s_waitcnt vmcnt(8)" ::: "memory");
        __builtin_amdgcn_s_barrier();
        __builtin_amdgcn_sched_barrier(0);
    }

    float* Cb = Cc + (size_t)b * sC;
#pragma unroll
    for (int mi = 0; mi < 8; ++mi) {
#pragma unroll
        for (int r = 0; r < 4; ++r) {
            int i = i0 + wy * 128 + mi * 16 + (lane >> 4) * 4 + r;
            float* cp = Cb + (size_t)i * ldc + j0 + wx * 64 + (lane & 15);
#pragma unroll
            for (int ni = 0; ni < 4; ++ni) cp[ni * 16] = acc[mi][ni][r];
        }
    }
}

// softmax over axis m (rows) of S[b,m,i], per column i — in place
__global__ void k_softmax_S(float* __restrict__ S) {
    int b = blockIdx.y;
    int jj = threadIdx.x % 64;
    int ig = threadIdx.x / 64;
    int j = blockIdx.x * 64 + jj;
    __shared__ float redm[4][64], reds[4][64];
    float mx = -1e30f;
    for (int i = ig; i < N_; i += 4) mx = fmaxf(mx, S[((size_t)b * N_ + i) * N_ + j]);
    redm[ig][jj] = mx;
    __syncthreads();
    mx = fmaxf(fmaxf(redm[0][jj], redm[1][jj]), fmaxf(redm[2][jj], redm[3][jj]));
    float sm = 0.f;
    for (int i = ig; i < N_; i += 4) sm += __expf(S[((size_t)b * N_ + i) * N_ + j] - mx);
    reds[ig][jj] = sm;
    __syncthreads();
    float tot = reds[0][jj] + reds[1][jj] + reds[2][jj] + reds[3][jj];
    float inv = 1.f / tot;
    for (int i = ig; i < N_; i += 4) {
        size_t o = ((size_t)b * N_ + i) * N_ + j;
        S[o] = __expf(S[o] - mx) * inv;
    }
}

// ---------------- fused epilogue via MFMA (unchanged) ----------------
__global__ __launch_bounds__(256) void k_final(const float* __restrict__ x,
        const float* __restrict__ sgin, const unsigned short* __restrict__ Wcat,
        const float* __restrict__ tc_b, const float* __restrict__ rc_b,
        const float* __restrict__ ln_g, const float* __restrict__ ln_b,
        float* __restrict__ out) {
    int b = blockIdx.y;
    int n0 = blockIdx.x * 4;
    int tid = threadIdx.x;
    int lane = tid & 63, wv = tid >> 6;

    __shared__ __align__(16) char smem[25600];
    unsigned short* sgb = (unsigned short*)smem;            // [4][26][64]
    unsigned short* xb  = (unsigned short*)(smem + 13312);  // [4][24][64]
    float* Cl = (float*)smem;                               // [96][66] (after reuse barrier)
    __shared__ float tbs[64], gs[64], bbs[64];
    __shared__ float mus[96], rss[96];

    if (tid < 64) {
        tbs[tid] = tc_b[tid] + rc_b[tid];
        gs[tid] = ln_g[tid];
        bbs[tid] = ln_b[tid];
    }
    for (int e = tid; e < 512; e += 256) {
        int nl = e >> 7, r = (e >> 6) & 1, c = e & 63;
        int tt = r ? 25 : 0;
        sgb[(nl * 26 + tt) * 64 + (((c >> 3) ^ (tt & 7)) << 3) + (c & 7)] = 0;
    }
    size_t base = ((size_t)b * N_ + n0) * CT_;
#pragma unroll
    for (int i = 0; i < 24; ++i) {
        int e = i * 256 + tid;
        int nl = e / CT_;
        int rem = e - nl * CT_;
        int c = rem / 24;
        int tl = rem - c * 24;
        float sv = fmaxf(sgin[base + e], 0.f);
        float xv = x[base + e];
        int tt = tl + 1;
        sgb[(nl * 26 + tt) * 64 + (((c >> 3) ^ (tt & 7)) << 3) + (c & 7)] = f2b(sv);
        xb[(nl * 24 + tl) * 64 + (((c >> 3) ^ (tl & 7)) << 3) + (c & 7)] = f2b(xv);
    }

    int ft = wv * 16 + (lane & 15);
    int g4 = lane >> 4;
    short8 bfr[8];
#pragma unroll
    for (int ks = 0; ks < 8; ++ks)
        bfr[ks] = *(const short8*)&Wcat[ft * 256 + ks * 32 + g4 * 8];

    int rnl[6], rt[6];
#pragma unroll
    for (int mi = 0; mi < 6; ++mi) {
        int row = mi * 16 + (lane & 15);
        rnl[mi] = row / 24;
        rt[mi] = row - rnl[mi] * 24;
    }

    __syncthreads();

    f32x4 acc[6];
#pragma unroll
    for (int mi = 0; mi < 6; ++mi) acc[mi] = (f32x4){0.f, 0.f, 0.f, 0.f};
#pragma unroll
    for (int mi = 0; mi < 6; ++mi) {
        int nl = rnl[mi], t = rt[mi];
#pragma unroll
        for (int ks = 0; ks < 8; ++ks) {
            const int sel = ks >> 1;
            int slot = (ks & 1) * 4 + g4;
            short8 af;
            if (sel < 3) {
                int tt = t + sel;
                af = *(const short8*)&sgb[(nl * 26 + tt) * 64 + ((slot ^ (tt & 7)) << 3)];
            } else {
                af = *(const short8*)&xb[(nl * 24 + t) * 64 + ((slot ^ (t & 7)) << 3)];
            }
            acc[mi] = __builtin_amdgcn_mfma_f32_16x16x32_bf16(af, bfr[ks], acc[mi], 0, 0, 0);
        }
    }

    __syncthreads();
#pragma unroll
    for (int mi = 0; mi < 6; ++mi)
#pragma unroll
        for (int r = 0; r < 4; ++r)
            Cl[(mi * 16 + (lane >> 4) * 4 + r) * 66 + wv * 16 + (lane & 15)] = acc[mi][r];
    __syncthreads();

    if (tid < 96) {
        float s = 0.f, s2 = 0.f;
#pragma unroll
        for (int f = 0; f < 64; ++f) {
            float v = fmaxf(Cl[tid * 66 + f] + tbs[f], 0.f);
            s += v; s2 += v * v;
        }
        float mu = s * (1.f / 64.f);
        float var = s2 * (1.f / 64.f) - mu * mu;
        mus[tid] = mu;
        rss[tid] = rsqrtf(var + 1e-5f);
    }
    __syncthreads();

#pragma unroll
    for (int i = 0; i < 24; ++i) {
        int e = i * 256 + tid;
        int nl = e / CT_;
        int rem = e - nl * CT_;
        int f = rem / 24;
        int t = rem - f * 24;
        int row = nl * 24 + t;
        float v = fmaxf(Cl[row * 66 + f] + tbs[f], 0.f);
        out[base + e] = (v - mus[row]) * rss[row] * gs[f] + bbs[f];
    }
}

extern "C" void kernel_launch(void* const* d_in, const int* in_sizes, int n_in,
                              void* d_out, int out_size, void* d_ws, size_t ws_size,
                              hipStream_t stream) {
    const float* x    = (const float*)d_in[0];
    const float* cheb = (const float*)d_in[1];
    const float* U1   = (const float*)d_in[2];
    const float* U2   = (const float*)d_in[3];
    const float* U3   = (const float*)d_in[4];
    const float* b_e  = (const float*)d_in[5];
    const float* V_e  = (const float*)d_in[6];
    const float* W1   = (const float*)d_in[7];
    const float* W2   = (const float*)d_in[8];
    const float* W3   = (const float*)d_in[9];
    const float* b_s  = (const float*)d_in[10];
    const float* V_s  = (const float*)d_in[11];
    const float* Theta= (const float*)d_in[12];
    const float* tc_w = (const float*)d_in[13];
    const float* tc_b = (const float*)d_in[14];
    const float* rc_w = (const float*)d_in[15];
    const float* rc_b = (const float*)d_in[16];
    const float* ln_g = (const float*)d_in[17];
    const float* ln_b = (const float*)d_in[18];
    float* out = (float*)d_out;

    char* base = (char*)d_ws;
    size_t o = 0;
    auto alloc = [&](size_t bytes) { size_t r = o; o += (bytes + 255) & ~(size_t)255; return r; };
    float* lhs_t   = (float*)(base + alloc((size_t)B_ * T_ * N_ * 4));
    float* rhs_t   = (float*)(base + alloc((size_t)B_ * N_ * T_ * 4));
    float* Ebuf    = (float*)(base + alloc((size_t)B_ * T_ * T_ * 4));
    float* partial = (float*)(base + alloc((size_t)B_ * 16 * CT_ * 4));
    float* lhs_t0  = (float*)(base + alloc((size_t)B_ * CT_ * 4));
    float* lhs_s   = (float*)(base + alloc((size_t)B_ * N_ * T_ * 4));
    float* rhs_s   = (float*)(base + alloc((size_t)B_ * T_ * N_ * 4));
    unsigned short* V_sb = (unsigned short*)(base + alloc((size_t)N_ * N_ * 2));
    unsigned short* Wcat = (unsigned short*)(base + alloc((size_t)F_ * 256 * 2));
    size_t regA = alloc((size_t)B_ * N_ * KS_ * 2);
    size_t regB = alloc((size_t)B_ * CT_ * KS_ * 2);
    float*          xw     = (float*)(base + regA);
    unsigned short* xT     = (unsigned short*)(base + regA);
    unsigned short* chebSt = (unsigned short*)(base + regA);
    unsigned short* sigA   = (unsigned short*)(base + regB);
    unsigned short* yT     = (unsigned short*)(base + regB);
    float* Sb  = out;        // S scores live in d_out until the stacked GEMM overwrites
    float* gcn = out;

    dim3 b256(256);
    k_cvt_vs<<<dim3(N_ * N_ / 256), b256, 0, stream>>>(V_s, V_sb);
    k_wcat<<<dim3((F_ * 256 + 255) / 256), b256, 0, stream>>>(tc_w, rc_w, Wcat);
    k_rhs_t<<<dim3((B_ * N_ * T_) / 256), b256, 0, stream>>>(x, U3, rhs_t);
    k_lhs_partial<<<dim3(16, B_), b256, 0, stream>>>(x, U1, partial);
    k_lhs_reduce<<<dim3((B_ * CT_) / 256), b256, 0, stream>>>(partial, lhs_t0);
    k_lhs_t<<<dim3((B_ * T_ * N_) / 256), b256, 0, stream>>>(lhs_t0, U2, lhs_t);
    k_temporal_E<<<dim3(B_), dim3(576), 0, stream>>>(lhs_t, rhs_t, b_e, V_e, Ebuf);
    k_xTAt<<<dim3(N_ * C_ / 256, B_), b256, 0, stream>>>(x, Ebuf, xw);
    k_spatial_prep<<<dim3(B_ * N_ / 256), b256, 0, stream>>>(xw, W1, W2, W3, lhs_s, rhs_s);
    k_transpose_x<<<dim3(CT_ / 64, N_ / 64, B_), b256, 0, stream>>>(x, xT);   // xw dead
    k_sig<<<dim3(N_ / 256, N_ / 64, B_), b256, 0, stream>>>(lhs_s, rhs_s, b_s, sigA);
    // S0 GEMM: M=1024, Ncols=1024, K=1024; nwg=512 (%8==0)
    k_gemm256<<<dim3(B_ * 4 * 4), dim3(512), 0, stream>>>(
        sigA, N_, (long)N_ * N_, V_sb, N_, 0, Sb, N_, (long)N_ * N_, N_, 4, 4);
    k_softmax_S<<<dim3(N_ / 64, B_), b256, 0, stream>>>(Sb);
    k_yT<<<dim3(N_ / 256, T_, B_), b256, 0, stream>>>(xT, Theta, yT);          // sigA dead
    k_chebSt<<<dim3(N_ / 64, N_ / 64, B_), b256, 0, stream>>>(cheb, Sb, chebSt); // xT dead
    // stacked GEMM: M=1024, Ncols=1536, K=3072; nwg=768 (%8==0)
    k_gemm256<<<dim3(B_ * 4 * 6), dim3(512), 0, stream>>>(
        chebSt, KS_, (long)N_ * KS_, yT, KS_, (long)CT_ * KS_,
        gcn, CT_, (long)N_ * CT_, KS_, 6, 4);                                 // Sb dead
    k_final<<<dim3(N_ / 4, B_), b256, 0, stream>>>(x, gcn, Wcat, tc_b, rc_b,
                                                   ln_g, ln_b, out);
}

// Round 7
// 1554.104 us; speedup vs baseline: 8.6486x; 1.0438x over previous
//
#include <hip/hip_runtime.h>

typedef __attribute__((ext_vector_type(8))) short short8;   // 8 bf16 (4 VGPRs)
typedef __attribute__((ext_vector_type(4))) float f32x4;

constexpr int B_ = 32;
constexpr int N_ = 1024;
constexpr int C_ = 64;
constexpr int T_ = 24;
constexpr int F_ = 64;
constexpr int CT_ = C_ * T_;     // 1536
constexpr int KS_ = 3072;        // stacked K = 3*1024

__device__ __forceinline__ float sigmoidf_(float x) {
    return 1.0f / (1.0f + __expf(-x));
}
__device__ __forceinline__ unsigned short f2b(float f) {   // RNE f32->bf16
    union { float f; unsigned u; } v; v.f = f;
    unsigned r = v.u + 0x7FFFu + ((v.u >> 16) & 1u);
    return (unsigned short)(r >> 16);
}
__device__ __forceinline__ float b2f(unsigned short h) {
    union { unsigned u; float f; } v; v.u = ((unsigned)h) << 16; return v.f;
}
__device__ __forceinline__ void gload_lds16(const unsigned short* g, unsigned short* l) {
    __builtin_amdgcn_global_load_lds(
        (const __attribute__((address_space(1))) unsigned int*)g,
        (__attribute__((address_space(3))) unsigned int*)l, 16, 0, 0);
}

// ---------------- temporal attention prep ----------------
__global__ void k_rhs_t(const float* __restrict__ x, const float* __restrict__ U3,
                        float* __restrict__ rhs_t) {
    int idx = blockIdx.x * 256 + threadIdx.x;
    if (idx >= B_ * N_ * T_) return;
    int t = idx % T_;
    int n = (idx / T_) % N_;
    int b = idx / (N_ * T_);
    const float* xp = x + ((size_t)(b * N_ + n)) * CT_ + t;
    float acc = 0.f;
#pragma unroll
    for (int c = 0; c < C_; ++c) acc += U3[c] * xp[c * T_];
    rhs_t[idx] = acc;
}

__global__ void k_lhs_partial(const float* __restrict__ x, const float* __restrict__ U1,
                              float* __restrict__ partial) {
    int b = blockIdx.y, chunk = blockIdx.x;
    int tid = threadIdx.x;
    float acc[6] = {0, 0, 0, 0, 0, 0};
    int n0 = chunk * 64;
    for (int nn = 0; nn < 64; ++nn) {
        int n = n0 + nn;
        float u = U1[n];
        const float* xp = x + ((size_t)(b * N_ + n)) * CT_;
#pragma unroll
        for (int e = 0; e < 6; ++e) acc[e] += u * xp[tid + e * 256];
    }
    float* pp = partial + ((size_t)(b * 16 + chunk)) * CT_;
#pragma unroll
    for (int e = 0; e < 6; ++e) pp[tid + e * 256] = acc[e];
}

__global__ void k_lhs_reduce(const float* __restrict__ partial, float* __restrict__ lhs_t0) {
    int idx = blockIdx.x * 256 + threadIdx.x;
    if (idx >= B_ * CT_) return;
    int b = idx / CT_, flat = idx % CT_;
    float acc = 0.f;
#pragma unroll
    for (int ch = 0; ch < 16; ++ch) acc += partial[((size_t)(b * 16 + ch)) * CT_ + flat];
    lhs_t0[idx] = acc;
}

__global__ void k_lhs_t(const float* __restrict__ lhs_t0, const float* __restrict__ U2,
                        float* __restrict__ lhs_t) {
    int idx = blockIdx.x * 256 + threadIdx.x;
    if (idx >= B_ * T_ * N_) return;
    int n2 = idx % N_;
    int t = (idx / N_) % T_;
    int b = idx / (T_ * N_);
    const float* l0 = lhs_t0 + (size_t)b * CT_;
    float acc = 0.f;
#pragma unroll
    for (int c = 0; c < C_; ++c) acc += l0[c * T_ + t] * U2[c * N_ + n2];
    lhs_t[idx] = acc;
}

__global__ void k_temporal_E(const float* __restrict__ lhs_t, const float* __restrict__ rhs_t,
                             const float* __restrict__ b_e, const float* __restrict__ V_e,
                             float* __restrict__ E) {
    int b = blockIdx.x;
    int tid = threadIdx.x;                               // 576 threads
    int i = tid / T_, u = tid % T_;
    __shared__ float sig[T_][T_];
    __shared__ float e0s[T_][T_];
    __shared__ float mcol[T_], scol[T_];
    const float* lt = lhs_t + (size_t)b * T_ * N_ + (size_t)i * N_;
    const float* rt = rhs_t + (size_t)b * N_ * T_ + u;
    float acc = 0.f;
    for (int n = 0; n < N_; ++n) acc += lt[n] * rt[(size_t)n * T_];
    sig[i][u] = sigmoidf_(acc + b_e[i * T_ + u]);
    __syncthreads();
    int j = u;
    float e0 = 0.f;
#pragma unroll
    for (int kk = 0; kk < T_; ++kk) e0 += sig[i][kk] * V_e[j * T_ + kk];
    e0s[i][j] = e0;
    __syncthreads();
    if (tid < T_) {
        float mx = -1e30f;
        for (int ii = 0; ii < T_; ++ii) mx = fmaxf(mx, e0s[ii][tid]);
        float s = 0.f;
        for (int ii = 0; ii < T_; ++ii) s += __expf(e0s[ii][tid] - mx);
        mcol[tid] = mx; scol[tid] = s;
    }
    __syncthreads();
    E[(size_t)b * T_ * T_ + i * T_ + j] = __expf(e0s[i][j] - mcol[j]) / scol[j];
}

__global__ void k_xTAt(const float* __restrict__ x, const float* __restrict__ E,
                       float* __restrict__ xw) {
    int b = blockIdx.y;
    int nc = blockIdx.x * 256 + threadIdx.x;
    __shared__ float Es[T_ * T_];
    for (int e = threadIdx.x; e < T_ * T_; e += 256) Es[e] = E[(size_t)b * T_ * T_ + e];
    __syncthreads();
    const float* xp = x + (size_t)b * N_ * CT_ + (size_t)nc * T_;
    float xv[T_];
#pragma unroll
    for (int t = 0; t < T_; ++t) xv[t] = xp[t];
    float* op = xw + (size_t)b * N_ * CT_ + (size_t)nc * T_;
#pragma unroll
    for (int u = 0; u < T_; ++u) {
        float acc = 0.f;
#pragma unroll
        for (int t = 0; t < T_; ++t) acc += xv[t] * Es[t * T_ + u];
        op[u] = acc;
    }
}

// ---------------- spatial attention prep ----------------
__global__ __launch_bounds__(256) void k_spatial_prep(const float* __restrict__ xw,
        const float* __restrict__ W1g, const float* __restrict__ W2,
        const float* __restrict__ W3g, float* __restrict__ lhs_s, float* __restrict__ rhs_s) {
    __shared__ float W2s[C_ * T_];
    __shared__ float W1s[T_];
    __shared__ float W3s[C_];
    int tid = threadIdx.x;
    for (int e = tid; e < C_ * T_; e += 256) W2s[e] = W2[e];
    if (tid < T_) W1s[tid] = W1g[tid];
    if (tid < C_) W3s[tid] = W3g[tid];
    __syncthreads();
    int idx = blockIdx.x * 256 + tid;
    int b = idx / N_, m = idx % N_;
    const float* xp = xw + (size_t)idx * CT_;
    float lacc[T_], racc[T_];
#pragma unroll
    for (int t = 0; t < T_; ++t) { lacc[t] = 0.f; racc[t] = 0.f; }
    for (int c = 0; c < C_; ++c) {
        float l0 = 0.f;
        float w3 = W3s[c];
        const float* xc = xp + c * T_;
#pragma unroll
        for (int t = 0; t < T_; ++t) {
            float v = xc[t];
            l0 += v * W1s[t];
            racc[t] += w3 * v;
        }
#pragma unroll
        for (int t2 = 0; t2 < T_; ++t2) lacc[t2] += l0 * W2s[c * T_ + t2];
    }
    float* lp = lhs_s + (size_t)idx * T_;
#pragma unroll
    for (int t = 0; t < T_; ++t) lp[t] = lacc[t];
#pragma unroll
    for (int t = 0; t < T_; ++t) rhs_s[((size_t)b * T_ + t) * N_ + m] = racc[t];
}

// ---------------- converters / builders ----------------
__global__ void k_cvt_vs(const float* __restrict__ v, unsigned short* __restrict__ o) {
    int i = blockIdx.x * 256 + threadIdx.x;
    o[i] = f2b(v[i]);
}

// Wcat[ft][k], k = sel*64+c: sel 0..2 -> tc_w taps, sel 3 -> rc_w.  bf16 [64][256]
__global__ void k_wcat(const float* __restrict__ tc_w, const float* __restrict__ rc_w,
                       unsigned short* __restrict__ Wcat) {
    int i = blockIdx.x * 256 + threadIdx.x;              // over 64*256
    if (i >= F_ * 256) return;
    int ft = i >> 8, k = i & 255;
    int sel = k >> 6, c = k & 63;
    float v = (sel < 3) ? tc_w[(ft * C_ + c) * 3 + sel] : rc_w[ft * C_ + c];
    Wcat[i] = f2b(v);
}

// xT[b][ct][m] (bf16) = x[b][m][ct]
__global__ __launch_bounds__(256) void k_transpose_x(const float* __restrict__ x,
                                                     unsigned short* __restrict__ xT) {
    __shared__ float tile[64][65];
    int b = blockIdx.z, m0 = blockIdx.y * 64, ct0 = blockIdx.x * 64;
    int tid = threadIdx.x;
#pragma unroll
    for (int e = 0; e < 16; ++e) {
        int idx = e * 256 + tid; int mm = idx >> 6, cc = idx & 63;
        tile[mm][cc] = x[((size_t)(b * N_ + m0 + mm)) * CT_ + ct0 + cc];
    }
    __syncthreads();
#pragma unroll
    for (int e = 0; e < 16; ++e) {
        int idx = e * 256 + tid; int rr = idx >> 6, mm = idx & 63;
        xT[((size_t)b * CT_ + ct0 + rr) * N_ + m0 + mm] = f2b(tile[mm][rr]);
    }
}

// sigA[b][i][k] (bf16) = sigmoid(dot24(lhs_s[b,i,:], rhs_s[b,:,k]) + b_s[i,k])
__global__ __launch_bounds__(256) void k_sig(const float* __restrict__ lhs_s,
        const float* __restrict__ rhs_s, const float* __restrict__ b_s,
        unsigned short* __restrict__ sigA) {
    int b = blockIdx.z, i0 = blockIdx.y * 64, k0 = blockIdx.x * 256;
    int tid = threadIdx.x;
    __shared__ float lh[64 * T_];
    __shared__ float rh[T_][256];
    for (int e = tid; e < 64 * T_; e += 256) lh[e] = lhs_s[((size_t)b * N_ + i0) * T_ + e];
#pragma unroll
    for (int t = 0; t < T_; ++t) rh[t][tid] = rhs_s[((size_t)b * T_ + t) * N_ + k0 + tid];
    __syncthreads();
    int kg = k0 + tid;
    for (int ii = 0; ii < 64; ++ii) {
        float acc = b_s[(size_t)(i0 + ii) * N_ + kg];
#pragma unroll
        for (int t = 0; t < T_; ++t) acc += lh[ii * T_ + t] * rh[t][tid];
        sigA[((size_t)b * N_ + i0 + ii) * N_ + kg] = f2b(sigmoidf_(acc));
    }
}

// yT[b][f*24+t][k*1024+m] (bf16) = sum_c Theta[k,c,f] * x[b,m,c,t]   (reads xT)
__global__ __launch_bounds__(256) void k_yT(const unsigned short* __restrict__ xT,
        const float* __restrict__ Theta, unsigned short* __restrict__ yT) {
    int b = blockIdx.z, t = blockIdx.y, m0 = blockIdx.x * 256;
    int tid = threadIdx.x;
    float xr[64];
#pragma unroll
    for (int c = 0; c < 64; ++c)
        xr[c] = b2f(xT[((size_t)b * CT_ + c * T_ + t) * N_ + m0 + tid]);
    for (int k = 0; k < 3; ++k) {
        float acc[64];
#pragma unroll
        for (int f = 0; f < 64; ++f) acc[f] = 0.f;
#pragma unroll 4
        for (int c = 0; c < 64; ++c) {
            float xc = xr[c];
            const float* th = Theta + ((size_t)k * 64 + c) * 64;   // uniform -> s_load
#pragma unroll
            for (int f = 0; f < 64; ++f) acc[f] = fmaf(th[f], xc, acc[f]);
        }
#pragma unroll
        for (int f = 0; f < 64; ++f)
            yT[((size_t)b * CT_ + f * T_ + t) * KS_ + k * N_ + m0 + tid] = f2b(acc[f]);
    }
}

// online softmax stats over axis m of S[b,m,i]: mst[b*N+i] = (max, 1/sum)
__global__ void k_smstats(const float* __restrict__ S, float2* __restrict__ mst) {
    int b = blockIdx.y;
    int jj = threadIdx.x % 64;
    int ig = threadIdx.x / 64;
    int j = blockIdx.x * 64 + jj;
    __shared__ float rm[4][64], rs[4][64];
    float m = -1e30f, s = 0.f;
    for (int i = ig; i < N_; i += 4) {
        float v = S[((size_t)b * N_ + i) * N_ + j];
        float mn = fmaxf(m, v);
        s = s * __expf(m - mn) + __expf(v - mn);
        m = mn;
    }
    rm[ig][jj] = m; rs[ig][jj] = s;
    __syncthreads();
    if (ig == 0) {
        float M = rm[0][jj], SS = rs[0][jj];
#pragma unroll
        for (int g = 1; g < 4; ++g) {
            float mg = rm[g][jj];
            float mn = fmaxf(M, mg);
            SS = SS * __expf(M - mn) + rs[g][jj] * __expf(mg - mn);
            M = mn;
        }
        mst[(size_t)b * N_ + j] = make_float2(M, 1.f / SS);
    }
}

// chebSt[b][i][k*1024+m] (bf16) = cheb[k][m][i] * softmax(S)[b][m][i]  (applies stats)
__global__ __launch_bounds__(256) void k_chebSt(const float* __restrict__ cheb,
        const float* __restrict__ S, const float2* __restrict__ mst,
        unsigned short* __restrict__ cs) {
    int b = blockIdx.z, i0 = blockIdx.y * 64, m0 = blockIdx.x * 64;
    int tid = threadIdx.x;
    __shared__ float st[64][65];
    __shared__ float cb[64][65];
    __shared__ float2 sst[64];
    if (tid < 64) sst[tid] = mst[(size_t)b * N_ + i0 + tid];
#pragma unroll
    for (int e = 0; e < 16; ++e) {
        int idx = e * 256 + tid; int mm = idx >> 6, ii = idx & 63;
        st[mm][ii] = S[((size_t)b * N_ + m0 + mm) * N_ + i0 + ii];
    }
    for (int k = 0; k < 3; ++k) {
        __syncthreads();
#pragma unroll
        for (int e = 0; e < 16; ++e) {
            int idx = e * 256 + tid; int mm = idx >> 6, ii = idx & 63;
            cb[mm][ii] = cheb[((size_t)k * N_ + m0 + mm) * N_ + i0 + ii];
        }
        __syncthreads();
#pragma unroll
        for (int e = 0; e < 16; ++e) {
            int idx = e * 256 + tid; int mm = idx & 63, ii = idx >> 6;
            float sm = __expf(st[mm][ii] - sst[ii].x) * sst[ii].y;
            cs[((size_t)b * N_ + i0 + ii) * KS_ + k * N_ + m0 + mm] =
                f2b(sm * cb[mm][ii]);
        }
    }
}

// ---------------- 256x256-tile MFMA GEMM, kk-granular software pipeline ----------------
// C[b] = A[b] * Bt[b]^T.  LDS: 2 x 64KB K-tile buffers.  Per K-tile:
//   READ kk1 frags -> MFMA kk0 (covers kk1 read latency) -> lgkm(0)+bar ->
//   STAGE(kt+2) -> vmcnt(8|0)+bar -> READ next-tile kk0 frags -> MFMA kk1
//   (covers next-tile read latency).  Counted vmcnt never drains mid-loop;
//   tail uses vmcnt(0) (fixes latent race at kt=nt-2).
__global__ __launch_bounds__(512, 2) void k_gemm256(
        const unsigned short* __restrict__ A, long lda, long sA,
        const unsigned short* __restrict__ Bt, long ldb, long sB,
        float* __restrict__ Cc, long ldc, long sC, int K, int nbx, int nby) {
    __shared__ __align__(16) unsigned short As[2][256 * 64];   // 2 x 32KB
    __shared__ __align__(16) unsigned short Bs[2][256 * 64];   // 2 x 32KB
    int tid = threadIdx.x;
    int lane = tid & 63, w = tid >> 6;
    int wy = w >> 2, wx = w & 3;                            // 2 x 4 waves -> 128x64 per wave

    int nwg = gridDim.x;
    int cpx = nwg >> 3;
    int logical = (blockIdx.x & 7) * cpx + (blockIdx.x >> 3);
    int tpb = nbx * nby;
    int b = logical / tpb;
    int tile = logical % tpb;
    int i0 = (tile / nbx) * 256;
    int j0 = (tile % nbx) * 256;

    const unsigned short* Ab = A + (size_t)b * sA + (size_t)i0 * lda;
    const unsigned short* Bb = Bt + (size_t)b * sB + (size_t)j0 * ldb;

    auto STAGE = [&](int kt, int d) {
        int kof = kt << 6;
#pragma unroll
        for (int e = 0; e < 4; ++e) {
            int chunk = e * 512 + tid;
            int row = chunk >> 3, slot = chunk & 7;
            int gslot = slot ^ (row & 7);                   // inverse swizzle on source
            gload_lds16(Ab + (size_t)row * lda + kof + gslot * 8, &As[d][chunk * 8]);
        }
#pragma unroll
        for (int e = 0; e < 4; ++e) {
            int chunk = e * 512 + tid;
            int row = chunk >> 3, slot = chunk & 7;
            int gslot = slot ^ (row & 7);
            gload_lds16(Bb + (size_t)row * ldb + kof + gslot * 8, &Bs[d][chunk * 8]);
        }
    };
    auto READF = [&](short8* af, short8* bfv,
                     const unsigned short* Asb, const unsigned short* Bsb, int kkb) {
#pragma unroll
        for (int mi = 0; mi < 8; ++mi) {
            int r = wy * 128 + mi * 16 + (lane & 15);
            int slot = (kkb + (lane >> 4)) ^ (r & 7);
            af[mi] = *(const short8*)&Asb[r * 64 + slot * 8];
        }
#pragma unroll
        for (int ni = 0; ni < 4; ++ni) {
            int r = wx * 64 + ni * 16 + (lane & 15);
            int slot = (kkb + (lane >> 4)) ^ (r & 7);
            bfv[ni] = *(const short8*)&Bsb[r * 64 + slot * 8];
        }
    };

    f32x4 acc[8][4];
#pragma unroll
    for (int mi = 0; mi < 8; ++mi)
#pragma unroll
        for (int ni = 0; ni < 4; ++ni) acc[mi][ni] = (f32x4){0.f, 0.f, 0.f, 0.f};

    int nt = K >> 6;
    STAGE(0, 0);
    STAGE(1, 1);
    asm volatile("s_waitcnt vmcnt(8)" ::: "memory");        // K-tile 0 resident
    __builtin_amdgcn_s_barrier();
    __builtin_amdgcn_sched_barrier(0);

    short8 a0[8], b0[4], a1[8], b1[4];
    READF(a0, b0, As[0], Bs[0], 0);                         // kk0 of tile 0

    for (int kt = 0; kt < nt; ++kt) {
        int cur = kt & 1;
        READF(a1, b1, As[cur], Bs[cur], 4);                 // kk1 of this tile
        __builtin_amdgcn_s_setprio(1);
#pragma unroll
        for (int mi = 0; mi < 8; ++mi)
#pragma unroll
            for (int ni = 0; ni < 4; ++ni)
                acc[mi][ni] = __builtin_amdgcn_mfma_f32_16x16x32_bf16(
                    a0[mi], b0[ni], acc[mi][ni], 0, 0, 0);
        __builtin_amdgcn_s_setprio(0);
        asm volatile("s_waitcnt lgkmcnt(0)" ::: "memory");  // all my reads of buf[cur] done
        __builtin_amdgcn_sched_barrier(0);
        __builtin_amdgcn_s_barrier();                       // all waves done with buf[cur]
        __builtin_amdgcn_sched_barrier(0);
        if (kt + 2 < nt) {
            STAGE(kt + 2, cur);                             // overwrite freed buffer
            asm volatile("s_waitcnt vmcnt(8)" ::: "memory"); // tile kt+1 retired, kt+2 in flight
        } else {
            asm volatile("s_waitcnt vmcnt(0)" ::: "memory"); // tail: drain (fixes race)
        }
        __builtin_amdgcn_s_barrier();                       // buf[cur^1] ready for all waves
        __builtin_amdgcn_sched_barrier(0);
        if (kt + 1 < nt)
            READF(a0, b0, As[cur ^ 1], Bs[cur ^ 1], 0);     // kk0 of next tile
        __builtin_amdgcn_s_setprio(1);
#pragma unroll
        for (int mi = 0; mi < 8; ++mi)
#pragma unroll
            for (int ni = 0; ni < 4; ++ni)
                acc[mi][ni] = __builtin_amdgcn_mfma_f32_16x16x32_bf16(
                    a1[mi], b1[ni], acc[mi][ni], 0, 0, 0);
        __builtin_amdgcn_s_setprio(0);
    }

    float* Cb = Cc + (size_t)b * sC;
#pragma unroll
    for (int mi = 0; mi < 8; ++mi) {
#pragma unroll
        for (int r = 0; r < 4; ++r) {
            int i = i0 + wy * 128 + mi * 16 + (lane >> 4) * 4 + r;
            float* cp = Cb + (size_t)i * ldc + j0 + wx * 64 + (lane & 15);
#pragma unroll
            for (int ni = 0; ni < 4; ++ni) cp[ni * 16] = acc[mi][ni][r];
        }
    }
}

// ---------------- fused epilogue via MFMA (unchanged) ----------------
__global__ __launch_bounds__(256) void k_final(const float* __restrict__ x,
        const float* __restrict__ sgin, const unsigned short* __restrict__ Wcat,
        const float* __restrict__ tc_b, const float* __restrict__ rc_b,
        const float* __restrict__ ln_g, const float* __restrict__ ln_b,
        float* __restrict__ out) {
    int b = blockIdx.y;
    int n0 = blockIdx.x * 4;
    int tid = threadIdx.x;
    int lane = tid & 63, wv = tid >> 6;

    __shared__ __align__(16) char smem[25600];
    unsigned short* sgb = (unsigned short*)smem;            // [4][26][64]
    unsigned short* xb  = (unsigned short*)(smem + 13312);  // [4][24][64]
    float* Cl = (float*)smem;                               // [96][66] (after reuse barrier)
    __shared__ float tbs[64], gs[64], bbs[64];
    __shared__ float mus[96], rss[96];

    if (tid < 64) {
        tbs[tid] = tc_b[tid] + rc_b[tid];
        gs[tid] = ln_g[tid];
        bbs[tid] = ln_b[tid];
    }
    for (int e = tid; e < 512; e += 256) {
        int nl = e >> 7, r = (e >> 6) & 1, c = e & 63;
        int tt = r ? 25 : 0;
        sgb[(nl * 26 + tt) * 64 + (((c >> 3) ^ (tt & 7)) << 3) + (c & 7)] = 0;
    }
    size_t base = ((size_t)b * N_ + n0) * CT_;
#pragma unroll
    for (int i = 0; i < 24; ++i) {
        int e = i * 256 + tid;
        int nl = e / CT_;
        int rem = e - nl * CT_;
        int c = rem / 24;
        int tl = rem - c * 24;
        float sv = fmaxf(sgin[base + e], 0.f);
        float xv = x[base + e];
        int tt = tl + 1;
        sgb[(nl * 26 + tt) * 64 + (((c >> 3) ^ (tt & 7)) << 3) + (c & 7)] = f2b(sv);
        xb[(nl * 24 + tl) * 64 + (((c >> 3) ^ (tl & 7)) << 3) + (c & 7)] = f2b(xv);
    }

    int ft = wv * 16 + (lane & 15);
    int g4 = lane >> 4;
    short8 bfr[8];
#pragma unroll
    for (int ks = 0; ks < 8; ++ks)
        bfr[ks] = *(const short8*)&Wcat[ft * 256 + ks * 32 + g4 * 8];

    int rnl[6], rt[6];
#pragma unroll
    for (int mi = 0; mi < 6; ++mi) {
        int row = mi * 16 + (lane & 15);
        rnl[mi] = row / 24;
        rt[mi] = row - rnl[mi] * 24;
    }

    __syncthreads();

    f32x4 acc[6];
#pragma unroll
    for (int mi = 0; mi < 6; ++mi) acc[mi] = (f32x4){0.f, 0.f, 0.f, 0.f};
#pragma unroll
    for (int mi = 0; mi < 6; ++mi) {
        int nl = rnl[mi], t = rt[mi];
#pragma unroll
        for (int ks = 0; ks < 8; ++ks) {
            const int sel = ks >> 1;
            int slot = (ks & 1) * 4 + g4;
            short8 af;
            if (sel < 3) {
                int tt = t + sel;
                af = *(const short8*)&sgb[(nl * 26 + tt) * 64 + ((slot ^ (tt & 7)) << 3)];
            } else {
                af = *(const short8*)&xb[(nl * 24 + t) * 64 + ((slot ^ (t & 7)) << 3)];
            }
            acc[mi] = __builtin_amdgcn_mfma_f32_16x16x32_bf16(af, bfr[ks], acc[mi], 0, 0, 0);
        }
    }

    __syncthreads();
#pragma unroll
    for (int mi = 0; mi < 6; ++mi)
#pragma unroll
        for (int r = 0; r < 4; ++r)
            Cl[(mi * 16 + (lane >> 4) * 4 + r) * 66 + wv * 16 + (lane & 15)] = acc[mi][r];
    __syncthreads();

    if (tid < 96) {
        float s = 0.f, s2 = 0.f;
#pragma unroll
        for (int f = 0; f < 64; ++f) {
            float v = fmaxf(Cl[tid * 66 + f] + tbs[f], 0.f);
            s += v; s2 += v * v;
        }
        float mu = s * (1.f / 64.f);
        float var = s2 * (1.f / 64.f) - mu * mu;
        mus[tid] = mu;
        rss[tid] = rsqrtf(var + 1e-5f);
    }
    __syncthreads();

#pragma unroll
    for (int i = 0; i < 24; ++i) {
        int e = i * 256 + tid;
        int nl = e / CT_;
        int rem = e - nl * CT_;
        int f = rem / 24;
        int t = rem - f * 24;
        int row = nl * 24 + t;
        float v = fmaxf(Cl[row * 66 + f] + tbs[f], 0.f);
        out[base + e] = (v - mus[row]) * rss[row] * gs[f] + bbs[f];
    }
}

extern "C" void kernel_launch(void* const* d_in, const int* in_sizes, int n_in,
                              void* d_out, int out_size, void* d_ws, size_t ws_size,
                              hipStream_t stream) {
    const float* x    = (const float*)d_in[0];
    const float* cheb = (const float*)d_in[1];
    const float* U1   = (const float*)d_in[2];
    const float* U2   = (const float*)d_in[3];
    const float* U3   = (const float*)d_in[4];
    const float* b_e  = (const float*)d_in[5];
    const float* V_e  = (const float*)d_in[6];
    const float* W1   = (const float*)d_in[7];
    const float* W2   = (const float*)d_in[8];
    const float* W3   = (const float*)d_in[9];
    const float* b_s  = (const float*)d_in[10];
    const float* V_s  = (const float*)d_in[11];
    const float* Theta= (const float*)d_in[12];
    const float* tc_w = (const float*)d_in[13];
    const float* tc_b = (const float*)d_in[14];
    const float* rc_w = (const float*)d_in[15];
    const float* rc_b = (const float*)d_in[16];
    const float* ln_g = (const float*)d_in[17];
    const float* ln_b = (const float*)d_in[18];
    float* out = (float*)d_out;

    char* base = (char*)d_ws;
    size_t o = 0;
    auto alloc = [&](size_t bytes) { size_t r = o; o += (bytes + 255) & ~(size_t)255; return r; };
    float* lhs_t   = (float*)(base + alloc((size_t)B_ * T_ * N_ * 4));
    float* rhs_t   = (float*)(base + alloc((size_t)B_ * N_ * T_ * 4));
    float* Ebuf    = (float*)(base + alloc((size_t)B_ * T_ * T_ * 4));
    float* partial = (float*)(base + alloc((size_t)B_ * 16 * CT_ * 4));
    float* lhs_t0  = (float*)(base + alloc((size_t)B_ * CT_ * 4));
    float* lhs_s   = (float*)(base + alloc((size_t)B_ * N_ * T_ * 4));
    float* rhs_s   = (float*)(base + alloc((size_t)B_ * T_ * N_ * 4));
    unsigned short* V_sb = (unsigned short*)(base + alloc((size_t)N_ * N_ * 2));
    unsigned short* Wcat = (unsigned short*)(base + alloc((size_t)F_ * 256 * 2));
    float2* mstats = (float2*)(base + alloc((size_t)B_ * N_ * 8));
    size_t regA = alloc((size_t)B_ * N_ * KS_ * 2);
    size_t regB = alloc((size_t)B_ * CT_ * KS_ * 2);
    float*          xw     = (float*)(base + regA);
    unsigned short* xT     = (unsigned short*)(base + regA);
    unsigned short* chebSt = (unsigned short*)(base + regA);
    unsigned short* sigA   = (unsigned short*)(base + regB);
    unsigned short* yT     = (unsigned short*)(base + regB);
    float* Sb  = out;        // S scores live in d_out until the stacked GEMM overwrites
    float* gcn = out;

    dim3 b256(256);
    k_cvt_vs<<<dim3(N_ * N_ / 256), b256, 0, stream>>>(V_s, V_sb);
    k_wcat<<<dim3((F_ * 256 + 255) / 256), b256, 0, stream>>>(tc_w, rc_w, Wcat);
    k_rhs_t<<<dim3((B_ * N_ * T_) / 256), b256, 0, stream>>>(x, U3, rhs_t);
    k_lhs_partial<<<dim3(16, B_), b256, 0, stream>>>(x, U1, partial);
    k_lhs_reduce<<<dim3((B_ * CT_) / 256), b256, 0, stream>>>(partial, lhs_t0);
    k_lhs_t<<<dim3((B_ * T_ * N_) / 256), b256, 0, stream>>>(lhs_t0, U2, lhs_t);
    k_temporal_E<<<dim3(B_), dim3(576), 0, stream>>>(lhs_t, rhs_t, b_e, V_e, Ebuf);
    k_xTAt<<<dim3(N_ * C_ / 256, B_), b256, 0, stream>>>(x, Ebuf, xw);
    k_spatial_prep<<<dim3(B_ * N_ / 256), b256, 0, stream>>>(xw, W1, W2, W3, lhs_s, rhs_s);
    k_transpose_x<<<dim3(CT_ / 64, N_ / 64, B_), b256, 0, stream>>>(x, xT);   // xw dead
    k_sig<<<dim3(N_ / 256, N_ / 64, B_), b256, 0, stream>>>(lhs_s, rhs_s, b_s, sigA);
    // S0 GEMM: M=1024, Ncols=1024, K=1024; nwg=512 (%8==0)
    k_gemm256<<<dim3(B_ * 4 * 4), dim3(512), 0, stream>>>(
        sigA, N_, (long)N_ * N_, V_sb, N_, 0, Sb, N_, (long)N_ * N_, N_, 4, 4);
    k_smstats<<<dim3(N_ / 64, B_), b256, 0, stream>>>(Sb, mstats);
    k_yT<<<dim3(N_ / 256, T_, B_), b256, 0, stream>>>(xT, Theta, yT);          // sigA dead
    k_chebSt<<<dim3(N_ / 64, N_ / 64, B_), b256, 0, stream>>>(cheb, Sb, mstats, chebSt); // xT dead
    // stacked GEMM: M=1024, Ncols=1536, K=3072; nwg=768 (%8==0)
    k_gemm256<<<dim3(B_ * 4 * 6), dim3(512), 0, stream>>>(
        chebSt, KS_, (long)N_ * KS_, yT, KS_, (long)CT_ * KS_,
        gcn, CT_, (long)N_ * CT_, KS_, 6, 4);                                 // Sb dead
    k_final<<<dim3(N_ / 4, B_), b256, 0, stream>>>(x, gcn, Wcat, tc_b, rc_b,
                                                   ln_g, ln_b, out);
}

// Round 8
// 1442.041 us; speedup vs baseline: 9.3207x; 1.0777x over previous
//
#include <hip/hip_runtime.h>

typedef __attribute__((ext_vector_type(8))) short short8;   // 8 bf16 (4 VGPRs)
typedef __attribute__((ext_vector_type(4))) float f32x4;

constexpr int B_ = 32;
constexpr int N_ = 1024;
constexpr int C_ = 64;
constexpr int T_ = 24;
constexpr int F_ = 64;
constexpr int CT_ = C_ * T_;     // 1536
constexpr int KS_ = 3072;        // stacked K = 3*1024

__device__ __forceinline__ float sigmoidf_(float x) {
    return 1.0f / (1.0f + __expf(-x));
}
__device__ __forceinline__ unsigned short f2b(float f) {   // RNE f32->bf16
    union { float f; unsigned u; } v; v.f = f;
    unsigned r = v.u + 0x7FFFu + ((v.u >> 16) & 1u);
    return (unsigned short)(r >> 16);
}
__device__ __forceinline__ float b2f(unsigned short h) {
    union { unsigned u; float f; } v; v.u = ((unsigned)h) << 16; return v.f;
}
__device__ __forceinline__ void gload_lds16(const unsigned short* g, unsigned short* l) {
    __builtin_amdgcn_global_load_lds(
        (const __attribute__((address_space(1))) unsigned int*)g,
        (__attribute__((address_space(3))) unsigned int*)l, 16, 0, 0);
}

// ---------------- temporal attention prep ----------------
__global__ void k_rhs_t(const float* __restrict__ x, const float* __restrict__ U3,
                        float* __restrict__ rhs_t) {
    int idx = blockIdx.x * 256 + threadIdx.x;
    if (idx >= B_ * N_ * T_) return;
    int t = idx % T_;
    int n = (idx / T_) % N_;
    int b = idx / (N_ * T_);
    const float* xp = x + ((size_t)(b * N_ + n)) * CT_ + t;
    float acc = 0.f;
#pragma unroll
    for (int c = 0; c < C_; ++c) acc += U3[c] * xp[c * T_];
    rhs_t[idx] = acc;
}

__global__ void k_lhs_partial(const float* __restrict__ x, const float* __restrict__ U1,
                              float* __restrict__ partial) {
    int b = blockIdx.y, chunk = blockIdx.x;
    int tid = threadIdx.x;
    float acc[6] = {0, 0, 0, 0, 0, 0};
    int n0 = chunk * 64;
    for (int nn = 0; nn < 64; ++nn) {
        int n = n0 + nn;
        float u = U1[n];
        const float* xp = x + ((size_t)(b * N_ + n)) * CT_;
#pragma unroll
        for (int e = 0; e < 6; ++e) acc[e] += u * xp[tid + e * 256];
    }
    float* pp = partial + ((size_t)(b * 16 + chunk)) * CT_;
#pragma unroll
    for (int e = 0; e < 6; ++e) pp[tid + e * 256] = acc[e];
}

__global__ void k_lhs_reduce(const float* __restrict__ partial, float* __restrict__ lhs_t0) {
    int idx = blockIdx.x * 256 + threadIdx.x;
    if (idx >= B_ * CT_) return;
    int b = idx / CT_, flat = idx % CT_;
    float acc = 0.f;
#pragma unroll
    for (int ch = 0; ch < 16; ++ch) acc += partial[((size_t)(b * 16 + ch)) * CT_ + flat];
    lhs_t0[idx] = acc;
}

__global__ void k_lhs_t(const float* __restrict__ lhs_t0, const float* __restrict__ U2,
                        float* __restrict__ lhs_t) {
    int idx = blockIdx.x * 256 + threadIdx.x;
    if (idx >= B_ * T_ * N_) return;
    int n2 = idx % N_;
    int t = (idx / N_) % T_;
    int b = idx / (T_ * N_);
    const float* l0 = lhs_t0 + (size_t)b * CT_;
    float acc = 0.f;
#pragma unroll
    for (int c = 0; c < C_; ++c) acc += l0[c * T_ + t] * U2[c * N_ + n2];
    lhs_t[idx] = acc;
}

__global__ void k_temporal_E(const float* __restrict__ lhs_t, const float* __restrict__ rhs_t,
                             const float* __restrict__ b_e, const float* __restrict__ V_e,
                             float* __restrict__ E) {
    int b = blockIdx.x;
    int tid = threadIdx.x;                               // 576 threads
    int i = tid / T_, u = tid % T_;
    __shared__ float sig[T_][T_];
    __shared__ float e0s[T_][T_];
    __shared__ float mcol[T_], scol[T_];
    const float* lt = lhs_t + (size_t)b * T_ * N_ + (size_t)i * N_;
    const float* rt = rhs_t + (size_t)b * N_ * T_ + u;
    float acc = 0.f;
    for (int n = 0; n < N_; ++n) acc += lt[n] * rt[(size_t)n * T_];
    sig[i][u] = sigmoidf_(acc + b_e[i * T_ + u]);
    __syncthreads();
    int j = u;
    float e0 = 0.f;
#pragma unroll
    for (int kk = 0; kk < T_; ++kk) e0 += sig[i][kk] * V_e[j * T_ + kk];
    e0s[i][j] = e0;
    __syncthreads();
    if (tid < T_) {
        float mx = -1e30f;
        for (int ii = 0; ii < T_; ++ii) mx = fmaxf(mx, e0s[ii][tid]);
        float s = 0.f;
        for (int ii = 0; ii < T_; ++ii) s += __expf(e0s[ii][tid] - mx);
        mcol[tid] = mx; scol[tid] = s;
    }
    __syncthreads();
    E[(size_t)b * T_ * T_ + i * T_ + j] = __expf(e0s[i][j] - mcol[j]) / scol[j];
}

// ---------------- fused: x_TAt (in-register) -> spatial prep ----------------
// Per block: 4 n-rows.  Thread (nl,c) computes u[j] = sum_t x[n][c][t]*E[t][j]
// in registers, then c-reductions via LDS produce lhs_s / rhs_s directly.
// Eliminates the 384MB xw round-trip.
__global__ __launch_bounds__(256) void k_tspatial(const float* __restrict__ x,
        const float* __restrict__ E, const float* __restrict__ W1g,
        const float* __restrict__ W2, const float* __restrict__ W3g,
        float* __restrict__ lhs_s, float* __restrict__ rhs_s) {
    int b = blockIdx.y;
    int n0 = blockIdx.x * 4;
    int tid = threadIdx.x;
    __shared__ float Es[T_ * T_];
    __shared__ float W1s[T_];
    __shared__ float W2s[C_ * T_];
    __shared__ float xr[4][64][25];                      // staged x, then reused for w3*u
    __shared__ float l0s[4][64];
    for (int e = tid; e < T_ * T_; e += 256) Es[e] = E[(size_t)b * T_ * T_ + e];
    for (int e = tid; e < C_ * T_; e += 256) W2s[e] = W2[e];
    if (tid < T_) W1s[tid] = W1g[tid];
    size_t base = ((size_t)b * N_ + n0) * CT_;
#pragma unroll
    for (int i = 0; i < 24; ++i) {
        int e = i * 256 + tid;
        int nl = e / CT_; int rem = e - nl * CT_; int c = rem / 24; int t = rem - c * 24;
        xr[nl][c][t] = x[base + e];
    }
    __syncthreads();
    int nl = tid >> 6, c = tid & 63;
    float xv[T_];
#pragma unroll
    for (int t = 0; t < T_; ++t) xv[t] = xr[nl][c][t];
    float w3 = W3g[c];
    float u[T_];
#pragma unroll
    for (int j = 0; j < T_; ++j) {
        float a = 0.f;
#pragma unroll
        for (int t = 0; t < T_; ++t) a += xv[t] * Es[t * T_ + j];
        u[j] = a;
    }
    float l0 = 0.f;
#pragma unroll
    for (int j = 0; j < T_; ++j) l0 += u[j] * W1s[j];
    // each thread owns row xr[nl][c][*]: safe in-place overwrite, no barrier needed
#pragma unroll
    for (int j = 0; j < T_; ++j) xr[nl][c][j] = w3 * u[j];
    l0s[nl][c] = l0;
    __syncthreads();
    if (tid < 4 * T_) {
        int t = tid % T_, g = tid / T_;
        float racc = 0.f, lacc = 0.f;
        for (int cc = 0; cc < 64; ++cc) {
            racc += xr[g][cc][t];
            lacc += l0s[g][cc] * W2s[cc * T_ + t];
        }
        rhs_s[((size_t)b * T_ + t) * N_ + n0 + g] = racc;
        lhs_s[((size_t)(b * N_ + n0 + g)) * T_ + t] = lacc;
    }
}

// ---------------- converters / builders ----------------
__global__ void k_cvt_vs(const float* __restrict__ v, unsigned short* __restrict__ o) {
    int i = blockIdx.x * 256 + threadIdx.x;
    o[i] = f2b(v[i]);
}

// Wcat[ft][k], k = sel*64+c: sel 0..2 -> tc_w taps, sel 3 -> rc_w.  bf16 [64][256]
__global__ void k_wcat(const float* __restrict__ tc_w, const float* __restrict__ rc_w,
                       unsigned short* __restrict__ Wcat) {
    int i = blockIdx.x * 256 + threadIdx.x;              // over 64*256
    if (i >= F_ * 256) return;
    int ft = i >> 8, k = i & 255;
    int sel = k >> 6, c = k & 63;
    float v = (sel < 3) ? tc_w[(ft * C_ + c) * 3 + sel] : rc_w[ft * C_ + c];
    Wcat[i] = f2b(v);
}

// xT[b][ct][m] (bf16) = x[b][m][ct]
__global__ __launch_bounds__(256) void k_transpose_x(const float* __restrict__ x,
                                                     unsigned short* __restrict__ xT) {
    __shared__ float tile[64][65];
    int b = blockIdx.z, m0 = blockIdx.y * 64, ct0 = blockIdx.x * 64;
    int tid = threadIdx.x;
#pragma unroll
    for (int e = 0; e < 16; ++e) {
        int idx = e * 256 + tid; int mm = idx >> 6, cc = idx & 63;
        tile[mm][cc] = x[((size_t)(b * N_ + m0 + mm)) * CT_ + ct0 + cc];
    }
    __syncthreads();
#pragma unroll
    for (int e = 0; e < 16; ++e) {
        int idx = e * 256 + tid; int rr = idx >> 6, mm = idx & 63;
        xT[((size_t)b * CT_ + ct0 + rr) * N_ + m0 + mm] = f2b(tile[mm][rr]);
    }
}

// sigA[b][i][k] (bf16) = sigmoid(dot24(lhs_s[b,i,:], rhs_s[b,:,k]) + b_s[i,k])
__global__ __launch_bounds__(256) void k_sig(const float* __restrict__ lhs_s,
        const float* __restrict__ rhs_s, const float* __restrict__ b_s,
        unsigned short* __restrict__ sigA) {
    int b = blockIdx.z, i0 = blockIdx.y * 64, k0 = blockIdx.x * 256;
    int tid = threadIdx.x;
    __shared__ float lh[64 * T_];
    __shared__ float rh[T_][256];
    for (int e = tid; e < 64 * T_; e += 256) lh[e] = lhs_s[((size_t)b * N_ + i0) * T_ + e];
#pragma unroll
    for (int t = 0; t < T_; ++t) rh[t][tid] = rhs_s[((size_t)b * T_ + t) * N_ + k0 + tid];
    __syncthreads();
    int kg = k0 + tid;
    for (int ii = 0; ii < 64; ++ii) {
        float acc = b_s[(size_t)(i0 + ii) * N_ + kg];
#pragma unroll
        for (int t = 0; t < T_; ++t) acc += lh[ii * T_ + t] * rh[t][tid];
        sigA[((size_t)b * N_ + i0 + ii) * N_ + kg] = f2b(sigmoidf_(acc));
    }
}

// yT[b][f*24+t][k*1024+m] (bf16) = sum_c Theta[k,c,f] * x[b,m,c,t]   (reads xT)
__global__ __launch_bounds__(256) void k_yT(const unsigned short* __restrict__ xT,
        const float* __restrict__ Theta, unsigned short* __restrict__ yT) {
    int b = blockIdx.z, t = blockIdx.y, m0 = blockIdx.x * 256;
    int tid = threadIdx.x;
    float xr[64];
#pragma unroll
    for (int c = 0; c < 64; ++c)
        xr[c] = b2f(xT[((size_t)b * CT_ + c * T_ + t) * N_ + m0 + tid]);
    for (int k = 0; k < 3; ++k) {
        float acc[64];
#pragma unroll
        for (int f = 0; f < 64; ++f) acc[f] = 0.f;
#pragma unroll 4
        for (int c = 0; c < 64; ++c) {
            float xc = xr[c];
            const float* th = Theta + ((size_t)k * 64 + c) * 64;   // uniform -> s_load
#pragma unroll
            for (int f = 0; f < 64; ++f) acc[f] = fmaf(th[f], xc, acc[f]);
        }
#pragma unroll
        for (int f = 0; f < 64; ++f)
            yT[((size_t)b * CT_ + f * T_ + t) * KS_ + k * N_ + m0 + tid] = f2b(acc[f]);
    }
}

// online softmax stats over axis m of S[b,m,i]: mst[b*N+i] = (max, 1/sum)
__global__ void k_smstats(const float* __restrict__ S, float2* __restrict__ mst) {
    int b = blockIdx.y;
    int jj = threadIdx.x % 64;
    int ig = threadIdx.x / 64;
    int j = blockIdx.x * 64 + jj;
    __shared__ float rm[4][64], rs[4][64];
    float m = -1e30f, s = 0.f;
    for (int i = ig; i < N_; i += 4) {
        float v = S[((size_t)b * N_ + i) * N_ + j];
        float mn = fmaxf(m, v);
        s = s * __expf(m - mn) + __expf(v - mn);
        m = mn;
    }
    rm[ig][jj] = m; rs[ig][jj] = s;
    __syncthreads();
    if (ig == 0) {
        float M = rm[0][jj], SS = rs[0][jj];
#pragma unroll
        for (int g = 1; g < 4; ++g) {
            float mg = rm[g][jj];
            float mn = fmaxf(M, mg);
            SS = SS * __expf(M - mn) + rs[g][jj] * __expf(mg - mn);
            M = mn;
        }
        mst[(size_t)b * N_ + j] = make_float2(M, 1.f / SS);
    }
}

// chebSt[b][i][k*1024+m] (bf16) = cheb[k][m][i] * softmax(S)[b][m][i]  (applies stats)
__global__ __launch_bounds__(256) void k_chebSt(const float* __restrict__ cheb,
        const float* __restrict__ S, const float2* __restrict__ mst,
        unsigned short* __restrict__ cs) {
    int b = blockIdx.z, i0 = blockIdx.y * 64, m0 = blockIdx.x * 64;
    int tid = threadIdx.x;
    __shared__ float st[64][65];
    __shared__ float cb[64][65];
    __shared__ float2 sst[64];
    if (tid < 64) sst[tid] = mst[(size_t)b * N_ + i0 + tid];
#pragma unroll
    for (int e = 0; e < 16; ++e) {
        int idx = e * 256 + tid; int mm = idx >> 6, ii = idx & 63;
        st[mm][ii] = S[((size_t)b * N_ + m0 + mm) * N_ + i0 + ii];
    }
    for (int k = 0; k < 3; ++k) {
        __syncthreads();
#pragma unroll
        for (int e = 0; e < 16; ++e) {
            int idx = e * 256 + tid; int mm = idx >> 6, ii = idx & 63;
            cb[mm][ii] = cheb[((size_t)k * N_ + m0 + mm) * N_ + i0 + ii];
        }
        __syncthreads();
#pragma unroll
        for (int e = 0; e < 16; ++e) {
            int idx = e * 256 + tid; int mm = idx & 63, ii = idx >> 6;
            float sm = __expf(st[mm][ii] - sst[ii].x) * sst[ii].y;
            cs[((size_t)b * N_ + i0 + ii) * KS_ + k * N_ + m0 + mm] =
                f2b(sm * cb[mm][ii]);
        }
    }
}

// ---------------- 256x256-tile MFMA GEMM, hybrid counted-vmcnt pipeline ----------------
// Per K-tile: READ kk1 -> MFMA kk0 (covers kk1 reads) -> lgkm(0)+bar ->
// STAGE(kt+2) -> MFMA kk1 (covers stage issue + kt+1 in-flight) -> vmcnt(8|0)+bar
// -> READ next-tile kk0 (exposed only by loop-back).  vmcnt never drains mid-loop.
__global__ __launch_bounds__(512, 2) void k_gemm256(
        const unsigned short* __restrict__ A, long lda, long sA,
        const unsigned short* __restrict__ Bt, long ldb, long sB,
        float* __restrict__ Cc, long ldc, long sC, int K, int nbx, int nby) {
    __shared__ __align__(16) unsigned short As[2][256 * 64];   // 2 x 32KB
    __shared__ __align__(16) unsigned short Bs[2][256 * 64];   // 2 x 32KB
    int tid = threadIdx.x;
    int lane = tid & 63, w = tid >> 6;
    int wy = w >> 2, wx = w & 3;                            // 2 x 4 waves -> 128x64 per wave

    int nwg = gridDim.x;
    int cpx = nwg >> 3;
    int logical = (blockIdx.x & 7) * cpx + (blockIdx.x >> 3);
    int tpb = nbx * nby;
    int b = logical / tpb;
    int tile = logical % tpb;
    int i0 = (tile / nbx) * 256;
    int j0 = (tile % nbx) * 256;

    const unsigned short* Ab = A + (size_t)b * sA + (size_t)i0 * lda;
    const unsigned short* Bb = Bt + (size_t)b * sB + (size_t)j0 * ldb;

    auto STAGE = [&](int kt, int d) {
        int kof = kt << 6;
#pragma unroll
        for (int e = 0; e < 4; ++e) {
            int chunk = e * 512 + tid;
            int row = chunk >> 3, slot = chunk & 7;
            int gslot = slot ^ (row & 7);                   // inverse swizzle on source
            gload_lds16(Ab + (size_t)row * lda + kof + gslot * 8, &As[d][chunk * 8]);
        }
#pragma unroll
        for (int e = 0; e < 4; ++e) {
            int chunk = e * 512 + tid;
            int row = chunk >> 3, slot = chunk & 7;
            int gslot = slot ^ (row & 7);
            gload_lds16(Bb + (size_t)row * ldb + kof + gslot * 8, &Bs[d][chunk * 8]);
        }
    };
    auto READF = [&](short8* af, short8* bfv,
                     const unsigned short* Asb, const unsigned short* Bsb, int kkb) {
#pragma unroll
        for (int mi = 0; mi < 8; ++mi) {
            int r = wy * 128 + mi * 16 + (lane & 15);
            int slot = (kkb + (lane >> 4)) ^ (r & 7);
            af[mi] = *(const short8*)&Asb[r * 64 + slot * 8];
        }
#pragma unroll
        for (int ni = 0; ni < 4; ++ni) {
            int r = wx * 64 + ni * 16 + (lane & 15);
            int slot = (kkb + (lane >> 4)) ^ (r & 7);
            bfv[ni] = *(const short8*)&Bsb[r * 64 + slot * 8];
        }
    };

    f32x4 acc[8][4];
#pragma unroll
    for (int mi = 0; mi < 8; ++mi)
#pragma unroll
        for (int ni = 0; ni < 4; ++ni) acc[mi][ni] = (f32x4){0.f, 0.f, 0.f, 0.f};

    int nt = K >> 6;
    STAGE(0, 0);
    STAGE(1, 1);
    asm volatile("s_waitcnt vmcnt(8)" ::: "memory");        // K-tile 0 resident
    __builtin_amdgcn_s_barrier();
    __builtin_amdgcn_sched_barrier(0);

    short8 a0[8], b0[4], a1[8], b1[4];
    READF(a0, b0, As[0], Bs[0], 0);                         // kk0 of tile 0

    for (int kt = 0; kt < nt; ++kt) {
        int cur = kt & 1;
        READF(a1, b1, As[cur], Bs[cur], 4);                 // kk1 of this tile
        __builtin_amdgcn_s_setprio(1);
#pragma unroll
        for (int mi = 0; mi < 8; ++mi)
#pragma unroll
            for (int ni = 0; ni < 4; ++ni)
                acc[mi][ni] = __builtin_amdgcn_mfma_f32_16x16x32_bf16(
                    a0[mi], b0[ni], acc[mi][ni], 0, 0, 0);
        __builtin_amdgcn_s_setprio(0);
        asm volatile("s_waitcnt lgkmcnt(0)" ::: "memory");  // my reads of buf[cur] done
        __builtin_amdgcn_sched_barrier(0);
        __builtin_amdgcn_s_barrier();                       // all waves done with buf[cur]
        __builtin_amdgcn_sched_barrier(0);
        if (kt + 2 < nt) STAGE(kt + 2, cur);                // overwrite freed buffer
        __builtin_amdgcn_sched_barrier(0);
        __builtin_amdgcn_s_setprio(1);
#pragma unroll
        for (int mi = 0; mi < 8; ++mi)
#pragma unroll
            for (int ni = 0; ni < 4; ++ni)
                acc[mi][ni] = __builtin_amdgcn_mfma_f32_16x16x32_bf16(
                    a1[mi], b1[ni], acc[mi][ni], 0, 0, 0);
        __builtin_amdgcn_s_setprio(0);
        if (kt + 2 < nt) {
            asm volatile("s_waitcnt vmcnt(8)" ::: "memory"); // kt+1 retired, kt+2 in flight
        } else {
            asm volatile("s_waitcnt vmcnt(0)" ::: "memory"); // tail: drain (race-safe)
        }
        __builtin_amdgcn_s_barrier();                       // buf[cur^1] ready for all waves
        __builtin_amdgcn_sched_barrier(0);
        if (kt + 1 < nt)
            READF(a0, b0, As[cur ^ 1], Bs[cur ^ 1], 0);     // kk0 of next tile
    }

    float* Cb = Cc + (size_t)b * sC;
#pragma unroll
    for (int mi = 0; mi < 8; ++mi) {
#pragma unroll
        for (int r = 0; r < 4; ++r) {
            int i = i0 + wy * 128 + mi * 16 + (lane >> 4) * 4 + r;
            float* cp = Cb + (size_t)i * ldc + j0 + wx * 64 + (lane & 15);
#pragma unroll
            for (int ni = 0; ni < 4; ++ni) cp[ni * 16] = acc[mi][ni][r];
        }
    }
}

// ---------------- fused epilogue via MFMA (unchanged) ----------------
__global__ __launch_bounds__(256) void k_final(const float* __restrict__ x,
        const float* __restrict__ sgin, const unsigned short* __restrict__ Wcat,
        const float* __restrict__ tc_b, const float* __restrict__ rc_b,
        const float* __restrict__ ln_g, const float* __restrict__ ln_b,
        float* __restrict__ out) {
    int b = blockIdx.y;
    int n0 = blockIdx.x * 4;
    int tid = threadIdx.x;
    int lane = tid & 63, wv = tid >> 6;

    __shared__ __align__(16) char smem[25600];
    unsigned short* sgb = (unsigned short*)smem;            // [4][26][64]
    unsigned short* xb  = (unsigned short*)(smem + 13312);  // [4][24][64]
    float* Cl = (float*)smem;                               // [96][66] (after reuse barrier)
    __shared__ float tbs[64], gs[64], bbs[64];
    __shared__ float mus[96], rss[96];

    if (tid < 64) {
        tbs[tid] = tc_b[tid] + rc_b[tid];
        gs[tid] = ln_g[tid];
        bbs[tid] = ln_b[tid];
    }
    for (int e = tid; e < 512; e += 256) {
        int nl = e >> 7, r = (e >> 6) & 1, c = e & 63;
        int tt = r ? 25 : 0;
        sgb[(nl * 26 + tt) * 64 + (((c >> 3) ^ (tt & 7)) << 3) + (c & 7)] = 0;
    }
    size_t base = ((size_t)b * N_ + n0) * CT_;
#pragma unroll
    for (int i = 0; i < 24; ++i) {
        int e = i * 256 + tid;
        int nl = e / CT_;
        int rem = e - nl * CT_;
        int c = rem / 24;
        int tl = rem - c * 24;
        float sv = fmaxf(sgin[base + e], 0.f);
        float xv = x[base + e];
        int tt = tl + 1;
        sgb[(nl * 26 + tt) * 64 + (((c >> 3) ^ (tt & 7)) << 3) + (c & 7)] = f2b(sv);
        xb[(nl * 24 + tl) * 64 + (((c >> 3) ^ (tl & 7)) << 3) + (c & 7)] = f2b(xv);
    }

    int ft = wv * 16 + (lane & 15);
    int g4 = lane >> 4;
    short8 bfr[8];
#pragma unroll
    for (int ks = 0; ks < 8; ++ks)
        bfr[ks] = *(const short8*)&Wcat[ft * 256 + ks * 32 + g4 * 8];

    int rnl[6], rt[6];
#pragma unroll
    for (int mi = 0; mi < 6; ++mi) {
        int row = mi * 16 + (lane & 15);
        rnl[mi] = row / 24;
        rt[mi] = row - rnl[mi] * 24;
    }

    __syncthreads();

    f32x4 acc[6];
#pragma unroll
    for (int mi = 0; mi < 6; ++mi) acc[mi] = (f32x4){0.f, 0.f, 0.f, 0.f};
#pragma unroll
    for (int mi = 0; mi < 6; ++mi) {
        int nl = rnl[mi], t = rt[mi];
#pragma unroll
        for (int ks = 0; ks < 8; ++ks) {
            const int sel = ks >> 1;
            int slot = (ks & 1) * 4 + g4;
            short8 af;
            if (sel < 3) {
                int tt = t + sel;
                af = *(const short8*)&sgb[(nl * 26 + tt) * 64 + ((slot ^ (tt & 7)) << 3)];
            } else {
                af = *(const short8*)&xb[(nl * 24 + t) * 64 + ((slot ^ (t & 7)) << 3)];
            }
            acc[mi] = __builtin_amdgcn_mfma_f32_16x16x32_bf16(af, bfr[ks], acc[mi], 0, 0, 0);
        }
    }

    __syncthreads();
#pragma unroll
    for (int mi = 0; mi < 6; ++mi)
#pragma unroll
        for (int r = 0; r < 4; ++r)
            Cl[(mi * 16 + (lane >> 4) * 4 + r) * 66 + wv * 16 + (lane & 15)] = acc[mi][r];
    __syncthreads();

    if (tid < 96) {
        float s = 0.f, s2 = 0.f;
#pragma unroll
        for (int f = 0; f < 64; ++f) {
            float v = fmaxf(Cl[tid * 66 + f] + tbs[f], 0.f);
            s += v; s2 += v * v;
        }
        float mu = s * (1.f / 64.f);
        float var = s2 * (1.f / 64.f) - mu * mu;
        mus[tid] = mu;
        rss[tid] = rsqrtf(var + 1e-5f);
    }
    __syncthreads();

#pragma unroll
    for (int i = 0; i < 24; ++i) {
        int e = i * 256 + tid;
        int nl = e / CT_;
        int rem = e - nl * CT_;
        int f = rem / 24;
        int t = rem - f * 24;
        int row = nl * 24 + t;
        float v = fmaxf(Cl[row * 66 + f] + tbs[f], 0.f);
        out[base + e] = (v - mus[row]) * rss[row] * gs[f] + bbs[f];
    }
}

extern "C" void kernel_launch(void* const* d_in, const int* in_sizes, int n_in,
                              void* d_out, int out_size, void* d_ws, size_t ws_size,
                              hipStream_t stream) {
    const float* x    = (const float*)d_in[0];
    const float* cheb = (const float*)d_in[1];
    const float* U1   = (const float*)d_in[2];
    const float* U2   = (const float*)d_in[3];
    const float* U3   = (const float*)d_in[4];
    const float* b_e  = (const float*)d_in[5];
    const float* V_e  = (const float*)d_in[6];
    const float* W1   = (const float*)d_in[7];
    const float* W2   = (const float*)d_in[8];
    const float* W3   = (const float*)d_in[9];
    const float* b_s  = (const float*)d_in[10];
    const float* V_s  = (const float*)d_in[11];
    const float* Theta= (const float*)d_in[12];
    const float* tc_w = (const float*)d_in[13];
    const float* tc_b = (const float*)d_in[14];
    const float* rc_w = (const float*)d_in[15];
    const float* rc_b = (const float*)d_in[16];
    const float* ln_g = (const float*)d_in[17];
    const float* ln_b = (const float*)d_in[18];
    float* out = (float*)d_out;

    char* base = (char*)d_ws;
    size_t o = 0;
    auto alloc = [&](size_t bytes) { size_t r = o; o += (bytes + 255) & ~(size_t)255; return r; };
    float* lhs_t   = (float*)(base + alloc((size_t)B_ * T_ * N_ * 4));
    float* rhs_t   = (float*)(base + alloc((size_t)B_ * N_ * T_ * 4));
    float* Ebuf    = (float*)(base + alloc((size_t)B_ * T_ * T_ * 4));
    float* partial = (float*)(base + alloc((size_t)B_ * 16 * CT_ * 4));
    float* lhs_t0  = (float*)(base + alloc((size_t)B_ * CT_ * 4));
    float* lhs_s   = (float*)(base + alloc((size_t)B_ * N_ * T_ * 4));
    float* rhs_s   = (float*)(base + alloc((size_t)B_ * T_ * N_ * 4));
    unsigned short* V_sb = (unsigned short*)(base + alloc((size_t)N_ * N_ * 2));
    unsigned short* Wcat = (unsigned short*)(base + alloc((size_t)F_ * 256 * 2));
    float2* mstats = (float2*)(base + alloc((size_t)B_ * N_ * 8));
    size_t regA = alloc((size_t)B_ * N_ * KS_ * 2);   // xT (bf16) -> chebSt (bf16)
    size_t regB = alloc((size_t)B_ * CT_ * KS_ * 2);  // sigA (bf16) -> yT (bf16)
    unsigned short* xT     = (unsigned short*)(base + regA);
    unsigned short* chebSt = (unsigned short*)(base + regA);
    unsigned short* sigA   = (unsigned short*)(base + regB);
    unsigned short* yT     = (unsigned short*)(base + regB);
    float* Sb  = out;        // S scores live in d_out until the stacked GEMM overwrites
    float* gcn = out;

    dim3 b256(256);
    k_cvt_vs<<<dim3(N_ * N_ / 256), b256, 0, stream>>>(V_s, V_sb);
    k_wcat<<<dim3((F_ * 256 + 255) / 256), b256, 0, stream>>>(tc_w, rc_w, Wcat);
    k_rhs_t<<<dim3((B_ * N_ * T_) / 256), b256, 0, stream>>>(x, U3, rhs_t);
    k_lhs_partial<<<dim3(16, B_), b256, 0, stream>>>(x, U1, partial);
    k_lhs_reduce<<<dim3((B_ * CT_) / 256), b256, 0, stream>>>(partial, lhs_t0);
    k_lhs_t<<<dim3((B_ * T_ * N_) / 256), b256, 0, stream>>>(lhs_t0, U2, lhs_t);
    k_temporal_E<<<dim3(B_), dim3(576), 0, stream>>>(lhs_t, rhs_t, b_e, V_e, Ebuf);
    k_tspatial<<<dim3(N_ / 4, B_), b256, 0, stream>>>(x, Ebuf, W1, W2, W3, lhs_s, rhs_s);
    k_transpose_x<<<dim3(CT_ / 64, N_ / 64, B_), b256, 0, stream>>>(x, xT);
    k_sig<<<dim3(N_ / 256, N_ / 64, B_), b256, 0, stream>>>(lhs_s, rhs_s, b_s, sigA);
    // S0 GEMM: M=1024, Ncols=1024, K=1024; nwg=512 (%8==0)
    k_gemm256<<<dim3(B_ * 4 * 4), dim3(512), 0, stream>>>(
        sigA, N_, (long)N_ * N_, V_sb, N_, 0, Sb, N_, (long)N_ * N_, N_, 4, 4);
    k_smstats<<<dim3(N_ / 64, B_), b256, 0, stream>>>(Sb, mstats);
    k_yT<<<dim3(N_ / 256, T_, B_), b256, 0, stream>>>(xT, Theta, yT);          // sigA dead
    k_chebSt<<<dim3(N_ / 64, N_ / 64, B_), b256, 0, stream>>>(cheb, Sb, mstats, chebSt); // xT dead
    // stacked GEMM: M=1024, Ncols=1536, K=3072; nwg=768 (%8==0)
    k_gemm256<<<dim3(B_ * 4 * 6), dim3(512), 0, stream>>>(
        chebSt, KS_, (long)N_ * KS_, yT, KS_, (long)CT_ * KS_,
        gcn, CT_, (long)N_ * CT_, KS_, 6, 4);                                 // Sb dead
    k_final<<<dim3(N_ / 4, B_), b256, 0, stream>>>(x, gcn, Wcat, tc_b, rc_b,
                                                   ln_g, ln_b, out);
}

// Round 9
// 1276.272 us; speedup vs baseline: 10.5313x; 1.1299x over previous
//
#include <hip/hip_runtime.h>

typedef __attribute__((ext_vector_type(8))) short short8;   // 8 bf16 (4 VGPRs)
typedef __attribute__((ext_vector_type(4))) float f32x4;

constexpr int B_ = 32;
constexpr int N_ = 1024;
constexpr int C_ = 64;
constexpr int T_ = 24;
constexpr int F_ = 64;
constexpr int CT_ = C_ * T_;     // 1536
constexpr int KS_ = 3072;        // stacked K = 3*1024

__device__ __forceinline__ float sigmoidf_(float x) {
    return 1.0f / (1.0f + __expf(-x));
}
__device__ __forceinline__ unsigned short f2b(float f) {   // RNE f32->bf16
    union { float f; unsigned u; } v; v.f = f;
    unsigned r = v.u + 0x7FFFu + ((v.u >> 16) & 1u);
    return (unsigned short)(r >> 16);
}
__device__ __forceinline__ float b2f(unsigned short h) {
    union { unsigned u; float f; } v; v.u = ((unsigned)h) << 16; return v.f;
}
__device__ __forceinline__ void gload_lds16(const unsigned short* g, unsigned short* l) {
    __builtin_amdgcn_global_load_lds(
        (const __attribute__((address_space(1))) unsigned int*)g,
        (__attribute__((address_space(3))) unsigned int*)l, 16, 0, 0);
}

// ---------------- temporal attention prep ----------------
__global__ void k_rhs_t(const float* __restrict__ x, const float* __restrict__ U3,
                        float* __restrict__ rhs_t) {
    int idx = blockIdx.x * 256 + threadIdx.x;
    if (idx >= B_ * N_ * T_) return;
    int t = idx % T_;
    int n = (idx / T_) % N_;
    int b = idx / (N_ * T_);
    const float* xp = x + ((size_t)(b * N_ + n)) * CT_ + t;
    float acc = 0.f;
#pragma unroll
    for (int c = 0; c < C_; ++c) acc += U3[c] * xp[c * T_];
    rhs_t[idx] = acc;
}

__global__ void k_lhs_partial(const float* __restrict__ x, const float* __restrict__ U1,
                              float* __restrict__ partial) {
    int b = blockIdx.y, chunk = blockIdx.x;
    int tid = threadIdx.x;
    float acc[6] = {0, 0, 0, 0, 0, 0};
    int n0 = chunk * 64;
    for (int nn = 0; nn < 64; ++nn) {
        int n = n0 + nn;
        float u = U1[n];
        const float* xp = x + ((size_t)(b * N_ + n)) * CT_;
#pragma unroll
        for (int e = 0; e < 6; ++e) acc[e] += u * xp[tid + e * 256];
    }
    float* pp = partial + ((size_t)(b * 16 + chunk)) * CT_;
#pragma unroll
    for (int e = 0; e < 6; ++e) pp[tid + e * 256] = acc[e];
}

__global__ void k_lhs_reduce(const float* __restrict__ partial, float* __restrict__ lhs_t0) {
    int idx = blockIdx.x * 256 + threadIdx.x;
    if (idx >= B_ * CT_) return;
    int b = idx / CT_, flat = idx % CT_;
    float acc = 0.f;
#pragma unroll
    for (int ch = 0; ch < 16; ++ch) acc += partial[((size_t)(b * 16 + ch)) * CT_ + flat];
    lhs_t0[idx] = acc;
}

__global__ void k_lhs_t(const float* __restrict__ lhs_t0, const float* __restrict__ U2,
                        float* __restrict__ lhs_t) {
    int idx = blockIdx.x * 256 + threadIdx.x;
    if (idx >= B_ * T_ * N_) return;
    int n2 = idx % N_;
    int t = (idx / N_) % T_;
    int b = idx / (T_ * N_);
    const float* l0 = lhs_t0 + (size_t)b * CT_;
    float acc = 0.f;
#pragma unroll
    for (int c = 0; c < C_; ++c) acc += l0[c * T_ + t] * U2[c * N_ + n2];
    lhs_t[idx] = acc;
}

__global__ void k_temporal_E(const float* __restrict__ lhs_t, const float* __restrict__ rhs_t,
                             const float* __restrict__ b_e, const float* __restrict__ V_e,
                             float* __restrict__ E) {
    int b = blockIdx.x;
    int tid = threadIdx.x;                               // 576 threads
    int i = tid / T_, u = tid % T_;
    __shared__ float sig[T_][T_];
    __shared__ float e0s[T_][T_];
    __shared__ float mcol[T_], scol[T_];
    const float* lt = lhs_t + (size_t)b * T_ * N_ + (size_t)i * N_;
    const float* rt = rhs_t + (size_t)b * N_ * T_ + u;
    float acc = 0.f;
    for (int n = 0; n < N_; ++n) acc += lt[n] * rt[(size_t)n * T_];
    sig[i][u] = sigmoidf_(acc + b_e[i * T_ + u]);
    __syncthreads();
    int j = u;
    float e0 = 0.f;
#pragma unroll
    for (int kk = 0; kk < T_; ++kk) e0 += sig[i][kk] * V_e[j * T_ + kk];
    e0s[i][j] = e0;
    __syncthreads();
    if (tid < T_) {
        float mx = -1e30f;
        for (int ii = 0; ii < T_; ++ii) mx = fmaxf(mx, e0s[ii][tid]);
        float s = 0.f;
        for (int ii = 0; ii < T_; ++ii) s += __expf(e0s[ii][tid] - mx);
        mcol[tid] = mx; scol[tid] = s;
    }
    __syncthreads();
    E[(size_t)b * T_ * T_ + i * T_ + j] = __expf(e0s[i][j] - mcol[j]) / scol[j];
}

// ---------------- fused: x_TAt (in-register) -> spatial prep ----------------
__global__ __launch_bounds__(256) void k_tspatial(const float* __restrict__ x,
        const float* __restrict__ E, const float* __restrict__ W1g,
        const float* __restrict__ W2, const float* __restrict__ W3g,
        float* __restrict__ lhs_s, float* __restrict__ rhs_s) {
    int b = blockIdx.y;
    int n0 = blockIdx.x * 4;
    int tid = threadIdx.x;
    __shared__ float Es[T_ * T_];
    __shared__ float W1s[T_];
    __shared__ float W2s[C_ * T_];
    __shared__ float xr[4][64][25];                      // staged x, then reused for w3*u
    __shared__ float l0s[4][64];
    for (int e = tid; e < T_ * T_; e += 256) Es[e] = E[(size_t)b * T_ * T_ + e];
    for (int e = tid; e < C_ * T_; e += 256) W2s[e] = W2[e];
    if (tid < T_) W1s[tid] = W1g[tid];
    size_t base = ((size_t)b * N_ + n0) * CT_;
#pragma unroll
    for (int i = 0; i < 24; ++i) {
        int e = i * 256 + tid;
        int nl = e / CT_; int rem = e - nl * CT_; int c = rem / 24; int t = rem - c * 24;
        xr[nl][c][t] = x[base + e];
    }
    __syncthreads();
    int nl = tid >> 6, c = tid & 63;
    float xv[T_];
#pragma unroll
    for (int t = 0; t < T_; ++t) xv[t] = xr[nl][c][t];
    float w3 = W3g[c];
    float u[T_];
#pragma unroll
    for (int j = 0; j < T_; ++j) {
        float a = 0.f;
#pragma unroll
        for (int t = 0; t < T_; ++t) a += xv[t] * Es[t * T_ + j];
        u[j] = a;
    }
    float l0 = 0.f;
#pragma unroll
    for (int j = 0; j < T_; ++j) l0 += u[j] * W1s[j];
#pragma unroll
    for (int j = 0; j < T_; ++j) xr[nl][c][j] = w3 * u[j];
    l0s[nl][c] = l0;
    __syncthreads();
    if (tid < 4 * T_) {
        int t = tid % T_, g = tid / T_;
        float racc = 0.f, lacc = 0.f;
        for (int cc = 0; cc < 64; ++cc) {
            racc += xr[g][cc][t];
            lacc += l0s[g][cc] * W2s[cc * T_ + t];
        }
        rhs_s[((size_t)b * T_ + t) * N_ + n0 + g] = racc;
        lhs_s[((size_t)(b * N_ + n0 + g)) * T_ + t] = lacc;
    }
}

// ---------------- converters / builders ----------------
__global__ void k_cvt_vs(const float* __restrict__ v, unsigned short* __restrict__ o) {
    int i = blockIdx.x * 256 + threadIdx.x;
    o[i] = f2b(v[i]);
}

// Wcat[ft][k], k = sel*64+c: sel 0..2 -> tc_w taps, sel 3 -> rc_w.  bf16 [64][256]
__global__ void k_wcat(const float* __restrict__ tc_w, const float* __restrict__ rc_w,
                       unsigned short* __restrict__ Wcat) {
    int i = blockIdx.x * 256 + threadIdx.x;              // over 64*256
    if (i >= F_ * 256) return;
    int ft = i >> 8, k = i & 255;
    int sel = k >> 6, c = k & 63;
    float v = (sel < 3) ? tc_w[(ft * C_ + c) * 3 + sel] : rc_w[ft * C_ + c];
    Wcat[i] = f2b(v);
}

// Thp[k*64+f][c] (bf16) = Theta[k][c][f]   -- A-operand for k_yTmm
__global__ void k_thp(const float* __restrict__ Theta, unsigned short* __restrict__ Thp) {
    int i = blockIdx.x * 256 + threadIdx.x;              // over 192*64
    if (i >= 192 * 64) return;
    int kf = i >> 6, c = i & 63;
    int k = kf >> 6, f = kf & 63;
    Thp[i] = f2b(Theta[((size_t)k * 64 + c) * 64 + f]);
}

// xTt[b][t][m][c] (bf16) = x[b][m][c][t]   -- K(c)-contiguous rows for k_yTmm
__global__ __launch_bounds__(256) void k_transpose_xt(const float* __restrict__ x,
        unsigned short* __restrict__ xTt) {
    int b = blockIdx.y, m0 = blockIdx.x * 16;
    int tid = threadIdx.x;
    __shared__ unsigned short tl[16 * CT_];              // 48KB, [ml][c*24+t]
    size_t base = ((size_t)b * N_ + m0) * CT_;
#pragma unroll 4
    for (int e = 0; e < 96; ++e) {
        int idx = e * 256 + tid;
        tl[idx] = f2b(x[base + idx]);
    }
    __syncthreads();
#pragma unroll 4
    for (int e = 0; e < 96; ++e) {
        int idx = e * 256 + tid;
        int c = idx & 63;
        int ml = (idx >> 6) & 15;
        int t = idx >> 10;                               // 0..23
        xTt[((size_t)(b * T_ + t) * N_ + m0 + ml) * 64 + c] = tl[ml * CT_ + c * 24 + t];
    }
}

// sigA[b][i][k] (bf16) = sigmoid(dot24(lhs_s[b,i,:], rhs_s[b,:,k]) + b_s[i,k])
__global__ __launch_bounds__(256) void k_sig(const float* __restrict__ lhs_s,
        const float* __restrict__ rhs_s, const float* __restrict__ b_s,
        unsigned short* __restrict__ sigA) {
    int b = blockIdx.z, i0 = blockIdx.y * 64, k0 = blockIdx.x * 256;
    int tid = threadIdx.x;
    __shared__ float lh[64 * T_];
    __shared__ float rh[T_][256];
    for (int e = tid; e < 64 * T_; e += 256) lh[e] = lhs_s[((size_t)b * N_ + i0) * T_ + e];
#pragma unroll
    for (int t = 0; t < T_; ++t) rh[t][tid] = rhs_s[((size_t)b * T_ + t) * N_ + k0 + tid];
    __syncthreads();
    int kg = k0 + tid;
    for (int ii = 0; ii < 64; ++ii) {
        float acc = b_s[(size_t)(i0 + ii) * N_ + kg];
#pragma unroll
        for (int t = 0; t < T_; ++t) acc += lh[ii * T_ + t] * rh[t][tid];
        sigA[((size_t)b * N_ + i0 + ii) * N_ + kg] = f2b(sigmoidf_(acc));
    }
}

// ---------------- yT via MFMA: yT[b][f*24+t][k*1024+m] = sum_c Thp[kf][c]*xTt[b][t][m][c]
// Block: (m-tile 128, b*24+t).  256 thr = 4 waves; wave w owns m [w*32, w*32+32),
// all 192 kf rows.  K=64, single tile; T2-swizzled staging (same as k_gemm256).
__global__ __launch_bounds__(256) void k_yTmm(const unsigned short* __restrict__ xTt,
        const unsigned short* __restrict__ Thp, unsigned short* __restrict__ yT) {
    int bt = blockIdx.y;
    int b = bt / T_, t = bt - b * T_;
    int m0 = blockIdx.x * 128;
    int tid = threadIdx.x;
    int lane = tid & 63, wv = tid >> 6;
    __shared__ __align__(16) unsigned short Asb[192 * 64];   // Thp, swizzled
    __shared__ __align__(16) unsigned short Bsb[128 * 64];   // xTt m-tile, swizzled
#pragma unroll
    for (int e = 0; e < 6; ++e) {                        // stage Thp (24KB)
        int chunk = e * 256 + tid;
        int row = chunk >> 3, slot = chunk & 7;
        int gslot = slot ^ (row & 7);
        gload_lds16(Thp + row * 64 + gslot * 8, &Asb[chunk * 8]);
    }
    const unsigned short* Bg = xTt + ((size_t)bt * N_ + m0) * 64;
#pragma unroll
    for (int e = 0; e < 4; ++e) {                        // stage B (16KB)
        int chunk = e * 256 + tid;
        int row = chunk >> 3, slot = chunk & 7;
        int gslot = slot ^ (row & 7);
        gload_lds16(Bg + (size_t)row * 64 + gslot * 8, &Bsb[chunk * 8]);
    }
    __syncthreads();                                     // drains vmcnt

    short8 bf[2][2];
#pragma unroll
    for (int ni = 0; ni < 2; ++ni)
#pragma unroll
        for (int kk = 0; kk < 2; ++kk) {
            int r = wv * 32 + ni * 16 + (lane & 15);
            int slot = (kk * 4 + (lane >> 4)) ^ (r & 7);
            bf[ni][kk] = *(const short8*)&Bsb[r * 64 + slot * 8];
        }
    f32x4 acc[12][2];
#pragma unroll
    for (int mi = 0; mi < 12; ++mi)
#pragma unroll
        for (int ni = 0; ni < 2; ++ni) acc[mi][ni] = (f32x4){0.f, 0.f, 0.f, 0.f};
#pragma unroll
    for (int mi = 0; mi < 12; ++mi) {
        short8 af[2];
#pragma unroll
        for (int kk = 0; kk < 2; ++kk) {
            int r = mi * 16 + (lane & 15);
            int slot = (kk * 4 + (lane >> 4)) ^ (r & 7);
            af[kk] = *(const short8*)&Asb[r * 64 + slot * 8];
        }
#pragma unroll
        for (int kk = 0; kk < 2; ++kk)
#pragma unroll
            for (int ni = 0; ni < 2; ++ni)
                acc[mi][ni] = __builtin_amdgcn_mfma_f32_16x16x32_bf16(
                    af[kk], bf[ni][kk], acc[mi][ni], 0, 0, 0);
    }
    // store: kf = mi*16 + (lane>>4)*4 + r; m = m0 + wv*32 + ni*16 + (lane&15)
    int mcol = m0 + wv * 32 + (lane & 15);
#pragma unroll
    for (int mi = 0; mi < 12; ++mi) {
#pragma unroll
        for (int r = 0; r < 4; ++r) {
            int kf = mi * 16 + (lane >> 4) * 4 + r;
            int k = kf >> 6, f = kf & 63;
            unsigned short* yp = yT + ((size_t)b * CT_ + f * T_ + t) * KS_ + k * N_ + mcol;
#pragma unroll
            for (int ni = 0; ni < 2; ++ni) yp[ni * 16] = f2b(acc[mi][ni][r]);
        }
    }
}

// online softmax stats over axis m of S[b,m,i]: mst[b*N+i] = (max, 1/sum)
__global__ void k_smstats(const float* __restrict__ S, float2* __restrict__ mst) {
    int b = blockIdx.y;
    int jj = threadIdx.x % 64;
    int ig = threadIdx.x / 64;
    int j = blockIdx.x * 64 + jj;
    __shared__ float rm[4][64], rs[4][64];
    float m = -1e30f, s = 0.f;
    for (int i = ig; i < N_; i += 4) {
        float v = S[((size_t)b * N_ + i) * N_ + j];
        float mn = fmaxf(m, v);
        s = s * __expf(m - mn) + __expf(v - mn);
        m = mn;
    }
    rm[ig][jj] = m; rs[ig][jj] = s;
    __syncthreads();
    if (ig == 0) {
        float M = rm[0][jj], SS = rs[0][jj];
#pragma unroll
        for (int g = 1; g < 4; ++g) {
            float mg = rm[g][jj];
            float mn = fmaxf(M, mg);
            SS = SS * __expf(M - mn) + rs[g][jj] * __expf(mg - mn);
            M = mn;
        }
        mst[(size_t)b * N_ + j] = make_float2(M, 1.f / SS);
    }
}

// chebSt[b][i][k*1024+m] (bf16) = cheb[k][m][i] * softmax(S)[b][m][i]  (applies stats)
__global__ __launch_bounds__(256) void k_chebSt(const float* __restrict__ cheb,
        const float* __restrict__ S, const float2* __restrict__ mst,
        unsigned short* __restrict__ cs) {
    int b = blockIdx.z, i0 = blockIdx.y * 64, m0 = blockIdx.x * 64;
    int tid = threadIdx.x;
    __shared__ float st[64][65];
    __shared__ float cb[64][65];
    __shared__ float2 sst[64];
    if (tid < 64) sst[tid] = mst[(size_t)b * N_ + i0 + tid];
#pragma unroll
    for (int e = 0; e < 16; ++e) {
        int idx = e * 256 + tid; int mm = idx >> 6, ii = idx & 63;
        st[mm][ii] = S[((size_t)b * N_ + m0 + mm) * N_ + i0 + ii];
    }
    for (int k = 0; k < 3; ++k) {
        __syncthreads();
#pragma unroll
        for (int e = 0; e < 16; ++e) {
            int idx = e * 256 + tid; int mm = idx >> 6, ii = idx & 63;
            cb[mm][ii] = cheb[((size_t)k * N_ + m0 + mm) * N_ + i0 + ii];
        }
        __syncthreads();
#pragma unroll
        for (int e = 0; e < 16; ++e) {
            int idx = e * 256 + tid; int mm = idx & 63, ii = idx >> 6;
            float sm = __expf(st[mm][ii] - sst[ii].x) * sst[ii].y;
            cs[((size_t)b * N_ + i0 + ii) * KS_ + k * N_ + m0 + mm] =
                f2b(sm * cb[mm][ii]);
        }
    }
}

// ---------------- 256x256-tile MFMA GEMM, hybrid counted-vmcnt pipeline ----------------
__global__ __launch_bounds__(512, 2) void k_gemm256(
        const unsigned short* __restrict__ A, long lda, long sA,
        const unsigned short* __restrict__ Bt, long ldb, long sB,
        float* __restrict__ Cc, long ldc, long sC, int K, int nbx, int nby) {
    __shared__ __align__(16) unsigned short As[2][256 * 64];   // 2 x 32KB
    __shared__ __align__(16) unsigned short Bs[2][256 * 64];   // 2 x 32KB
    int tid = threadIdx.x;
    int lane = tid & 63, w = tid >> 6;
    int wy = w >> 2, wx = w & 3;                            // 2 x 4 waves -> 128x64 per wave

    int nwg = gridDim.x;
    int cpx = nwg >> 3;
    int logical = (blockIdx.x & 7) * cpx + (blockIdx.x >> 3);
    int tpb = nbx * nby;
    int b = logical / tpb;
    int tile = logical % tpb;
    int i0 = (tile / nbx) * 256;
    int j0 = (tile % nbx) * 256;

    const unsigned short* Ab = A + (size_t)b * sA + (size_t)i0 * lda;
    const unsigned short* Bb = Bt + (size_t)b * sB + (size_t)j0 * ldb;

    auto STAGE = [&](int kt, int d) {
        int kof = kt << 6;
#pragma unroll
        for (int e = 0; e < 4; ++e) {
            int chunk = e * 512 + tid;
            int row = chunk >> 3, slot = chunk & 7;
            int gslot = slot ^ (row & 7);                   // inverse swizzle on source
            gload_lds16(Ab + (size_t)row * lda + kof + gslot * 8, &As[d][chunk * 8]);
        }
#pragma unroll
        for (int e = 0; e < 4; ++e) {
            int chunk = e * 512 + tid;
            int row = chunk >> 3, slot = chunk & 7;
            int gslot = slot ^ (row & 7);
            gload_lds16(Bb + (size_t)row * ldb + kof + gslot * 8, &Bs[d][chunk * 8]);
        }
    };
    auto READF = [&](short8* af, short8* bfv,
                     const unsigned short* Asb, const unsigned short* Bsb, int kkb) {
#pragma unroll
        for (int mi = 0; mi < 8; ++mi) {
            int r = wy * 128 + mi * 16 + (lane & 15);
            int slot = (kkb + (lane >> 4)) ^ (r & 7);
            af[mi] = *(const short8*)&Asb[r * 64 + slot * 8];
        }
#pragma unroll
        for (int ni = 0; ni < 4; ++ni) {
            int r = wx * 64 + ni * 16 + (lane & 15);
            int slot = (kkb + (lane >> 4)) ^ (r & 7);
            bfv[ni] = *(const short8*)&Bsb[r * 64 + slot * 8];
        }
    };

    f32x4 acc[8][4];
#pragma unroll
    for (int mi = 0; mi < 8; ++mi)
#pragma unroll
        for (int ni = 0; ni < 4; ++ni) acc[mi][ni] = (f32x4){0.f, 0.f, 0.f, 0.f};

    int nt = K >> 6;
    STAGE(0, 0);
    STAGE(1, 1);
    asm volatile("s_waitcnt vmcnt(8)" ::: "memory");        // K-tile 0 resident
    __builtin_amdgcn_s_barrier();
    __builtin_amdgcn_sched_barrier(0);

    short8 a0[8], b0[4], a1[8], b1[4];
    READF(a0, b0, As[0], Bs[0], 0);                         // kk0 of tile 0

    for (int kt = 0; kt < nt; ++kt) {
        int cur = kt & 1;
        READF(a1, b1, As[cur], Bs[cur], 4);                 // kk1 of this tile
        __builtin_amdgcn_s_setprio(1);
#pragma unroll
        for (int mi = 0; mi < 8; ++mi)
#pragma unroll
            for (int ni = 0; ni < 4; ++ni)
                acc[mi][ni] = __builtin_amdgcn_mfma_f32_16x16x32_bf16(
                    a0[mi], b0[ni], acc[mi][ni], 0, 0, 0);
        __builtin_amdgcn_s_setprio(0);
        asm volatile("s_waitcnt lgkmcnt(0)" ::: "memory");  // my reads of buf[cur] done
        __builtin_amdgcn_sched_barrier(0);
        __builtin_amdgcn_s_barrier();                       // all waves done with buf[cur]
        __builtin_amdgcn_sched_barrier(0);
        if (kt + 2 < nt) STAGE(kt + 2, cur);                // overwrite freed buffer
        __builtin_amdgcn_sched_barrier(0);
        __builtin_amdgcn_s_setprio(1);
#pragma unroll
        for (int mi = 0; mi < 8; ++mi)
#pragma unroll
            for (int ni = 0; ni < 4; ++ni)
                acc[mi][ni] = __builtin_amdgcn_mfma_f32_16x16x32_bf16(
                    a1[mi], b1[ni], acc[mi][ni], 0, 0, 0);
        __builtin_amdgcn_s_setprio(0);
        if (kt + 2 < nt) {
            asm volatile("s_waitcnt vmcnt(8)" ::: "memory"); // kt+1 retired, kt+2 in flight
        } else {
            asm volatile("s_waitcnt vmcnt(0)" ::: "memory"); // tail: drain (race-safe)
        }
        __builtin_amdgcn_s_barrier();                       // buf[cur^1] ready for all waves
        __builtin_amdgcn_sched_barrier(0);
        if (kt + 1 < nt)
            READF(a0, b0, As[cur ^ 1], Bs[cur ^ 1], 0);     // kk0 of next tile
    }

    float* Cb = Cc + (size_t)b * sC;
#pragma unroll
    for (int mi = 0; mi < 8; ++mi) {
#pragma unroll
        for (int r = 0; r < 4; ++r) {
            int i = i0 + wy * 128 + mi * 16 + (lane >> 4) * 4 + r;
            float* cp = Cb + (size_t)i * ldc + j0 + wx * 64 + (lane & 15);
#pragma unroll
            for (int ni = 0; ni < 4; ++ni) cp[ni * 16] = acc[mi][ni][r];
        }
    }
}

// ---------------- fused epilogue via MFMA (unchanged) ----------------
__global__ __launch_bounds__(256) void k_final(const float* __restrict__ x,
        const float* __restrict__ sgin, const unsigned short* __restrict__ Wcat,
        const float* __restrict__ tc_b, const float* __restrict__ rc_b,
        const float* __restrict__ ln_g, const float* __restrict__ ln_b,
        float* __restrict__ out) {
    int b = blockIdx.y;
    int n0 = blockIdx.x * 4;
    int tid = threadIdx.x;
    int lane = tid & 63, wv = tid >> 6;

    __shared__ __align__(16) char smem[25600];
    unsigned short* sgb = (unsigned short*)smem;            // [4][26][64]
    unsigned short* xb  = (unsigned short*)(smem + 13312);  // [4][24][64]
    float* Cl = (float*)smem;                               // [96][66] (after reuse barrier)
    __shared__ float tbs[64], gs[64], bbs[64];
    __shared__ float mus[96], rss[96];

    if (tid < 64) {
        tbs[tid] = tc_b[tid] + rc_b[tid];
        gs[tid] = ln_g[tid];
        bbs[tid] = ln_b[tid];
    }
    for (int e = tid; e < 512; e += 256) {
        int nl = e >> 7, r = (e >> 6) & 1, c = e & 63;
        int tt = r ? 25 : 0;
        sgb[(nl * 26 + tt) * 64 + (((c >> 3) ^ (tt & 7)) << 3) + (c & 7)] = 0;
    }
    size_t base = ((size_t)b * N_ + n0) * CT_;
#pragma unroll
    for (int i = 0; i < 24; ++i) {
        int e = i * 256 + tid;
        int nl = e / CT_;
        int rem = e - nl * CT_;
        int c = rem / 24;
        int tl = rem - c * 24;
        float sv = fmaxf(sgin[base + e], 0.f);
        float xv = x[base + e];
        int tt = tl + 1;
        sgb[(nl * 26 + tt) * 64 + (((c >> 3) ^ (tt & 7)) << 3) + (c & 7)] = f2b(sv);
        xb[(nl * 24 + tl) * 64 + (((c >> 3) ^ (tl & 7)) << 3) + (c & 7)] = f2b(xv);
    }

    int ft = wv * 16 + (lane & 15);
    int g4 = lane >> 4;
    short8 bfr[8];
#pragma unroll
    for (int ks = 0; ks < 8; ++ks)
        bfr[ks] = *(const short8*)&Wcat[ft * 256 + ks * 32 + g4 * 8];

    int rnl[6], rt[6];
#pragma unroll
    for (int mi = 0; mi < 6; ++mi) {
        int row = mi * 16 + (lane & 15);
        rnl[mi] = row / 24;
        rt[mi] = row - rnl[mi] * 24;
    }

    __syncthreads();

    f32x4 acc[6];
#pragma unroll
    for (int mi = 0; mi < 6; ++mi) acc[mi] = (f32x4){0.f, 0.f, 0.f, 0.f};
#pragma unroll
    for (int mi = 0; mi < 6; ++mi) {
        int nl = rnl[mi], t = rt[mi];
#pragma unroll
        for (int ks = 0; ks < 8; ++ks) {
            const int sel = ks >> 1;
            int slot = (ks & 1) * 4 + g4;
            short8 af;
            if (sel < 3) {
                int tt = t + sel;
                af = *(const short8*)&sgb[(nl * 26 + tt) * 64 + ((slot ^ (tt & 7)) << 3)];
            } else {
                af = *(const short8*)&xb[(nl * 24 + t) * 64 + ((slot ^ (t & 7)) << 3)];
            }
            acc[mi] = __builtin_amdgcn_mfma_f32_16x16x32_bf16(af, bfr[ks], acc[mi], 0, 0, 0);
        }
    }

    __syncthreads();
#pragma unroll
    for (int mi = 0; mi < 6; ++mi)
#pragma unroll
        for (int r = 0; r < 4; ++r)
            Cl[(mi * 16 + (lane >> 4) * 4 + r) * 66 + wv * 16 + (lane & 15)] = acc[mi][r];
    __syncthreads();

    if (tid < 96) {
        float s = 0.f, s2 = 0.f;
#pragma unroll
        for (int f = 0; f < 64; ++f) {
            float v = fmaxf(Cl[tid * 66 + f] + tbs[f], 0.f);
            s += v; s2 += v * v;
        }
        float mu = s * (1.f / 64.f);
        float var = s2 * (1.f / 64.f) - mu * mu;
        mus[tid] = mu;
        rss[tid] = rsqrtf(var + 1e-5f);
    }
    __syncthreads();

#pragma unroll
    for (int i = 0; i < 24; ++i) {
        int e = i * 256 + tid;
        int nl = e / CT_;
        int rem = e - nl * CT_;
        int f = rem / 24;
        int t = rem - f * 24;
        int row = nl * 24 + t;
        float v = fmaxf(Cl[row * 66 + f] + tbs[f], 0.f);
        out[base + e] = (v - mus[row]) * rss[row] * gs[f] + bbs[f];
    }
}

extern "C" void kernel_launch(void* const* d_in, const int* in_sizes, int n_in,
                              void* d_out, int out_size, void* d_ws, size_t ws_size,
                              hipStream_t stream) {
    const float* x    = (const float*)d_in[0];
    const float* cheb = (const float*)d_in[1];
    const float* U1   = (const float*)d_in[2];
    const float* U2   = (const float*)d_in[3];
    const float* U3   = (const float*)d_in[4];
    const float* b_e  = (const float*)d_in[5];
    const float* V_e  = (const float*)d_in[6];
    const float* W1   = (const float*)d_in[7];
    const float* W2   = (const float*)d_in[8];
    const float* W3   = (const float*)d_in[9];
    const float* b_s  = (const float*)d_in[10];
    const float* V_s  = (const float*)d_in[11];
    const float* Theta= (const float*)d_in[12];
    const float* tc_w = (const float*)d_in[13];
    const float* tc_b = (const float*)d_in[14];
    const float* rc_w = (const float*)d_in[15];
    const float* rc_b = (const float*)d_in[16];
    const float* ln_g = (const float*)d_in[17];
    const float* ln_b = (const float*)d_in[18];
    float* out = (float*)d_out;

    char* base = (char*)d_ws;
    size_t o = 0;
    auto alloc = [&](size_t bytes) { size_t r = o; o += (bytes + 255) & ~(size_t)255; return r; };
    float* lhs_t   = (float*)(base + alloc((size_t)B_ * T_ * N_ * 4));
    float* rhs_t   = (float*)(base + alloc((size_t)B_ * N_ * T_ * 4));
    float* Ebuf    = (float*)(base + alloc((size_t)B_ * T_ * T_ * 4));
    float* partial = (float*)(base + alloc((size_t)B_ * 16 * CT_ * 4));
    float* lhs_t0  = (float*)(base + alloc((size_t)B_ * CT_ * 4));
    float* lhs_s   = (float*)(base + alloc((size_t)B_ * N_ * T_ * 4));
    float* rhs_s   = (float*)(base + alloc((size_t)B_ * T_ * N_ * 4));
    unsigned short* V_sb = (unsigned short*)(base + alloc((size_t)N_ * N_ * 2));
    unsigned short* Wcat = (unsigned short*)(base + alloc((size_t)F_ * 256 * 2));
    unsigned short* Thp  = (unsigned short*)(base + alloc((size_t)192 * 64 * 2));
    float2* mstats = (float2*)(base + alloc((size_t)B_ * N_ * 8));
    size_t regA = alloc((size_t)B_ * N_ * KS_ * 2);   // xTt (bf16) -> chebSt (bf16)
    size_t regB = alloc((size_t)B_ * CT_ * KS_ * 2);  // sigA (bf16) -> yT (bf16)
    unsigned short* xTt    = (unsigned short*)(base + regA);
    unsigned short* chebSt = (unsigned short*)(base + regA);
    unsigned short* sigA   = (unsigned short*)(base + regB);
    unsigned short* yT     = (unsigned short*)(base + regB);
    float* Sb  = out;        // S scores live in d_out until the stacked GEMM overwrites
    float* gcn = out;

    dim3 b256(256);
    k_cvt_vs<<<dim3(N_ * N_ / 256), b256, 0, stream>>>(V_s, V_sb);
    k_wcat<<<dim3((F_ * 256 + 255) / 256), b256, 0, stream>>>(tc_w, rc_w, Wcat);
    k_thp<<<dim3((192 * 64 + 255) / 256), b256, 0, stream>>>(Theta, Thp);
    k_rhs_t<<<dim3((B_ * N_ * T_) / 256), b256, 0, stream>>>(x, U3, rhs_t);
    k_lhs_partial<<<dim3(16, B_), b256, 0, stream>>>(x, U1, partial);
    k_lhs_reduce<<<dim3((B_ * CT_) / 256), b256, 0, stream>>>(partial, lhs_t0);
    k_lhs_t<<<dim3((B_ * T_ * N_) / 256), b256, 0, stream>>>(lhs_t0, U2, lhs_t);
    k_temporal_E<<<dim3(B_), dim3(576), 0, stream>>>(lhs_t, rhs_t, b_e, V_e, Ebuf);
    k_tspatial<<<dim3(N_ / 4, B_), b256, 0, stream>>>(x, Ebuf, W1, W2, W3, lhs_s, rhs_s);
    k_transpose_xt<<<dim3(N_ / 16, B_), b256, 0, stream>>>(x, xTt);
    k_sig<<<dim3(N_ / 256, N_ / 64, B_), b256, 0, stream>>>(lhs_s, rhs_s, b_s, sigA);
    // S0 GEMM: M=1024, Ncols=1024, K=1024; nwg=512 (%8==0)
    k_gemm256<<<dim3(B_ * 4 * 4), dim3(512), 0, stream>>>(
        sigA, N_, (long)N_ * N_, V_sb, N_, 0, Sb, N_, (long)N_ * N_, N_, 4, 4);
    k_smstats<<<dim3(N_ / 64, B_), b256, 0, stream>>>(Sb, mstats);
    k_yTmm<<<dim3(N_ / 128, B_ * T_), b256, 0, stream>>>(xTt, Thp, yT);        // sigA dead
    k_chebSt<<<dim3(N_ / 64, N_ / 64, B_), b256, 0, stream>>>(cheb, Sb, mstats, chebSt); // xTt dead
    // stacked GEMM: M=1024, Ncols=1536, K=3072; nwg=768 (%8==0)
    k_gemm256<<<dim3(B_ * 4 * 6), dim3(512), 0, stream>>>(
        chebSt, KS_, (long)N_ * KS_, yT, KS_, (long)CT_ * KS_,
        gcn, CT_, (long)N_ * CT_, KS_, 6, 4);                                 // Sb dead
    k_final<<<dim3(N_ / 4, B_), b256, 0, stream>>>(x, gcn, Wcat, tc_b, rc_b,
                                                   ln_g, ln_b, out);
}

// Round 10
// 1186.746 us; speedup vs baseline: 11.3258x; 1.0754x over previous
//
#include <hip/hip_runtime.h>

typedef __attribute__((ext_vector_type(8))) short short8;   // 8 bf16 (4 VGPRs)
typedef __attribute__((ext_vector_type(4))) float f32x4;

constexpr int B_ = 32;
constexpr int N_ = 1024;
constexpr int C_ = 64;
constexpr int T_ = 24;
constexpr int F_ = 64;
constexpr int CT_ = C_ * T_;     // 1536
constexpr int KS_ = 3072;        // stacked K = 3*1024

__device__ __forceinline__ float sigmoidf_(float x) {
    return 1.0f / (1.0f + __expf(-x));
}
__device__ __forceinline__ unsigned short f2b(float f) {   // RNE f32->bf16
    union { float f; unsigned u; } v; v.f = f;
    unsigned r = v.u + 0x7FFFu + ((v.u >> 16) & 1u);
    return (unsigned short)(r >> 16);
}
__device__ __forceinline__ float b2f(unsigned short h) {
    union { unsigned u; float f; } v; v.u = ((unsigned)h) << 16; return v.f;
}
__device__ __forceinline__ void gload_lds16(const unsigned short* g, unsigned short* l) {
    __builtin_amdgcn_global_load_lds(
        (const __attribute__((address_space(1))) unsigned int*)g,
        (__attribute__((address_space(3))) unsigned int*)l, 16, 0, 0);
}

// ---------------- temporal attention prep ----------------
__global__ void k_rhs_t(const float* __restrict__ x, const float* __restrict__ U3,
                        float* __restrict__ rhs_t) {
    int idx = blockIdx.x * 256 + threadIdx.x;
    if (idx >= B_ * N_ * T_) return;
    int t = idx % T_;
    int n = (idx / T_) % N_;
    int b = idx / (N_ * T_);
    const float* xp = x + ((size_t)(b * N_ + n)) * CT_ + t;
    float acc = 0.f;
#pragma unroll
    for (int c = 0; c < C_; ++c) acc += U3[c] * xp[c * T_];
    rhs_t[idx] = acc;
}

__global__ void k_lhs_partial(const float* __restrict__ x, const float* __restrict__ U1,
                              float* __restrict__ partial) {
    int b = blockIdx.y, chunk = blockIdx.x;
    int tid = threadIdx.x;
    float acc[6] = {0, 0, 0, 0, 0, 0};
    int n0 = chunk * 64;
    for (int nn = 0; nn < 64; ++nn) {
        int n = n0 + nn;
        float u = U1[n];
        const float* xp = x + ((size_t)(b * N_ + n)) * CT_;
#pragma unroll
        for (int e = 0; e < 6; ++e) acc[e] += u * xp[tid + e * 256];
    }
    float* pp = partial + ((size_t)(b * 16 + chunk)) * CT_;
#pragma unroll
    for (int e = 0; e < 6; ++e) pp[tid + e * 256] = acc[e];
}

__global__ void k_lhs_reduce(const float* __restrict__ partial, float* __restrict__ lhs_t0) {
    int idx = blockIdx.x * 256 + threadIdx.x;
    if (idx >= B_ * CT_) return;
    int b = idx / CT_, flat = idx % CT_;
    float acc = 0.f;
#pragma unroll
    for (int ch = 0; ch < 16; ++ch) acc += partial[((size_t)(b * 16 + ch)) * CT_ + flat];
    lhs_t0[idx] = acc;
}

__global__ void k_lhs_t(const float* __restrict__ lhs_t0, const float* __restrict__ U2,
                        float* __restrict__ lhs_t) {
    int idx = blockIdx.x * 256 + threadIdx.x;
    if (idx >= B_ * T_ * N_) return;
    int n2 = idx % N_;
    int t = (idx / N_) % T_;
    int b = idx / (T_ * N_);
    const float* l0 = lhs_t0 + (size_t)b * CT_;
    float acc = 0.f;
#pragma unroll
    for (int c = 0; c < C_; ++c) acc += l0[c * T_ + t] * U2[c * N_ + n2];
    lhs_t[idx] = acc;
}

__global__ void k_temporal_E(const float* __restrict__ lhs_t, const float* __restrict__ rhs_t,
                             const float* __restrict__ b_e, const float* __restrict__ V_e,
                             float* __restrict__ E) {
    int b = blockIdx.x;
    int tid = threadIdx.x;                               // 576 threads
    int i = tid / T_, u = tid % T_;
    __shared__ float sig[T_][T_];
    __shared__ float e0s[T_][T_];
    __shared__ float mcol[T_], scol[T_];
    const float* lt = lhs_t + (size_t)b * T_ * N_ + (size_t)i * N_;
    const float* rt = rhs_t + (size_t)b * N_ * T_ + u;
    float acc = 0.f;
    for (int n = 0; n < N_; ++n) acc += lt[n] * rt[(size_t)n * T_];
    sig[i][u] = sigmoidf_(acc + b_e[i * T_ + u]);
    __syncthreads();
    int j = u;
    float e0 = 0.f;
#pragma unroll
    for (int kk = 0; kk < T_; ++kk) e0 += sig[i][kk] * V_e[j * T_ + kk];
    e0s[i][j] = e0;
    __syncthreads();
    if (tid < T_) {
        float mx = -1e30f;
        for (int ii = 0; ii < T_; ++ii) mx = fmaxf(mx, e0s[ii][tid]);
        float s = 0.f;
        for (int ii = 0; ii < T_; ++ii) s += __expf(e0s[ii][tid] - mx);
        mcol[tid] = mx; scol[tid] = s;
    }
    __syncthreads();
    E[(size_t)b * T_ * T_ + i * T_ + j] = __expf(e0s[i][j] - mcol[j]) / scol[j];
}

// ---------------- fused: x_TAt (in-register) -> spatial prep + xTt emit ----------------
// Per block: 4 n-rows.  Stages x once (float4), emits bf16 xTt (kills the separate
// transpose kernel's 192MB x read), computes u=x@E in registers, reduces to lhs_s/rhs_s.
__global__ __launch_bounds__(256) void k_tspatial(const float* __restrict__ x,
        const float* __restrict__ E, const float* __restrict__ W1g,
        const float* __restrict__ W2, const float* __restrict__ W3g,
        float* __restrict__ lhs_s, float* __restrict__ rhs_s,
        unsigned short* __restrict__ xTt) {
    int b = blockIdx.y;
    int n0 = blockIdx.x * 4;
    int tid = threadIdx.x;
    __shared__ float Es[T_ * T_];
    __shared__ float W1s[T_];
    __shared__ float W2s[C_ * T_];
    __shared__ float xr[4][64][25];                      // staged x, then reused for w3*u
    __shared__ float l0s[4][64];
    for (int e = tid; e < T_ * T_; e += 256) Es[e] = E[(size_t)b * T_ * T_ + e];
    for (int e = tid; e < C_ * T_; e += 256) W2s[e] = W2[e];
    if (tid < T_) W1s[tid] = W1g[tid];
    size_t base = ((size_t)b * N_ + n0) * CT_;
    const float4* x4 = (const float4*)(x + base);
#pragma unroll
    for (int i = 0; i < 6; ++i) {
        int e4 = i * 256 + tid;
        float4 v = x4[e4];
        int e = e4 * 4;
        int nl = e / CT_; int rem = e - nl * CT_; int c = rem / 24; int tl = rem - c * 24;
        xr[nl][c][tl] = v.x; xr[nl][c][tl + 1] = v.y;
        xr[nl][c][tl + 2] = v.z; xr[nl][c][tl + 3] = v.w;
    }
    __syncthreads();
    int nl = tid >> 6, c = tid & 63;
    float xv[T_];
#pragma unroll
    for (int t = 0; t < T_; ++t) xv[t] = xr[nl][c][t];
    // emit xTt[b][t][n][c] bf16 from staged x (coalesced 128B chunks)
#pragma unroll
    for (int i = 0; i < 24; ++i) {
        int idx = i * 256 + tid;
        int cc = idx & 63, nn = (idx >> 6) & 3, t = idx >> 8;
        xTt[((size_t)(b * T_ + t) * N_ + n0 + nn) * 64 + cc] = f2b(xr[nn][cc][t]);
    }
    float w3 = W3g[c];
    float u[T_];
#pragma unroll
    for (int j = 0; j < T_; ++j) {
        float a = 0.f;
#pragma unroll
        for (int t = 0; t < T_; ++t) a += xv[t] * Es[t * T_ + j];
        u[j] = a;
    }
    float l0 = 0.f;
#pragma unroll
    for (int j = 0; j < T_; ++j) l0 += u[j] * W1s[j];
    __syncthreads();                                     // xTt-emit LDS reads done
#pragma unroll
    for (int j = 0; j < T_; ++j) xr[nl][c][j] = w3 * u[j];
    l0s[nl][c] = l0;
    __syncthreads();
    if (tid < 4 * T_) {
        int t = tid % T_, g = tid / T_;
        float racc = 0.f, lacc = 0.f;
        for (int cc = 0; cc < 64; ++cc) {
            racc += xr[g][cc][t];
            lacc += l0s[g][cc] * W2s[cc * T_ + t];
        }
        rhs_s[((size_t)b * T_ + t) * N_ + n0 + g] = racc;
        lhs_s[((size_t)(b * N_ + n0 + g)) * T_ + t] = lacc;
    }
}

// ---------------- converters / builders ----------------
__global__ void k_cvt_vs(const float* __restrict__ v, unsigned short* __restrict__ o) {
    int i = blockIdx.x * 256 + threadIdx.x;
    o[i] = f2b(v[i]);
}

// Wcat[ft][k], k = sel*64+c: sel 0..2 -> tc_w taps, sel 3 -> rc_w.  bf16 [64][256]
__global__ void k_wcat(const float* __restrict__ tc_w, const float* __restrict__ rc_w,
                       unsigned short* __restrict__ Wcat) {
    int i = blockIdx.x * 256 + threadIdx.x;              // over 64*256
    if (i >= F_ * 256) return;
    int ft = i >> 8, k = i & 255;
    int sel = k >> 6, c = k & 63;
    float v = (sel < 3) ? tc_w[(ft * C_ + c) * 3 + sel] : rc_w[ft * C_ + c];
    Wcat[i] = f2b(v);
}

// Thp[k*64+f][c] (bf16) = Theta[k][c][f]   -- A-operand for k_yTmm
__global__ void k_thp(const float* __restrict__ Theta, unsigned short* __restrict__ Thp) {
    int i = blockIdx.x * 256 + threadIdx.x;              // over 192*64
    if (i >= 192 * 64) return;
    int kf = i >> 6, c = i & 63;
    int k = kf >> 6, f = kf & 63;
    Thp[i] = f2b(Theta[((size_t)k * 64 + c) * 64 + f]);
}

// sigA[b][i][k] (bf16) = sigmoid(dot24(lhs_s[b,i,:], rhs_s[b,:,k]) + b_s[i,k])
__global__ __launch_bounds__(256) void k_sig(const float* __restrict__ lhs_s,
        const float* __restrict__ rhs_s, const float* __restrict__ b_s,
        unsigned short* __restrict__ sigA) {
    int b = blockIdx.z, i0 = blockIdx.y * 64, k0 = blockIdx.x * 256;
    int tid = threadIdx.x;
    __shared__ float lh[64 * T_];
    __shared__ float rh[T_][256];
    for (int e = tid; e < 64 * T_; e += 256) lh[e] = lhs_s[((size_t)b * N_ + i0) * T_ + e];
#pragma unroll
    for (int t = 0; t < T_; ++t) rh[t][tid] = rhs_s[((size_t)b * T_ + t) * N_ + k0 + tid];
    __syncthreads();
    int kg = k0 + tid;
    for (int ii = 0; ii < 64; ++ii) {
        float acc = b_s[(size_t)(i0 + ii) * N_ + kg];
#pragma unroll
        for (int t = 0; t < T_; ++t) acc += lh[ii * T_ + t] * rh[t][tid];
        sigA[((size_t)b * N_ + i0 + ii) * N_ + kg] = f2b(sigmoidf_(acc));
    }
}

// ---------------- yT via MFMA (unchanged) ----------------
__global__ __launch_bounds__(256) void k_yTmm(const unsigned short* __restrict__ xTt,
        const unsigned short* __restrict__ Thp, unsigned short* __restrict__ yT) {
    int bt = blockIdx.y;
    int b = bt / T_, t = bt - b * T_;
    int m0 = blockIdx.x * 128;
    int tid = threadIdx.x;
    int lane = tid & 63, wv = tid >> 6;
    __shared__ __align__(16) unsigned short Asb[192 * 64];   // Thp, swizzled
    __shared__ __align__(16) unsigned short Bsb[128 * 64];   // xTt m-tile, swizzled
#pragma unroll
    for (int e = 0; e < 6; ++e) {                        // stage Thp (24KB)
        int chunk = e * 256 + tid;
        int row = chunk >> 3, slot = chunk & 7;
        int gslot = slot ^ (row & 7);
        gload_lds16(Thp + row * 64 + gslot * 8, &Asb[chunk * 8]);
    }
    const unsigned short* Bg = xTt + ((size_t)bt * N_ + m0) * 64;
#pragma unroll
    for (int e = 0; e < 4; ++e) {                        // stage B (16KB)
        int chunk = e * 256 + tid;
        int row = chunk >> 3, slot = chunk & 7;
        int gslot = slot ^ (row & 7);
        gload_lds16(Bg + (size_t)row * 64 + gslot * 8, &Bsb[chunk * 8]);
    }
    __syncthreads();                                     // drains vmcnt

    short8 bf[2][2];
#pragma unroll
    for (int ni = 0; ni < 2; ++ni)
#pragma unroll
        for (int kk = 0; kk < 2; ++kk) {
            int r = wv * 32 + ni * 16 + (lane & 15);
            int slot = (kk * 4 + (lane >> 4)) ^ (r & 7);
            bf[ni][kk] = *(const short8*)&Bsb[r * 64 + slot * 8];
        }
    f32x4 acc[12][2];
#pragma unroll
    for (int mi = 0; mi < 12; ++mi)
#pragma unroll
        for (int ni = 0; ni < 2; ++ni) acc[mi][ni] = (f32x4){0.f, 0.f, 0.f, 0.f};
#pragma unroll
    for (int mi = 0; mi < 12; ++mi) {
        short8 af[2];
#pragma unroll
        for (int kk = 0; kk < 2; ++kk) {
            int r = mi * 16 + (lane & 15);
            int slot = (kk * 4 + (lane >> 4)) ^ (r & 7);
            af[kk] = *(const short8*)&Asb[r * 64 + slot * 8];
        }
#pragma unroll
        for (int kk = 0; kk < 2; ++kk)
#pragma unroll
            for (int ni = 0; ni < 2; ++ni)
                acc[mi][ni] = __builtin_amdgcn_mfma_f32_16x16x32_bf16(
                    af[kk], bf[ni][kk], acc[mi][ni], 0, 0, 0);
    }
    int mcol = m0 + wv * 32 + (lane & 15);
#pragma unroll
    for (int mi = 0; mi < 12; ++mi) {
#pragma unroll
        for (int r = 0; r < 4; ++r) {
            int kf = mi * 16 + (lane >> 4) * 4 + r;
            int k = kf >> 6, f = kf & 63;
            unsigned short* yp = yT + ((size_t)b * CT_ + f * T_ + t) * KS_ + k * N_ + mcol;
#pragma unroll
            for (int ni = 0; ni < 2; ++ni) yp[ni * 16] = f2b(acc[mi][ni][r]);
        }
    }
}

// online softmax stats over axis m of S[b,m,i]: mst[b*N+i] = (max, 1/sum)
__global__ void k_smstats(const float* __restrict__ S, float2* __restrict__ mst) {
    int b = blockIdx.y;
    int jj = threadIdx.x % 64;
    int ig = threadIdx.x / 64;
    int j = blockIdx.x * 64 + jj;
    __shared__ float rm[4][64], rs[4][64];
    float m = -1e30f, s = 0.f;
    for (int i = ig; i < N_; i += 4) {
        float v = S[((size_t)b * N_ + i) * N_ + j];
        float mn = fmaxf(m, v);
        s = s * __expf(m - mn) + __expf(v - mn);
        m = mn;
    }
    rm[ig][jj] = m; rs[ig][jj] = s;
    __syncthreads();
    if (ig == 0) {
        float M = rm[0][jj], SS = rs[0][jj];
#pragma unroll
        for (int g = 1; g < 4; ++g) {
            float mg = rm[g][jj];
            float mn = fmaxf(M, mg);
            SS = SS * __expf(M - mn) + rs[g][jj] * __expf(mg - mn);
            M = mn;
        }
        mst[(size_t)b * N_ + j] = make_float2(M, 1.f / SS);
    }
}

// chebSt[b][i][k*1024+m] (bf16) = cheb[k][m][i] * softmax(S)[b][m][i]  (float4 reads)
__global__ __launch_bounds__(256) void k_chebSt(const float* __restrict__ cheb,
        const float* __restrict__ S, const float2* __restrict__ mst,
        unsigned short* __restrict__ cs) {
    int b = blockIdx.z, i0 = blockIdx.y * 64, m0 = blockIdx.x * 64;
    int tid = threadIdx.x;
    __shared__ float st[64][65];
    __shared__ float cb[64][65];
    __shared__ float2 sst[64];
    if (tid < 64) sst[tid] = mst[(size_t)b * N_ + i0 + tid];
#pragma unroll
    for (int e = 0; e < 4; ++e) {
        int idx4 = e * 256 + tid;
        int mm = idx4 >> 4, ii0 = (idx4 & 15) * 4;
        float4 v = *(const float4*)&S[((size_t)b * N_ + m0 + mm) * N_ + i0 + ii0];
        st[mm][ii0] = v.x; st[mm][ii0 + 1] = v.y; st[mm][ii0 + 2] = v.z; st[mm][ii0 + 3] = v.w;
    }
    for (int k = 0; k < 3; ++k) {
        __syncthreads();
#pragma unroll
        for (int e = 0; e < 4; ++e) {
            int idx4 = e * 256 + tid;
            int mm = idx4 >> 4, ii0 = (idx4 & 15) * 4;
            float4 v = *(const float4*)&cheb[((size_t)k * N_ + m0 + mm) * N_ + i0 + ii0];
            cb[mm][ii0] = v.x; cb[mm][ii0 + 1] = v.y; cb[mm][ii0 + 2] = v.z; cb[mm][ii0 + 3] = v.w;
        }
        __syncthreads();
#pragma unroll
        for (int e = 0; e < 16; ++e) {
            int idx = e * 256 + tid; int mm = idx & 63, ii = idx >> 6;
            float sm = __expf(st[mm][ii] - sst[ii].x) * sst[ii].y;
            cs[((size_t)b * N_ + i0 + ii) * KS_ + k * N_ + m0 + mm] =
                f2b(sm * cb[mm][ii]);
        }
    }
}

// ---------------- 256x256-tile MFMA GEMM, hybrid counted-vmcnt pipeline ----------------
__global__ __launch_bounds__(512, 2) void k_gemm256(
        const unsigned short* __restrict__ A, long lda, long sA,
        const unsigned short* __restrict__ Bt, long ldb, long sB,
        float* __restrict__ Cc, long ldc, long sC, int K, int nbx, int nby) {
    __shared__ __align__(16) unsigned short As[2][256 * 64];   // 2 x 32KB
    __shared__ __align__(16) unsigned short Bs[2][256 * 64];   // 2 x 32KB
    int tid = threadIdx.x;
    int lane = tid & 63, w = tid >> 6;
    int wy = w >> 2, wx = w & 3;                            // 2 x 4 waves -> 128x64 per wave

    int nwg = gridDim.x;
    int cpx = nwg >> 3;
    int logical = (blockIdx.x & 7) * cpx + (blockIdx.x >> 3);
    int tpb = nbx * nby;
    int b = logical / tpb;
    int tile = logical % tpb;
    int i0 = (tile / nbx) * 256;
    int j0 = (tile % nbx) * 256;

    const unsigned short* Ab = A + (size_t)b * sA + (size_t)i0 * lda;
    const unsigned short* Bb = Bt + (size_t)b * sB + (size_t)j0 * ldb;

    auto STAGE = [&](int kt, int d) {
        int kof = kt << 6;
#pragma unroll
        for (int e = 0; e < 4; ++e) {
            int chunk = e * 512 + tid;
            int row = chunk >> 3, slot = chunk & 7;
            int gslot = slot ^ (row & 7);                   // inverse swizzle on source
            gload_lds16(Ab + (size_t)row * lda + kof + gslot * 8, &As[d][chunk * 8]);
        }
#pragma unroll
        for (int e = 0; e < 4; ++e) {
            int chunk = e * 512 + tid;
            int row = chunk >> 3, slot = chunk & 7;
            int gslot = slot ^ (row & 7);
            gload_lds16(Bb + (size_t)row * ldb + kof + gslot * 8, &Bs[d][chunk * 8]);
        }
    };
    auto READF = [&](short8* af, short8* bfv,
                     const unsigned short* Asb, const unsigned short* Bsb, int kkb) {
#pragma unroll
        for (int mi = 0; mi < 8; ++mi) {
            int r = wy * 128 + mi * 16 + (lane & 15);
            int slot = (kkb + (lane >> 4)) ^ (r & 7);
            af[mi] = *(const short8*)&Asb[r * 64 + slot * 8];
        }
#pragma unroll
        for (int ni = 0; ni < 4; ++ni) {
            int r = wx * 64 + ni * 16 + (lane & 15);
            int slot = (kkb + (lane >> 4)) ^ (r & 7);
            bfv[ni] = *(const short8*)&Bsb[r * 64 + slot * 8];
        }
    };

    f32x4 acc[8][4];
#pragma unroll
    for (int mi = 0; mi < 8; ++mi)
#pragma unroll
        for (int ni = 0; ni < 4; ++ni) acc[mi][ni] = (f32x4){0.f, 0.f, 0.f, 0.f};

    int nt = K >> 6;
    STAGE(0, 0);
    STAGE(1, 1);
    asm volatile("s_waitcnt vmcnt(8)" ::: "memory");        // K-tile 0 resident
    __builtin_amdgcn_s_barrier();
    __builtin_amdgcn_sched_barrier(0);

    short8 a0[8], b0[4], a1[8], b1[4];
    READF(a0, b0, As[0], Bs[0], 0);                         // kk0 of tile 0

    for (int kt = 0; kt < nt; ++kt) {
        int cur = kt & 1;
        READF(a1, b1, As[cur], Bs[cur], 4);                 // kk1 of this tile
        __builtin_amdgcn_s_setprio(1);
#pragma unroll
        for (int mi = 0; mi < 8; ++mi)
#pragma unroll
            for (int ni = 0; ni < 4; ++ni)
                acc[mi][ni] = __builtin_amdgcn_mfma_f32_16x16x32_bf16(
                    a0[mi], b0[ni], acc[mi][ni], 0, 0, 0);
        __builtin_amdgcn_s_setprio(0);
        asm volatile("s_waitcnt lgkmcnt(0)" ::: "memory");  // my reads of buf[cur] done
        __builtin_amdgcn_sched_barrier(0);
        __builtin_amdgcn_s_barrier();                       // all waves done with buf[cur]
        __builtin_amdgcn_sched_barrier(0);
        if (kt + 2 < nt) STAGE(kt + 2, cur);                // overwrite freed buffer
        __builtin_amdgcn_sched_barrier(0);
        __builtin_amdgcn_s_setprio(1);
#pragma unroll
        for (int mi = 0; mi < 8; ++mi)
#pragma unroll
            for (int ni = 0; ni < 4; ++ni)
                acc[mi][ni] = __builtin_amdgcn_mfma_f32_16x16x32_bf16(
                    a1[mi], b1[ni], acc[mi][ni], 0, 0, 0);
        __builtin_amdgcn_s_setprio(0);
        if (kt + 2 < nt) {
            asm volatile("s_waitcnt vmcnt(8)" ::: "memory"); // kt+1 retired, kt+2 in flight
        } else {
            asm volatile("s_waitcnt vmcnt(0)" ::: "memory"); // tail: drain (race-safe)
        }
        __builtin_amdgcn_s_barrier();                       // buf[cur^1] ready for all waves
        __builtin_amdgcn_sched_barrier(0);
        if (kt + 1 < nt)
            READF(a0, b0, As[cur ^ 1], Bs[cur ^ 1], 0);     // kk0 of next tile
    }

    float* Cb = Cc + (size_t)b * sC;
#pragma unroll
    for (int mi = 0; mi < 8; ++mi) {
#pragma unroll
        for (int r = 0; r < 4; ++r) {
            int i = i0 + wy * 128 + mi * 16 + (lane >> 4) * 4 + r;
            float* cp = Cb + (size_t)i * ldc + j0 + wx * 64 + (lane & 15);
#pragma unroll
            for (int ni = 0; ni < 4; ++ni) cp[ni * 16] = acc[mi][ni][r];
        }
    }
}

// ---------------- fused epilogue via MFMA (float4 I/O) ----------------
__global__ __launch_bounds__(256) void k_final(const float* __restrict__ x,
        const float* __restrict__ sgin, const unsigned short* __restrict__ Wcat,
        const float* __restrict__ tc_b, const float* __restrict__ rc_b,
        const float* __restrict__ ln_g, const float* __restrict__ ln_b,
        float* __restrict__ out) {
    int b = blockIdx.y;
    int n0 = blockIdx.x * 4;
    int tid = threadIdx.x;
    int lane = tid & 63, wv = tid >> 6;

    __shared__ __align__(16) char smem[25600];
    unsigned short* sgb = (unsigned short*)smem;            // [4][26][64]
    unsigned short* xb  = (unsigned short*)(smem + 13312);  // [4][24][64]
    float* Cl = (float*)smem;                               // [96][66] (after reuse barrier)
    __shared__ float tbs[64], gs[64], bbs[64];
    __shared__ float mus[96], rss[96];

    if (tid < 64) {
        tbs[tid] = tc_b[tid] + rc_b[tid];
        gs[tid] = ln_g[tid];
        bbs[tid] = ln_b[tid];
    }
    for (int e = tid; e < 512; e += 256) {
        int nl = e >> 7, r = (e >> 6) & 1, c = e & 63;
        int tt = r ? 25 : 0;
        sgb[(nl * 26 + tt) * 64 + (((c >> 3) ^ (tt & 7)) << 3) + (c & 7)] = 0;
    }
    size_t base = ((size_t)b * N_ + n0) * CT_;
    const float4* sg4 = (const float4*)(sgin + base);
    const float4* xg4 = (const float4*)(x + base);
#pragma unroll
    for (int i = 0; i < 6; ++i) {
        int e4 = i * 256 + tid;
        float4 sv4 = sg4[e4];
        float4 xv4 = xg4[e4];
        int e = e4 * 4;
        int nl = e / CT_;
        int rem = e - nl * CT_;
        int c = rem / 24;
        int tl = rem - c * 24;
        float sv[4] = {sv4.x, sv4.y, sv4.z, sv4.w};
        float xv[4] = {xv4.x, xv4.y, xv4.z, xv4.w};
#pragma unroll
        for (int j = 0; j < 4; ++j) {
            int tt = tl + j + 1;
            sgb[(nl * 26 + tt) * 64 + (((c >> 3) ^ (tt & 7)) << 3) + (c & 7)] =
                f2b(fmaxf(sv[j], 0.f));
            int tj = tl + j;
            xb[(nl * 24 + tj) * 64 + (((c >> 3) ^ (tj & 7)) << 3) + (c & 7)] = f2b(xv[j]);
        }
    }

    int ft = wv * 16 + (lane & 15);
    int g4 = lane >> 4;
    short8 bfr[8];
#pragma unroll
    for (int ks = 0; ks < 8; ++ks)
        bfr[ks] = *(const short8*)&Wcat[ft * 256 + ks * 32 + g4 * 8];

    int rnl[6], rt[6];
#pragma unroll
    for (int mi = 0; mi < 6; ++mi) {
        int row = mi * 16 + (lane & 15);
        rnl[mi] = row / 24;
        rt[mi] = row - rnl[mi] * 24;
    }

    __syncthreads();

    f32x4 acc[6];
#pragma unroll
    for (int mi = 0; mi < 6; ++mi) acc[mi] = (f32x4){0.f, 0.f, 0.f, 0.f};
#pragma unroll
    for (int mi = 0; mi < 6; ++mi) {
        int nl = rnl[mi], t = rt[mi];
#pragma unroll
        for (int ks = 0; ks < 8; ++ks) {
            const int sel = ks >> 1;
            int slot = (ks & 1) * 4 + g4;
            short8 af;
            if (sel < 3) {
                int tt = t + sel;
                af = *(const short8*)&sgb[(nl * 26 + tt) * 64 + ((slot ^ (tt & 7)) << 3)];
            } else {
                af = *(const short8*)&xb[(nl * 24 + t) * 64 + ((slot ^ (t & 7)) << 3)];
            }
            acc[mi] = __builtin_amdgcn_mfma_f32_16x16x32_bf16(af, bfr[ks], acc[mi], 0, 0, 0);
        }
    }

    __syncthreads();
#pragma unroll
    for (int mi = 0; mi < 6; ++mi)
#pragma unroll
        for (int r = 0; r < 4; ++r)
            Cl[(mi * 16 + (lane >> 4) * 4 + r) * 66 + wv * 16 + (lane & 15)] = acc[mi][r];
    __syncthreads();

    if (tid < 96) {
        float s = 0.f, s2 = 0.f;
#pragma unroll
        for (int f = 0; f < 64; ++f) {
            float v = fmaxf(Cl[tid * 66 + f] + tbs[f], 0.f);
            s += v; s2 += v * v;
        }
        float mu = s * (1.f / 64.f);
        float var = s2 * (1.f / 64.f) - mu * mu;
        mus[tid] = mu;
        rss[tid] = rsqrtf(var + 1e-5f);
    }
    __syncthreads();

    float4* o4 = (float4*)(out + base);
#pragma unroll
    for (int i = 0; i < 6; ++i) {
        int e4 = i * 256 + tid;
        int e = e4 * 4;
        int nl = e / CT_;
        int rem = e - nl * CT_;
        int f = rem / 24;
        int t0v = rem - f * 24;
        float g = gs[f], bb2 = bbs[f], tb2 = tbs[f];
        float vals[4];
#pragma unroll
        for (int j = 0; j < 4; ++j) {
            int row = nl * 24 + t0v + j;
            float v = fmaxf(Cl[row * 66 + f] + tb2, 0.f);
            vals[j] = (v - mus[row]) * rss[row] * g + bb2;
        }
        float4 r;
        r.x = vals[0]; r.y = vals[1]; r.z = vals[2]; r.w = vals[3];
        o4[e4] = r;
    }
}

extern "C" void kernel_launch(void* const* d_in, const int* in_sizes, int n_in,
                              void* d_out, int out_size, void* d_ws, size_t ws_size,
                              hipStream_t stream) {
    const float* x    = (const float*)d_in[0];
    const float* cheb = (const float*)d_in[1];
    const float* U1   = (const float*)d_in[2];
    const float* U2   = (const float*)d_in[3];
    const float* U3   = (const float*)d_in[4];
    const float* b_e  = (const float*)d_in[5];
    const float* V_e  = (const float*)d_in[6];
    const float* W1   = (const float*)d_in[7];
    const float* W2   = (const float*)d_in[8];
    const float* W3   = (const float*)d_in[9];
    const float* b_s  = (const float*)d_in[10];
    const float* V_s  = (const float*)d_in[11];
    const float* Theta= (const float*)d_in[12];
    const float* tc_w = (const float*)d_in[13];
    const float* tc_b = (const float*)d_in[14];
    const float* rc_w = (const float*)d_in[15];
    const float* rc_b = (const float*)d_in[16];
    const float* ln_g = (const float*)d_in[17];
    const float* ln_b = (const float*)d_in[18];
    float* out = (float*)d_out;

    char* base = (char*)d_ws;
    size_t o = 0;
    auto alloc = [&](size_t bytes) { size_t r = o; o += (bytes + 255) & ~(size_t)255; return r; };
    float* lhs_t   = (float*)(base + alloc((size_t)B_ * T_ * N_ * 4));
    float* rhs_t   = (float*)(base + alloc((size_t)B_ * N_ * T_ * 4));
    float* Ebuf    = (float*)(base + alloc((size_t)B_ * T_ * T_ * 4));
    float* partial = (float*)(base + alloc((size_t)B_ * 16 * CT_ * 4));
    float* lhs_t0  = (float*)(base + alloc((size_t)B_ * CT_ * 4));
    float* lhs_s   = (float*)(base + alloc((size_t)B_ * N_ * T_ * 4));
    float* rhs_s   = (float*)(base + alloc((size_t)B_ * T_ * N_ * 4));
    unsigned short* V_sb = (unsigned short*)(base + alloc((size_t)N_ * N_ * 2));
    unsigned short* Wcat = (unsigned short*)(base + alloc((size_t)F_ * 256 * 2));
    unsigned short* Thp  = (unsigned short*)(base + alloc((size_t)192 * 64 * 2));
    float2* mstats = (float2*)(base + alloc((size_t)B_ * N_ * 8));
    size_t regA = alloc((size_t)B_ * N_ * KS_ * 2);   // xTt (bf16) -> chebSt (bf16)
    size_t regB = alloc((size_t)B_ * CT_ * KS_ * 2);  // sigA (bf16) -> yT (bf16)
    unsigned short* xTt    = (unsigned short*)(base + regA);
    unsigned short* chebSt = (unsigned short*)(base + regA);
    unsigned short* sigA   = (unsigned short*)(base + regB);
    unsigned short* yT     = (unsigned short*)(base + regB);
    float* Sb  = out;        // S scores live in d_out until the stacked GEMM overwrites
    float* gcn = out;

    dim3 b256(256);
    k_cvt_vs<<<dim3(N_ * N_ / 256), b256, 0, stream>>>(V_s, V_sb);
    k_wcat<<<dim3((F_ * 256 + 255) / 256), b256, 0, stream>>>(tc_w, rc_w, Wcat);
    k_thp<<<dim3((192 * 64 + 255) / 256), b256, 0, stream>>>(Theta, Thp);
    k_rhs_t<<<dim3((B_ * N_ * T_) / 256), b256, 0, stream>>>(x, U3, rhs_t);
    k_lhs_partial<<<dim3(16, B_), b256, 0, stream>>>(x, U1, partial);
    k_lhs_reduce<<<dim3((B_ * CT_) / 256), b256, 0, stream>>>(partial, lhs_t0);
    k_lhs_t<<<dim3((B_ * T_ * N_) / 256), b256, 0, stream>>>(lhs_t0, U2, lhs_t);
    k_temporal_E<<<dim3(B_), dim3(576), 0, stream>>>(lhs_t, rhs_t, b_e, V_e, Ebuf);
    k_tspatial<<<dim3(N_ / 4, B_), b256, 0, stream>>>(x, Ebuf, W1, W2, W3,
                                                      lhs_s, rhs_s, xTt);
    k_sig<<<dim3(N_ / 256, N_ / 64, B_), b256, 0, stream>>>(lhs_s, rhs_s, b_s, sigA);
    // S0 GEMM: M=1024, Ncols=1024, K=1024; nwg=512 (%8==0)
    k_gemm256<<<dim3(B_ * 4 * 4), dim3(512), 0, stream>>>(
        sigA, N_, (long)N_ * N_, V_sb, N_, 0, Sb, N_, (long)N_ * N_, N_, 4, 4);
    k_smstats<<<dim3(N_ / 64, B_), b256, 0, stream>>>(Sb, mstats);
    k_yTmm<<<dim3(N_ / 128, B_ * T_), b256, 0, stream>>>(xTt, Thp, yT);        // sigA dead
    k_chebSt<<<dim3(N_ / 64, N_ / 64, B_), b256, 0, stream>>>(cheb, Sb, mstats, chebSt); // xTt dead
    // stacked GEMM: M=1024, Ncols=1536, K=3072; nwg=768 (%8==0)
    k_gemm256<<<dim3(B_ * 4 * 6), dim3(512), 0, stream>>>(
        chebSt, KS_, (long)N_ * KS_, yT, KS_, (long)CT_ * KS_,
        gcn, CT_, (long)N_ * CT_, KS_, 6, 4);                                 // Sb dead
    k_final<<<dim3(N_ / 4, B_), b256, 0, stream>>>(x, gcn, Wcat, tc_b, rc_b,
                                                   ln_g, ln_b, out);
}

// Round 11
// 1154.345 us; speedup vs baseline: 11.6437x; 1.0281x over previous
//
#include <hip/hip_runtime.h>

typedef __attribute__((ext_vector_type(8))) short short8;   // 8 bf16 (4 VGPRs)
typedef __attribute__((ext_vector_type(4))) float f32x4;

constexpr int B_ = 32;
constexpr int N_ = 1024;
constexpr int C_ = 64;
constexpr int T_ = 24;
constexpr int F_ = 64;
constexpr int CT_ = C_ * T_;     // 1536
constexpr int KS_ = 3072;        // stacked K = 3*1024

__device__ __forceinline__ float sigmoidf_(float x) {
    return 1.0f / (1.0f + __expf(-x));
}
__device__ __forceinline__ unsigned short f2b(float f) {   // RNE f32->bf16
    union { float f; unsigned u; } v; v.f = f;
    unsigned r = v.u + 0x7FFFu + ((v.u >> 16) & 1u);
    return (unsigned short)(r >> 16);
}
__device__ __forceinline__ float b2f(unsigned short h) {
    union { unsigned u; float f; } v; v.u = ((unsigned)h) << 16; return v.f;
}
__device__ __forceinline__ void gload_lds16(const unsigned short* g, unsigned short* l) {
    __builtin_amdgcn_global_load_lds(
        (const __attribute__((address_space(1))) unsigned int*)g,
        (__attribute__((address_space(3))) unsigned int*)l, 16, 0, 0);
}

// ---------------- temporal attention prep ----------------
// rhs_t[b,n,t] = sum_c U3[c]*x[b,n,c,t].  Block = (b, 8 n-rows); float4-staged LDS.
__global__ __launch_bounds__(256) void k_rhs_t(const float* __restrict__ x,
        const float* __restrict__ U3, float* __restrict__ rhs_t) {
    int b = blockIdx.y, n0 = blockIdx.x * 8;
    int tid = threadIdx.x;
    __shared__ float xr[8 * CT_];                        // 48 KB
    __shared__ float u3s[C_];
    if (tid < C_) u3s[tid] = U3[tid];
    const float4* x4 = (const float4*)(x + ((size_t)(b * N_ + n0)) * CT_);
#pragma unroll
    for (int e = 0; e < 12; ++e) {
        int i4 = e * 256 + tid;
        float4 v = x4[i4];
        int i = i4 * 4;
        xr[i] = v.x; xr[i + 1] = v.y; xr[i + 2] = v.z; xr[i + 3] = v.w;
    }
    __syncthreads();
    if (tid < 192) {
        int n = tid / 24, t = tid % 24;
        const float* xn = xr + n * CT_ + t;
        float acc = 0.f;
#pragma unroll
        for (int c = 0; c < C_; ++c) acc += u3s[c] * xn[c * 24];
        rhs_t[((size_t)(b * N_ + n0 + n)) * T_ + t] = acc;
    }
}

__global__ void k_lhs_partial(const float* __restrict__ x, const float* __restrict__ U1,
                              float* __restrict__ partial) {
    int b = blockIdx.y, chunk = blockIdx.x;
    int tid = threadIdx.x;
    float acc[6] = {0, 0, 0, 0, 0, 0};
    int n0 = chunk * 64;
    for (int nn = 0; nn < 64; ++nn) {
        int n = n0 + nn;
        float u = U1[n];
        const float* xp = x + ((size_t)(b * N_ + n)) * CT_;
#pragma unroll
        for (int e = 0; e < 6; ++e) acc[e] += u * xp[tid + e * 256];
    }
    float* pp = partial + ((size_t)(b * 16 + chunk)) * CT_;
#pragma unroll
    for (int e = 0; e < 6; ++e) pp[tid + e * 256] = acc[e];
}

__global__ void k_lhs_reduce(const float* __restrict__ partial, float* __restrict__ lhs_t0) {
    int idx = blockIdx.x * 256 + threadIdx.x;
    if (idx >= B_ * CT_) return;
    int b = idx / CT_, flat = idx % CT_;
    float acc = 0.f;
#pragma unroll
    for (int ch = 0; ch < 16; ++ch) acc += partial[((size_t)(b * 16 + ch)) * CT_ + flat];
    lhs_t0[idx] = acc;
}

__global__ void k_lhs_t(const float* __restrict__ lhs_t0, const float* __restrict__ U2,
                        float* __restrict__ lhs_t) {
    int idx = blockIdx.x * 256 + threadIdx.x;
    if (idx >= B_ * T_ * N_) return;
    int n2 = idx % N_;
    int t = (idx / N_) % T_;
    int b = idx / (T_ * N_);
    const float* l0 = lhs_t0 + (size_t)b * CT_;
    float acc = 0.f;
#pragma unroll
    for (int c = 0; c < C_; ++c) acc += l0[c * T_ + t] * U2[c * N_ + n2];
    lhs_t[idx] = acc;
}

__global__ void k_temporal_E(const float* __restrict__ lhs_t, const float* __restrict__ rhs_t,
                             const float* __restrict__ b_e, const float* __restrict__ V_e,
                             float* __restrict__ E) {
    int b = blockIdx.x;
    int tid = threadIdx.x;                               // 576 threads
    int i = tid / T_, u = tid % T_;
    __shared__ float sig[T_][T_];
    __shared__ float e0s[T_][T_];
    __shared__ float mcol[T_], scol[T_];
    const float* lt = lhs_t + (size_t)b * T_ * N_ + (size_t)i * N_;
    const float* rt = rhs_t + (size_t)b * N_ * T_ + u;
    float acc = 0.f;
    for (int n = 0; n < N_; ++n) acc += lt[n] * rt[(size_t)n * T_];
    sig[i][u] = sigmoidf_(acc + b_e[i * T_ + u]);
    __syncthreads();
    int j = u;
    float e0 = 0.f;
#pragma unroll
    for (int kk = 0; kk < T_; ++kk) e0 += sig[i][kk] * V_e[j * T_ + kk];
    e0s[i][j] = e0;
    __syncthreads();
    if (tid < T_) {
        float mx = -1e30f;
        for (int ii = 0; ii < T_; ++ii) mx = fmaxf(mx, e0s[ii][tid]);
        float s = 0.f;
        for (int ii = 0; ii < T_; ++ii) s += __expf(e0s[ii][tid] - mx);
        mcol[tid] = mx; scol[tid] = s;
    }
    __syncthreads();
    E[(size_t)b * T_ * T_ + i * T_ + j] = __expf(e0s[i][j] - mcol[j]) / scol[j];
}

// ---------------- fused: x_TAt (in-register) -> spatial prep + xTt emit ----------------
__global__ __launch_bounds__(256) void k_tspatial(const float* __restrict__ x,
        const float* __restrict__ E, const float* __restrict__ W1g,
        const float* __restrict__ W2, const float* __restrict__ W3g,
        float* __restrict__ lhs_s, float* __restrict__ rhs_s,
        unsigned short* __restrict__ xTt) {
    int b = blockIdx.y;
    int n0 = blockIdx.x * 4;
    int tid = threadIdx.x;
    __shared__ float Es[T_ * T_];
    __shared__ float W1s[T_];
    __shared__ float W2s[C_ * T_];
    __shared__ float xr[4][64][25];                      // staged x, then reused for w3*u
    __shared__ float l0s[4][64];
    for (int e = tid; e < T_ * T_; e += 256) Es[e] = E[(size_t)b * T_ * T_ + e];
    for (int e = tid; e < C_ * T_; e += 256) W2s[e] = W2[e];
    if (tid < T_) W1s[tid] = W1g[tid];
    size_t base = ((size_t)b * N_ + n0) * CT_;
    const float4* x4 = (const float4*)(x + base);
#pragma unroll
    for (int i = 0; i < 6; ++i) {
        int e4 = i * 256 + tid;
        float4 v = x4[e4];
        int e = e4 * 4;
        int nl = e / CT_; int rem = e - nl * CT_; int c = rem / 24; int tl = rem - c * 24;
        xr[nl][c][tl] = v.x; xr[nl][c][tl + 1] = v.y;
        xr[nl][c][tl + 2] = v.z; xr[nl][c][tl + 3] = v.w;
    }
    __syncthreads();
    int nl = tid >> 6, c = tid & 63;
    float xv[T_];
#pragma unroll
    for (int t = 0; t < T_; ++t) xv[t] = xr[nl][c][t];
    // emit xTt[b][t][n][c] bf16 from staged x (coalesced 128B chunks)
#pragma unroll
    for (int i = 0; i < 24; ++i) {
        int idx = i * 256 + tid;
        int cc = idx & 63, nn = (idx >> 6) & 3, t = idx >> 8;
        xTt[((size_t)(b * T_ + t) * N_ + n0 + nn) * 64 + cc] = f2b(xr[nn][cc][t]);
    }
    float w3 = W3g[c];
    float u[T_];
#pragma unroll
    for (int j = 0; j < T_; ++j) {
        float a = 0.f;
#pragma unroll
        for (int t = 0; t < T_; ++t) a += xv[t] * Es[t * T_ + j];
        u[j] = a;
    }
    float l0 = 0.f;
#pragma unroll
    for (int j = 0; j < T_; ++j) l0 += u[j] * W1s[j];
    __syncthreads();                                     // xTt-emit LDS reads done
#pragma unroll
    for (int j = 0; j < T_; ++j) xr[nl][c][j] = w3 * u[j];
    l0s[nl][c] = l0;
    __syncthreads();
    if (tid < 4 * T_) {
        int t = tid % T_, g = tid / T_;
        float racc = 0.f, lacc = 0.f;
        for (int cc = 0; cc < 64; ++cc) {
            racc += xr[g][cc][t];
            lacc += l0s[g][cc] * W2s[cc * T_ + t];
        }
        rhs_s[((size_t)b * T_ + t) * N_ + n0 + g] = racc;
        lhs_s[((size_t)(b * N_ + n0 + g)) * T_ + t] = lacc;
    }
}

// ---------------- converters / builders ----------------
__global__ void k_cvt_vs(const float* __restrict__ v, unsigned short* __restrict__ o) {
    int i = blockIdx.x * 256 + threadIdx.x;
    o[i] = f2b(v[i]);
}

// Wcat[ft][k], k = sel*64+c: sel 0..2 -> tc_w taps, sel 3 -> rc_w.  bf16 [64][256]
__global__ void k_wcat(const float* __restrict__ tc_w, const float* __restrict__ rc_w,
                       unsigned short* __restrict__ Wcat) {
    int i = blockIdx.x * 256 + threadIdx.x;              // over 64*256
    if (i >= F_ * 256) return;
    int ft = i >> 8, k = i & 255;
    int sel = k >> 6, c = k & 63;
    float v = (sel < 3) ? tc_w[(ft * C_ + c) * 3 + sel] : rc_w[ft * C_ + c];
    Wcat[i] = f2b(v);
}

// Thp[k*64+f][c] (bf16) = Theta[k][c][f]   -- A-operand for k_yTmm
__global__ void k_thp(const float* __restrict__ Theta, unsigned short* __restrict__ Thp) {
    int i = blockIdx.x * 256 + threadIdx.x;              // over 192*64
    if (i >= 192 * 64) return;
    int kf = i >> 6, c = i & 63;
    int k = kf >> 6, f = kf & 63;
    Thp[i] = f2b(Theta[((size_t)k * 64 + c) * 64 + f]);
}

// sigA[b][i][k] (bf16) = sigmoid(dot24(lhs_s[b,i,:], rhs_s[b,:,k]) + b_s[i,k])
__global__ __launch_bounds__(256) void k_sig(const float* __restrict__ lhs_s,
        const float* __restrict__ rhs_s, const float* __restrict__ b_s,
        unsigned short* __restrict__ sigA) {
    int b = blockIdx.z, i0 = blockIdx.y * 64, k0 = blockIdx.x * 256;
    int tid = threadIdx.x;
    __shared__ float lh[64 * T_];
    __shared__ float rh[T_][256];
    for (int e = tid; e < 64 * T_; e += 256) lh[e] = lhs_s[((size_t)b * N_ + i0) * T_ + e];
#pragma unroll
    for (int t = 0; t < T_; ++t) rh[t][tid] = rhs_s[((size_t)b * T_ + t) * N_ + k0 + tid];
    __syncthreads();
    int kg = k0 + tid;
    for (int ii = 0; ii < 64; ++ii) {
        float acc = b_s[(size_t)(i0 + ii) * N_ + kg];
#pragma unroll
        for (int t = 0; t < T_; ++t) acc += lh[ii * T_ + t] * rh[t][tid];
        sigA[((size_t)b * N_ + i0 + ii) * N_ + kg] = f2b(sigmoidf_(acc));
    }
}

// ---------------- yT via MFMA, coalesced stores through LDS C-tile ----------------
// yT[b][f*24+t][k*1024+m] = sum_c Thp[kf][c]*xTt[b][t][m][c].
// After MFMA: acc -> bf16 Cl[96][136] (reuses dead Bsb region) in two 96-row halves,
// then uint4 stores where 16 consecutive lanes cover one 256B output row.
__global__ __launch_bounds__(256) void k_yTmm(const unsigned short* __restrict__ xTt,
        const unsigned short* __restrict__ Thp, unsigned short* __restrict__ yT) {
    int bt = blockIdx.y;
    int b = bt / T_, t = bt - b * T_;
    int m0 = blockIdx.x * 128;
    int tid = threadIdx.x;
    int lane = tid & 63, wv = tid >> 6;
    __shared__ __align__(16) char smem[50688];
    unsigned short* Asb = (unsigned short*)smem;             // [192*64] 24576B (live whole kernel)
    unsigned short* Bsb = (unsigned short*)(smem + 24576);   // [128*64] 16384B
    unsigned short* Cl  = (unsigned short*)(smem + 24576);   // [96][136] 26112B (after Bsb dead)
#pragma unroll
    for (int e = 0; e < 6; ++e) {                        // stage Thp (24KB)
        int chunk = e * 256 + tid;
        int row = chunk >> 3, slot = chunk & 7;
        int gslot = slot ^ (row & 7);
        gload_lds16(Thp + row * 64 + gslot * 8, &Asb[chunk * 8]);
    }
    const unsigned short* Bg = xTt + ((size_t)bt * N_ + m0) * 64;
#pragma unroll
    for (int e = 0; e < 4; ++e) {                        // stage B (16KB)
        int chunk = e * 256 + tid;
        int row = chunk >> 3, slot = chunk & 7;
        int gslot = slot ^ (row & 7);
        gload_lds16(Bg + (size_t)row * 64 + gslot * 8, &Bsb[chunk * 8]);
    }
    __syncthreads();                                     // drains vmcnt

    short8 bf[2][2];
#pragma unroll
    for (int ni = 0; ni < 2; ++ni)
#pragma unroll
        for (int kk = 0; kk < 2; ++kk) {
            int r = wv * 32 + ni * 16 + (lane & 15);
            int slot = (kk * 4 + (lane >> 4)) ^ (r & 7);
            bf[ni][kk] = *(const short8*)&Bsb[r * 64 + slot * 8];
        }
    f32x4 acc[12][2];
#pragma unroll
    for (int mi = 0; mi < 12; ++mi)
#pragma unroll
        for (int ni = 0; ni < 2; ++ni) acc[mi][ni] = (f32x4){0.f, 0.f, 0.f, 0.f};
#pragma unroll
    for (int mi = 0; mi < 12; ++mi) {
        short8 af[2];
#pragma unroll
        for (int kk = 0; kk < 2; ++kk) {
            int r = mi * 16 + (lane & 15);
            int slot = (kk * 4 + (lane >> 4)) ^ (r & 7);
            af[kk] = *(const short8*)&Asb[r * 64 + slot * 8];
        }
#pragma unroll
        for (int kk = 0; kk < 2; ++kk)
#pragma unroll
            for (int ni = 0; ni < 2; ++ni)
                acc[mi][ni] = __builtin_amdgcn_mfma_f32_16x16x32_bf16(
                    af[kk], bf[ni][kk], acc[mi][ni], 0, 0, 0);
    }
    // two halves: kf rows [0,96) and [96,192)
#pragma unroll
    for (int h = 0; h < 2; ++h) {
        __syncthreads();                                 // all LDS reads (Bsb/prev Cl) done
#pragma unroll
        for (int mi2 = 0; mi2 < 6; ++mi2) {
            int mi = h * 6 + mi2;
#pragma unroll
            for (int r = 0; r < 4; ++r) {
                int row = mi2 * 16 + (lane >> 4) * 4 + r;
#pragma unroll
                for (int ni = 0; ni < 2; ++ni)
                    Cl[row * 136 + wv * 32 + ni * 16 + (lane & 15)] = f2b(acc[mi][ni][r]);
            }
        }
        __syncthreads();
#pragma unroll
        for (int e = 0; e < 6; ++e) {
            int idx = e * 256 + tid;                     // 96 rows x 16 segs
            int row = idx >> 4, seg = idx & 15;
            int kf = h * 96 + row;
            int k = kf >> 6, f = kf & 63;
            uint4 v = *(const uint4*)&Cl[row * 136 + seg * 8];
            *(uint4*)&yT[((size_t)b * CT_ + f * T_ + t) * KS_ + k * N_ + m0 + seg * 8] = v;
        }
    }
}

// online softmax stats over axis m of S[b,m,i]: mst[b*N+i] = (max, 1/sum)
__global__ void k_smstats(const float* __restrict__ S, float2* __restrict__ mst) {
    int b = blockIdx.y;
    int jj = threadIdx.x % 64;
    int ig = threadIdx.x / 64;
    int j = blockIdx.x * 64 + jj;
    __shared__ float rm[4][64], rs[4][64];
    float m = -1e30f, s = 0.f;
    for (int i = ig; i < N_; i += 4) {
        float v = S[((size_t)b * N_ + i) * N_ + j];
        float mn = fmaxf(m, v);
        s = s * __expf(m - mn) + __expf(v - mn);
        m = mn;
    }
    rm[ig][jj] = m; rs[ig][jj] = s;
    __syncthreads();
    if (ig == 0) {
        float M = rm[0][jj], SS = rs[0][jj];
#pragma unroll
        for (int g = 1; g < 4; ++g) {
            float mg = rm[g][jj];
            float mn = fmaxf(M, mg);
            SS = SS * __expf(M - mn) + rs[g][jj] * __expf(mg - mn);
            M = mn;
        }
        mst[(size_t)b * N_ + j] = make_float2(M, 1.f / SS);
    }
}

// chebSt[b][i][k*1024+m] (bf16) = cheb[k][m][i] * softmax(S)[b][m][i]  (float4 reads)
__global__ __launch_bounds__(256) void k_chebSt(const float* __restrict__ cheb,
        const float* __restrict__ S, const float2* __restrict__ mst,
        unsigned short* __restrict__ cs) {
    int b = blockIdx.z, i0 = blockIdx.y * 64, m0 = blockIdx.x * 64;
    int tid = threadIdx.x;
    __shared__ float st[64][65];
    __shared__ float cb[64][65];
    __shared__ float2 sst[64];
    if (tid < 64) sst[tid] = mst[(size_t)b * N_ + i0 + tid];
#pragma unroll
    for (int e = 0; e < 4; ++e) {
        int idx4 = e * 256 + tid;
        int mm = idx4 >> 4, ii0 = (idx4 & 15) * 4;
        float4 v = *(const float4*)&S[((size_t)b * N_ + m0 + mm) * N_ + i0 + ii0];
        st[mm][ii0] = v.x; st[mm][ii0 + 1] = v.y; st[mm][ii0 + 2] = v.z; st[mm][ii0 + 3] = v.w;
    }
    for (int k = 0; k < 3; ++k) {
        __syncthreads();
#pragma unroll
        for (int e = 0; e < 4; ++e) {
            int idx4 = e * 256 + tid;
            int mm = idx4 >> 4, ii0 = (idx4 & 15) * 4;
            float4 v = *(const float4*)&cheb[((size_t)k * N_ + m0 + mm) * N_ + i0 + ii0];
            cb[mm][ii0] = v.x; cb[mm][ii0 + 1] = v.y; cb[mm][ii0 + 2] = v.z; cb[mm][ii0 + 3] = v.w;
        }
        __syncthreads();
#pragma unroll
        for (int e = 0; e < 16; ++e) {
            int idx = e * 256 + tid; int mm = idx & 63, ii = idx >> 6;
            float sm = __expf(st[mm][ii] - sst[ii].x) * sst[ii].y;
            cs[((size_t)b * N_ + i0 + ii) * KS_ + k * N_ + m0 + mm] =
                f2b(sm * cb[mm][ii]);
        }
    }
}

// ---------------- 256x256-tile MFMA GEMM, hybrid counted-vmcnt pipeline ----------------
__global__ __launch_bounds__(512, 2) void k_gemm256(
        const unsigned short* __restrict__ A, long lda, long sA,
        const unsigned short* __restrict__ Bt, long ldb, long sB,
        float* __restrict__ Cc, long ldc, long sC, int K, int nbx, int nby) {
    __shared__ __align__(16) unsigned short As[2][256 * 64];   // 2 x 32KB
    __shared__ __align__(16) unsigned short Bs[2][256 * 64];   // 2 x 32KB
    int tid = threadIdx.x;
    int lane = tid & 63, w = tid >> 6;
    int wy = w >> 2, wx = w & 3;                            // 2 x 4 waves -> 128x64 per wave

    int nwg = gridDim.x;
    int cpx = nwg >> 3;
    int logical = (blockIdx.x & 7) * cpx + (blockIdx.x >> 3);
    int tpb = nbx * nby;
    int b = logical / tpb;
    int tile = logical % tpb;
    int i0 = (tile / nbx) * 256;
    int j0 = (tile % nbx) * 256;

    const unsigned short* Ab = A + (size_t)b * sA + (size_t)i0 * lda;
    const unsigned short* Bb = Bt + (size_t)b * sB + (size_t)j0 * ldb;

    auto STAGE = [&](int kt, int d) {
        int kof = kt << 6;
#pragma unroll
        for (int e = 0; e < 4; ++e) {
            int chunk = e * 512 + tid;
            int row = chunk >> 3, slot = chunk & 7;
            int gslot = slot ^ (row & 7);                   // inverse swizzle on source
            gload_lds16(Ab + (size_t)row * lda + kof + gslot * 8, &As[d][chunk * 8]);
        }
#pragma unroll
        for (int e = 0; e < 4; ++e) {
            int chunk = e * 512 + tid;
            int row = chunk >> 3, slot = chunk & 7;
            int gslot = slot ^ (row & 7);
            gload_lds16(Bb + (size_t)row * ldb + kof + gslot * 8, &Bs[d][chunk * 8]);
        }
    };
    auto READF = [&](short8* af, short8* bfv,
                     const unsigned short* Asb, const unsigned short* Bsb, int kkb) {
#pragma unroll
        for (int mi = 0; mi < 8; ++mi) {
            int r = wy * 128 + mi * 16 + (lane & 15);
            int slot = (kkb + (lane >> 4)) ^ (r & 7);
            af[mi] = *(const short8*)&Asb[r * 64 + slot * 8];
        }
#pragma unroll
        for (int ni = 0; ni < 4; ++ni) {
            int r = wx * 64 + ni * 16 + (lane & 15);
            int slot = (kkb + (lane >> 4)) ^ (r & 7);
            bfv[ni] = *(const short8*)&Bsb[r * 64 + slot * 8];
        }
    };

    f32x4 acc[8][4];
#pragma unroll
    for (int mi = 0; mi < 8; ++mi)
#pragma unroll
        for (int ni = 0; ni < 4; ++ni) acc[mi][ni] = (f32x4){0.f, 0.f, 0.f, 0.f};

    int nt = K >> 6;
    STAGE(0, 0);
    STAGE(1, 1);
    asm volatile("s_waitcnt vmcnt(8)" ::: "memory");        // K-tile 0 resident
    __builtin_amdgcn_s_barrier();
    __builtin_amdgcn_sched_barrier(0);

    short8 a0[8], b0[4], a1[8], b1[4];
    READF(a0, b0, As[0], Bs[0], 0);                         // kk0 of tile 0

    for (int kt = 0; kt < nt; ++kt) {
        int cur = kt & 1;
        READF(a1, b1, As[cur], Bs[cur], 4);                 // kk1 of this tile
        __builtin_amdgcn_s_setprio(1);
#pragma unroll
        for (int mi = 0; mi < 8; ++mi)
#pragma unroll
            for (int ni = 0; ni < 4; ++ni)
                acc[mi][ni] = __builtin_amdgcn_mfma_f32_16x16x32_bf16(
                    a0[mi], b0[ni], acc[mi][ni], 0, 0, 0);
        __builtin_amdgcn_s_setprio(0);
        asm volatile("s_waitcnt lgkmcnt(0)" ::: "memory");  // my reads of buf[cur] done
        __builtin_amdgcn_sched_barrier(0);
        __builtin_amdgcn_s_barrier();                       // all waves done with buf[cur]
        __builtin_amdgcn_sched_barrier(0);
        if (kt + 2 < nt) STAGE(kt + 2, cur);                // overwrite freed buffer
        __builtin_amdgcn_sched_barrier(0);
        __builtin_amdgcn_s_setprio(1);
#pragma unroll
        for (int mi = 0; mi < 8; ++mi)
#pragma unroll
            for (int ni = 0; ni < 4; ++ni)
                acc[mi][ni] = __builtin_amdgcn_mfma_f32_16x16x32_bf16(
                    a1[mi], b1[ni], acc[mi][ni], 0, 0, 0);
        __builtin_amdgcn_s_setprio(0);
        if (kt + 2 < nt) {
            asm volatile("s_waitcnt vmcnt(8)" ::: "memory"); // kt+1 retired, kt+2 in flight
        } else {
            asm volatile("s_waitcnt vmcnt(0)" ::: "memory"); // tail: drain (race-safe)
        }
        __builtin_amdgcn_s_barrier();                       // buf[cur^1] ready for all waves
        __builtin_amdgcn_sched_barrier(0);
        if (kt + 1 < nt)
            READF(a0, b0, As[cur ^ 1], Bs[cur ^ 1], 0);     // kk0 of next tile
    }

    float* Cb = Cc + (size_t)b * sC;
#pragma unroll
    for (int mi = 0; mi < 8; ++mi) {
#pragma unroll
        for (int r = 0; r < 4; ++r) {
            int i = i0 + wy * 128 + mi * 16 + (lane >> 4) * 4 + r;
            float* cp = Cb + (size_t)i * ldc + j0 + wx * 64 + (lane & 15);
#pragma unroll
            for (int ni = 0; ni < 4; ++ni) cp[ni * 16] = acc[mi][ni][r];
        }
    }
}

// ---------------- fused epilogue via MFMA (float4 I/O) ----------------
__global__ __launch_bounds__(256) void k_final(const float* __restrict__ x,
        const float* __restrict__ sgin, const unsigned short* __restrict__ Wcat,
        const float* __restrict__ tc_b, const float* __restrict__ rc_b,
        const float* __restrict__ ln_g, const float* __restrict__ ln_b,
        float* __restrict__ out) {
    int b = blockIdx.y;
    int n0 = blockIdx.x * 4;
    int tid = threadIdx.x;
    int lane = tid & 63, wv = tid >> 6;

    __shared__ __align__(16) char smem[25600];
    unsigned short* sgb = (unsigned short*)smem;            // [4][26][64]
    unsigned short* xb  = (unsigned short*)(smem + 13312);  // [4][24][64]
    float* Cl = (float*)smem;                               // [96][66] (after reuse barrier)
    __shared__ float tbs[64], gs[64], bbs[64];
    __shared__ float mus[96], rss[96];

    if (tid < 64) {
        tbs[tid] = tc_b[tid] + rc_b[tid];
        gs[tid] = ln_g[tid];
        bbs[tid] = ln_b[tid];
    }
    for (int e = tid; e < 512; e += 256) {
        int nl = e >> 7, r = (e >> 6) & 1, c = e & 63;
        int tt = r ? 25 : 0;
        sgb[(nl * 26 + tt) * 64 + (((c >> 3) ^ (tt & 7)) << 3) + (c & 7)] = 0;
    }
    size_t base = ((size_t)b * N_ + n0) * CT_;
    const float4* sg4 = (const float4*)(sgin + base);
    const float4* xg4 = (const float4*)(x + base);
#pragma unroll
    for (int i = 0; i < 6; ++i) {
        int e4 = i * 256 + tid;
        float4 sv4 = sg4[e4];
        float4 xv4 = xg4[e4];
        int e = e4 * 4;
        int nl = e / CT_;
        int rem = e - nl * CT_;
        int c = rem / 24;
        int tl = rem - c * 24;
        float sv[4] = {sv4.x, sv4.y, sv4.z, sv4.w};
        float xv[4] = {xv4.x, xv4.y, xv4.z, xv4.w};
#pragma unroll
        for (int j = 0; j < 4; ++j) {
            int tt = tl + j + 1;
            sgb[(nl * 26 + tt) * 64 + (((c >> 3) ^ (tt & 7)) << 3) + (c & 7)] =
                f2b(fmaxf(sv[j], 0.f));
            int tj = tl + j;
            xb[(nl * 24 + tj) * 64 + (((c >> 3) ^ (tj & 7)) << 3) + (c & 7)] = f2b(xv[j]);
        }
    }

    int ft = wv * 16 + (lane & 15);
    int g4 = lane >> 4;
    short8 bfr[8];
#pragma unroll
    for (int ks = 0; ks < 8; ++ks)
        bfr[ks] = *(const short8*)&Wcat[ft * 256 + ks * 32 + g4 * 8];

    int rnl[6], rt[6];
#pragma unroll
    for (int mi = 0; mi < 6; ++mi) {
        int row = mi * 16 + (lane & 15);
        rnl[mi] = row / 24;
        rt[mi] = row - rnl[mi] * 24;
    }

    __syncthreads();

    f32x4 acc[6];
#pragma unroll
    for (int mi = 0; mi < 6; ++mi) acc[mi] = (f32x4){0.f, 0.f, 0.f, 0.f};
#pragma unroll
    for (int mi = 0; mi < 6; ++mi) {
        int nl = rnl[mi], t = rt[mi];
#pragma unroll
        for (int ks = 0; ks < 8; ++ks) {
            const int sel = ks >> 1;
            int slot = (ks & 1) * 4 + g4;
            short8 af;
            if (sel < 3) {
                int tt = t + sel;
                af = *(const short8*)&sgb[(nl * 26 + tt) * 64 + ((slot ^ (tt & 7)) << 3)];
            } else {
                af = *(const short8*)&xb[(nl * 24 + t) * 64 + ((slot ^ (t & 7)) << 3)];
            }
            acc[mi] = __builtin_amdgcn_mfma_f32_16x16x32_bf16(af, bfr[ks], acc[mi], 0, 0, 0);
        }
    }

    __syncthreads();
#pragma unroll
    for (int mi = 0; mi < 6; ++mi)
#pragma unroll
        for (int r = 0; r < 4; ++r)
            Cl[(mi * 16 + (lane >> 4) * 4 + r) * 66 + wv * 16 + (lane & 15)] = acc[mi][r];
    __syncthreads();

    if (tid < 96) {
        float s = 0.f, s2 = 0.f;
#pragma unroll
        for (int f = 0; f < 64; ++f) {
            float v = fmaxf(Cl[tid * 66 + f] + tbs[f], 0.f);
            s += v; s2 += v * v;
        }
        float mu = s * (1.f / 64.f);
        float var = s2 * (1.f / 64.f) - mu * mu;
        mus[tid] = mu;
        rss[tid] = rsqrtf(var + 1e-5f);
    }
    __syncthreads();

    float4* o4 = (float4*)(out + base);
#pragma unroll
    for (int i = 0; i < 6; ++i) {
        int e4 = i * 256 + tid;
        int e = e4 * 4;
        int nl = e / CT_;
        int rem = e - nl * CT_;
        int f = rem / 24;
        int t0v = rem - f * 24;
        float g = gs[f], bb2 = bbs[f], tb2 = tbs[f];
        float vals[4];
#pragma unroll
        for (int j = 0; j < 4; ++j) {
            int row = nl * 24 + t0v + j;
            float v = fmaxf(Cl[row * 66 + f] + tb2, 0.f);
            vals[j] = (v - mus[row]) * rss[row] * g + bb2;
        }
        float4 r;
        r.x = vals[0]; r.y = vals[1]; r.z = vals[2]; r.w = vals[3];
        o4[e4] = r;
    }
}

extern "C" void kernel_launch(void* const* d_in, const int* in_sizes, int n_in,
                              void* d_out, int out_size, void* d_ws, size_t ws_size,
                              hipStream_t stream) {
    const float* x    = (const float*)d_in[0];
    const float* cheb = (const float*)d_in[1];
    const float* U1   = (const float*)d_in[2];
    const float* U2   = (const float*)d_in[3];
    const float* U3   = (const float*)d_in[4];
    const float* b_e  = (const float*)d_in[5];
    const float* V_e  = (const float*)d_in[6];
    const float* W1   = (const float*)d_in[7];
    const float* W2   = (const float*)d_in[8];
    const float* W3   = (const float*)d_in[9];
    const float* b_s  = (const float*)d_in[10];
    const float* V_s  = (const float*)d_in[11];
    const float* Theta= (const float*)d_in[12];
    const float* tc_w = (const float*)d_in[13];
    const float* tc_b = (const float*)d_in[14];
    const float* rc_w = (const float*)d_in[15];
    const float* rc_b = (const float*)d_in[16];
    const float* ln_g = (const float*)d_in[17];
    const float* ln_b = (const float*)d_in[18];
    float* out = (float*)d_out;

    char* base = (char*)d_ws;
    size_t o = 0;
    auto alloc = [&](size_t bytes) { size_t r = o; o += (bytes + 255) & ~(size_t)255; return r; };
    float* lhs_t   = (float*)(base + alloc((size_t)B_ * T_ * N_ * 4));
    float* rhs_t   = (float*)(base + alloc((size_t)B_ * N_ * T_ * 4));
    float* Ebuf    = (float*)(base + alloc((size_t)B_ * T_ * T_ * 4));
    float* partial = (float*)(base + alloc((size_t)B_ * 16 * CT_ * 4));
    float* lhs_t0  = (float*)(base + alloc((size_t)B_ * CT_ * 4));
    float* lhs_s   = (float*)(base + alloc((size_t)B_ * N_ * T_ * 4));
    float* rhs_s   = (float*)(base + alloc((size_t)B_ * T_ * N_ * 4));
    unsigned short* V_sb = (unsigned short*)(base + alloc((size_t)N_ * N_ * 2));
    unsigned short* Wcat = (unsigned short*)(base + alloc((size_t)F_ * 256 * 2));
    unsigned short* Thp  = (unsigned short*)(base + alloc((size_t)192 * 64 * 2));
    float2* mstats = (float2*)(base + alloc((size_t)B_ * N_ * 8));
    size_t regA = alloc((size_t)B_ * N_ * KS_ * 2);   // xTt (bf16) -> chebSt (bf16)
    size_t regB = alloc((size_t)B_ * CT_ * KS_ * 2);  // sigA (bf16) -> yT (bf16)
    unsigned short* xTt    = (unsigned short*)(base + regA);
    unsigned short* chebSt = (unsigned short*)(base + regA);
    unsigned short* sigA   = (unsigned short*)(base + regB);
    unsigned short* yT     = (unsigned short*)(base + regB);
    float* Sb  = out;        // S scores live in d_out until the stacked GEMM overwrites
    float* gcn = out;

    dim3 b256(256);
    k_cvt_vs<<<dim3(N_ * N_ / 256), b256, 0, stream>>>(V_s, V_sb);
    k_wcat<<<dim3((F_ * 256 + 255) / 256), b256, 0, stream>>>(tc_w, rc_w, Wcat);
    k_thp<<<dim3((192 * 64 + 255) / 256), b256, 0, stream>>>(Theta, Thp);
    k_rhs_t<<<dim3(N_ / 8, B_), b256, 0, stream>>>(x, U3, rhs_t);
    k_lhs_partial<<<dim3(16, B_), b256, 0, stream>>>(x, U1, partial);
    k_lhs_reduce<<<dim3((B_ * CT_) / 256), b256, 0, stream>>>(partial, lhs_t0);
    k_lhs_t<<<dim3((B_ * T_ * N_) / 256), b256, 0, stream>>>(lhs_t0, U2, lhs_t);
    k_temporal_E<<<dim3(B_), dim3(576), 0, stream>>>(lhs_t, rhs_t, b_e, V_e, Ebuf);
    k_tspatial<<<dim3(N_ / 4, B_), b256, 0, stream>>>(x, Ebuf, W1, W2, W3,
                                                      lhs_s, rhs_s, xTt);
    k_sig<<<dim3(N_ / 256, N_ / 64, B_), b256, 0, stream>>>(lhs_s, rhs_s, b_s, sigA);
    // S0 GEMM: M=1024, Ncols=1024, K=1024; nwg=512 (%8==0)
    k_gemm256<<<dim3(B_ * 4 * 4), dim3(512), 0, stream>>>(
        sigA, N_, (long)N_ * N_, V_sb, N_, 0, Sb, N_, (long)N_ * N_, N_, 4, 4);
    k_smstats<<<dim3(N_ / 64, B_), b256, 0, stream>>>(Sb, mstats);
    k_yTmm<<<dim3(N_ / 128, B_ * T_), b256, 0, stream>>>(xTt, Thp, yT);        // sigA dead
    k_chebSt<<<dim3(N_ / 64, N_ / 64, B_), b256, 0, stream>>>(cheb, Sb, mstats, chebSt); // xTt dead
    // stacked GEMM: M=1024, Ncols=1536, K=3072; nwg=768 (%8==0)
    k_gemm256<<<dim3(B_ * 4 * 6), dim3(512), 0, stream>>>(
        chebSt, KS_, (long)N_ * KS_, yT, KS_, (long)CT_ * KS_,
        gcn, CT_, (long)N_ * CT_, KS_, 6, 4);                                 // Sb dead
    k_final<<<dim3(N_ / 4, B_), b256, 0, stream>>>(x, gcn, Wcat, tc_b, rc_b,
                                                   ln_g, ln_b, out);
}

// Round 12
// 1066.780 us; speedup vs baseline: 12.5994x; 1.0821x over previous
//
#include <hip/hip_runtime.h>

typedef __attribute__((ext_vector_type(8))) short short8;   // 8 bf16 (4 VGPRs)
typedef __attribute__((ext_vector_type(4))) float f32x4;

constexpr int B_ = 32;
constexpr int N_ = 1024;
constexpr int C_ = 64;
constexpr int T_ = 24;
constexpr int F_ = 64;
constexpr int CT_ = C_ * T_;     // 1536
constexpr int KS_ = 3072;        // stacked K = 3*1024

__device__ __forceinline__ float sigmoidf_(float x) {
    return 1.0f / (1.0f + __expf(-x));
}
__device__ __forceinline__ unsigned short f2b(float f) {   // RNE f32->bf16
    union { float f; unsigned u; } v; v.f = f;
    unsigned r = v.u + 0x7FFFu + ((v.u >> 16) & 1u);
    return (unsigned short)(r >> 16);
}
__device__ __forceinline__ float b2f(unsigned short h) {
    union { unsigned u; float f; } v; v.u = ((unsigned)h) << 16; return v.f;
}
__device__ __forceinline__ void gload_lds16(const unsigned short* g, unsigned short* l) {
    __builtin_amdgcn_global_load_lds(
        (const __attribute__((address_space(1))) unsigned int*)g,
        (__attribute__((address_space(3))) unsigned int*)l, 16, 0, 0);
}

// ---------------- fused x reductions: rhs_t + U1-partial (one x read) ----------------
// Block = (b, 32 n-rows in 4 phases of 8).  rhs_t[b,n,t] = sum_c U3[c]*x[b,n,c,t];
// partial[b][chunk][ct] = sum_{n in chunk} U1[n]*x[b,n,ct].
__global__ __launch_bounds__(256) void k_xreduce(const float* __restrict__ x,
        const float* __restrict__ U1, const float* __restrict__ U3,
        float* __restrict__ rhs_t, float* __restrict__ partial) {
    int b = blockIdx.y, g0 = blockIdx.x * 32;
    int tid = threadIdx.x;
    __shared__ float xr[8 * CT_];                        // 48 KB
    __shared__ float u3s[C_];
    if (tid < C_) u3s[tid] = U3[tid];
    float pacc[6] = {0, 0, 0, 0, 0, 0};
    for (int ph = 0; ph < 4; ++ph) {
        int n0 = g0 + ph * 8;
        __syncthreads();                                 // prev phase LDS reads done
        const float4* x4 = (const float4*)(x + ((size_t)(b * N_ + n0)) * CT_);
#pragma unroll
        for (int e = 0; e < 12; ++e) {
            int i4 = e * 256 + tid;
            float4 v = x4[i4];
            int i = i4 * 4;
            xr[i] = v.x; xr[i + 1] = v.y; xr[i + 2] = v.z; xr[i + 3] = v.w;
        }
        __syncthreads();
        if (tid < 192) {
            int n = tid / 24, t = tid % 24;
            const float* xn = xr + n * CT_ + t;
            float acc = 0.f;
#pragma unroll
            for (int c = 0; c < C_; ++c) acc += u3s[c] * xn[c * 24];
            rhs_t[((size_t)(b * N_ + n0 + n)) * T_ + t] = acc;
        }
#pragma unroll
        for (int n = 0; n < 8; ++n) {
            float u = U1[n0 + n];                        // uniform -> scalar
            const float* xn = xr + n * CT_;
#pragma unroll
            for (int e = 0; e < 6; ++e) pacc[e] += u * xn[tid + e * 256];
        }
    }
    float* pp = partial + ((size_t)(b * 32 + blockIdx.x)) * CT_;
#pragma unroll
    for (int e = 0; e < 6; ++e) pp[tid + e * 256] = pacc[e];
}

__global__ void k_lhs_reduce(const float* __restrict__ partial, float* __restrict__ lhs_t0) {
    int idx = blockIdx.x * 256 + threadIdx.x;
    if (idx >= B_ * CT_) return;
    int b = idx / CT_, flat = idx % CT_;
    float acc = 0.f;
#pragma unroll
    for (int ch = 0; ch < 32; ++ch) acc += partial[((size_t)(b * 32 + ch)) * CT_ + flat];
    lhs_t0[idx] = acc;
}

__global__ void k_lhs_t(const float* __restrict__ lhs_t0, const float* __restrict__ U2,
                        float* __restrict__ lhs_t) {
    int idx = blockIdx.x * 256 + threadIdx.x;
    if (idx >= B_ * T_ * N_) return;
    int n2 = idx % N_;
    int t = (idx / N_) % T_;
    int b = idx / (T_ * N_);
    const float* l0 = lhs_t0 + (size_t)b * CT_;
    float acc = 0.f;
#pragma unroll
    for (int c = 0; c < C_; ++c) acc += l0[c * T_ + t] * U2[c * N_ + n2];
    lhs_t[idx] = acc;
}

// prod_t partials: ptp[b][ch][i][u] = sum_{n in ch} lhs_t[b,i,n]*rhs_t[b,n,u]
// 256 blocks (8 n-chunks x 32 b), LDS-staged, 128-fma dots (kills the 32-block
// serial-1024-dot latency kernel).
__global__ __launch_bounds__(576) void k_prodt(const float* __restrict__ lhs_t,
        const float* __restrict__ rhs_t, float* __restrict__ ptp) {
    int b = blockIdx.y, ch = blockIdx.x;
    int tid = threadIdx.x;
    __shared__ float lt[24][128];
    __shared__ float rt[128][25];
    int n0 = ch * 128;
    for (int e = tid; e < 24 * 128; e += 576) {
        int i = e >> 7, nn = e & 127;
        lt[i][nn] = lhs_t[((size_t)b * T_ + i) * N_ + n0 + nn];
    }
    const float* rg = rhs_t + ((size_t)b * N_ + n0) * T_;
    for (int e = tid; e < 128 * 24; e += 576) {
        int nn = e / 24, t = e - nn * 24;
        rt[nn][t] = rg[e];
    }
    __syncthreads();
    int i = tid / 24, u = tid - (tid / 24) * 24;
    float acc = 0.f;
#pragma unroll 8
    for (int nn = 0; nn < 128; ++nn) acc += lt[i][nn] * rt[nn][u];
    ptp[(((size_t)b * 8 + ch) * 24 + i) * 24 + u] = acc;
}

__global__ void k_temporal_E(const float* __restrict__ ptp,
                             const float* __restrict__ b_e, const float* __restrict__ V_e,
                             float* __restrict__ E) {
    int b = blockIdx.x;
    int tid = threadIdx.x;                               // 576 threads
    int i = tid / T_, u = tid % T_;
    __shared__ float sig[T_][T_];
    __shared__ float e0s[T_][T_];
    __shared__ float mcol[T_], scol[T_];
    float acc = 0.f;
#pragma unroll
    for (int ch = 0; ch < 8; ++ch)
        acc += ptp[(((size_t)b * 8 + ch) * 24 + i) * 24 + u];
    sig[i][u] = sigmoidf_(acc + b_e[i * T_ + u]);
    __syncthreads();
    int j = u;
    float e0 = 0.f;
#pragma unroll
    for (int kk = 0; kk < T_; ++kk) e0 += sig[i][kk] * V_e[j * T_ + kk];
    e0s[i][j] = e0;
    __syncthreads();
    if (tid < T_) {
        float mx = -1e30f;
        for (int ii = 0; ii < T_; ++ii) mx = fmaxf(mx, e0s[ii][tid]);
        float s = 0.f;
        for (int ii = 0; ii < T_; ++ii) s += __expf(e0s[ii][tid] - mx);
        mcol[tid] = mx; scol[tid] = s;
    }
    __syncthreads();
    E[(size_t)b * T_ * T_ + i * T_ + j] = __expf(e0s[i][j] - mcol[j]) / scol[j];
}

// ---------------- fused: x_TAt (in-register) -> spatial prep + xTt emit ----------------
__global__ __launch_bounds__(256) void k_tspatial(const float* __restrict__ x,
        const float* __restrict__ E, const float* __restrict__ W1g,
        const float* __restrict__ W2, const float* __restrict__ W3g,
        float* __restrict__ lhs_s, float* __restrict__ rhs_s,
        unsigned short* __restrict__ xTt) {
    int b = blockIdx.y;
    int n0 = blockIdx.x * 4;
    int tid = threadIdx.x;
    __shared__ float Es[T_ * T_];
    __shared__ float W1s[T_];
    __shared__ float W2s[C_ * T_];
    __shared__ float xr[4][64][25];                      // staged x, then reused for w3*u
    __shared__ float l0s[4][64];
    for (int e = tid; e < T_ * T_; e += 256) Es[e] = E[(size_t)b * T_ * T_ + e];
    for (int e = tid; e < C_ * T_; e += 256) W2s[e] = W2[e];
    if (tid < T_) W1s[tid] = W1g[tid];
    size_t base = ((size_t)b * N_ + n0) * CT_;
    const float4* x4 = (const float4*)(x + base);
#pragma unroll
    for (int i = 0; i < 6; ++i) {
        int e4 = i * 256 + tid;
        float4 v = x4[e4];
        int e = e4 * 4;
        int nl = e / CT_; int rem = e - nl * CT_; int c = rem / 24; int tl = rem - c * 24;
        xr[nl][c][tl] = v.x; xr[nl][c][tl + 1] = v.y;
        xr[nl][c][tl + 2] = v.z; xr[nl][c][tl + 3] = v.w;
    }
    __syncthreads();
    int nl = tid >> 6, c = tid & 63;
    float xv[T_];
#pragma unroll
    for (int t = 0; t < T_; ++t) xv[t] = xr[nl][c][t];
    // emit xTt[b][t][n][c] bf16 from staged x (coalesced 128B chunks)
#pragma unroll
    for (int i = 0; i < 24; ++i) {
        int idx = i * 256 + tid;
        int cc = idx & 63, nn = (idx >> 6) & 3, t = idx >> 8;
        xTt[((size_t)(b * T_ + t) * N_ + n0 + nn) * 64 + cc] = f2b(xr[nn][cc][t]);
    }
    float w3 = W3g[c];
    float u[T_];
#pragma unroll
    for (int j = 0; j < T_; ++j) {
        float a = 0.f;
#pragma unroll
        for (int t = 0; t < T_; ++t) a += xv[t] * Es[t * T_ + j];
        u[j] = a;
    }
    float l0 = 0.f;
#pragma unroll
    for (int j = 0; j < T_; ++j) l0 += u[j] * W1s[j];
    __syncthreads();                                     // xTt-emit LDS reads done
#pragma unroll
    for (int j = 0; j < T_; ++j) xr[nl][c][j] = w3 * u[j];
    l0s[nl][c] = l0;
    __syncthreads();
    if (tid < 4 * T_) {
        int t = tid % T_, g = tid / T_;
        float racc = 0.f, lacc = 0.f;
        for (int cc = 0; cc < 64; ++cc) {
            racc += xr[g][cc][t];
            lacc += l0s[g][cc] * W2s[cc * T_ + t];
        }
        rhs_s[((size_t)b * T_ + t) * N_ + n0 + g] = racc;
        lhs_s[((size_t)(b * N_ + n0 + g)) * T_ + t] = lacc;
    }
}

// ---------------- converters / builders ----------------
__global__ void k_cvt_vs(const float* __restrict__ v, unsigned short* __restrict__ o) {
    int i = blockIdx.x * 256 + threadIdx.x;
    o[i] = f2b(v[i]);
}

// Wcat[ft][k], k = sel*64+c: sel 0..2 -> tc_w taps, sel 3 -> rc_w.  bf16 [64][256]
__global__ void k_wcat(const float* __restrict__ tc_w, const float* __restrict__ rc_w,
                       unsigned short* __restrict__ Wcat) {
    int i = blockIdx.x * 256 + threadIdx.x;              // over 64*256
    if (i >= F_ * 256) return;
    int ft = i >> 8, k = i & 255;
    int sel = k >> 6, c = k & 63;
    float v = (sel < 3) ? tc_w[(ft * C_ + c) * 3 + sel] : rc_w[ft * C_ + c];
    Wcat[i] = f2b(v);
}

// Thp[k*64+f][c] (bf16) = Theta[k][c][f]   -- A-operand for k_yTmm
__global__ void k_thp(const float* __restrict__ Theta, unsigned short* __restrict__ Thp) {
    int i = blockIdx.x * 256 + threadIdx.x;              // over 192*64
    if (i >= 192 * 64) return;
    int kf = i >> 6, c = i & 63;
    int k = kf >> 6, f = kf & 63;
    Thp[i] = f2b(Theta[((size_t)k * 64 + c) * 64 + f]);
}

// sigA[b][i][k] (bf16) = sigmoid(dot24(lhs_s[b,i,:], rhs_s[b,:,k]) + b_s[i,k])
__global__ __launch_bounds__(256) void k_sig(const float* __restrict__ lhs_s,
        const float* __restrict__ rhs_s, const float* __restrict__ b_s,
        unsigned short* __restrict__ sigA) {
    int b = blockIdx.z, i0 = blockIdx.y * 64, k0 = blockIdx.x * 256;
    int tid = threadIdx.x;
    __shared__ float lh[64 * T_];
    __shared__ float rh[T_][256];
    for (int e = tid; e < 64 * T_; e += 256) lh[e] = lhs_s[((size_t)b * N_ + i0) * T_ + e];
#pragma unroll
    for (int t = 0; t < T_; ++t) rh[t][tid] = rhs_s[((size_t)b * T_ + t) * N_ + k0 + tid];
    __syncthreads();
    int kg = k0 + tid;
    for (int ii = 0; ii < 64; ++ii) {
        float acc = b_s[(size_t)(i0 + ii) * N_ + kg];
#pragma unroll
        for (int t = 0; t < T_; ++t) acc += lh[ii * T_ + t] * rh[t][tid];
        sigA[((size_t)b * N_ + i0 + ii) * N_ + kg] = f2b(sigmoidf_(acc));
    }
}

// ---------------- yT via MFMA, coalesced stores through LDS C-tile ----------------
__global__ __launch_bounds__(256) void k_yTmm(const unsigned short* __restrict__ xTt,
        const unsigned short* __restrict__ Thp, unsigned short* __restrict__ yT) {
    int bt = blockIdx.y;
    int b = bt / T_, t = bt - b * T_;
    int m0 = blockIdx.x * 128;
    int tid = threadIdx.x;
    int lane = tid & 63, wv = tid >> 6;
    __shared__ __align__(16) char smem[50688];
    unsigned short* Asb = (unsigned short*)smem;             // [192*64] (live whole kernel)
    unsigned short* Bsb = (unsigned short*)(smem + 24576);   // [128*64]
    unsigned short* Cl  = (unsigned short*)(smem + 24576);   // [96][136] (after Bsb dead)
#pragma unroll
    for (int e = 0; e < 6; ++e) {                        // stage Thp (24KB)
        int chunk = e * 256 + tid;
        int row = chunk >> 3, slot = chunk & 7;
        int gslot = slot ^ (row & 7);
        gload_lds16(Thp + row * 64 + gslot * 8, &Asb[chunk * 8]);
    }
    const unsigned short* Bg = xTt + ((size_t)bt * N_ + m0) * 64;
#pragma unroll
    for (int e = 0; e < 4; ++e) {                        // stage B (16KB)
        int chunk = e * 256 + tid;
        int row = chunk >> 3, slot = chunk & 7;
        int gslot = slot ^ (row & 7);
        gload_lds16(Bg + (size_t)row * 64 + gslot * 8, &Bsb[chunk * 8]);
    }
    __syncthreads();                                     // drains vmcnt

    short8 bf[2][2];
#pragma unroll
    for (int ni = 0; ni < 2; ++ni)
#pragma unroll
        for (int kk = 0; kk < 2; ++kk) {
            int r = wv * 32 + ni * 16 + (lane & 15);
            int slot = (kk * 4 + (lane >> 4)) ^ (r & 7);
            bf[ni][kk] = *(const short8*)&Bsb[r * 64 + slot * 8];
        }
    f32x4 acc[12][2];
#pragma unroll
    for (int mi = 0; mi < 12; ++mi)
#pragma unroll
        for (int ni = 0; ni < 2; ++ni) acc[mi][ni] = (f32x4){0.f, 0.f, 0.f, 0.f};
#pragma unroll
    for (int mi = 0; mi < 12; ++mi) {
        short8 af[2];
#pragma unroll
        for (int kk = 0; kk < 2; ++kk) {
            int r = mi * 16 + (lane & 15);
            int slot = (kk * 4 + (lane >> 4)) ^ (r & 7);
            af[kk] = *(const short8*)&Asb[r * 64 + slot * 8];
        }
#pragma unroll
        for (int kk = 0; kk < 2; ++kk)
#pragma unroll
            for (int ni = 0; ni < 2; ++ni)
                acc[mi][ni] = __builtin_amdgcn_mfma_f32_16x16x32_bf16(
                    af[kk], bf[ni][kk], acc[mi][ni], 0, 0, 0);
    }
#pragma unroll
    for (int h = 0; h < 2; ++h) {
        __syncthreads();
#pragma unroll
        for (int mi2 = 0; mi2 < 6; ++mi2) {
            int mi = h * 6 + mi2;
#pragma unroll
            for (int r = 0; r < 4; ++r) {
                int row = mi2 * 16 + (lane >> 4) * 4 + r;
#pragma unroll
                for (int ni = 0; ni < 2; ++ni)
                    Cl[row * 136 + wv * 32 + ni * 16 + (lane & 15)] = f2b(acc[mi][ni][r]);
            }
        }
        __syncthreads();
#pragma unroll
        for (int e = 0; e < 6; ++e) {
            int idx = e * 256 + tid;
            int row = idx >> 4, seg = idx & 15;
            int kf = h * 96 + row;
            int k = kf >> 6, f = kf & 63;
            uint4 v = *(const uint4*)&Cl[row * 136 + seg * 8];
            *(uint4*)&yT[((size_t)b * CT_ + f * T_ + t) * KS_ + k * N_ + m0 + seg * 8] = v;
        }
    }
}

// online softmax stats over axis m of S[b,m,i]: mst[b*N+i] = (max, 1/sum)
__global__ void k_smstats(const float* __restrict__ S, float2* __restrict__ mst) {
    int b = blockIdx.y;
    int jj = threadIdx.x % 64;
    int ig = threadIdx.x / 64;
    int j = blockIdx.x * 64 + jj;
    __shared__ float rm[4][64], rs[4][64];
    float m = -1e30f, s = 0.f;
    for (int i = ig; i < N_; i += 4) {
        float v = S[((size_t)b * N_ + i) * N_ + j];
        float mn = fmaxf(m, v);
        s = s * __expf(m - mn) + __expf(v - mn);
        m = mn;
    }
    rm[ig][jj] = m; rs[ig][jj] = s;
    __syncthreads();
    if (ig == 0) {
        float M = rm[0][jj], SS = rs[0][jj];
#pragma unroll
        for (int g = 1; g < 4; ++g) {
            float mg = rm[g][jj];
            float mn = fmaxf(M, mg);
            SS = SS * __expf(M - mn) + rs[g][jj] * __expf(mg - mn);
            M = mn;
        }
        mst[(size_t)b * N_ + j] = make_float2(M, 1.f / SS);
    }
}

// chebSt[b][i][k*1024+m] (bf16) = cheb[k][m][i] * softmax(S)[b][m][i]  (float4 reads)
__global__ __launch_bounds__(256) void k_chebSt(const float* __restrict__ cheb,
        const float* __restrict__ S, const float2* __restrict__ mst,
        unsigned short* __restrict__ cs) {
    int b = blockIdx.z, i0 = blockIdx.y * 64, m0 = blockIdx.x * 64;
    int tid = threadIdx.x;
    __shared__ float st[64][65];
    __shared__ float cb[64][65];
    __shared__ float2 sst[64];
    if (tid < 64) sst[tid] = mst[(size_t)b * N_ + i0 + tid];
#pragma unroll
    for (int e = 0; e < 4; ++e) {
        int idx4 = e * 256 + tid;
        int mm = idx4 >> 4, ii0 = (idx4 & 15) * 4;
        float4 v = *(const float4*)&S[((size_t)b * N_ + m0 + mm) * N_ + i0 + ii0];
        st[mm][ii0] = v.x; st[mm][ii0 + 1] = v.y; st[mm][ii0 + 2] = v.z; st[mm][ii0 + 3] = v.w;
    }
    for (int k = 0; k < 3; ++k) {
        __syncthreads();
#pragma unroll
        for (int e = 0; e < 4; ++e) {
            int idx4 = e * 256 + tid;
            int mm = idx4 >> 4, ii0 = (idx4 & 15) * 4;
            float4 v = *(const float4*)&cheb[((size_t)k * N_ + m0 + mm) * N_ + i0 + ii0];
            cb[mm][ii0] = v.x; cb[mm][ii0 + 1] = v.y; cb[mm][ii0 + 2] = v.z; cb[mm][ii0 + 3] = v.w;
        }
        __syncthreads();
#pragma unroll
        for (int e = 0; e < 16; ++e) {
            int idx = e * 256 + tid; int mm = idx & 63, ii = idx >> 6;
            float sm = __expf(st[mm][ii] - sst[ii].x) * sst[ii].y;
            cs[((size_t)b * N_ + i0 + ii) * KS_ + k * N_ + m0 + mm] =
                f2b(sm * cb[mm][ii]);
        }
    }
}

// ---------------- 256x256-tile MFMA GEMM, hybrid counted-vmcnt pipeline ----------------
__global__ __launch_bounds__(512, 2) void k_gemm256(
        const unsigned short* __restrict__ A, long lda, long sA,
        const unsigned short* __restrict__ Bt, long ldb, long sB,
        float* __restrict__ Cc, long ldc, long sC, int K, int nbx, int nby) {
    __shared__ __align__(16) unsigned short As[2][256 * 64];   // 2 x 32KB
    __shared__ __align__(16) unsigned short Bs[2][256 * 64];   // 2 x 32KB
    int tid = threadIdx.x;
    int lane = tid & 63, w = tid >> 6;
    int wy = w >> 2, wx = w & 3;                            // 2 x 4 waves -> 128x64 per wave

    int nwg = gridDim.x;
    int cpx = nwg >> 3;
    int logical = (blockIdx.x & 7) * cpx + (blockIdx.x >> 3);
    int tpb = nbx * nby;
    int b = logical / tpb;
    int tile = logical % tpb;
    int i0 = (tile / nbx) * 256;
    int j0 = (tile % nbx) * 256;

    const unsigned short* Ab = A + (size_t)b * sA + (size_t)i0 * lda;
    const unsigned short* Bb = Bt + (size_t)b * sB + (size_t)j0 * ldb;

    auto STAGE = [&](int kt, int d) {
        int kof = kt << 6;
#pragma unroll
        for (int e = 0; e < 4; ++e) {
            int chunk = e * 512 + tid;
            int row = chunk >> 3, slot = chunk & 7;
            int gslot = slot ^ (row & 7);                   // inverse swizzle on source
            gload_lds16(Ab + (size_t)row * lda + kof + gslot * 8, &As[d][chunk * 8]);
        }
#pragma unroll
        for (int e = 0; e < 4; ++e) {
            int chunk = e * 512 + tid;
            int row = chunk >> 3, slot = chunk & 7;
            int gslot = slot ^ (row & 7);
            gload_lds16(Bb + (size_t)row * ldb + kof + gslot * 8, &Bs[d][chunk * 8]);
        }
    };
    auto READF = [&](short8* af, short8* bfv,
                     const unsigned short* Asb, const unsigned short* Bsb, int kkb) {
#pragma unroll
        for (int mi = 0; mi < 8; ++mi) {
            int r = wy * 128 + mi * 16 + (lane & 15);
            int slot = (kkb + (lane >> 4)) ^ (r & 7);
            af[mi] = *(const short8*)&Asb[r * 64 + slot * 8];
        }
#pragma unroll
        for (int ni = 0; ni < 4; ++ni) {
            int r = wx * 64 + ni * 16 + (lane & 15);
            int slot = (kkb + (lane >> 4)) ^ (r & 7);
            bfv[ni] = *(const short8*)&Bsb[r * 64 + slot * 8];
        }
    };

    f32x4 acc[8][4];
#pragma unroll
    for (int mi = 0; mi < 8; ++mi)
#pragma unroll
        for (int ni = 0; ni < 4; ++ni) acc[mi][ni] = (f32x4){0.f, 0.f, 0.f, 0.f};

    int nt = K >> 6;
    STAGE(0, 0);
    STAGE(1, 1);
    asm volatile("s_waitcnt vmcnt(8)" ::: "memory");        // K-tile 0 resident
    __builtin_amdgcn_s_barrier();
    __builtin_amdgcn_sched_barrier(0);

    short8 a0[8], b0[4], a1[8], b1[4];
    READF(a0, b0, As[0], Bs[0], 0);                         // kk0 of tile 0

    for (int kt = 0; kt < nt; ++kt) {
        int cur = kt & 1;
        READF(a1, b1, As[cur], Bs[cur], 4);                 // kk1 of this tile
        __builtin_amdgcn_s_setprio(1);
#pragma unroll
        for (int mi = 0; mi < 8; ++mi)
#pragma unroll
            for (int ni = 0; ni < 4; ++ni)
                acc[mi][ni] = __builtin_amdgcn_mfma_f32_16x16x32_bf16(
                    a0[mi], b0[ni], acc[mi][ni], 0, 0, 0);
        __builtin_amdgcn_s_setprio(0);
        asm volatile("s_waitcnt lgkmcnt(0)" ::: "memory");  // my reads of buf[cur] done
        __builtin_amdgcn_sched_barrier(0);
        __builtin_amdgcn_s_barrier();                       // all waves done with buf[cur]
        __builtin_amdgcn_sched_barrier(0);
        if (kt + 2 < nt) STAGE(kt + 2, cur);                // overwrite freed buffer
        __builtin_amdgcn_sched_barrier(0);
        __builtin_amdgcn_s_setprio(1);
#pragma unroll
        for (int mi = 0; mi < 8; ++mi)
#pragma unroll
            for (int ni = 0; ni < 4; ++ni)
                acc[mi][ni] = __builtin_amdgcn_mfma_f32_16x16x32_bf16(
                    a1[mi], b1[ni], acc[mi][ni], 0, 0, 0);
        __builtin_amdgcn_s_setprio(0);
        if (kt + 2 < nt) {
            asm volatile("s_waitcnt vmcnt(8)" ::: "memory"); // kt+1 retired, kt+2 in flight
        } else {
            asm volatile("s_waitcnt vmcnt(0)" ::: "memory"); // tail: drain (race-safe)
        }
        __builtin_amdgcn_s_barrier();                       // buf[cur^1] ready for all waves
        __builtin_amdgcn_sched_barrier(0);
        if (kt + 1 < nt)
            READF(a0, b0, As[cur ^ 1], Bs[cur ^ 1], 0);     // kk0 of next tile
    }

    float* Cb = Cc + (size_t)b * sC;
#pragma unroll
    for (int mi = 0; mi < 8; ++mi) {
#pragma unroll
        for (int r = 0; r < 4; ++r) {
            int i = i0 + wy * 128 + mi * 16 + (lane >> 4) * 4 + r;
            float* cp = Cb + (size_t)i * ldc + j0 + wx * 64 + (lane & 15);
#pragma unroll
            for (int ni = 0; ni < 4; ++ni) cp[ni * 16] = acc[mi][ni][r];
        }
    }
}

// ---------------- fused epilogue via MFMA (float4 I/O) ----------------
__global__ __launch_bounds__(256) void k_final(const float* __restrict__ x,
        const float* __restrict__ sgin, const unsigned short* __restrict__ Wcat,
        const float* __restrict__ tc_b, const float* __restrict__ rc_b,
        const float* __restrict__ ln_g, const float* __restrict__ ln_b,
        float* __restrict__ out) {
    int b = blockIdx.y;
    int n0 = blockIdx.x * 4;
    int tid = threadIdx.x;
    int lane = tid & 63, wv = tid >> 6;

    __shared__ __align__(16) char smem[25600];
    unsigned short* sgb = (unsigned short*)smem;            // [4][26][64]
    unsigned short* xb  = (unsigned short*)(smem + 13312);  // [4][24][64]
    float* Cl = (float*)smem;                               // [96][66] (after reuse barrier)
    __shared__ float tbs[64], gs[64], bbs[64];
    __shared__ float mus[96], rss[96];

    if (tid < 64) {
        tbs[tid] = tc_b[tid] + rc_b[tid];
        gs[tid] = ln_g[tid];
        bbs[tid] = ln_b[tid];
    }
    for (int e = tid; e < 512; e += 256) {
        int nl = e >> 7, r = (e >> 6) & 1, c = e & 63;
        int tt = r ? 25 : 0;
        sgb[(nl * 26 + tt) * 64 + (((c >> 3) ^ (tt & 7)) << 3) + (c & 7)] = 0;
    }
    size_t base = ((size_t)b * N_ + n0) * CT_;
    const float4* sg4 = (const float4*)(sgin + base);
    const float4* xg4 = (const float4*)(x + base);
#pragma unroll
    for (int i = 0; i < 6; ++i) {
        int e4 = i * 256 + tid;
        float4 sv4 = sg4[e4];
        float4 xv4 = xg4[e4];
        int e = e4 * 4;
        int nl = e / CT_;
        int rem = e - nl * CT_;
        int c = rem / 24;
        int tl = rem - c * 24;
        float sv[4] = {sv4.x, sv4.y, sv4.z, sv4.w};
        float xv[4] = {xv4.x, xv4.y, xv4.z, xv4.w};
#pragma unroll
        for (int j = 0; j < 4; ++j) {
            int tt = tl + j + 1;
            sgb[(nl * 26 + tt) * 64 + (((c >> 3) ^ (tt & 7)) << 3) + (c & 7)] =
                f2b(fmaxf(sv[j], 0.f));
            int tj = tl + j;
            xb[(nl * 24 + tj) * 64 + (((c >> 3) ^ (tj & 7)) << 3) + (c & 7)] = f2b(xv[j]);
        }
    }

    int ft = wv * 16 + (lane & 15);
    int g4 = lane >> 4;
    short8 bfr[8];
#pragma unroll
    for (int ks = 0; ks < 8; ++ks)
        bfr[ks] = *(const short8*)&Wcat[ft * 256 + ks * 32 + g4 * 8];

    int rnl[6], rt[6];
#pragma unroll
    for (int mi = 0; mi < 6; ++mi) {
        int row = mi * 16 + (lane & 15);
        rnl[mi] = row / 24;
        rt[mi] = row - rnl[mi] * 24;
    }

    __syncthreads();

    f32x4 acc[6];
#pragma unroll
    for (int mi = 0; mi < 6; ++mi) acc[mi] = (f32x4){0.f, 0.f, 0.f, 0.f};
#pragma unroll
    for (int mi = 0; mi < 6; ++mi) {
        int nl = rnl[mi], t = rt[mi];
#pragma unroll
        for (int ks = 0; ks < 8; ++ks) {
            const int sel = ks >> 1;
            int slot = (ks & 1) * 4 + g4;
            short8 af;
            if (sel < 3) {
                int tt = t + sel;
                af = *(const short8*)&sgb[(nl * 26 + tt) * 64 + ((slot ^ (tt & 7)) << 3)];
            } else {
                af = *(const short8*)&xb[(nl * 24 + t) * 64 + ((slot ^ (t & 7)) << 3)];
            }
            acc[mi] = __builtin_amdgcn_mfma_f32_16x16x32_bf16(af, bfr[ks], acc[mi], 0, 0, 0);
        }
    }

    __syncthreads();
#pragma unroll
    for (int mi = 0; mi < 6; ++mi)
#pragma unroll
        for (int r = 0; r < 4; ++r)
            Cl[(mi * 16 + (lane >> 4) * 4 + r) * 66 + wv * 16 + (lane & 15)] = acc[mi][r];
    __syncthreads();

    if (tid < 96) {
        float s = 0.f, s2 = 0.f;
#pragma unroll
        for (int f = 0; f < 64; ++f) {
            float v = fmaxf(Cl[tid * 66 + f] + tbs[f], 0.f);
            s += v; s2 += v * v;
        }
        float mu = s * (1.f / 64.f);
        float var = s2 * (1.f / 64.f) - mu * mu;
        mus[tid] = mu;
        rss[tid] = rsqrtf(var + 1e-5f);
    }
    __syncthreads();

    float4* o4 = (float4*)(out + base);
#pragma unroll
    for (int i = 0; i < 6; ++i) {
        int e4 = i * 256 + tid;
        int e = e4 * 4;
        int nl = e / CT_;
        int rem = e - nl * CT_;
        int f = rem / 24;
        int t0v = rem - f * 24;
        float g = gs[f], bb2 = bbs[f], tb2 = tbs[f];
        float vals[4];
#pragma unroll
        for (int j = 0; j < 4; ++j) {
            int row = nl * 24 + t0v + j;
            float v = fmaxf(Cl[row * 66 + f] + tb2, 0.f);
            vals[j] = (v - mus[row]) * rss[row] * g + bb2;
        }
        float4 r;
        r.x = vals[0]; r.y = vals[1]; r.z = vals[2]; r.w = vals[3];
        o4[e4] = r;
    }
}

extern "C" void kernel_launch(void* const* d_in, const int* in_sizes, int n_in,
                              void* d_out, int out_size, void* d_ws, size_t ws_size,
                              hipStream_t stream) {
    const float* x    = (const float*)d_in[0];
    const float* cheb = (const float*)d_in[1];
    const float* U1   = (const float*)d_in[2];
    const float* U2   = (const float*)d_in[3];
    const float* U3   = (const float*)d_in[4];
    const float* b_e  = (const float*)d_in[5];
    const float* V_e  = (const float*)d_in[6];
    const float* W1   = (const float*)d_in[7];
    const float* W2   = (const float*)d_in[8];
    const float* W3   = (const float*)d_in[9];
    const float* b_s  = (const float*)d_in[10];
    const float* V_s  = (const float*)d_in[11];
    const float* Theta= (const float*)d_in[12];
    const float* tc_w = (const float*)d_in[13];
    const float* tc_b = (const float*)d_in[14];
    const float* rc_w = (const float*)d_in[15];
    const float* rc_b = (const float*)d_in[16];
    const float* ln_g = (const float*)d_in[17];
    const float* ln_b = (const float*)d_in[18];
    float* out = (float*)d_out;

    char* base = (char*)d_ws;
    size_t o = 0;
    auto alloc = [&](size_t bytes) { size_t r = o; o += (bytes + 255) & ~(size_t)255; return r; };
    float* lhs_t   = (float*)(base + alloc((size_t)B_ * T_ * N_ * 4));
    float* rhs_t   = (float*)(base + alloc((size_t)B_ * N_ * T_ * 4));
    float* Ebuf    = (float*)(base + alloc((size_t)B_ * T_ * T_ * 4));
    float* partial = (float*)(base + alloc((size_t)B_ * 32 * CT_ * 4));
    float* ptp     = (float*)(base + alloc((size_t)B_ * 8 * T_ * T_ * 4));
    float* lhs_t0  = (float*)(base + alloc((size_t)B_ * CT_ * 4));
    float* lhs_s   = (float*)(base + alloc((size_t)B_ * N_ * T_ * 4));
    float* rhs_s   = (float*)(base + alloc((size_t)B_ * T_ * N_ * 4));
    unsigned short* V_sb = (unsigned short*)(base + alloc((size_t)N_ * N_ * 2));
    unsigned short* Wcat = (unsigned short*)(base + alloc((size_t)F_ * 256 * 2));
    unsigned short* Thp  = (unsigned short*)(base + alloc((size_t)192 * 64 * 2));
    float2* mstats = (float2*)(base + alloc((size_t)B_ * N_ * 8));
    size_t regA = alloc((size_t)B_ * N_ * KS_ * 2);   // xTt (bf16) -> chebSt (bf16)
    size_t regB = alloc((size_t)B_ * CT_ * KS_ * 2);  // sigA (bf16) -> yT (bf16)
    unsigned short* xTt    = (unsigned short*)(base + regA);
    unsigned short* chebSt = (unsigned short*)(base + regA);
    unsigned short* sigA   = (unsigned short*)(base + regB);
    unsigned short* yT     = (unsigned short*)(base + regB);
    float* Sb  = out;        // S scores live in d_out until the stacked GEMM overwrites
    float* gcn = out;

    dim3 b256(256);
    k_cvt_vs<<<dim3(N_ * N_ / 256), b256, 0, stream>>>(V_s, V_sb);
    k_wcat<<<dim3((F_ * 256 + 255) / 256), b256, 0, stream>>>(tc_w, rc_w, Wcat);
    k_thp<<<dim3((192 * 64 + 255) / 256), b256, 0, stream>>>(Theta, Thp);
    k_xreduce<<<dim3(N_ / 32, B_), b256, 0, stream>>>(x, U1, U3, rhs_t, partial);
    k_lhs_reduce<<<dim3((B_ * CT_ + 255) / 256), b256, 0, stream>>>(partial, lhs_t0);
    k_lhs_t<<<dim3((B_ * T_ * N_) / 256), b256, 0, stream>>>(lhs_t0, U2, lhs_t);
    k_prodt<<<dim3(8, B_), dim3(576), 0, stream>>>(lhs_t, rhs_t, ptp);
    k_temporal_E<<<dim3(B_), dim3(576), 0, stream>>>(ptp, b_e, V_e, Ebuf);
    k_tspatial<<<dim3(N_ / 4, B_), b256, 0, stream>>>(x, Ebuf, W1, W2, W3,
                                                      lhs_s, rhs_s, xTt);
    k_sig<<<dim3(N_ / 256, N_ / 64, B_), b256, 0, stream>>>(lhs_s, rhs_s, b_s, sigA);
    // S0 GEMM: M=1024, Ncols=1024, K=1024; nwg=512 (%8==0)
    k_gemm256<<<dim3(B_ * 4 * 4), dim3(512), 0, stream>>>(
        sigA, N_, (long)N_ * N_, V_sb, N_, 0, Sb, N_, (long)N_ * N_, N_, 4, 4);
    k_smstats<<<dim3(N_ / 64, B_), b256, 0, stream>>>(Sb, mstats);
    k_yTmm<<<dim3(N_ / 128, B_ * T_), b256, 0, stream>>>(xTt, Thp, yT);        // sigA dead
    k_chebSt<<<dim3(N_ / 64, N_ / 64, B_), b256, 0, stream>>>(cheb, Sb, mstats, chebSt); // xTt dead
    // stacked GEMM: M=1024, Ncols=1536, K=3072; nwg=768 (%8==0)
    k_gemm256<<<dim3(B_ * 4 * 6), dim3(512), 0, stream>>>(
        chebSt, KS_, (long)N_ * KS_, yT, KS_, (long)CT_ * KS_,
        gcn, CT_, (long)N_ * CT_, KS_, 6, 4);                                 // Sb dead
    k_final<<<dim3(N_ / 4, B_), b256, 0, stream>>>(x, gcn, Wcat, tc_b, rc_b,
                                                   ln_g, ln_b, out);
}

// Round 13
// 1062.545 us; speedup vs baseline: 12.6496x; 1.0040x over previous
//
#include <hip/hip_runtime.h>

typedef __attribute__((ext_vector_type(8))) short short8;   // 8 bf16 (4 VGPRs)
typedef __attribute__((ext_vector_type(4))) float f32x4;
typedef __attribute__((ext_vector_type(4))) unsigned short ushort4_;

constexpr int B_ = 32;
constexpr int N_ = 1024;
constexpr int C_ = 64;
constexpr int T_ = 24;
constexpr int F_ = 64;
constexpr int CT_ = C_ * T_;     // 1536
constexpr int KS_ = 3072;        // stacked K = 3*1024

__device__ __forceinline__ float sigmoidf_(float x) {
    return 1.0f / (1.0f + __expf(-x));
}
__device__ __forceinline__ unsigned short f2b(float f) {   // RNE f32->bf16
    union { float f; unsigned u; } v; v.f = f;
    unsigned r = v.u + 0x7FFFu + ((v.u >> 16) & 1u);
    return (unsigned short)(r >> 16);
}
__device__ __forceinline__ float b2f(unsigned short h) {
    union { unsigned u; float f; } v; v.u = ((unsigned)h) << 16; return v.f;
}
__device__ __forceinline__ void gload_lds16(const unsigned short* g, unsigned short* l) {
    __builtin_amdgcn_global_load_lds(
        (const __attribute__((address_space(1))) unsigned int*)g,
        (__attribute__((address_space(3))) unsigned int*)l, 16, 0, 0);
}

// ---------------- fused x reductions: rhs_t + U1-partial (one x read) ----------------
__global__ __launch_bounds__(256) void k_xreduce(const float* __restrict__ x,
        const float* __restrict__ U1, const float* __restrict__ U3,
        float* __restrict__ rhs_t, float* __restrict__ partial) {
    int b = blockIdx.y, g0 = blockIdx.x * 32;
    int tid = threadIdx.x;
    __shared__ float xr[8 * CT_];                        // 48 KB
    __shared__ float u3s[C_];
    if (tid < C_) u3s[tid] = U3[tid];
    float pacc[6] = {0, 0, 0, 0, 0, 0};
    for (int ph = 0; ph < 4; ++ph) {
        int n0 = g0 + ph * 8;
        __syncthreads();                                 // prev phase LDS reads done
        const float4* x4 = (const float4*)(x + ((size_t)(b * N_ + n0)) * CT_);
#pragma unroll
        for (int e = 0; e < 12; ++e) {
            int i4 = e * 256 + tid;
            float4 v = x4[i4];
            int i = i4 * 4;
            xr[i] = v.x; xr[i + 1] = v.y; xr[i + 2] = v.z; xr[i + 3] = v.w;
        }
        __syncthreads();
        if (tid < 192) {
            int n = tid / 24, t = tid % 24;
            const float* xn = xr + n * CT_ + t;
            float acc = 0.f;
#pragma unroll
            for (int c = 0; c < C_; ++c) acc += u3s[c] * xn[c * 24];
            rhs_t[((size_t)(b * N_ + n0 + n)) * T_ + t] = acc;
        }
#pragma unroll
        for (int n = 0; n < 8; ++n) {
            float u = U1[n0 + n];                        // uniform -> scalar
            const float* xn = xr + n * CT_;
#pragma unroll
            for (int e = 0; e < 6; ++e) pacc[e] += u * xn[tid + e * 256];
        }
    }
    float* pp = partial + ((size_t)(b * 32 + blockIdx.x)) * CT_;
#pragma unroll
    for (int e = 0; e < 6; ++e) pp[tid + e * 256] = pacc[e];
}

__global__ void k_lhs_reduce(const float* __restrict__ partial, float* __restrict__ lhs_t0) {
    int idx = blockIdx.x * 256 + threadIdx.x;
    if (idx >= B_ * CT_) return;
    int b = idx / CT_, flat = idx % CT_;
    float acc = 0.f;
#pragma unroll
    for (int ch = 0; ch < 32; ++ch) acc += partial[((size_t)(b * 32 + ch)) * CT_ + flat];
    lhs_t0[idx] = acc;
}

__global__ void k_lhs_t(const float* __restrict__ lhs_t0, const float* __restrict__ U2,
                        float* __restrict__ lhs_t) {
    int idx = blockIdx.x * 256 + threadIdx.x;
    if (idx >= B_ * T_ * N_) return;
    int n2 = idx % N_;
    int t = (idx / N_) % T_;
    int b = idx / (T_ * N_);
    const float* l0 = lhs_t0 + (size_t)b * CT_;
    float acc = 0.f;
#pragma unroll
    for (int c = 0; c < C_; ++c) acc += l0[c * T_ + t] * U2[c * N_ + n2];
    lhs_t[idx] = acc;
}

// prod_t partials: ptp[b][ch][i][u] = sum_{n in ch} lhs_t[b,i,n]*rhs_t[b,n,u]
__global__ __launch_bounds__(576) void k_prodt(const float* __restrict__ lhs_t,
        const float* __restrict__ rhs_t, float* __restrict__ ptp) {
    int b = blockIdx.y, ch = blockIdx.x;
    int tid = threadIdx.x;
    __shared__ float lt[24][128];
    __shared__ float rt[128][25];
    int n0 = ch * 128;
    for (int e = tid; e < 24 * 128; e += 576) {
        int i = e >> 7, nn = e & 127;
        lt[i][nn] = lhs_t[((size_t)b * T_ + i) * N_ + n0 + nn];
    }
    const float* rg = rhs_t + ((size_t)b * N_ + n0) * T_;
    for (int e = tid; e < 128 * 24; e += 576) {
        int nn = e / 24, t = e - nn * 24;
        rt[nn][t] = rg[e];
    }
    __syncthreads();
    int i = tid / 24, u = tid - (tid / 24) * 24;
    float acc = 0.f;
#pragma unroll 8
    for (int nn = 0; nn < 128; ++nn) acc += lt[i][nn] * rt[nn][u];
    ptp[(((size_t)b * 8 + ch) * 24 + i) * 24 + u] = acc;
}

__global__ void k_temporal_E(const float* __restrict__ ptp,
                             const float* __restrict__ b_e, const float* __restrict__ V_e,
                             float* __restrict__ E) {
    int b = blockIdx.x;
    int tid = threadIdx.x;                               // 576 threads
    int i = tid / T_, u = tid % T_;
    __shared__ float sig[T_][T_];
    __shared__ float e0s[T_][T_];
    __shared__ float mcol[T_], scol[T_];
    float acc = 0.f;
#pragma unroll
    for (int ch = 0; ch < 8; ++ch)
        acc += ptp[(((size_t)b * 8 + ch) * 24 + i) * 24 + u];
    sig[i][u] = sigmoidf_(acc + b_e[i * T_ + u]);
    __syncthreads();
    int j = u;
    float e0 = 0.f;
#pragma unroll
    for (int kk = 0; kk < T_; ++kk) e0 += sig[i][kk] * V_e[j * T_ + kk];
    e0s[i][j] = e0;
    __syncthreads();
    if (tid < T_) {
        float mx = -1e30f;
        for (int ii = 0; ii < T_; ++ii) mx = fmaxf(mx, e0s[ii][tid]);
        float s = 0.f;
        for (int ii = 0; ii < T_; ++ii) s += __expf(e0s[ii][tid] - mx);
        mcol[tid] = mx; scol[tid] = s;
    }
    __syncthreads();
    E[(size_t)b * T_ * T_ + i * T_ + j] = __expf(e0s[i][j] - mcol[j]) / scol[j];
}

// ---------------- fused: x_TAt (in-register) -> spatial prep + xTt emit ----------------
__global__ __launch_bounds__(256) void k_tspatial(const float* __restrict__ x,
        const float* __restrict__ E, const float* __restrict__ W1g,
        const float* __restrict__ W2, const float* __restrict__ W3g,
        float* __restrict__ lhs_s, float* __restrict__ rhs_s,
        unsigned short* __restrict__ xTt) {
    int b = blockIdx.y;
    int n0 = blockIdx.x * 4;
    int tid = threadIdx.x;
    __shared__ float Es[T_ * T_];
    __shared__ float W1s[T_];
    __shared__ float W2s[C_ * T_];
    __shared__ float xr[4][64][25];                      // staged x, then reused for w3*u
    __shared__ float l0s[4][64];
    for (int e = tid; e < T_ * T_; e += 256) Es[e] = E[(size_t)b * T_ * T_ + e];
    for (int e = tid; e < C_ * T_; e += 256) W2s[e] = W2[e];
    if (tid < T_) W1s[tid] = W1g[tid];
    size_t base = ((size_t)b * N_ + n0) * CT_;
    const float4* x4 = (const float4*)(x + base);
#pragma unroll
    for (int i = 0; i < 6; ++i) {
        int e4 = i * 256 + tid;
        float4 v = x4[e4];
        int e = e4 * 4;
        int nl = e / CT_; int rem = e - nl * CT_; int c = rem / 24; int tl = rem - c * 24;
        xr[nl][c][tl] = v.x; xr[nl][c][tl + 1] = v.y;
        xr[nl][c][tl + 2] = v.z; xr[nl][c][tl + 3] = v.w;
    }
    __syncthreads();
    int nl = tid >> 6, c = tid & 63;
    float xv[T_];
#pragma unroll
    for (int t = 0; t < T_; ++t) xv[t] = xr[nl][c][t];
    // emit xTt[b][t][n][c] bf16 from staged x (coalesced 128B chunks)
#pragma unroll
    for (int i = 0; i < 24; ++i) {
        int idx = i * 256 + tid;
        int cc = idx & 63, nn = (idx >> 6) & 3, t = idx >> 8;
        xTt[((size_t)(b * T_ + t) * N_ + n0 + nn) * 64 + cc] = f2b(xr[nn][cc][t]);
    }
    float w3 = W3g[c];
    float u[T_];
#pragma unroll
    for (int j = 0; j < T_; ++j) {
        float a = 0.f;
#pragma unroll
        for (int t = 0; t < T_; ++t) a += xv[t] * Es[t * T_ + j];
        u[j] = a;
    }
    float l0 = 0.f;
#pragma unroll
    for (int j = 0; j < T_; ++j) l0 += u[j] * W1s[j];
    __syncthreads();                                     // xTt-emit LDS reads done
#pragma unroll
    for (int j = 0; j < T_; ++j) xr[nl][c][j] = w3 * u[j];
    l0s[nl][c] = l0;
    __syncthreads();
    if (tid < 4 * T_) {
        int t = tid % T_, g = tid / T_;
        float racc = 0.f, lacc = 0.f;
        for (int cc = 0; cc < 64; ++cc) {
            racc += xr[g][cc][t];
            lacc += l0s[g][cc] * W2s[cc * T_ + t];
        }
        rhs_s[((size_t)b * T_ + t) * N_ + n0 + g] = racc;
        lhs_s[((size_t)(b * N_ + n0 + g)) * T_ + t] = lacc;
    }
}

// ---------------- converters / builders ----------------
__global__ void k_cvt_vs(const float* __restrict__ v, unsigned short* __restrict__ o) {
    int i = blockIdx.x * 256 + threadIdx.x;
    o[i] = f2b(v[i]);
}

// Wcat[ft][k], k = sel*64+c: sel 0..2 -> tc_w taps, sel 3 -> rc_w.  bf16 [64][256]
__global__ void k_wcat(const float* __restrict__ tc_w, const float* __restrict__ rc_w,
                       unsigned short* __restrict__ Wcat) {
    int i = blockIdx.x * 256 + threadIdx.x;              // over 64*256
    if (i >= F_ * 256) return;
    int ft = i >> 8, k = i & 255;
    int sel = k >> 6, c = k & 63;
    float v = (sel < 3) ? tc_w[(ft * C_ + c) * 3 + sel] : rc_w[ft * C_ + c];
    Wcat[i] = f2b(v);
}

// Thp[k*64+f][c] (bf16) = Theta[k][c][f]   -- A-operand for k_yTmm
__global__ void k_thp(const float* __restrict__ Theta, unsigned short* __restrict__ Thp) {
    int i = blockIdx.x * 256 + threadIdx.x;              // over 192*64
    if (i >= 192 * 64) return;
    int kf = i >> 6, c = i & 63;
    int k = kf >> 6, f = kf & 63;
    Thp[i] = f2b(Theta[((size_t)k * 64 + c) * 64 + f]);
}

// sigA[b][i][k] (bf16) = sigmoid(dot24(lhs_s[b,i,:], rhs_s[b,:,k]) + b_s[i,k])
__global__ __launch_bounds__(256) void k_sig(const float* __restrict__ lhs_s,
        const float* __restrict__ rhs_s, const float* __restrict__ b_s,
        unsigned short* __restrict__ sigA) {
    int b = blockIdx.z, i0 = blockIdx.y * 64, k0 = blockIdx.x * 256;
    int tid = threadIdx.x;
    __shared__ float lh[64 * T_];
    __shared__ float rh[T_][256];
    for (int e = tid; e < 64 * T_; e += 256) lh[e] = lhs_s[((size_t)b * N_ + i0) * T_ + e];
#pragma unroll
    for (int t = 0; t < T_; ++t) rh[t][tid] = rhs_s[((size_t)b * T_ + t) * N_ + k0 + tid];
    __syncthreads();
    int kg = k0 + tid;
    for (int ii = 0; ii < 64; ++ii) {
        float acc = b_s[(size_t)(i0 + ii) * N_ + kg];
#pragma unroll
        for (int t = 0; t < T_; ++t) acc += lh[ii * T_ + t] * rh[t][tid];
        sigA[((size_t)b * N_ + i0 + ii) * N_ + kg] = f2b(sigmoidf_(acc));
    }
}

// ---------------- yT via MFMA, coalesced stores through LDS C-tile ----------------
__global__ __launch_bounds__(256) void k_yTmm(const unsigned short* __restrict__ xTt,
        const unsigned short* __restrict__ Thp, unsigned short* __restrict__ yT) {
    int bt = blockIdx.y;
    int b = bt / T_, t = bt - b * T_;
    int m0 = blockIdx.x * 128;
    int tid = threadIdx.x;
    int lane = tid & 63, wv = tid >> 6;
    __shared__ __align__(16) char smem[50688];
    unsigned short* Asb = (unsigned short*)smem;             // [192*64] (live whole kernel)
    unsigned short* Bsb = (unsigned short*)(smem + 24576);   // [128*64]
    unsigned short* Cl  = (unsigned short*)(smem + 24576);   // [96][136] (after Bsb dead)
#pragma unroll
    for (int e = 0; e < 6; ++e) {                        // stage Thp (24KB)
        int chunk = e * 256 + tid;
        int row = chunk >> 3, slot = chunk & 7;
        int gslot = slot ^ (row & 7);
        gload_lds16(Thp + row * 64 + gslot * 8, &Asb[chunk * 8]);
    }
    const unsigned short* Bg = xTt + ((size_t)bt * N_ + m0) * 64;
#pragma unroll
    for (int e = 0; e < 4; ++e) {                        // stage B (16KB)
        int chunk = e * 256 + tid;
        int row = chunk >> 3, slot = chunk & 7;
        int gslot = slot ^ (row & 7);
        gload_lds16(Bg + (size_t)row * 64 + gslot * 8, &Bsb[chunk * 8]);
    }
    __syncthreads();                                     // drains vmcnt

    short8 bf[2][2];
#pragma unroll
    for (int ni = 0; ni < 2; ++ni)
#pragma unroll
        for (int kk = 0; kk < 2; ++kk) {
            int r = wv * 32 + ni * 16 + (lane & 15);
            int slot = (kk * 4 + (lane >> 4)) ^ (r & 7);
            bf[ni][kk] = *(const short8*)&Bsb[r * 64 + slot * 8];
        }
    f32x4 acc[12][2];
#pragma unroll
    for (int mi = 0; mi < 12; ++mi)
#pragma unroll
        for (int ni = 0; ni < 2; ++ni) acc[mi][ni] = (f32x4){0.f, 0.f, 0.f, 0.f};
#pragma unroll
    for (int mi = 0; mi < 12; ++mi) {
        short8 af[2];
#pragma unroll
        for (int kk = 0; kk < 2; ++kk) {
            int r = mi * 16 + (lane & 15);
            int slot = (kk * 4 + (lane >> 4)) ^ (r & 7);
            af[kk] = *(const short8*)&Asb[r * 64 + slot * 8];
        }
#pragma unroll
        for (int kk = 0; kk < 2; ++kk)
#pragma unroll
            for (int ni = 0; ni < 2; ++ni)
                acc[mi][ni] = __builtin_amdgcn_mfma_f32_16x16x32_bf16(
                    af[kk], bf[ni][kk], acc[mi][ni], 0, 0, 0);
    }
#pragma unroll
    for (int h = 0; h < 2; ++h) {
        __syncthreads();
#pragma unroll
        for (int mi2 = 0; mi2 < 6; ++mi2) {
            int mi = h * 6 + mi2;
#pragma unroll
            for (int r = 0; r < 4; ++r) {
                int row = mi2 * 16 + (lane >> 4) * 4 + r;
#pragma unroll
                for (int ni = 0; ni < 2; ++ni)
                    Cl[row * 136 + wv * 32 + ni * 16 + (lane & 15)] = f2b(acc[mi][ni][r]);
            }
        }
        __syncthreads();
#pragma unroll
        for (int e = 0; e < 6; ++e) {
            int idx = e * 256 + tid;
            int row = idx >> 4, seg = idx & 15;
            int kf = h * 96 + row;
            int k = kf >> 6, f = kf & 63;
            uint4 v = *(const uint4*)&Cl[row * 136 + seg * 8];
            *(uint4*)&yT[((size_t)b * CT_ + f * T_ + t) * KS_ + k * N_ + m0 + seg * 8] = v;
        }
    }
}

// online softmax stats over axis m of S[b,m,i] (bf16): mst[b*N+i] = (max, 1/sum)
__global__ void k_smstats(const unsigned short* __restrict__ S, float2* __restrict__ mst) {
    int b = blockIdx.y;
    int jj = threadIdx.x % 64;
    int ig = threadIdx.x / 64;
    int j = blockIdx.x * 64 + jj;
    __shared__ float rm[4][64], rs[4][64];
    float m = -1e30f, s = 0.f;
    for (int i = ig; i < N_; i += 4) {
        float v = b2f(S[((size_t)b * N_ + i) * N_ + j]);
        float mn = fmaxf(m, v);
        s = s * __expf(m - mn) + __expf(v - mn);
        m = mn;
    }
    rm[ig][jj] = m; rs[ig][jj] = s;
    __syncthreads();
    if (ig == 0) {
        float M = rm[0][jj], SS = rs[0][jj];
#pragma unroll
        for (int g = 1; g < 4; ++g) {
            float mg = rm[g][jj];
            float mn = fmaxf(M, mg);
            SS = SS * __expf(M - mn) + rs[g][jj] * __expf(mg - mn);
            M = mn;
        }
        mst[(size_t)b * N_ + j] = make_float2(M, 1.f / SS);
    }
}

// chebSt[b][i][k*1024+m] (bf16) = cheb[k][m][i] * softmax(S)[b][m][i]  (bf16 S reads)
__global__ __launch_bounds__(256) void k_chebSt(const float* __restrict__ cheb,
        const unsigned short* __restrict__ S, const float2* __restrict__ mst,
        unsigned short* __restrict__ cs) {
    int b = blockIdx.z, i0 = blockIdx.y * 64, m0 = blockIdx.x * 64;
    int tid = threadIdx.x;
    __shared__ float st[64][65];
    __shared__ float cb[64][65];
    __shared__ float2 sst[64];
    if (tid < 64) sst[tid] = mst[(size_t)b * N_ + i0 + tid];
#pragma unroll
    for (int e = 0; e < 4; ++e) {
        int idx4 = e * 256 + tid;
        int mm = idx4 >> 4, ii0 = (idx4 & 15) * 4;
        ushort4_ v = *(const ushort4_*)&S[((size_t)b * N_ + m0 + mm) * N_ + i0 + ii0];
        st[mm][ii0] = b2f(v.x); st[mm][ii0 + 1] = b2f(v.y);
        st[mm][ii0 + 2] = b2f(v.z); st[mm][ii0 + 3] = b2f(v.w);
    }
    for (int k = 0; k < 3; ++k) {
        __syncthreads();
#pragma unroll
        for (int e = 0; e < 4; ++e) {
            int idx4 = e * 256 + tid;
            int mm = idx4 >> 4, ii0 = (idx4 & 15) * 4;
            float4 v = *(const float4*)&cheb[((size_t)k * N_ + m0 + mm) * N_ + i0 + ii0];
            cb[mm][ii0] = v.x; cb[mm][ii0 + 1] = v.y; cb[mm][ii0 + 2] = v.z; cb[mm][ii0 + 3] = v.w;
        }
        __syncthreads();
#pragma unroll
        for (int e = 0; e < 16; ++e) {
            int idx = e * 256 + tid; int mm = idx & 63, ii = idx >> 6;
            float sm = __expf(st[mm][ii] - sst[ii].x) * sst[ii].y;
            cs[((size_t)b * N_ + i0 + ii) * KS_ + k * N_ + m0 + mm] =
                f2b(sm * cb[mm][ii]);
        }
    }
}

// ---------------- 256x256-tile MFMA GEMM, hybrid counted-vmcnt pipeline ----------------
// obf: 0 -> f32 C, 1 -> bf16 C (ldc in elements either way)
__global__ __launch_bounds__(512, 2) void k_gemm256(
        const unsigned short* __restrict__ A, long lda, long sA,
        const unsigned short* __restrict__ Bt, long ldb, long sB,
        void* __restrict__ Cc, long ldc, long sC, int K, int nbx, int nby, int obf) {
    __shared__ __align__(16) unsigned short As[2][256 * 64];   // 2 x 32KB
    __shared__ __align__(16) unsigned short Bs[2][256 * 64];   // 2 x 32KB
    int tid = threadIdx.x;
    int lane = tid & 63, w = tid >> 6;
    int wy = w >> 2, wx = w & 3;                            // 2 x 4 waves -> 128x64 per wave

    int nwg = gridDim.x;
    int cpx = nwg >> 3;
    int logical = (blockIdx.x & 7) * cpx + (blockIdx.x >> 3);
    int tpb = nbx * nby;
    int b = logical / tpb;
    int tile = logical % tpb;
    int i0 = (tile / nbx) * 256;
    int j0 = (tile % nbx) * 256;

    const unsigned short* Ab = A + (size_t)b * sA + (size_t)i0 * lda;
    const unsigned short* Bb = Bt + (size_t)b * sB + (size_t)j0 * ldb;

    auto STAGE = [&](int kt, int d) {
        int kof = kt << 6;
#pragma unroll
        for (int e = 0; e < 4; ++e) {
            int chunk = e * 512 + tid;
            int row = chunk >> 3, slot = chunk & 7;
            int gslot = slot ^ (row & 7);                   // inverse swizzle on source
            gload_lds16(Ab + (size_t)row * lda + kof + gslot * 8, &As[d][chunk * 8]);
        }
#pragma unroll
        for (int e = 0; e < 4; ++e) {
            int chunk = e * 512 + tid;
            int row = chunk >> 3, slot = chunk & 7;
            int gslot = slot ^ (row & 7);
            gload_lds16(Bb + (size_t)row * ldb + kof + gslot * 8, &Bs[d][chunk * 8]);
        }
    };
    auto READF = [&](short8* af, short8* bfv,
                     const unsigned short* Asb, const unsigned short* Bsb, int kkb) {
#pragma unroll
        for (int mi = 0; mi < 8; ++mi) {
            int r = wy * 128 + mi * 16 + (lane & 15);
            int slot = (kkb + (lane >> 4)) ^ (r & 7);
            af[mi] = *(const short8*)&Asb[r * 64 + slot * 8];
        }
#pragma unroll
        for (int ni = 0; ni < 4; ++ni) {
            int r = wx * 64 + ni * 16 + (lane & 15);
            int slot = (kkb + (lane >> 4)) ^ (r & 7);
            bfv[ni] = *(const short8*)&Bsb[r * 64 + slot * 8];
        }
    };

    f32x4 acc[8][4];
#pragma unroll
    for (int mi = 0; mi < 8; ++mi)
#pragma unroll
        for (int ni = 0; ni < 4; ++ni) acc[mi][ni] = (f32x4){0.f, 0.f, 0.f, 0.f};

    int nt = K >> 6;
    STAGE(0, 0);
    STAGE(1, 1);
    asm volatile("s_waitcnt vmcnt(8)" ::: "memory");        // K-tile 0 resident
    __builtin_amdgcn_s_barrier();
    __builtin_amdgcn_sched_barrier(0);

    short8 a0[8], b0[4], a1[8], b1[4];
    READF(a0, b0, As[0], Bs[0], 0);                         // kk0 of tile 0

    for (int kt = 0; kt < nt; ++kt) {
        int cur = kt & 1;
        READF(a1, b1, As[cur], Bs[cur], 4);                 // kk1 of this tile
        __builtin_amdgcn_s_setprio(1);
#pragma unroll
        for (int mi = 0; mi < 8; ++mi)
#pragma unroll
            for (int ni = 0; ni < 4; ++ni)
                acc[mi][ni] = __builtin_amdgcn_mfma_f32_16x16x32_bf16(
                    a0[mi], b0[ni], acc[mi][ni], 0, 0, 0);
        __builtin_amdgcn_s_setprio(0);
        asm volatile("s_waitcnt lgkmcnt(0)" ::: "memory");  // my reads of buf[cur] done
        __builtin_amdgcn_sched_barrier(0);
        __builtin_amdgcn_s_barrier();                       // all waves done with buf[cur]
        __builtin_amdgcn_sched_barrier(0);
        if (kt + 2 < nt) STAGE(kt + 2, cur);                // overwrite freed buffer
        __builtin_amdgcn_sched_barrier(0);
        __builtin_amdgcn_s_setprio(1);
#pragma unroll
        for (int mi = 0; mi < 8; ++mi)
#pragma unroll
            for (int ni = 0; ni < 4; ++ni)
                acc[mi][ni] = __builtin_amdgcn_mfma_f32_16x16x32_bf16(
                    a1[mi], b1[ni], acc[mi][ni], 0, 0, 0);
        __builtin_amdgcn_s_setprio(0);
        if (kt + 2 < nt) {
            asm volatile("s_waitcnt vmcnt(8)" ::: "memory"); // kt+1 retired, kt+2 in flight
        } else {
            asm volatile("s_waitcnt vmcnt(0)" ::: "memory"); // tail: drain (race-safe)
        }
        __builtin_amdgcn_s_barrier();                       // buf[cur^1] ready for all waves
        __builtin_amdgcn_sched_barrier(0);
        if (kt + 1 < nt)
            READF(a0, b0, As[cur ^ 1], Bs[cur ^ 1], 0);     // kk0 of next tile
    }

    if (obf) {
        unsigned short* Cb = (unsigned short*)Cc + (size_t)b * sC;
#pragma unroll
        for (int mi = 0; mi < 8; ++mi) {
#pragma unroll
            for (int r = 0; r < 4; ++r) {
                int i = i0 + wy * 128 + mi * 16 + (lane >> 4) * 4 + r;
                unsigned short* cp = Cb + (size_t)i * ldc + j0 + wx * 64 + (lane & 15);
#pragma unroll
                for (int ni = 0; ni < 4; ++ni) cp[ni * 16] = f2b(acc[mi][ni][r]);
            }
        }
    } else {
        float* Cb = (float*)Cc + (size_t)b * sC;
#pragma unroll
        for (int mi = 0; mi < 8; ++mi) {
#pragma unroll
            for (int r = 0; r < 4; ++r) {
                int i = i0 + wy * 128 + mi * 16 + (lane >> 4) * 4 + r;
                float* cp = Cb + (size_t)i * ldc + j0 + wx * 64 + (lane & 15);
#pragma unroll
                for (int ni = 0; ni < 4; ++ni) cp[ni * 16] = acc[mi][ni][r];
            }
        }
    }
}

// ---------------- fused epilogue via MFMA (float4 I/O) ----------------
__global__ __launch_bounds__(256) void k_final(const float* __restrict__ x,
        const float* __restrict__ sgin, const unsigned short* __restrict__ Wcat,
        const float* __restrict__ tc_b, const float* __restrict__ rc_b,
        const float* __restrict__ ln_g, const float* __restrict__ ln_b,
        float* __restrict__ out) {
    int b = blockIdx.y;
    int n0 = blockIdx.x * 4;
    int tid = threadIdx.x;
    int lane = tid & 63, wv = tid >> 6;

    __shared__ __align__(16) char smem[25600];
    unsigned short* sgb = (unsigned short*)smem;            // [4][26][64]
    unsigned short* xb  = (unsigned short*)(smem + 13312);  // [4][24][64]
    float* Cl = (float*)smem;                               // [96][66] (after reuse barrier)
    __shared__ float tbs[64], gs[64], bbs[64];
    __shared__ float mus[96], rss[96];

    if (tid < 64) {
        tbs[tid] = tc_b[tid] + rc_b[tid];
        gs[tid] = ln_g[tid];
        bbs[tid] = ln_b[tid];
    }
    for (int e = tid; e < 512; e += 256) {
        int nl = e >> 7, r = (e >> 6) & 1, c = e & 63;
        int tt = r ? 25 : 0;
        sgb[(nl * 26 + tt) * 64 + (((c >> 3) ^ (tt & 7)) << 3) + (c & 7)] = 0;
    }
    size_t base = ((size_t)b * N_ + n0) * CT_;
    const float4* sg4 = (const float4*)(sgin + base);
    const float4* xg4 = (const float4*)(x + base);
#pragma unroll
    for (int i = 0; i < 6; ++i) {
        int e4 = i * 256 + tid;
        float4 sv4 = sg4[e4];
        float4 xv4 = xg4[e4];
        int e = e4 * 4;
        int nl = e / CT_;
        int rem = e - nl * CT_;
        int c = rem / 24;
        int tl = rem - c * 24;
        float sv[4] = {sv4.x, sv4.y, sv4.z, sv4.w};
        float xv[4] = {xv4.x, xv4.y, xv4.z, xv4.w};
#pragma unroll
        for (int j = 0; j < 4; ++j) {
            int tt = tl + j + 1;
            sgb[(nl * 26 + tt) * 64 + (((c >> 3) ^ (tt & 7)) << 3) + (c & 7)] =
                f2b(fmaxf(sv[j], 0.f));
            int tj = tl + j;
            xb[(nl * 24 + tj) * 64 + (((c >> 3) ^ (tj & 7)) << 3) + (c & 7)] = f2b(xv[j]);
        }
    }

    int ft = wv * 16 + (lane & 15);
    int g4 = lane >> 4;
    short8 bfr[8];
#pragma unroll
    for (int ks = 0; ks < 8; ++ks)
        bfr[ks] = *(const short8*)&Wcat[ft * 256 + ks * 32 + g4 * 8];

    int rnl[6], rt[6];
#pragma unroll
    for (int mi = 0; mi < 6; ++mi) {
        int row = mi * 16 + (lane & 15);
        rnl[mi] = row / 24;
        rt[mi] = row - rnl[mi] * 24;
    }

    __syncthreads();

    f32x4 acc[6];
#pragma unroll
    for (int mi = 0; mi < 6; ++mi) acc[mi] = (f32x4){0.f, 0.f, 0.f, 0.f};
#pragma unroll
    for (int mi = 0; mi < 6; ++mi) {
        int nl = rnl[mi], t = rt[mi];
#pragma unroll
        for (int ks = 0; ks < 8; ++ks) {
            const int sel = ks >> 1;
            int slot = (ks & 1) * 4 + g4;
            short8 af;
            if (sel < 3) {
                int tt = t + sel;
                af = *(const short8*)&sgb[(nl * 26 + tt) * 64 + ((slot ^ (tt & 7)) << 3)];
            } else {
                af = *(const short8*)&xb[(nl * 24 + t) * 64 + ((slot ^ (t & 7)) << 3)];
            }
            acc[mi] = __builtin_amdgcn_mfma_f32_16x16x32_bf16(af, bfr[ks], acc[mi], 0, 0, 0);
        }
    }

    __syncthreads();
#pragma unroll
    for (int mi = 0; mi < 6; ++mi)
#pragma unroll
        for (int r = 0; r < 4; ++r)
            Cl[(mi * 16 + (lane >> 4) * 4 + r) * 66 + wv * 16 + (lane & 15)] = acc[mi][r];
    __syncthreads();

    if (tid < 96) {
        float s = 0.f, s2 = 0.f;
#pragma unroll
        for (int f = 0; f < 64; ++f) {
            float v = fmaxf(Cl[tid * 66 + f] + tbs[f], 0.f);
            s += v; s2 += v * v;
        }
        float mu = s * (1.f / 64.f);
        float var = s2 * (1.f / 64.f) - mu * mu;
        mus[tid] = mu;
        rss[tid] = rsqrtf(var + 1e-5f);
    }
    __syncthreads();

    float4* o4 = (float4*)(out + base);
#pragma unroll
    for (int i = 0; i < 6; ++i) {
        int e4 = i * 256 + tid;
        int e = e4 * 4;
        int nl = e / CT_;
        int rem = e - nl * CT_;
        int f = rem / 24;
        int t0v = rem - f * 24;
        float g = gs[f], bb2 = bbs[f], tb2 = tbs[f];
        float vals[4];
#pragma unroll
        for (int j = 0; j < 4; ++j) {
            int row = nl * 24 + t0v + j;
            float v = fmaxf(Cl[row * 66 + f] + tb2, 0.f);
            vals[j] = (v - mus[row]) * rss[row] * g + bb2;
        }
        float4 r;
        r.x = vals[0]; r.y = vals[1]; r.z = vals[2]; r.w = vals[3];
        o4[e4] = r;
    }
}

extern "C" void kernel_launch(void* const* d_in, const int* in_sizes, int n_in,
                              void* d_out, int out_size, void* d_ws, size_t ws_size,
                              hipStream_t stream) {
    const float* x    = (const float*)d_in[0];
    const float* cheb = (const float*)d_in[1];
    const float* U1   = (const float*)d_in[2];
    const float* U2   = (const float*)d_in[3];
    const float* U3   = (const float*)d_in[4];
    const float* b_e  = (const float*)d_in[5];
    const float* V_e  = (const float*)d_in[6];
    const float* W1   = (const float*)d_in[7];
    const float* W2   = (const float*)d_in[8];
    const float* W3   = (const float*)d_in[9];
    const float* b_s  = (const float*)d_in[10];
    const float* V_s  = (const float*)d_in[11];
    const float* Theta= (const float*)d_in[12];
    const float* tc_w = (const float*)d_in[13];
    const float* tc_b = (const float*)d_in[14];
    const float* rc_w = (const float*)d_in[15];
    const float* rc_b = (const float*)d_in[16];
    const float* ln_g = (const float*)d_in[17];
    const float* ln_b = (const float*)d_in[18];
    float* out = (float*)d_out;

    char* base = (char*)d_ws;
    size_t o = 0;
    auto alloc = [&](size_t bytes) { size_t r = o; o += (bytes + 255) & ~(size_t)255; return r; };
    float* lhs_t   = (float*)(base + alloc((size_t)B_ * T_ * N_ * 4));
    float* rhs_t   = (float*)(base + alloc((size_t)B_ * N_ * T_ * 4));
    float* Ebuf    = (float*)(base + alloc((size_t)B_ * T_ * T_ * 4));
    float* partial = (float*)(base + alloc((size_t)B_ * 32 * CT_ * 4));
    float* ptp     = (float*)(base + alloc((size_t)B_ * 8 * T_ * T_ * 4));
    float* lhs_t0  = (float*)(base + alloc((size_t)B_ * CT_ * 4));
    float* lhs_s   = (float*)(base + alloc((size_t)B_ * N_ * T_ * 4));
    float* rhs_s   = (float*)(base + alloc((size_t)B_ * T_ * N_ * 4));
    unsigned short* V_sb = (unsigned short*)(base + alloc((size_t)N_ * N_ * 2));
    unsigned short* Wcat = (unsigned short*)(base + alloc((size_t)F_ * 256 * 2));
    unsigned short* Thp  = (unsigned short*)(base + alloc((size_t)192 * 64 * 2));
    float2* mstats = (float2*)(base + alloc((size_t)B_ * N_ * 8));
    size_t regA = alloc((size_t)B_ * N_ * KS_ * 2);   // xTt (bf16) -> chebSt (bf16)
    size_t regB = alloc((size_t)B_ * CT_ * KS_ * 2);  // sigA (bf16) -> yT (bf16)
    unsigned short* xTt    = (unsigned short*)(base + regA);
    unsigned short* chebSt = (unsigned short*)(base + regA);
    unsigned short* sigA   = (unsigned short*)(base + regB);
    unsigned short* yT     = (unsigned short*)(base + regB);
    unsigned short* Sb = (unsigned short*)out;   // bf16 S scores in d_out (dead before gcn write)
    float* gcn = out;

    dim3 b256(256);
    k_cvt_vs<<<dim3(N_ * N_ / 256), b256, 0, stream>>>(V_s, V_sb);
    k_wcat<<<dim3((F_ * 256 + 255) / 256), b256, 0, stream>>>(tc_w, rc_w, Wcat);
    k_thp<<<dim3((192 * 64 + 255) / 256), b256, 0, stream>>>(Theta, Thp);
    k_xreduce<<<dim3(N_ / 32, B_), b256, 0, stream>>>(x, U1, U3, rhs_t, partial);
    k_lhs_reduce<<<dim3((B_ * CT_ + 255) / 256), b256, 0, stream>>>(partial, lhs_t0);
    k_lhs_t<<<dim3((B_ * T_ * N_) / 256), b256, 0, stream>>>(lhs_t0, U2, lhs_t);
    k_prodt<<<dim3(8, B_), dim3(576), 0, stream>>>(lhs_t, rhs_t, ptp);
    k_temporal_E<<<dim3(B_), dim3(576), 0, stream>>>(ptp, b_e, V_e, Ebuf);
    k_tspatial<<<dim3(N_ / 4, B_), b256, 0, stream>>>(x, Ebuf, W1, W2, W3,
                                                      lhs_s, rhs_s, xTt);
    k_sig<<<dim3(N_ / 256, N_ / 64, B_), b256, 0, stream>>>(lhs_s, rhs_s, b_s, sigA);
    // S0 GEMM: M=1024, Ncols=1024, K=1024; bf16 C; nwg=512 (%8==0)
    k_gemm256<<<dim3(B_ * 4 * 4), dim3(512), 0, stream>>>(
        sigA, N_, (long)N_ * N_, V_sb, N_, 0, Sb, N_, (long)N_ * N_, N_, 4, 4, 1);
    k_smstats<<<dim3(N_ / 64, B_), b256, 0, stream>>>(Sb, mstats);
    k_yTmm<<<dim3(N_ / 128, B_ * T_), b256, 0, stream>>>(xTt, Thp, yT);        // sigA dead
    k_chebSt<<<dim3(N_ / 64, N_ / 64, B_), b256, 0, stream>>>(cheb, Sb, mstats, chebSt); // xTt dead
    // stacked GEMM: M=1024, Ncols=1536, K=3072; f32 C; nwg=768 (%8==0)
    k_gemm256<<<dim3(B_ * 4 * 6), dim3(512), 0, stream>>>(
        chebSt, KS_, (long)N_ * KS_, yT, KS_, (long)CT_ * KS_,
        gcn, CT_, (long)N_ * CT_, KS_, 6, 4, 0);                              // Sb dead
    k_final<<<dim3(N_ / 4, B_), b256, 0, stream>>>(x, gcn, Wcat, tc_b, rc_b,
                                                   ln_g, ln_b, out);
}

// Round 14
// 992.738 us; speedup vs baseline: 13.5391x; 1.0703x over previous
//
#include <hip/hip_runtime.h>

typedef __attribute__((ext_vector_type(8))) short short8;   // 8 bf16 (4 VGPRs)
typedef __attribute__((ext_vector_type(4))) float f32x4;
typedef __attribute__((ext_vector_type(4))) unsigned short ushort4_;

constexpr int B_ = 32;
constexpr int N_ = 1024;
constexpr int C_ = 64;
constexpr int T_ = 24;
constexpr int F_ = 64;
constexpr int CT_ = C_ * T_;     // 1536
constexpr int KS_ = 3072;        // stacked K = 3*1024

__device__ __forceinline__ float sigmoidf_(float x) {
    return 1.0f / (1.0f + __expf(-x));
}
__device__ __forceinline__ unsigned short f2b(float f) {   // RNE f32->bf16
    union { float f; unsigned u; } v; v.f = f;
    unsigned r = v.u + 0x7FFFu + ((v.u >> 16) & 1u);
    return (unsigned short)(r >> 16);
}
__device__ __forceinline__ float b2f(unsigned short h) {
    union { unsigned u; float f; } v; v.u = ((unsigned)h) << 16; return v.f;
}
__device__ __forceinline__ void gload_lds16(const unsigned short* g, unsigned short* l) {
    __builtin_amdgcn_global_load_lds(
        (const __attribute__((address_space(1))) unsigned int*)g,
        (__attribute__((address_space(3))) unsigned int*)l, 16, 0, 0);
}

// ---------------- fused x reductions: rhs_t + U1-partial (one x read) ----------------
__global__ __launch_bounds__(256) void k_xreduce(const float* __restrict__ x,
        const float* __restrict__ U1, const float* __restrict__ U3,
        float* __restrict__ rhs_t, float* __restrict__ partial) {
    int b = blockIdx.y, g0 = blockIdx.x * 32;
    int tid = threadIdx.x;
    __shared__ float xr[8 * CT_];                        // 48 KB
    __shared__ float u3s[C_];
    if (tid < C_) u3s[tid] = U3[tid];
    float pacc[6] = {0, 0, 0, 0, 0, 0};
    for (int ph = 0; ph < 4; ++ph) {
        int n0 = g0 + ph * 8;
        __syncthreads();                                 // prev phase LDS reads done
        const float4* x4 = (const float4*)(x + ((size_t)(b * N_ + n0)) * CT_);
#pragma unroll
        for (int e = 0; e < 12; ++e) {
            int i4 = e * 256 + tid;
            float4 v = x4[i4];
            int i = i4 * 4;
            xr[i] = v.x; xr[i + 1] = v.y; xr[i + 2] = v.z; xr[i + 3] = v.w;
        }
        __syncthreads();
        if (tid < 192) {
            int n = tid / 24, t = tid % 24;
            const float* xn = xr + n * CT_ + t;
            float acc = 0.f;
#pragma unroll
            for (int c = 0; c < C_; ++c) acc += u3s[c] * xn[c * 24];
            rhs_t[((size_t)(b * N_ + n0 + n)) * T_ + t] = acc;
        }
#pragma unroll
        for (int n = 0; n < 8; ++n) {
            float u = U1[n0 + n];                        // uniform -> scalar
            const float* xn = xr + n * CT_;
#pragma unroll
            for (int e = 0; e < 6; ++e) pacc[e] += u * xn[tid + e * 256];
        }
    }
    float* pp = partial + ((size_t)(b * 32 + blockIdx.x)) * CT_;
#pragma unroll
    for (int e = 0; e < 6; ++e) pp[tid + e * 256] = pacc[e];
}

__global__ void k_lhs_reduce(const float* __restrict__ partial, float* __restrict__ lhs_t0) {
    int idx = blockIdx.x * 256 + threadIdx.x;
    if (idx >= B_ * CT_) return;
    int b = idx / CT_, flat = idx % CT_;
    float acc = 0.f;
#pragma unroll
    for (int ch = 0; ch < 32; ++ch) acc += partial[((size_t)(b * 32 + ch)) * CT_ + flat];
    lhs_t0[idx] = acc;
}

__global__ void k_lhs_t(const float* __restrict__ lhs_t0, const float* __restrict__ U2,
                        float* __restrict__ lhs_t) {
    int idx = blockIdx.x * 256 + threadIdx.x;
    if (idx >= B_ * T_ * N_) return;
    int n2 = idx % N_;
    int t = (idx / N_) % T_;
    int b = idx / (T_ * N_);
    const float* l0 = lhs_t0 + (size_t)b * CT_;
    float acc = 0.f;
#pragma unroll
    for (int c = 0; c < C_; ++c) acc += l0[c * T_ + t] * U2[c * N_ + n2];
    lhs_t[idx] = acc;
}

// prod_t partials: ptp[b][ch][i][u] = sum_{n in ch} lhs_t[b,i,n]*rhs_t[b,n,u]
__global__ __launch_bounds__(576) void k_prodt(const float* __restrict__ lhs_t,
        const float* __restrict__ rhs_t, float* __restrict__ ptp) {
    int b = blockIdx.y, ch = blockIdx.x;
    int tid = threadIdx.x;
    __shared__ float lt[24][128];
    __shared__ float rt[128][25];
    int n0 = ch * 128;
    for (int e = tid; e < 24 * 128; e += 576) {
        int i = e >> 7, nn = e & 127;
        lt[i][nn] = lhs_t[((size_t)b * T_ + i) * N_ + n0 + nn];
    }
    const float* rg = rhs_t + ((size_t)b * N_ + n0) * T_;
    for (int e = tid; e < 128 * 24; e += 576) {
        int nn = e / 24, t = e - nn * 24;
        rt[nn][t] = rg[e];
    }
    __syncthreads();
    int i = tid / 24, u = tid - (tid / 24) * 24;
    float acc = 0.f;
#pragma unroll 8
    for (int nn = 0; nn < 128; ++nn) acc += lt[i][nn] * rt[nn][u];
    ptp[(((size_t)b * 8 + ch) * 24 + i) * 24 + u] = acc;
}

__global__ void k_temporal_E(const float* __restrict__ ptp,
                             const float* __restrict__ b_e, const float* __restrict__ V_e,
                             float* __restrict__ E) {
    int b = blockIdx.x;
    int tid = threadIdx.x;                               // 576 threads
    int i = tid / T_, u = tid % T_;
    __shared__ float sig[T_][T_];
    __shared__ float e0s[T_][T_];
    __shared__ float mcol[T_], scol[T_];
    float acc = 0.f;
#pragma unroll
    for (int ch = 0; ch < 8; ++ch)
        acc += ptp[(((size_t)b * 8 + ch) * 24 + i) * 24 + u];
    sig[i][u] = sigmoidf_(acc + b_e[i * T_ + u]);
    __syncthreads();
    int j = u;
    float e0 = 0.f;
#pragma unroll
    for (int kk = 0; kk < T_; ++kk) e0 += sig[i][kk] * V_e[j * T_ + kk];
    e0s[i][j] = e0;
    __syncthreads();
    if (tid < T_) {
        float mx = -1e30f;
        for (int ii = 0; ii < T_; ++ii) mx = fmaxf(mx, e0s[ii][tid]);
        float s = 0.f;
        for (int ii = 0; ii < T_; ++ii) s += __expf(e0s[ii][tid] - mx);
        mcol[tid] = mx; scol[tid] = s;
    }
    __syncthreads();
    E[(size_t)b * T_ * T_ + i * T_ + j] = __expf(e0s[i][j] - mcol[j]) / scol[j];
}

// ---------------- fused: x_TAt (in-register) -> spatial prep + xTt emit ----------------
__global__ __launch_bounds__(256) void k_tspatial(const float* __restrict__ x,
        const float* __restrict__ E, const float* __restrict__ W1g,
        const float* __restrict__ W2, const float* __restrict__ W3g,
        float* __restrict__ lhs_s, float* __restrict__ rhs_s,
        unsigned short* __restrict__ xTt) {
    int b = blockIdx.y;
    int n0 = blockIdx.x * 4;
    int tid = threadIdx.x;
    __shared__ float Es[T_ * T_];
    __shared__ float W1s[T_];
    __shared__ float W2s[C_ * T_];
    __shared__ float xr[4][64][25];                      // staged x, then reused for w3*u
    __shared__ float l0s[4][64];
    for (int e = tid; e < T_ * T_; e += 256) Es[e] = E[(size_t)b * T_ * T_ + e];
    for (int e = tid; e < C_ * T_; e += 256) W2s[e] = W2[e];
    if (tid < T_) W1s[tid] = W1g[tid];
    size_t base = ((size_t)b * N_ + n0) * CT_;
    const float4* x4 = (const float4*)(x + base);
#pragma unroll
    for (int i = 0; i < 6; ++i) {
        int e4 = i * 256 + tid;
        float4 v = x4[e4];
        int e = e4 * 4;
        int nl = e / CT_; int rem = e - nl * CT_; int c = rem / 24; int tl = rem - c * 24;
        xr[nl][c][tl] = v.x; xr[nl][c][tl + 1] = v.y;
        xr[nl][c][tl + 2] = v.z; xr[nl][c][tl + 3] = v.w;
    }
    __syncthreads();
    int nl = tid >> 6, c = tid & 63;
    float xv[T_];
#pragma unroll
    for (int t = 0; t < T_; ++t) xv[t] = xr[nl][c][t];
    // emit xTt[b][t][n][c] bf16 from staged x (coalesced 128B chunks)
#pragma unroll
    for (int i = 0; i < 24; ++i) {
        int idx = i * 256 + tid;
        int cc = idx & 63, nn = (idx >> 6) & 3, t = idx >> 8;
        xTt[((size_t)(b * T_ + t) * N_ + n0 + nn) * 64 + cc] = f2b(xr[nn][cc][t]);
    }
    float w3 = W3g[c];
    float u[T_];
#pragma unroll
    for (int j = 0; j < T_; ++j) {
        float a = 0.f;
#pragma unroll
        for (int t = 0; t < T_; ++t) a += xv[t] * Es[t * T_ + j];
        u[j] = a;
    }
    float l0 = 0.f;
#pragma unroll
    for (int j = 0; j < T_; ++j) l0 += u[j] * W1s[j];
    __syncthreads();                                     // xTt-emit LDS reads done
#pragma unroll
    for (int j = 0; j < T_; ++j) xr[nl][c][j] = w3 * u[j];
    l0s[nl][c] = l0;
    __syncthreads();
    if (tid < 4 * T_) {
        int t = tid % T_, g = tid / T_;
        float racc = 0.f, lacc = 0.f;
        for (int cc = 0; cc < 64; ++cc) {
            racc += xr[g][cc][t];
            lacc += l0s[g][cc] * W2s[cc * T_ + t];
        }
        rhs_s[((size_t)b * T_ + t) * N_ + n0 + g] = racc;
        lhs_s[((size_t)(b * N_ + n0 + g)) * T_ + t] = lacc;
    }
}

// ---------------- converters / builders ----------------
__global__ void k_cvt_bf(const float* __restrict__ v, unsigned short* __restrict__ o) {
    int i = blockIdx.x * 256 + threadIdx.x;
    o[i] = f2b(v[i]);
}

// Wcat[ft][k], k = sel*64+c: sel 0..2 -> tc_w taps, sel 3 -> rc_w.  bf16 [64][256]
__global__ void k_wcat(const float* __restrict__ tc_w, const float* __restrict__ rc_w,
                       unsigned short* __restrict__ Wcat) {
    int i = blockIdx.x * 256 + threadIdx.x;              // over 64*256
    if (i >= F_ * 256) return;
    int ft = i >> 8, k = i & 255;
    int sel = k >> 6, c = k & 63;
    float v = (sel < 3) ? tc_w[(ft * C_ + c) * 3 + sel] : rc_w[ft * C_ + c];
    Wcat[i] = f2b(v);
}

// Thp[k*64+f][c] (bf16) = Theta[k][c][f]   -- A-operand for k_yTmm
__global__ void k_thp(const float* __restrict__ Theta, unsigned short* __restrict__ Thp) {
    int i = blockIdx.x * 256 + threadIdx.x;              // over 192*64
    if (i >= 192 * 64) return;
    int kf = i >> 6, c = i & 63;
    int k = kf >> 6, f = kf & 63;
    Thp[i] = f2b(Theta[((size_t)k * 64 + c) * 64 + f]);
}

// sigA[b][i][k] (bf16) = sigmoid(dot24(lhs_s[b,i,:], rhs_s[b,:,k]) + b_s[i,k])
__global__ __launch_bounds__(256) void k_sig(const float* __restrict__ lhs_s,
        const float* __restrict__ rhs_s, const float* __restrict__ b_s,
        unsigned short* __restrict__ sigA) {
    int b = blockIdx.z, i0 = blockIdx.y * 64, k0 = blockIdx.x * 256;
    int tid = threadIdx.x;
    __shared__ float lh[64 * T_];
    __shared__ float rh[T_][256];
    for (int e = tid; e < 64 * T_; e += 256) lh[e] = lhs_s[((size_t)b * N_ + i0) * T_ + e];
#pragma unroll
    for (int t = 0; t < T_; ++t) rh[t][tid] = rhs_s[((size_t)b * T_ + t) * N_ + k0 + tid];
    __syncthreads();
    int kg = k0 + tid;
    for (int ii = 0; ii < 64; ++ii) {
        float acc = b_s[(size_t)(i0 + ii) * N_ + kg];
#pragma unroll
        for (int t = 0; t < T_; ++t) acc += lh[ii * T_ + t] * rh[t][tid];
        sigA[((size_t)b * N_ + i0 + ii) * N_ + kg] = f2b(sigmoidf_(acc));
    }
}

// ---------------- yT via MFMA, coalesced stores through LDS C-tile ----------------
__global__ __launch_bounds__(256) void k_yTmm(const unsigned short* __restrict__ xTt,
        const unsigned short* __restrict__ Thp, unsigned short* __restrict__ yT) {
    int bt = blockIdx.y;
    int b = bt / T_, t = bt - b * T_;
    int m0 = blockIdx.x * 128;
    int tid = threadIdx.x;
    int lane = tid & 63, wv = tid >> 6;
    __shared__ __align__(16) char smem[50688];
    unsigned short* Asb = (unsigned short*)smem;             // [192*64] (live whole kernel)
    unsigned short* Bsb = (unsigned short*)(smem + 24576);   // [128*64]
    unsigned short* Cl  = (unsigned short*)(smem + 24576);   // [96][136] (after Bsb dead)
#pragma unroll
    for (int e = 0; e < 6; ++e) {                        // stage Thp (24KB)
        int chunk = e * 256 + tid;
        int row = chunk >> 3, slot = chunk & 7;
        int gslot = slot ^ (row & 7);
        gload_lds16(Thp + row * 64 + gslot * 8, &Asb[chunk * 8]);
    }
    const unsigned short* Bg = xTt + ((size_t)bt * N_ + m0) * 64;
#pragma unroll
    for (int e = 0; e < 4; ++e) {                        // stage B (16KB)
        int chunk = e * 256 + tid;
        int row = chunk >> 3, slot = chunk & 7;
        int gslot = slot ^ (row & 7);
        gload_lds16(Bg + (size_t)row * 64 + gslot * 8, &Bsb[chunk * 8]);
    }
    __syncthreads();                                     // drains vmcnt

    short8 bf[2][2];
#pragma unroll
    for (int ni = 0; ni < 2; ++ni)
#pragma unroll
        for (int kk = 0; kk < 2; ++kk) {
            int r = wv * 32 + ni * 16 + (lane & 15);
            int slot = (kk * 4 + (lane >> 4)) ^ (r & 7);
            bf[ni][kk] = *(const short8*)&Bsb[r * 64 + slot * 8];
        }
    f32x4 acc[12][2];
#pragma unroll
    for (int mi = 0; mi < 12; ++mi)
#pragma unroll
        for (int ni = 0; ni < 2; ++ni) acc[mi][ni] = (f32x4){0.f, 0.f, 0.f, 0.f};
#pragma unroll
    for (int mi = 0; mi < 12; ++mi) {
        short8 af[2];
#pragma unroll
        for (int kk = 0; kk < 2; ++kk) {
            int r = mi * 16 + (lane & 15);
            int slot = (kk * 4 + (lane >> 4)) ^ (r & 7);
            af[kk] = *(const short8*)&Asb[r * 64 + slot * 8];
        }
#pragma unroll
        for (int kk = 0; kk < 2; ++kk)
#pragma unroll
            for (int ni = 0; ni < 2; ++ni)
                acc[mi][ni] = __builtin_amdgcn_mfma_f32_16x16x32_bf16(
                    af[kk], bf[ni][kk], acc[mi][ni], 0, 0, 0);
    }
#pragma unroll
    for (int h = 0; h < 2; ++h) {
        __syncthreads();
#pragma unroll
        for (int mi2 = 0; mi2 < 6; ++mi2) {
            int mi = h * 6 + mi2;
#pragma unroll
            for (int r = 0; r < 4; ++r) {
                int row = mi2 * 16 + (lane >> 4) * 4 + r;
#pragma unroll
                for (int ni = 0; ni < 2; ++ni)
                    Cl[row * 136 + wv * 32 + ni * 16 + (lane & 15)] = f2b(acc[mi][ni][r]);
            }
        }
        __syncthreads();
#pragma unroll
        for (int e = 0; e < 6; ++e) {
            int idx = e * 256 + tid;
            int row = idx >> 4, seg = idx & 15;
            int kf = h * 96 + row;
            int k = kf >> 6, f = kf & 63;
            uint4 v = *(const uint4*)&Cl[row * 136 + seg * 8];
            *(uint4*)&yT[((size_t)b * CT_ + f * T_ + t) * KS_ + k * N_ + m0 + seg * 8] = v;
        }
    }
}

// online softmax stats over axis m of S[b,m,i] (bf16): mst[b*N+i] = (max, 1/sum)
__global__ void k_smstats(const unsigned short* __restrict__ S, float2* __restrict__ mst) {
    int b = blockIdx.y;
    int jj = threadIdx.x % 64;
    int ig = threadIdx.x / 64;
    int j = blockIdx.x * 64 + jj;
    __shared__ float rm[4][64], rs[4][64];
    float m = -1e30f, s = 0.f;
    for (int i = ig; i < N_; i += 4) {
        float v = b2f(S[((size_t)b * N_ + i) * N_ + j]);
        float mn = fmaxf(m, v);
        s = s * __expf(m - mn) + __expf(v - mn);
        m = mn;
    }
    rm[ig][jj] = m; rs[ig][jj] = s;
    __syncthreads();
    if (ig == 0) {
        float M = rm[0][jj], SS = rs[0][jj];
#pragma unroll
        for (int g = 1; g < 4; ++g) {
            float mg = rm[g][jj];
            float mn = fmaxf(M, mg);
            SS = SS * __expf(M - mn) + rs[g][jj] * __expf(mg - mn);
            M = mn;
        }
        mst[(size_t)b * N_ + j] = make_float2(M, 1.f / SS);
    }
}

// chebSt[b][i][k*1024+m] (bf16) = chb[k][m][i] * softmax(S)[b][m][i]  (bf16 reads)
__global__ __launch_bounds__(256) void k_chebSt(const unsigned short* __restrict__ chb,
        const unsigned short* __restrict__ S, const float2* __restrict__ mst,
        unsigned short* __restrict__ cs) {
    int b = blockIdx.z, i0 = blockIdx.y * 64, m0 = blockIdx.x * 64;
    int tid = threadIdx.x;
    __shared__ float st[64][65];
    __shared__ float cb[64][65];
    __shared__ float2 sst[64];
    if (tid < 64) sst[tid] = mst[(size_t)b * N_ + i0 + tid];
#pragma unroll
    for (int e = 0; e < 4; ++e) {
        int idx4 = e * 256 + tid;
        int mm = idx4 >> 4, ii0 = (idx4 & 15) * 4;
        ushort4_ v = *(const ushort4_*)&S[((size_t)b * N_ + m0 + mm) * N_ + i0 + ii0];
        st[mm][ii0] = b2f(v.x); st[mm][ii0 + 1] = b2f(v.y);
        st[mm][ii0 + 2] = b2f(v.z); st[mm][ii0 + 3] = b2f(v.w);
    }
    for (int k = 0; k < 3; ++k) {
        __syncthreads();
#pragma unroll
        for (int e = 0; e < 4; ++e) {
            int idx4 = e * 256 + tid;
            int mm = idx4 >> 4, ii0 = (idx4 & 15) * 4;
            ushort4_ v = *(const ushort4_*)&chb[((size_t)k * N_ + m0 + mm) * N_ + i0 + ii0];
            cb[mm][ii0] = b2f(v.x); cb[mm][ii0 + 1] = b2f(v.y);
            cb[mm][ii0 + 2] = b2f(v.z); cb[mm][ii0 + 3] = b2f(v.w);
        }
        __syncthreads();
#pragma unroll
        for (int e = 0; e < 16; ++e) {
            int idx = e * 256 + tid; int mm = idx & 63, ii = idx >> 6;
            float sm = __expf(st[mm][ii] - sst[ii].x) * sst[ii].y;
            cs[((size_t)b * N_ + i0 + ii) * KS_ + k * N_ + m0 + mm] =
                f2b(sm * cb[mm][ii]);
        }
    }
}

// ---------------- 256x256-tile MFMA GEMM, hybrid counted-vmcnt pipeline ----------------
// obf: 0 -> f32 C, 1 -> bf16 C (ldc in elements either way)
__global__ __launch_bounds__(512, 2) void k_gemm256(
        const unsigned short* __restrict__ A, long lda, long sA,
        const unsigned short* __restrict__ Bt, long ldb, long sB,
        void* __restrict__ Cc, long ldc, long sC, int K, int nbx, int nby, int obf) {
    __shared__ __align__(16) unsigned short As[2][256 * 64];   // 2 x 32KB
    __shared__ __align__(16) unsigned short Bs[2][256 * 64];   // 2 x 32KB
    int tid = threadIdx.x;
    int lane = tid & 63, w = tid >> 6;
    int wy = w >> 2, wx = w & 3;                            // 2 x 4 waves -> 128x64 per wave

    int nwg = gridDim.x;
    int cpx = nwg >> 3;
    int logical = (blockIdx.x & 7) * cpx + (blockIdx.x >> 3);
    int tpb = nbx * nby;
    int b = logical / tpb;
    int tile = logical % tpb;
    int i0 = (tile / nbx) * 256;
    int j0 = (tile % nbx) * 256;

    const unsigned short* Ab = A + (size_t)b * sA + (size_t)i0 * lda;
    const unsigned short* Bb = Bt + (size_t)b * sB + (size_t)j0 * ldb;

    auto STAGE = [&](int kt, int d) {
        int kof = kt << 6;
#pragma unroll
        for (int e = 0; e < 4; ++e) {
            int chunk = e * 512 + tid;
            int row = chunk >> 3, slot = chunk & 7;
            int gslot = slot ^ (row & 7);                   // inverse swizzle on source
            gload_lds16(Ab + (size_t)row * lda + kof + gslot * 8, &As[d][chunk * 8]);
        }
#pragma unroll
        for (int e = 0; e < 4; ++e) {
            int chunk = e * 512 + tid;
            int row = chunk >> 3, slot = chunk & 7;
            int gslot = slot ^ (row & 7);
            gload_lds16(Bb + (size_t)row * ldb + kof + gslot * 8, &Bs[d][chunk * 8]);
        }
    };
    auto READF = [&](short8* af, short8* bfv,
                     const unsigned short* Asb, const unsigned short* Bsb, int kkb) {
#pragma unroll
        for (int mi = 0; mi < 8; ++mi) {
            int r = wy * 128 + mi * 16 + (lane & 15);
            int slot = (kkb + (lane >> 4)) ^ (r & 7);
            af[mi] = *(const short8*)&Asb[r * 64 + slot * 8];
        }
#pragma unroll
        for (int ni = 0; ni < 4; ++ni) {
            int r = wx * 64 + ni * 16 + (lane & 15);
            int slot = (kkb + (lane >> 4)) ^ (r & 7);
            bfv[ni] = *(const short8*)&Bsb[r * 64 + slot * 8];
        }
    };

    f32x4 acc[8][4];
#pragma unroll
    for (int mi = 0; mi < 8; ++mi)
#pragma unroll
        for (int ni = 0; ni < 4; ++ni) acc[mi][ni] = (f32x4){0.f, 0.f, 0.f, 0.f};

    int nt = K >> 6;
    STAGE(0, 0);
    STAGE(1, 1);
    asm volatile("s_waitcnt vmcnt(8)" ::: "memory");        // K-tile 0 resident
    __builtin_amdgcn_s_barrier();
    __builtin_amdgcn_sched_barrier(0);

    short8 a0[8], b0[4], a1[8], b1[4];
    READF(a0, b0, As[0], Bs[0], 0);                         // kk0 of tile 0

    for (int kt = 0; kt < nt; ++kt) {
        int cur = kt & 1;
        READF(a1, b1, As[cur], Bs[cur], 4);                 // kk1 of this tile
        __builtin_amdgcn_s_setprio(1);
#pragma unroll
        for (int mi = 0; mi < 8; ++mi)
#pragma unroll
            for (int ni = 0; ni < 4; ++ni)
                acc[mi][ni] = __builtin_amdgcn_mfma_f32_16x16x32_bf16(
                    a0[mi], b0[ni], acc[mi][ni], 0, 0, 0);
        __builtin_amdgcn_s_setprio(0);
        asm volatile("s_waitcnt lgkmcnt(0)" ::: "memory");  // my reads of buf[cur] done
        __builtin_amdgcn_sched_barrier(0);
        __builtin_amdgcn_s_barrier();                       // all waves done with buf[cur]
        __builtin_amdgcn_sched_barrier(0);
        if (kt + 2 < nt) STAGE(kt + 2, cur);                // overwrite freed buffer
        __builtin_amdgcn_sched_barrier(0);
        __builtin_amdgcn_s_setprio(1);
#pragma unroll
        for (int mi = 0; mi < 8; ++mi)
#pragma unroll
            for (int ni = 0; ni < 4; ++ni)
                acc[mi][ni] = __builtin_amdgcn_mfma_f32_16x16x32_bf16(
                    a1[mi], b1[ni], acc[mi][ni], 0, 0, 0);
        __builtin_amdgcn_s_setprio(0);
        if (kt + 2 < nt) {
            asm volatile("s_waitcnt vmcnt(8)" ::: "memory"); // kt+1 retired, kt+2 in flight
        } else {
            asm volatile("s_waitcnt vmcnt(0)" ::: "memory"); // tail: drain (race-safe)
        }
        __builtin_amdgcn_s_barrier();                       // buf[cur^1] ready for all waves
        __builtin_amdgcn_sched_barrier(0);
        if (kt + 1 < nt)
            READF(a0, b0, As[cur ^ 1], Bs[cur ^ 1], 0);     // kk0 of next tile
    }

    if (obf) {
        unsigned short* Cb = (unsigned short*)Cc + (size_t)b * sC;
#pragma unroll
        for (int mi = 0; mi < 8; ++mi) {
#pragma unroll
            for (int r = 0; r < 4; ++r) {
                int i = i0 + wy * 128 + mi * 16 + (lane >> 4) * 4 + r;
                unsigned short* cp = Cb + (size_t)i * ldc + j0 + wx * 64 + (lane & 15);
#pragma unroll
                for (int ni = 0; ni < 4; ++ni) cp[ni * 16] = f2b(acc[mi][ni][r]);
            }
        }
    } else {
        float* Cb = (float*)Cc + (size_t)b * sC;
#pragma unroll
        for (int mi = 0; mi < 8; ++mi) {
#pragma unroll
            for (int r = 0; r < 4; ++r) {
                int i = i0 + wy * 128 + mi * 16 + (lane >> 4) * 4 + r;
                float* cp = Cb + (size_t)i * ldc + j0 + wx * 64 + (lane & 15);
#pragma unroll
                for (int ni = 0; ni < 4; ++ni) cp[ni * 16] = acc[mi][ni][r];
            }
        }
    }
}

// ---------------- fused epilogue via MFMA; sbf selects bf16/f32 gcn input ----------------
__global__ __launch_bounds__(256) void k_final(const float* __restrict__ x,
        const void* __restrict__ sgin, int sbf, const unsigned short* __restrict__ Wcat,
        const float* __restrict__ tc_b, const float* __restrict__ rc_b,
        const float* __restrict__ ln_g, const float* __restrict__ ln_b,
        float* __restrict__ out) {
    int b = blockIdx.y;
    int n0 = blockIdx.x * 4;
    int tid = threadIdx.x;
    int lane = tid & 63, wv = tid >> 6;

    __shared__ __align__(16) char smem[25600];
    unsigned short* sgb = (unsigned short*)smem;            // [4][26][64]
    unsigned short* xb  = (unsigned short*)(smem + 13312);  // [4][24][64]
    float* Cl = (float*)smem;                               // [96][66] (after reuse barrier)
    __shared__ float tbs[64], gs[64], bbs[64];
    __shared__ float mus[96], rss[96];

    if (tid < 64) {
        tbs[tid] = tc_b[tid] + rc_b[tid];
        gs[tid] = ln_g[tid];
        bbs[tid] = ln_b[tid];
    }
    for (int e = tid; e < 512; e += 256) {
        int nl = e >> 7, r = (e >> 6) & 1, c = e & 63;
        int tt = r ? 25 : 0;
        sgb[(nl * 26 + tt) * 64 + (((c >> 3) ^ (tt & 7)) << 3) + (c & 7)] = 0;
    }
    size_t base = ((size_t)b * N_ + n0) * CT_;
    const float4* xg4 = (const float4*)(x + base);
#pragma unroll
    for (int i = 0; i < 6; ++i) {                       // x staging (f32)
        int e4 = i * 256 + tid;
        float4 xv4 = xg4[e4];
        int e = e4 * 4;
        int nl = e / CT_;
        int rem = e - nl * CT_;
        int c = rem / 24;
        int tl = rem - c * 24;
        float xv[4] = {xv4.x, xv4.y, xv4.z, xv4.w};
#pragma unroll
        for (int j = 0; j < 4; ++j) {
            int tj = tl + j;
            xb[(nl * 24 + tj) * 64 + (((c >> 3) ^ (tj & 7)) << 3) + (c & 7)] = f2b(xv[j]);
        }
    }
    if (sbf) {                                          // gcn staging (bf16 input)
        const uint4* sg8 = (const uint4*)((const unsigned short*)sgin + base);
#pragma unroll
        for (int i = 0; i < 3; ++i) {
            int e8 = i * 256 + tid;
            uint4 v = sg8[e8];
            const unsigned short* sp = (const unsigned short*)&v;
            int e = e8 * 8;
            int nl = e / CT_;
            int rem = e - nl * CT_;
            int c = rem / 24;
            int tl = rem - c * 24;                       // tl in {0,8,16}
#pragma unroll
            for (int j = 0; j < 8; ++j) {
                int tt = tl + j + 1;
                unsigned short sb = sp[j];
                sgb[(nl * 26 + tt) * 64 + (((c >> 3) ^ (tt & 7)) << 3) + (c & 7)] =
                    (sb & 0x8000u) ? (unsigned short)0 : sb;   // relu on bf16 bits
            }
        }
    } else {                                            // gcn staging (f32 input)
        const float4* sg4 = (const float4*)((const float*)sgin + base);
#pragma unroll
        for (int i = 0; i < 6; ++i) {
            int e4 = i * 256 + tid;
            float4 sv4 = sg4[e4];
            int e = e4 * 4;
            int nl = e / CT_;
            int rem = e - nl * CT_;
            int c = rem / 24;
            int tl = rem - c * 24;
            float sv[4] = {sv4.x, sv4.y, sv4.z, sv4.w};
#pragma unroll
            for (int j = 0; j < 4; ++j) {
                int tt = tl + j + 1;
                sgb[(nl * 26 + tt) * 64 + (((c >> 3) ^ (tt & 7)) << 3) + (c & 7)] =
                    f2b(fmaxf(sv[j], 0.f));
            }
        }
    }

    int ft = wv * 16 + (lane & 15);
    int g4 = lane >> 4;
    short8 bfr[8];
#pragma unroll
    for (int ks = 0; ks < 8; ++ks)
        bfr[ks] = *(const short8*)&Wcat[ft * 256 + ks * 32 + g4 * 8];

    int rnl[6], rt[6];
#pragma unroll
    for (int mi = 0; mi < 6; ++mi) {
        int row = mi * 16 + (lane & 15);
        rnl[mi] = row / 24;
        rt[mi] = row - rnl[mi] * 24;
    }

    __syncthreads();

    f32x4 acc[6];
#pragma unroll
    for (int mi = 0; mi < 6; ++mi) acc[mi] = (f32x4){0.f, 0.f, 0.f, 0.f};
#pragma unroll
    for (int mi = 0; mi < 6; ++mi) {
        int nl = rnl[mi], t = rt[mi];
#pragma unroll
        for (int ks = 0; ks < 8; ++ks) {
            const int sel = ks >> 1;
            int slot = (ks & 1) * 4 + g4;
            short8 af;
            if (sel < 3) {
                int tt = t + sel;
                af = *(const short8*)&sgb[(nl * 26 + tt) * 64 + ((slot ^ (tt & 7)) << 3)];
            } else {
                af = *(const short8*)&xb[(nl * 24 + t) * 64 + ((slot ^ (t & 7)) << 3)];
            }
            acc[mi] = __builtin_amdgcn_mfma_f32_16x16x32_bf16(af, bfr[ks], acc[mi], 0, 0, 0);
        }
    }

    __syncthreads();
#pragma unroll
    for (int mi = 0; mi < 6; ++mi)
#pragma unroll
        for (int r = 0; r < 4; ++r)
            Cl[(mi * 16 + (lane >> 4) * 4 + r) * 66 + wv * 16 + (lane & 15)] = acc[mi][r];
    __syncthreads();

    if (tid < 96) {
        float s = 0.f, s2 = 0.f;
#pragma unroll
        for (int f = 0; f < 64; ++f) {
            float v = fmaxf(Cl[tid * 66 + f] + tbs[f], 0.f);
            s += v; s2 += v * v;
        }
        float mu = s * (1.f / 64.f);
        float var = s2 * (1.f / 64.f) - mu * mu;
        mus[tid] = mu;
        rss[tid] = rsqrtf(var + 1e-5f);
    }
    __syncthreads();

    float4* o4 = (float4*)(out + base);
#pragma unroll
    for (int i = 0; i < 6; ++i) {
        int e4 = i * 256 + tid;
        int e = e4 * 4;
        int nl = e / CT_;
        int rem = e - nl * CT_;
        int f = rem / 24;
        int t0v = rem - f * 24;
        float g = gs[f], bb2 = bbs[f], tb2 = tbs[f];
        float vals[4];
#pragma unroll
        for (int j = 0; j < 4; ++j) {
            int row = nl * 24 + t0v + j;
            float v = fmaxf(Cl[row * 66 + f] + tb2, 0.f);
            vals[j] = (v - mus[row]) * rss[row] * g + bb2;
        }
        float4 r;
        r.x = vals[0]; r.y = vals[1]; r.z = vals[2]; r.w = vals[3];
        o4[e4] = r;
    }
}

extern "C" void kernel_launch(void* const* d_in, const int* in_sizes, int n_in,
                              void* d_out, int out_size, void* d_ws, size_t ws_size,
                              hipStream_t stream) {
    const float* x    = (const float*)d_in[0];
    const float* cheb = (const float*)d_in[1];
    const float* U1   = (const float*)d_in[2];
    const float* U2   = (const float*)d_in[3];
    const float* U3   = (const float*)d_in[4];
    const float* b_e  = (const float*)d_in[5];
    const float* V_e  = (const float*)d_in[6];
    const float* W1   = (const float*)d_in[7];
    const float* W2   = (const float*)d_in[8];
    const float* W3   = (const float*)d_in[9];
    const float* b_s  = (const float*)d_in[10];
    const float* V_s  = (const float*)d_in[11];
    const float* Theta= (const float*)d_in[12];
    const float* tc_w = (const float*)d_in[13];
    const float* tc_b = (const float*)d_in[14];
    const float* rc_w = (const float*)d_in[15];
    const float* rc_b = (const float*)d_in[16];
    const float* ln_g = (const float*)d_in[17];
    const float* ln_b = (const float*)d_in[18];
    float* out = (float*)d_out;

    char* base = (char*)d_ws;
    size_t o = 0;
    auto alloc = [&](size_t bytes) { size_t r = o; o += (bytes + 255) & ~(size_t)255; return r; };
    float* lhs_t   = (float*)(base + alloc((size_t)B_ * T_ * N_ * 4));
    float* rhs_t   = (float*)(base + alloc((size_t)B_ * N_ * T_ * 4));
    float* Ebuf    = (float*)(base + alloc((size_t)B_ * T_ * T_ * 4));
    float* partial = (float*)(base + alloc((size_t)B_ * 32 * CT_ * 4));
    float* ptp     = (float*)(base + alloc((size_t)B_ * 8 * T_ * T_ * 4));
    float* lhs_t0  = (float*)(base + alloc((size_t)B_ * CT_ * 4));
    float* lhs_s   = (float*)(base + alloc((size_t)B_ * N_ * T_ * 4));
    float* rhs_s   = (float*)(base + alloc((size_t)B_ * T_ * N_ * 4));
    unsigned short* V_sb = (unsigned short*)(base + alloc((size_t)N_ * N_ * 2));
    unsigned short* Wcat = (unsigned short*)(base + alloc((size_t)F_ * 256 * 2));
    unsigned short* Thp  = (unsigned short*)(base + alloc((size_t)192 * 64 * 2));
    unsigned short* chb  = (unsigned short*)(base + alloc((size_t)3 * N_ * N_ * 2));
    float2* mstats = (float2*)(base + alloc((size_t)B_ * N_ * 8));
    size_t regA = alloc((size_t)B_ * N_ * KS_ * 2);   // xTt (bf16) -> chebSt (bf16)
    size_t regB = alloc((size_t)B_ * CT_ * KS_ * 2);  // sigA (bf16) -> yT (bf16)
    unsigned short* xTt    = (unsigned short*)(base + regA);
    unsigned short* chebSt = (unsigned short*)(base + regA);
    unsigned short* sigA   = (unsigned short*)(base + regB);
    unsigned short* yT     = (unsigned short*)(base + regB);
    unsigned short* Sb = (unsigned short*)out;   // bf16 S scores in d_out (dead before gcn)

    // optional aux region: bf16 gcn (halves stacked-GEMM write + k_final read).
    // deterministic: ws_size is constant across calls -> same path every call.
    size_t gcn_bytes = (size_t)B_ * N_ * CT_ * 2;
    int use_aux = (ws_size >= o + gcn_bytes + 256) ? 1 : 0;
    unsigned short* gcnb = use_aux ? (unsigned short*)(base + alloc(gcn_bytes)) : nullptr;
    void* gcn_ptr = use_aux ? (void*)gcnb : (void*)out;
    const void* sgin = use_aux ? (const void*)gcnb : (const void*)out;

    dim3 b256(256);
    k_cvt_bf<<<dim3(N_ * N_ / 256), b256, 0, stream>>>(V_s, V_sb);
    k_cvt_bf<<<dim3(3 * N_ * N_ / 256), b256, 0, stream>>>(cheb, chb);
    k_wcat<<<dim3((F_ * 256 + 255) / 256), b256, 0, stream>>>(tc_w, rc_w, Wcat);
    k_thp<<<dim3((192 * 64 + 255) / 256), b256, 0, stream>>>(Theta, Thp);
    k_xreduce<<<dim3(N_ / 32, B_), b256, 0, stream>>>(x, U1, U3, rhs_t, partial);
    k_lhs_reduce<<<dim3((B_ * CT_ + 255) / 256), b256, 0, stream>>>(partial, lhs_t0);
    k_lhs_t<<<dim3((B_ * T_ * N_) / 256), b256, 0, stream>>>(lhs_t0, U2, lhs_t);
    k_prodt<<<dim3(8, B_), dim3(576), 0, stream>>>(lhs_t, rhs_t, ptp);
    k_temporal_E<<<dim3(B_), dim3(576), 0, stream>>>(ptp, b_e, V_e, Ebuf);
    k_tspatial<<<dim3(N_ / 4, B_), b256, 0, stream>>>(x, Ebuf, W1, W2, W3,
                                                      lhs_s, rhs_s, xTt);
    k_sig<<<dim3(N_ / 256, N_ / 64, B_), b256, 0, stream>>>(lhs_s, rhs_s, b_s, sigA);
    // S0 GEMM: M=1024, Ncols=1024, K=1024; bf16 C; nwg=512 (%8==0)
    k_gemm256<<<dim3(B_ * 4 * 4), dim3(512), 0, stream>>>(
        sigA, N_, (long)N_ * N_, V_sb, N_, 0, Sb, N_, (long)N_ * N_, N_, 4, 4, 1);
    k_smstats<<<dim3(N_ / 64, B_), b256, 0, stream>>>(Sb, mstats);
    k_yTmm<<<dim3(N_ / 128, B_ * T_), b256, 0, stream>>>(xTt, Thp, yT);        // sigA dead
    k_chebSt<<<dim3(N_ / 64, N_ / 64, B_), b256, 0, stream>>>(chb, Sb, mstats, chebSt); // xTt dead
    // stacked GEMM: M=1024, Ncols=1536, K=3072; nwg=768 (%8==0); bf16 C if aux fits
    k_gemm256<<<dim3(B_ * 4 * 6), dim3(512), 0, stream>>>(
        chebSt, KS_, (long)N_ * KS_, yT, KS_, (long)CT_ * KS_,
        gcn_ptr, CT_, (long)N_ * CT_, KS_, 6, 4, use_aux);                    // Sb dead
    k_final<<<dim3(N_ / 4, B_), b256, 0, stream>>>(x, sgin, use_aux, Wcat, tc_b, rc_b,
                                                   ln_g, ln_b, out);
}